// Round 1
// baseline (396.883 us; speedup 1.0000x reference)
//
#include <hip/hip_runtime.h>
#include <math.h>

#define NN 50000
#define NE 800000
#define NFD 256
#define HD 64
#define QDD 128
#define TDD 32
#define NTT 64
#define NLAY 3
#define LCLAMP 6.1030340f   // atanh(1 - 1e-5)
#define CHUNK 1024
#define NCHUNK 49           // ceil(50000/1024)
#define NBUCK 196           // ceil(50000/256) coarse buckets (dst >> 8)
#define EPB 4096            // edges per k_bin block
#define NBINBLK 196         // ceil(800000/4096)
#define PST 72              // k_proj LDS tile stride (shorts for staging, floats for epilogue)

typedef unsigned int uint;
typedef unsigned short ushort;
typedef __attribute__((ext_vector_type(8))) short bf16x8;
typedef __attribute__((ext_vector_type(4))) float f32x4;

__device__ __forceinline__ ushort f2bf(float f) {
  uint u = __float_as_uint(f);
  uint r = (u + 0x7FFFu + ((u >> 16) & 1u)) >> 16;
  return (ushort)r;
}
__device__ __forceinline__ short f2bfs(float f) { return (short)f2bf(f); }
__device__ __forceinline__ float bf2f(short s) { return __uint_as_float(((uint)(ushort)s) << 16); }
__device__ __forceinline__ float bflo(uint w) { return __uint_as_float(w << 16); }
__device__ __forceinline__ float bfhi(uint w) { return __uint_as_float(w & 0xFFFF0000u); }

// A-frag from 8 consecutive f32
__device__ __forceinline__ bf16x8 frag_f32(const float* p) {
  float4 a = *(const float4*)p;
  float4 b = *(const float4*)(p + 4);
  bf16x8 r;
  r[0] = f2bfs(a.x); r[1] = f2bfs(a.y); r[2] = f2bfs(a.z); r[3] = f2bfs(a.w);
  r[4] = f2bfs(b.x); r[5] = f2bfs(b.y); r[6] = f2bfs(b.z); r[7] = f2bfs(b.w);
  return r;
}
// B-frag from row-major W[K][64]: k=k0+quad*8+j, n=j0+lane15
__device__ __forceinline__ bf16x8 bfrag_w(const float* W, int k0, int j0, int lane15, int quad) {
  bf16x8 r;
#pragma unroll
  for (int j = 0; j < 8; ++j) r[j] = f2bfs(W[(k0 + quad * 8 + j) * HD + j0 + lane15]);
  return r;
}

// ---------------------------------------------------------------- setup
__global__ void k_setup(const float* __restrict__ edge_desc, const float* __restrict__ query,
                        const float* __restrict__ Wq, const float* __restrict__ bq,
                        const float* __restrict__ Ws, const float* __restrict__ bs,
                        const float* __restrict__ attn_a,
                        const float* __restrict__ Wns1, const float* __restrict__ bns1,
                        const float* __restrict__ Wes1, const float* __restrict__ bes1,
                        float* __restrict__ out_type_emb,
                        float* __restrict__ qb, float* __restrict__ ta3,
                        float* __restrict__ qe) {
  __shared__ float te_l[NTT * TDD];
  __shared__ float q_l[HD];
  int t = threadIdx.x;
  if (t < HD) {
    float acc = bq[t];
    for (int k = 0; k < QDD; ++k) acc += query[k] * Wq[k * HD + t];
    q_l[t] = acc;
  }
  for (int idx = t; idx < NTT * TDD; idx += 256) {
    int ty = idx / TDD, d = idx % TDD;
    float acc = bs[d];
    for (int k = 0; k < 64; ++k) acc += edge_desc[ty * 64 + k] * Ws[k * TDD + d];
    float v = tanhf(acc);
    te_l[idx] = v;
    out_type_emb[idx] = v;
  }
  __syncthreads();
  if (t < NLAY * NTT) {
    int l = t / NTT, ty = t % NTT;
    float acc = 0.f;
    for (int d = 0; d < TDD; ++d) acc += te_l[ty * TDD + d] * attn_a[l * (2 * HD + TDD) + 2 * HD + d];
    ta3[t] = acc;
  }
  if (t < HD) {
    float a1 = bns1[t], a2 = bes1[t];
    for (int k = 0; k < HD; ++k) {
      a1 += q_l[k] * Wns1[(HD + k) * HD + t];
      a2 += q_l[k] * Wes1[(2 * HD + TDD + k) * HD + t];
    }
    qb[t] = a1;
    qe[t] = a2;
  }
}

// Te2bf[ty][j] = bf16(type_emb[ty] @ Wes1[te-part] + qe)
__global__ void k_te2(const float* __restrict__ te, const float* __restrict__ qe,
                      const float* __restrict__ Wes1, ushort* __restrict__ Te2bf) {
  int idx = blockIdx.x * 256 + threadIdx.x;   // 4096 total
  int ty = idx >> 6, j = idx & 63;
  float acc = qe[j];
#pragma unroll
  for (int d = 0; d < TDD; ++d) acc += te[ty * TDD + d] * Wes1[(2 * HD + d) * HD + j];
  Te2bf[idx] = f2bf(acc);
}

// ---------------------------------------------------------------- CSR build
__global__ void k_hist(const int* __restrict__ dst, int* __restrict__ cnt) {
  int e = blockIdx.x * 256 + threadIdx.x;
  if (e < NE) atomicAdd(&cnt[dst[e]], 1);
}

__global__ void k_scanA(const int* __restrict__ cnt, int* __restrict__ bsum) {
  __shared__ int ws[4];
  int t = threadIdx.x;
  int c0 = blockIdx.x * CHUNK;
  int s = 0;
#pragma unroll
  for (int it = 0; it < 4; ++it) {
    int i = c0 + it * 256 + t;
    if (i < NN) s += cnt[i];
  }
#pragma unroll
  for (int off = 1; off < 64; off <<= 1) s += __shfl_xor(s, off, 64);
  if ((t & 63) == 0) ws[t >> 6] = s;
  __syncthreads();
  if (t == 0) bsum[blockIdx.x] = ws[0] + ws[1] + ws[2] + ws[3];
}

__global__ void k_scanB(const int* __restrict__ bsum, int* __restrict__ boff,
                        int* __restrict__ row_ptr) {
  int t = threadIdx.x;  // 64 threads
  int v = (t < NCHUNK) ? bsum[t] : 0;
  int x = v;
#pragma unroll
  for (int off = 1; off < 64; off <<= 1) {
    int y = __shfl_up(x, off, 64);
    if (t >= off) x += y;
  }
  if (t < NCHUNK) boff[t] = x - v;
  if (t == 63) row_ptr[NN] = x;
}

// also emits bucket_cursor[b] = row_ptr[b*256] (k_binit merged in)
__global__ void k_scanC(const int* __restrict__ cnt, const int* __restrict__ boff,
                        int* __restrict__ row_ptr, int* __restrict__ bucket_cursor) {
  __shared__ int wsum[4], woff_s[4];
  int t = threadIdx.x;
  int c0 = blockIdx.x * CHUNK;
  int i0 = c0 + t * 4;
  int v0 = (i0 + 0 < NN) ? cnt[i0 + 0] : 0;
  int v1 = (i0 + 1 < NN) ? cnt[i0 + 1] : 0;
  int v2 = (i0 + 2 < NN) ? cnt[i0 + 2] : 0;
  int v3 = (i0 + 3 < NN) ? cnt[i0 + 3] : 0;
  int s4 = v0 + v1 + v2 + v3;
  int lane = t & 63, wid = t >> 6;
  int x = s4;
#pragma unroll
  for (int off = 1; off < 64; off <<= 1) {
    int y = __shfl_up(x, off, 64);
    if (lane >= off) x += y;
  }
  if (lane == 63) wsum[wid] = x;
  __syncthreads();
  if (t == 0) {
    int a = 0;
    for (int i = 0; i < 4; ++i) { woff_s[i] = a; a += wsum[i]; }
  }
  __syncthreads();
  int base = boff[blockIdx.x] + woff_s[wid] + (x - s4);
  int r0 = base, r1 = base + v0, r2 = r1 + v1, r3 = r2 + v2;
  if (i0 + 0 < NN) {
    row_ptr[i0 + 0] = r0;
    if ((i0 & 255) == 0) bucket_cursor[i0 >> 8] = r0;
  }
  if (i0 + 1 < NN) row_ptr[i0 + 1] = r1;
  if (i0 + 2 < NN) row_ptr[i0 + 2] = r2;
  if (i0 + 3 < NN) row_ptr[i0 + 3] = r3;
}

// phase B: bin edges by coarse bucket (dst>>8) into packed ebuf (uint2: pk, eid).
// pk: src(16) | type(6)<<16 | (dst&255)<<22
__global__ void __launch_bounds__(256) k_bin(const int* __restrict__ src,
                                             const int* __restrict__ dst,
                                             const int* __restrict__ etype,
                                             int* __restrict__ bucket_cursor,
                                             uint2* __restrict__ ebuf) {
  __shared__ int cntl[NBUCK];
  __shared__ int gbase[NBUCK];
  int t = threadIdx.x;
  for (int i = t; i < NBUCK; i += 256) cntl[i] = 0;
  __syncthreads();
  int e0 = blockIdx.x * EPB;
  int dd[16];
  uint pk[16];
  int rk[16];
#pragma unroll
  for (int c = 0; c < 4; ++c) {
    int eb = e0 + c * 1024 + t * 4;
    if (eb < NE) {   // NE%4==0 => eb<NE implies eb+3<NE
      int4 s4 = *(const int4*)&src[eb];
      int4 d4 = *(const int4*)&dst[eb];
      int4 y4 = *(const int4*)&etype[eb];
      int ds[4] = {d4.x, d4.y, d4.z, d4.w};
      int ss[4] = {s4.x, s4.y, s4.z, s4.w};
      int ys[4] = {y4.x, y4.y, y4.z, y4.w};
#pragma unroll
      for (int j = 0; j < 4; ++j) {
        int idx = c * 4 + j;
        int d = ds[j];
        dd[idx] = d;
        pk[idx] = (uint)ss[j] | ((uint)ys[j] << 16) | ((uint)(d & 255) << 22);
        rk[idx] = atomicAdd(&cntl[d >> 8], 1);
      }
    } else {
#pragma unroll
      for (int j = 0; j < 4; ++j) dd[c * 4 + j] = -1;
    }
  }
  __syncthreads();
  if (t < NBUCK && cntl[t] > 0) gbase[t] = atomicAdd(&bucket_cursor[t], cntl[t]);
  __syncthreads();
#pragma unroll
  for (int i = 0; i < 16; ++i) {
    if (dd[i] >= 0) {
      uint eid = (uint)(e0 + ((i >> 2) << 10) + t * 4 + (i & 3));
      ebuf[gbase[dd[i] >> 8] + rk[i]] = make_uint2(pk[i], eid);
    }
  }
}

// phase C: per-bucket scatter to final CSR slot; per-node cursors in LDS
__global__ void __launch_bounds__(256) k_scatter2(const int* __restrict__ row_ptr,
                                                  const uint2* __restrict__ ebuf,
                                                  uint* __restrict__ csr,
                                                  uint* __restrict__ csr_eid) {
  __shared__ int curs[256];
  int b = blockIdx.x;
  int n0 = b << 8;
  int t = threadIdx.x;
  int n = n0 + t;
  curs[t] = (n < NN) ? row_ptr[n] : 0;
  __syncthreads();
  int n1 = n0 + 256; if (n1 > NN) n1 = NN;
  int lo = row_ptr[n0];
  int hi = row_ptr[n1];
  for (int i = lo + t; i < hi; i += 256) {
    uint2 v = ebuf[i];
    int j = (v.x >> 22) & 255;
    int pos = atomicAdd(&curs[j], 1);
    csr[pos] = v.x & 0x3FFFFFu;
    csr_eid[pos] = v.y;
  }
}

// ---------------------------------------------------------------- k_proj (MFMA, pipelined staging)
// + fused layer-0 k_msg: ht0 tile is already in LDS, so also emit msgbf/p_src/p_dst.
// (the global ht0 store was dead — removed; only the LDS copy is consumed)
__global__ void __launch_bounds__(256) k_proj(const float* __restrict__ X,
                                              const float* __restrict__ Wn,
                                              const float* __restrict__ bn,
                                              const float* __restrict__ ts_p,
                                              const float* __restrict__ Wmp0,
                                              const float* __restrict__ bmp0,
                                              const float* __restrict__ attn0,
                                              ushort* __restrict__ msgbf,
                                              float* __restrict__ p_src,
                                              float* __restrict__ p_dst) {
  __shared__ ushort buf[2][64 * PST];            // 2 x 9216 B
  float* st = (float*)&buf[0][0];                // epilogue alias: 64 x 72 f32
  int t = threadIdx.x;
  int lane = t & 63, wv = t >> 6;
  int lane15 = lane & 15, quad = lane >> 4;
  int n0 = blockIdx.x * 64;
  int j0 = wv * 16;
  bf16x8 B[8];
#pragma unroll
  for (int fb = 0; fb < 8; ++fb) B[fb] = bfrag_w(Wn, fb * 32, j0, lane15, quad);

  int srow = t >> 2;
  int scg = (t & 3) * 16;
  int grow = n0 + srow; if (grow >= NN) grow = NN - 1;
  const float* xrow = X + (size_t)grow * NFD + scg;

  f32x4 acc[4];
#pragma unroll
  for (int mt = 0; mt < 4; ++mt) acc[mt] = (f32x4){0.f, 0.f, 0.f, 0.f};

  float4 r0 = *(const float4*)(xrow + 0);
  float4 r1 = *(const float4*)(xrow + 4);
  float4 r2 = *(const float4*)(xrow + 8);
  float4 r3 = *(const float4*)(xrow + 12);

  for (int c = 0; c < 4; ++c) {
    ushort* wp = &buf[c & 1][srow * PST + scg];
    uint4 o0, o1;
    o0.x = (uint)f2bf(r0.x) | ((uint)f2bf(r0.y) << 16);
    o0.y = (uint)f2bf(r0.z) | ((uint)f2bf(r0.w) << 16);
    o0.z = (uint)f2bf(r1.x) | ((uint)f2bf(r1.y) << 16);
    o0.w = (uint)f2bf(r1.z) | ((uint)f2bf(r1.w) << 16);
    o1.x = (uint)f2bf(r2.x) | ((uint)f2bf(r2.y) << 16);
    o1.y = (uint)f2bf(r2.z) | ((uint)f2bf(r2.w) << 16);
    o1.z = (uint)f2bf(r3.x) | ((uint)f2bf(r3.y) << 16);
    o1.w = (uint)f2bf(r3.z) | ((uint)f2bf(r3.w) << 16);
    *(uint4*)wp = o0;
    *(uint4*)(wp + 8) = o1;
    if (c < 3) {
      const float* nx = xrow + (c + 1) * 64;
      r0 = *(const float4*)(nx + 0);
      r1 = *(const float4*)(nx + 4);
      r2 = *(const float4*)(nx + 8);
      r3 = *(const float4*)(nx + 12);
    }
    __syncthreads();
    const ushort* bp = &buf[c & 1][0];
#pragma unroll
    for (int mt = 0; mt < 4; ++mt) {
#pragma unroll
      for (int ks = 0; ks < 2; ++ks) {
        bf16x8 A = *(const bf16x8*)&bp[(mt * 16 + lane15) * PST + ks * 32 + quad * 8];
        acc[mt] = __builtin_amdgcn_mfma_f32_16x16x32_bf16(A, B[c * 2 + ks], acc[mt], 0, 0, 0);
      }
    }
  }
  __syncthreads();
  // epilogue: (acc+bn)*ts into st, norm-clamp, write scaled back to st
  float ts = ts_p[0];
  float vb = bn[j0 + lane15];
#pragma unroll
  for (int mt = 0; mt < 4; ++mt)
#pragma unroll
    for (int i = 0; i < 4; ++i)
      st[(mt * 16 + quad * 4 + i) * PST + j0 + lane15] = (acc[mt][i] + vb) * ts;
  __syncthreads();
  {
    int r = t >> 2, p = t & 3;
    float* rp = &st[r * PST + p * 16];
    float4 v0 = *(const float4*)(rp + 0);
    float4 v1 = *(const float4*)(rp + 4);
    float4 v2 = *(const float4*)(rp + 8);
    float4 v3 = *(const float4*)(rp + 12);
    float ssq = v0.x*v0.x + v0.y*v0.y + v0.z*v0.z + v0.w*v0.w
              + v1.x*v1.x + v1.y*v1.y + v1.z*v1.z + v1.w*v1.w
              + v2.x*v2.x + v2.y*v2.y + v2.z*v2.z + v2.w*v2.w
              + v3.x*v3.x + v3.y*v3.y + v3.z*v3.z + v3.w*v3.w;
    ssq += __shfl_xor(ssq, 1, 64);
    ssq += __shfl_xor(ssq, 2, 64);
    float nu = fmaxf(sqrtf(ssq), 1e-15f);
    float sc = fminf(nu, LCLAMP) / nu;
    *(float4*)(rp + 0) = make_float4(v0.x*sc, v0.y*sc, v0.z*sc, v0.w*sc);
    *(float4*)(rp + 4) = make_float4(v1.x*sc, v1.y*sc, v1.z*sc, v1.w*sc);
    *(float4*)(rp + 8) = make_float4(v2.x*sc, v2.y*sc, v2.z*sc, v2.w*sc);
    *(float4*)(rp + 12) = make_float4(v3.x*sc, v3.y*sc, v3.z*sc, v3.w*sc);
  }
  __syncthreads();
  // fused layer-0 msg: wave handles 16 rows of the tile (all in st, scaled)
  {
    bf16x8 Bm0[4], Bm1[4];
    float vbm[4];
#pragma unroll
    for (int jt = 0; jt < 4; ++jt) {
      Bm0[jt] = bfrag_w(Wmp0, 0, jt * 16, lane15, quad);
      Bm1[jt] = bfrag_w(Wmp0, 32, jt * 16, lane15, quad);
      vbm[jt] = bmp0[jt * 16 + lane15];
    }
    int mrow = wv * 16 + lane15;
    bf16x8 A0 = frag_f32(&st[mrow * PST + quad * 8]);
    bf16x8 A1 = frag_f32(&st[mrow * PST + 32 + quad * 8]);
#pragma unroll
    for (int jt = 0; jt < 4; ++jt) {
      f32x4 z = {0.f, 0.f, 0.f, 0.f};
      z = __builtin_amdgcn_mfma_f32_16x16x32_bf16(A0, Bm0[jt], z, 0, 0, 0);
      z = __builtin_amdgcn_mfma_f32_16x16x32_bf16(A1, Bm1[jt], z, 0, 0, 0);
#pragma unroll
      for (int i = 0; i < 4; ++i) {
        int r = n0 + wv * 16 + quad * 4 + i;
        if (r < NN) msgbf[(size_t)r * HD + jt * 16 + lane15] = f2bf(z[i] + vbm[jt]);
      }
    }
    float4 a1l = *(const float4*)&attn0[quad * 8];
    float4 a1h = *(const float4*)&attn0[quad * 8 + 4];
    float4 a1l2 = *(const float4*)&attn0[32 + quad * 8];
    float4 a1h2 = *(const float4*)&attn0[32 + quad * 8 + 4];
    float4 a2l = *(const float4*)&attn0[64 + quad * 8];
    float4 a2h = *(const float4*)&attn0[64 + quad * 8 + 4];
    float4 a2l2 = *(const float4*)&attn0[96 + quad * 8];
    float4 a2h2 = *(const float4*)&attn0[96 + quad * 8 + 4];
    float p1 = bf2f(A0[0])*a1l.x + bf2f(A0[1])*a1l.y + bf2f(A0[2])*a1l.z + bf2f(A0[3])*a1l.w
             + bf2f(A0[4])*a1h.x + bf2f(A0[5])*a1h.y + bf2f(A0[6])*a1h.z + bf2f(A0[7])*a1h.w
             + bf2f(A1[0])*a1l2.x + bf2f(A1[1])*a1l2.y + bf2f(A1[2])*a1l2.z + bf2f(A1[3])*a1l2.w
             + bf2f(A1[4])*a1h2.x + bf2f(A1[5])*a1h2.y + bf2f(A1[6])*a1h2.z + bf2f(A1[7])*a1h2.w;
    float p2 = bf2f(A0[0])*a2l.x + bf2f(A0[1])*a2l.y + bf2f(A0[2])*a2l.z + bf2f(A0[3])*a2l.w
             + bf2f(A0[4])*a2h.x + bf2f(A0[5])*a2h.y + bf2f(A0[6])*a2h.z + bf2f(A0[7])*a2h.w
             + bf2f(A1[0])*a2l2.x + bf2f(A1[1])*a2l2.y + bf2f(A1[2])*a2l2.z + bf2f(A1[3])*a2l2.w
             + bf2f(A1[4])*a2h2.x + bf2f(A1[5])*a2h2.y + bf2f(A1[6])*a2h2.z + bf2f(A1[7])*a2h2.w;
    p1 += __shfl_xor(p1, 16, 64); p1 += __shfl_xor(p1, 32, 64);
    p2 += __shfl_xor(p2, 16, 64); p2 += __shfl_xor(p2, 32, 64);
    int prow = n0 + mrow;
    if (quad == 0 && prow < NN) { p_src[prow] = p1; p_dst[prow] = p2; }
  }
}

// ---------------------------------------------------------------- msg = ht @ Wmp + bmp (bf16 in, bf16 out); p_src/p_dst (MFMA)
__global__ void __launch_bounds__(256) k_msg(const ushort* __restrict__ htbf,
                                             const float* __restrict__ Wmp_l,
                                             const float* __restrict__ bmp_l,
                                             const float* __restrict__ attn_l,
                                             ushort* __restrict__ msgbf,
                                             float* __restrict__ p_src,
                                             float* __restrict__ p_dst) {
  int t = threadIdx.x;
  int lane = t & 63, wv = t >> 6;
  int lane15 = lane & 15, quad = lane >> 4;
  int m0 = blockIdx.x * 64 + wv * 16;
  bf16x8 B[4][2];
  float vb[4];
#pragma unroll
  for (int jt = 0; jt < 4; ++jt) {
    B[jt][0] = bfrag_w(Wmp_l, 0, jt * 16, lane15, quad);
    B[jt][1] = bfrag_w(Wmp_l, 32, jt * 16, lane15, quad);
    vb[jt] = bmp_l[jt * 16 + lane15];
  }
  int row = m0 + lane15;
  int rowc = row < NN ? row : NN - 1;
  const ushort* hp = htbf + (size_t)rowc * HD;
  bf16x8 A0 = *(const bf16x8*)(hp + quad * 8);
  bf16x8 A1 = *(const bf16x8*)(hp + 32 + quad * 8);
  f32x4 acc[4];
#pragma unroll
  for (int jt = 0; jt < 4; ++jt) {
    f32x4 z = {0.f, 0.f, 0.f, 0.f};
    z = __builtin_amdgcn_mfma_f32_16x16x32_bf16(A0, B[jt][0], z, 0, 0, 0);
    z = __builtin_amdgcn_mfma_f32_16x16x32_bf16(A1, B[jt][1], z, 0, 0, 0);
    acc[jt] = z;
  }
#pragma unroll
  for (int jt = 0; jt < 4; ++jt)
#pragma unroll
    for (int i = 0; i < 4; ++i) {
      int r = m0 + quad * 4 + i;
      if (r < NN) msgbf[(size_t)r * HD + jt * 16 + lane15] = f2bf(acc[jt][i] + vb[jt]);
    }
  float4 a1l = *(const float4*)&attn_l[quad * 8];
  float4 a1h = *(const float4*)&attn_l[quad * 8 + 4];
  float4 a1l2 = *(const float4*)&attn_l[32 + quad * 8];
  float4 a1h2 = *(const float4*)&attn_l[32 + quad * 8 + 4];
  float4 a2l = *(const float4*)&attn_l[64 + quad * 8];
  float4 a2h = *(const float4*)&attn_l[64 + quad * 8 + 4];
  float4 a2l2 = *(const float4*)&attn_l[96 + quad * 8];
  float4 a2h2 = *(const float4*)&attn_l[96 + quad * 8 + 4];
  float p1 = bf2f(A0[0])*a1l.x + bf2f(A0[1])*a1l.y + bf2f(A0[2])*a1l.z + bf2f(A0[3])*a1l.w
           + bf2f(A0[4])*a1h.x + bf2f(A0[5])*a1h.y + bf2f(A0[6])*a1h.z + bf2f(A0[7])*a1h.w
           + bf2f(A1[0])*a1l2.x + bf2f(A1[1])*a1l2.y + bf2f(A1[2])*a1l2.z + bf2f(A1[3])*a1l2.w
           + bf2f(A1[4])*a1h2.x + bf2f(A1[5])*a1h2.y + bf2f(A1[6])*a1h2.z + bf2f(A1[7])*a1h2.w;
  float p2 = bf2f(A0[0])*a2l.x + bf2f(A0[1])*a2l.y + bf2f(A0[2])*a2l.z + bf2f(A0[3])*a2l.w
           + bf2f(A0[4])*a2h.x + bf2f(A0[5])*a2h.y + bf2f(A0[6])*a2h.z + bf2f(A0[7])*a2h.w
           + bf2f(A1[0])*a2l2.x + bf2f(A1[1])*a2l2.y + bf2f(A1[2])*a2l2.z + bf2f(A1[3])*a2l2.w
           + bf2f(A1[4])*a2h2.x + bf2f(A1[5])*a2h2.y + bf2f(A1[6])*a2h2.z + bf2f(A1[7])*a2h2.w;
  p1 += __shfl_xor(p1, 16, 64); p1 += __shfl_xor(p1, 32, 64);
  p2 += __shfl_xor(p2, 16, 64); p2 += __shfl_xor(p2, 32, 64);
  if (quad == 0 && row < NN) { p_src[row] = p1; p_dst[row] = p2; }
}

// ---------------------------------------------------------------- softmax-aggregate (wave/node, 8-wide gather)
// OB=1: write bf16 ht (intermediate layers). OB=0: write f32 ht (final layer).
template <int OB>
__global__ void __launch_bounds__(256) k_agg(const int* __restrict__ row_ptr,
                                             const uint* __restrict__ csr,
                                             const float* __restrict__ p_src,
                                             const float* __restrict__ p_dst,
                                             const float* __restrict__ ta_l,
                                             const ushort* __restrict__ msgbf,
                                             float* __restrict__ ht_out,
                                             ushort* __restrict__ htbf_out,
                                             float* __restrict__ s_buf) {
  int lane = threadIdx.x & 63;
  int n = (blockIdx.x * 256 + threadIdx.x) >> 6;
  if (n >= NN) return;
  int start = row_ptr[n], end = row_ptr[n + 1];
  int deg = end - start;
  float pd = p_dst[n];
  int lq = lane & 7, lg = lane >> 3;
  float acc[8];
#pragma unroll
  for (int u = 0; u < 8; ++u) acc[u] = 0.f;
  float exsum = 0.f;

  if (deg <= 64) {
    bool valid = lane < deg;
    float s = -3.4e38f;
    int sidx = 0;
    if (valid) {
      uint pk = csr[start + lane];
      sidx = (int)(pk & 0xFFFFu);
      int ty = (int)(pk >> 16);
      float v = p_src[sidx] + pd + ta_l[ty];
      s = (v > 0.f) ? v : 0.2f * v;
    }
    float m = s;
#pragma unroll
    for (int off = 32; off >= 1; off >>= 1) m = fmaxf(m, __shfl_xor(m, off, 64));
    float ex = valid ? __expf(s - m) : 0.f;
    exsum = ex;
    for (int it = 0; it < deg; it += 8) {
      int el = it + lg;
      float exk = __shfl(ex, el, 64);
      int sk = __shfl(sidx, el, 64);
      if (el < deg) {
        uint4 mv = *(const uint4*)&msgbf[(size_t)sk * HD + lq * 8];
        acc[0] += exk * bflo(mv.x); acc[1] += exk * bfhi(mv.x);
        acc[2] += exk * bflo(mv.y); acc[3] += exk * bfhi(mv.y);
        acc[4] += exk * bflo(mv.z); acc[5] += exk * bfhi(mv.z);
        acc[6] += exk * bflo(mv.w); acc[7] += exk * bfhi(mv.w);
      }
    }
  } else {
    float m = -3.4e38f;
    for (int base = start; base < end; base += 64) {
      int i = base + lane;
      float s = -3.4e38f;
      if (i < end) {
        uint pk = csr[i];
        int sidx = (int)(pk & 0xFFFFu);
        int ty = (int)(pk >> 16);
        float v = p_src[sidx] + pd + ta_l[ty];
        s = (v > 0.f) ? v : 0.2f * v;
        s_buf[i] = s;
      }
      m = fmaxf(m, s);
    }
#pragma unroll
    for (int off = 32; off >= 1; off >>= 1) m = fmaxf(m, __shfl_xor(m, off, 64));
    for (int base = start; base < end; base += 64) {
      int i = base + lane;
      if (i < end) {
        float ex = __expf(s_buf[i] - m);
        s_buf[i] = ex;
        exsum += ex;
      }
    }
    for (int it = start; it < end; it += 8) {
      int el = it + lg;
      if (el < end) {
        float exk = s_buf[el];
        int sk = (int)(csr[el] & 0xFFFFu);
        uint4 mv = *(const uint4*)&msgbf[(size_t)sk * HD + lq * 8];
        acc[0] += exk * bflo(mv.x); acc[1] += exk * bfhi(mv.x);
        acc[2] += exk * bflo(mv.y); acc[3] += exk * bfhi(mv.y);
        acc[4] += exk * bflo(mv.z); acc[5] += exk * bfhi(mv.z);
        acc[6] += exk * bflo(mv.w); acc[7] += exk * bfhi(mv.w);
      }
    }
  }
#pragma unroll
  for (int u = 0; u < 8; ++u) {
    acc[u] += __shfl_xor(acc[u], 8, 64);
    acc[u] += __shfl_xor(acc[u], 16, 64);
    acc[u] += __shfl_xor(acc[u], 32, 64);
  }
#pragma unroll
  for (int off = 32; off >= 1; off >>= 1) exsum += __shfl_xor(exsum, off, 64);
  float inv = 1.f / (exsum + 1e-15f);
  float ss = 0.f;
#pragma unroll
  for (int u = 0; u < 8; ++u) {
    float v = fmaxf(acc[u] * inv, 0.f);
    acc[u] = v;
    ss += v * v;
  }
  ss += __shfl_xor(ss, 1, 64);
  ss += __shfl_xor(ss, 2, 64);
  ss += __shfl_xor(ss, 4, 64);
  float nu = fmaxf(sqrtf(ss), 1e-15f);
  float sc = fminf(nu, LCLAMP) / nu;
  if (lane < 8) {
    if (OB) {
      uint4 o;
      o.x = (uint)f2bf(acc[0] * sc) | ((uint)f2bf(acc[1] * sc) << 16);
      o.y = (uint)f2bf(acc[2] * sc) | ((uint)f2bf(acc[3] * sc) << 16);
      o.z = (uint)f2bf(acc[4] * sc) | ((uint)f2bf(acc[5] * sc) << 16);
      o.w = (uint)f2bf(acc[6] * sc) | ((uint)f2bf(acc[7] * sc) << 16);
      *(uint4*)&htbf_out[(size_t)n * HD + lane * 8] = o;
    } else {
      *(float4*)&ht_out[(size_t)n * HD + lane * 8] =
          make_float4(acc[0] * sc, acc[1] * sc, acc[2] * sc, acc[3] * sc);
      *(float4*)&ht_out[(size_t)n * HD + lane * 8 + 4] =
          make_float4(acc[4] * sc, acc[5] * sc, acc[6] * sc, acc[7] * sc);
    }
  }
}

// ---------------------------------------------------------------- heads (MFMA)
__global__ void __launch_bounds__(256) k_score(const float* __restrict__ ht,
                                               const float* __restrict__ Wns1,
                                               const float* __restrict__ qb,
                                               const float* __restrict__ Wns2,
                                               const float* __restrict__ bns2,
                                               const float* __restrict__ Wes1,
                                               float* __restrict__ node_scores,
                                               float* __restrict__ h_out,
                                               ushort* __restrict__ Asrc,
                                               ushort* __restrict__ Adst) {
  int t = threadIdx.x;
  int lane = t & 63, wv = t >> 6;
  int lane15 = lane & 15, quad = lane >> 4;
  int n0 = blockIdx.x * 64;
  int m0 = n0 + wv * 16;
  int row = m0 + lane15;
  int rowc = row < NN ? row : NN - 1;
  bf16x8 A0 = frag_f32(ht + (size_t)rowc * HD + quad * 8);
  bf16x8 A1 = frag_f32(ht + (size_t)rowc * HD + 32 + quad * 8);

  // node head
  {
    f32x4 acc[4];
#pragma unroll
    for (int jt = 0; jt < 4; ++jt) {
      bf16x8 b0 = bfrag_w(Wns1, 0, jt * 16, lane15, quad);
      bf16x8 b1 = bfrag_w(Wns1, 32, jt * 16, lane15, quad);
      f32x4 z = {0.f, 0.f, 0.f, 0.f};
      z = __builtin_amdgcn_mfma_f32_16x16x32_bf16(A0, b0, z, 0, 0, 0);
      z = __builtin_amdgcn_mfma_f32_16x16x32_bf16(A1, b1, z, 0, 0, 0);
      acc[jt] = z;
    }
    float vqb[4], vw2[4];
#pragma unroll
    for (int jt = 0; jt < 4; ++jt) { vqb[jt] = qb[jt * 16 + lane15]; vw2[jt] = Wns2[jt * 16 + lane15]; }
    float b2 = bns2[0];
#pragma unroll
    for (int i = 0; i < 4; ++i) {
      float si = 0.f;
#pragma unroll
      for (int jt = 0; jt < 4; ++jt) si += fmaxf(acc[jt][i] + vqb[jt], 0.f) * vw2[jt];
      si += __shfl_xor(si, 1, 64);
      si += __shfl_xor(si, 2, 64);
      si += __shfl_xor(si, 4, 64);
      si += __shfl_xor(si, 8, 64);
      int r = m0 + quad * 4 + i;
      if (lane15 == 0 && r < NN) node_scores[r] = 1.f / (1.f + __expf(-(si + b2)));
    }
  }
  // Asrc
  {
#pragma unroll
    for (int jt = 0; jt < 4; ++jt) {
      bf16x8 b0 = bfrag_w(Wes1, 0, jt * 16, lane15, quad);
      bf16x8 b1 = bfrag_w(Wes1, 32, jt * 16, lane15, quad);
      f32x4 z = {0.f, 0.f, 0.f, 0.f};
      z = __builtin_amdgcn_mfma_f32_16x16x32_bf16(A0, b0, z, 0, 0, 0);
      z = __builtin_amdgcn_mfma_f32_16x16x32_bf16(A1, b1, z, 0, 0, 0);
#pragma unroll
      for (int i = 0; i < 4; ++i) {
        int r = m0 + quad * 4 + i;
        if (r < NN) Asrc[(size_t)r * HD + jt * 16 + lane15] = f2bf(z[i]);
      }
    }
  }
  // Adst
  {
    const float* W = Wes1 + 64 * HD;
#pragma unroll
    for (int jt = 0; jt < 4; ++jt) {
      bf16x8 b0 = bfrag_w(W, 0, jt * 16, lane15, quad);
      bf16x8 b1 = bfrag_w(W, 32, jt * 16, lane15, quad);
      f32x4 z = {0.f, 0.f, 0.f, 0.f};
      z = __builtin_amdgcn_mfma_f32_16x16x32_bf16(A0, b0, z, 0, 0, 0);
      z = __builtin_amdgcn_mfma_f32_16x16x32_bf16(A1, b1, z, 0, 0, 0);
#pragma unroll
      for (int i = 0; i < 4; ++i) {
        int r = m0 + quad * 4 + i;
        if (r < NN) Adst[(size_t)r * HD + jt * 16 + lane15] = f2bf(z[i]);
      }
    }
  }
  // h_out: exact f32 pass
  {
    int r = t >> 2, p = t & 3;
    int gr = n0 + r;
    int grc = gr < NN ? gr : NN - 1;
    const float* rp = ht + (size_t)grc * HD + p * 16;
    float4 v0 = *(const float4*)(rp + 0);
    float4 v1 = *(const float4*)(rp + 4);
    float4 v2 = *(const float4*)(rp + 8);
    float4 v3 = *(const float4*)(rp + 12);
    float ssq = v0.x*v0.x + v0.y*v0.y + v0.z*v0.z + v0.w*v0.w
              + v1.x*v1.x + v1.y*v1.y + v1.z*v1.z + v1.w*v1.w
              + v2.x*v2.x + v2.y*v2.y + v2.z*v2.z + v2.w*v2.w
              + v3.x*v3.x + v3.y*v3.y + v3.z*v3.z + v3.w*v3.w;
    ssq += __shfl_xor(ssq, 1, 64);
    ssq += __shfl_xor(ssq, 2, 64);
    float nu = fmaxf(sqrtf(ssq), 1e-15f);
    float hs = tanhf(nu) / nu;
    if (gr < NN) {
      float* op = h_out + (size_t)gr * HD + p * 16;
      *(float4*)(op + 0)  = make_float4(v0.x*hs, v0.y*hs, v0.z*hs, v0.w*hs);
      *(float4*)(op + 4)  = make_float4(v1.x*hs, v1.y*hs, v1.z*hs, v1.w*hs);
      *(float4*)(op + 8)  = make_float4(v2.x*hs, v2.y*hs, v2.z*hs, v2.w*hs);
      *(float4*)(op + 12) = make_float4(v3.x*hs, v3.y*hs, v3.z*hs, v3.w*hs);
    }
  }
}

// ---------------------------------------------------------------- edge scores (CSR order: wave/node, Adst in regs)
// halves the random-gather traffic vs original-edge-order: only Asrc is gathered.
__global__ void __launch_bounds__(256) k_edge(const int* __restrict__ row_ptr,
                                              const uint* __restrict__ csr,
                                              const uint* __restrict__ csr_eid,
                                              const ushort* __restrict__ Asrc,
                                              const ushort* __restrict__ Adst,
                                              const ushort* __restrict__ Te2bf,
                                              const float* __restrict__ Wes2,
                                              const float* __restrict__ bes2,
                                              float* __restrict__ edge_scores) {
  int t = threadIdx.x;
  int lane = t & 63;
  int n = (blockIdx.x * 256 + t) >> 6;
  if (n >= NN) return;
  int lq = lane & 7, lg = lane >> 3;
  int start = row_ptr[n], end = row_ptr[n + 1];
  if (start >= end) return;
  uint4 bv = *(const uint4*)&Adst[(size_t)n * HD + lq * 8];
  const float* wp = &Wes2[lq * 8];
  float4 w0 = *(const float4*)wp;
  float4 w1 = *(const float4*)(wp + 4);
  float b2 = bes2[0];
  for (int it = start; it < end; it += 8) {
    int e = it + lg;
    bool valid = e < end;
    float p = 0.f;
    if (valid) {
      uint pk = csr[e];                    // 8 lanes/group same addr -> broadcast
      int si = (int)(pk & 0xFFFFu);
      int ty = (int)((pk >> 16) & 0x3Fu);
      uint4 av = *(const uint4*)&Asrc[(size_t)si * HD + lq * 8];
      uint4 tv = *(const uint4*)&Te2bf[ty * HD + lq * 8];
      p += fmaxf(bflo(av.x) + bflo(bv.x) + bflo(tv.x), 0.f) * w0.x;
      p += fmaxf(bfhi(av.x) + bfhi(bv.x) + bfhi(tv.x), 0.f) * w0.y;
      p += fmaxf(bflo(av.y) + bflo(bv.y) + bflo(tv.y), 0.f) * w0.z;
      p += fmaxf(bfhi(av.y) + bfhi(bv.y) + bfhi(tv.y), 0.f) * w0.w;
      p += fmaxf(bflo(av.z) + bflo(bv.z) + bflo(tv.z), 0.f) * w1.x;
      p += fmaxf(bfhi(av.z) + bfhi(bv.z) + bfhi(tv.z), 0.f) * w1.y;
      p += fmaxf(bflo(av.w) + bflo(bv.w) + bflo(tv.w), 0.f) * w1.z;
      p += fmaxf(bfhi(av.w) + bfhi(bv.w) + bfhi(tv.w), 0.f) * w1.w;
    }
    p += __shfl_xor(p, 1, 64);
    p += __shfl_xor(p, 2, 64);
    p += __shfl_xor(p, 4, 64);
    if (valid && lq == 0) edge_scores[csr_eid[e]] = 1.f / (1.f + __expf(-(p + b2)));
  }
}

// ---------------------------------------------------------------- launch
extern "C" void kernel_launch(void* const* d_in, const int* in_sizes, int n_in,
                              void* d_out, int out_size, void* d_ws, size_t ws_size,
                              hipStream_t stream) {
  const float* node_features = (const float*)d_in[0];
  const float* edge_desc = (const float*)d_in[1];
  const float* query = (const float*)d_in[2];
  const float* Wn = (const float*)d_in[3];
  const float* bn = (const float*)d_in[4];
  const float* ts = (const float*)d_in[5];
  const float* Wq = (const float*)d_in[6];
  const float* bq = (const float*)d_in[7];
  const float* Ws_ = (const float*)d_in[8];
  const float* bs = (const float*)d_in[9];
  const float* attn_a = (const float*)d_in[10];
  const float* Wmp = (const float*)d_in[11];
  const float* bmp = (const float*)d_in[12];
  const float* Wns1 = (const float*)d_in[13];
  const float* bns1 = (const float*)d_in[14];
  const float* Wns2 = (const float*)d_in[15];
  const float* bns2 = (const float*)d_in[16];
  const float* Wes1 = (const float*)d_in[17];
  const float* bes1 = (const float*)d_in[18];
  const float* Wes2 = (const float*)d_in[19];
  const float* bes2 = (const float*)d_in[20];
  const int* edge_index = (const int*)d_in[21];
  const int* etype = (const int*)d_in[22];
  const int* src = edge_index;
  const int* dst = edge_index + NE;

  float* out_ns = (float*)d_out;
  float* out_es = out_ns + NN;
  float* out_h = out_es + NE;
  float* out_te = out_h + (size_t)NN * HD;

  char* w = (char*)d_ws;
  auto alloc = [&](size_t bytes) {
    char* p = w;
    w += (bytes + 1023) & ~(size_t)1023;
    return p;
  };
  float* ht_f = (float*)alloc((size_t)NN * HD * 4);        // final-layer f32 ht
  ushort* htbf = (ushort*)alloc((size_t)NN * HD * 2);      // intermediate bf16 ht
  ushort* msgbf = (ushort*)alloc((size_t)NN * HD * 2);
  ushort* Asrc = (ushort*)alloc((size_t)NN * HD * 2);
  ushort* Adst = (ushort*)alloc((size_t)NN * HD * 2);
  float* p_src = (float*)alloc(NN * 4);
  float* p_dst = (float*)alloc(NN * 4);
  float* s_buf = (float*)alloc(NE * 4);
  float* qb = (float*)alloc(HD * 4);
  float* qe = (float*)alloc(HD * 4);
  float* ta3 = (float*)alloc(NLAY * NTT * 4);
  ushort* Te2bf = (ushort*)alloc(NTT * HD * 2);
  int* cnt = (int*)alloc(NN * 4);
  int* row_ptr = (int*)alloc((NN + 1) * 4);
  int* bsum = (int*)alloc(NCHUNK * 4);
  int* boff = (int*)alloc(NCHUNK * 4);
  int* bucket_cursor = (int*)alloc(NBUCK * 4);
  uint* csr = (uint*)alloc(NE * 4);
  uint* csr_eid = (uint*)alloc(NE * 4);
  // ebuf (NE x 8B = 6.4 MB) aliases Asrc (6.4 MB exactly): CSR build finishes
  // before k_score writes Asrc. No overlap in stream order.
  uint2* ebuf = (uint2*)Asrc;

  hipMemsetAsync(cnt, 0, NN * 4, stream);
  k_setup<<<1, 256, 0, stream>>>(edge_desc, query, Wq, bq, Ws_, bs, attn_a, Wns1, bns1,
                                 Wes1, bes1, out_te, qb, ta3, qe);
  k_te2<<<16, 256, 0, stream>>>(out_te, qe, Wes1, Te2bf);
  k_hist<<<NE / 256, 256, 0, stream>>>(dst, cnt);
  k_scanA<<<NCHUNK, 256, 0, stream>>>(cnt, bsum);
  k_scanB<<<1, 64, 0, stream>>>(bsum, boff, row_ptr);
  k_scanC<<<NCHUNK, 256, 0, stream>>>(cnt, boff, row_ptr, bucket_cursor);
  k_bin<<<NBINBLK, 256, 0, stream>>>(src, dst, etype, bucket_cursor, ebuf);
  k_scatter2<<<NBUCK, 256, 0, stream>>>(row_ptr, ebuf, csr, csr_eid);
  // k_proj with fused layer-0 msg (no ht0 global store — it was dead)
  k_proj<<<(NN + 63) / 64, 256, 0, stream>>>(node_features, Wn, bn, ts,
                                             Wmp, bmp, attn_a, msgbf, p_src, p_dst);

  const int AGG_GRID = (NN + 3) / 4;
  // layer 0
  k_agg<1><<<AGG_GRID, 256, 0, stream>>>(row_ptr, csr, p_src, p_dst, ta3 + 0 * NTT,
                                         msgbf, nullptr, htbf, s_buf);
  // layer 1
  k_msg<<<(NN + 63) / 64, 256, 0, stream>>>(htbf, Wmp + 1 * HD * HD, bmp + 1 * HD,
                                            attn_a + 1 * (2 * HD + TDD), msgbf, p_src, p_dst);
  k_agg<1><<<AGG_GRID, 256, 0, stream>>>(row_ptr, csr, p_src, p_dst, ta3 + 1 * NTT,
                                         msgbf, nullptr, htbf, s_buf);
  // layer 2
  k_msg<<<(NN + 63) / 64, 256, 0, stream>>>(htbf, Wmp + 2 * HD * HD, bmp + 2 * HD,
                                            attn_a + 2 * (2 * HD + TDD), msgbf, p_src, p_dst);
  k_agg<0><<<AGG_GRID, 256, 0, stream>>>(row_ptr, csr, p_src, p_dst, ta3 + 2 * NTT,
                                         msgbf, ht_f, nullptr, s_buf);

  k_score<<<(NN + 63) / 64, 256, 0, stream>>>(ht_f, Wns1, qb, Wns2, bns2, Wes1,
                                              out_ns, out_h, Asrc, Adst);
  k_edge<<<(NN + 3) / 4, 256, 0, stream>>>(row_ptr, csr, csr_eid, Asrc, Adst, Te2bf,
                                           Wes2, bes2, out_es);
}

// Round 2
// 392.532 us; speedup vs baseline: 1.0111x; 1.0111x over previous
//
#include <hip/hip_runtime.h>
#include <math.h>

#define NN 50000
#define NE 800000
#define NFD 256
#define HD 64
#define QDD 128
#define TDD 32
#define NTT 64
#define NLAY 3
#define LCLAMP 6.1030340f   // atanh(1 - 1e-5)
#define CHUNK 1024
#define NCHUNK 49           // ceil(50000/1024)
#define NBUCK 196           // ceil(50000/256) coarse buckets (dst >> 8)
#define EPB 4096            // edges per k_bin block
#define NBINBLK 196         // ceil(800000/4096)
#define PST 72              // k_proj LDS tile stride

typedef unsigned int uint;
typedef unsigned short ushort;
typedef __attribute__((ext_vector_type(8))) short bf16x8;
typedef __attribute__((ext_vector_type(4))) float f32x4;

__device__ __forceinline__ ushort f2bf(float f) {
  uint u = __float_as_uint(f);
  uint r = (u + 0x7FFFu + ((u >> 16) & 1u)) >> 16;
  return (ushort)r;
}
__device__ __forceinline__ short f2bfs(float f) { return (short)f2bf(f); }
__device__ __forceinline__ float bf2f(short s) { return __uint_as_float(((uint)(ushort)s) << 16); }
__device__ __forceinline__ float bflo(uint w) { return __uint_as_float(w << 16); }
__device__ __forceinline__ float bfhi(uint w) { return __uint_as_float(w & 0xFFFF0000u); }

// A-frag from 8 consecutive f32
__device__ __forceinline__ bf16x8 frag_f32(const float* p) {
  float4 a = *(const float4*)p;
  float4 b = *(const float4*)(p + 4);
  bf16x8 r;
  r[0] = f2bfs(a.x); r[1] = f2bfs(a.y); r[2] = f2bfs(a.z); r[3] = f2bfs(a.w);
  r[4] = f2bfs(b.x); r[5] = f2bfs(b.y); r[6] = f2bfs(b.z); r[7] = f2bfs(b.w);
  return r;
}
// B-frag from row-major W[K][64]: k=k0+quad*8+j, n=j0+lane15
__device__ __forceinline__ bf16x8 bfrag_w(const float* W, int k0, int j0, int lane15, int quad) {
  bf16x8 r;
#pragma unroll
  for (int j = 0; j < 8; ++j) r[j] = f2bfs(W[(k0 + quad * 8 + j) * HD + j0 + lane15]);
  return r;
}

// ---------------------------------------------------------------- device bodies
__device__ void d_setup(const float* __restrict__ edge_desc, const float* __restrict__ query,
                        const float* __restrict__ Wq, const float* __restrict__ bq,
                        const float* __restrict__ Ws, const float* __restrict__ bs,
                        const float* __restrict__ attn_a,
                        const float* __restrict__ Wns1, const float* __restrict__ bns1,
                        const float* __restrict__ Wes1, const float* __restrict__ bes1,
                        const float* __restrict__ Wmp,
                        float* __restrict__ out_type_emb,
                        float* __restrict__ qb, float* __restrict__ ta3,
                        float* __restrict__ qe, ushort* __restrict__ WmpPk) {
  __shared__ float te_l[NTT * TDD];
  __shared__ float q_l[HD];
  int t = threadIdx.x;
  if (t < HD) {
    float acc = bq[t];
    for (int k = 0; k < QDD; ++k) acc += query[k] * Wq[k * HD + t];
    q_l[t] = acc;
  }
  for (int idx = t; idx < NTT * TDD; idx += 256) {
    int ty = idx / TDD, d = idx % TDD;
    float acc = bs[d];
    for (int k = 0; k < 64; ++k) acc += edge_desc[ty * 64 + k] * Ws[k * TDD + d];
    float v = tanhf(acc);
    te_l[idx] = v;
    out_type_emb[idx] = v;
  }
  __syncthreads();
  if (t < NLAY * NTT) {
    int l = t / NTT, ty = t % NTT;
    float acc = 0.f;
    for (int d = 0; d < TDD; ++d) acc += te_l[ty * TDD + d] * attn_a[l * (2 * HD + TDD) + 2 * HD + d];
    ta3[t] = acc;
  }
  if (t < HD) {
    float a1 = bns1[t], a2 = bes1[t];
    for (int k = 0; k < HD; ++k) {
      a1 += q_l[k] * Wns1[(HD + k) * HD + t];
      a2 += q_l[k] * Wes1[(2 * HD + TDD + k) * HD + t];
    }
    qb[t] = a1;
    qe[t] = a2;
  }
  // pack Wmp B-frags: WmpPk[(((l*4+jt)*2+f)*64 + lane)*8 + j]
  //   = bf16(Wmp[l][(f*32 + quad*8 + j)][jt*16 + lane15])
  for (int idx = t; idx < NLAY * 4 * 2 * 64 * 8; idx += 256) {
    int j = idx & 7, lane = (idx >> 3) & 63, f = (idx >> 9) & 1, jl = idx >> 10;
    int l = jl >> 2, jt = jl & 3, q = lane >> 4, l15 = lane & 15;
    WmpPk[idx] = f2bf(Wmp[l * HD * HD + (f * 32 + q * 8 + j) * HD + jt * 16 + l15]);
  }
}

__device__ void d_proj(int pbid,
                       const float* __restrict__ X,
                       const float* __restrict__ Wn,
                       const float* __restrict__ bn,
                       const float* __restrict__ ts_p,
                       const ushort* __restrict__ WmpPk,   // layer-0 frags at offset 0
                       const float* __restrict__ bmp0,
                       const float* __restrict__ attn0,
                       ushort* __restrict__ msgbf,
                       float* __restrict__ p_src,
                       float* __restrict__ p_dst) {
  __shared__ ushort buf[2][64 * PST];            // 2 x 9216 B
  float* st = (float*)&buf[0][0];                // epilogue alias: 64 x 72 f32
  int t = threadIdx.x;
  int lane = t & 63, wv = t >> 6;
  int lane15 = lane & 15, quad = lane >> 4;
  int n0 = pbid * 64;
  int j0 = wv * 16;
  bf16x8 B[8];
#pragma unroll
  for (int fb = 0; fb < 8; ++fb) B[fb] = bfrag_w(Wn, fb * 32, j0, lane15, quad);

  int srow = t >> 2;
  int scg = (t & 3) * 16;
  int grow = n0 + srow; if (grow >= NN) grow = NN - 1;
  const float* xrow = X + (size_t)grow * NFD + scg;

  f32x4 acc[4];
#pragma unroll
  for (int mt = 0; mt < 4; ++mt) acc[mt] = (f32x4){0.f, 0.f, 0.f, 0.f};

  float4 r0 = *(const float4*)(xrow + 0);
  float4 r1 = *(const float4*)(xrow + 4);
  float4 r2 = *(const float4*)(xrow + 8);
  float4 r3 = *(const float4*)(xrow + 12);

  for (int c = 0; c < 4; ++c) {
    ushort* wp = &buf[c & 1][srow * PST + scg];
    uint4 o0, o1;
    o0.x = (uint)f2bf(r0.x) | ((uint)f2bf(r0.y) << 16);
    o0.y = (uint)f2bf(r0.z) | ((uint)f2bf(r0.w) << 16);
    o0.z = (uint)f2bf(r1.x) | ((uint)f2bf(r1.y) << 16);
    o0.w = (uint)f2bf(r1.z) | ((uint)f2bf(r1.w) << 16);
    o1.x = (uint)f2bf(r2.x) | ((uint)f2bf(r2.y) << 16);
    o1.y = (uint)f2bf(r2.z) | ((uint)f2bf(r2.w) << 16);
    o1.z = (uint)f2bf(r3.x) | ((uint)f2bf(r3.y) << 16);
    o1.w = (uint)f2bf(r3.z) | ((uint)f2bf(r3.w) << 16);
    *(uint4*)wp = o0;
    *(uint4*)(wp + 8) = o1;
    if (c < 3) {
      const float* nx = xrow + (c + 1) * 64;
      r0 = *(const float4*)(nx + 0);
      r1 = *(const float4*)(nx + 4);
      r2 = *(const float4*)(nx + 8);
      r3 = *(const float4*)(nx + 12);
    }
    __syncthreads();
    const ushort* bp = &buf[c & 1][0];
#pragma unroll
    for (int mt = 0; mt < 4; ++mt) {
#pragma unroll
      for (int ks = 0; ks < 2; ++ks) {
        bf16x8 A = *(const bf16x8*)&bp[(mt * 16 + lane15) * PST + ks * 32 + quad * 8];
        acc[mt] = __builtin_amdgcn_mfma_f32_16x16x32_bf16(A, B[c * 2 + ks], acc[mt], 0, 0, 0);
      }
    }
  }
  __syncthreads();
  float ts = ts_p[0];
  float vb = bn[j0 + lane15];
#pragma unroll
  for (int mt = 0; mt < 4; ++mt)
#pragma unroll
    for (int i = 0; i < 4; ++i)
      st[(mt * 16 + quad * 4 + i) * PST + j0 + lane15] = (acc[mt][i] + vb) * ts;
  __syncthreads();
  {
    int r = t >> 2, p = t & 3;
    float* rp = &st[r * PST + p * 16];
    float4 v0 = *(const float4*)(rp + 0);
    float4 v1 = *(const float4*)(rp + 4);
    float4 v2 = *(const float4*)(rp + 8);
    float4 v3 = *(const float4*)(rp + 12);
    float ssq = v0.x*v0.x + v0.y*v0.y + v0.z*v0.z + v0.w*v0.w
              + v1.x*v1.x + v1.y*v1.y + v1.z*v1.z + v1.w*v1.w
              + v2.x*v2.x + v2.y*v2.y + v2.z*v2.z + v2.w*v2.w
              + v3.x*v3.x + v3.y*v3.y + v3.z*v3.z + v3.w*v3.w;
    ssq += __shfl_xor(ssq, 1, 64);
    ssq += __shfl_xor(ssq, 2, 64);
    float nu = fmaxf(sqrtf(ssq), 1e-15f);
    float sc = fminf(nu, LCLAMP) / nu;
    *(float4*)(rp + 0) = make_float4(v0.x*sc, v0.y*sc, v0.z*sc, v0.w*sc);
    *(float4*)(rp + 4) = make_float4(v1.x*sc, v1.y*sc, v1.z*sc, v1.w*sc);
    *(float4*)(rp + 8) = make_float4(v2.x*sc, v2.y*sc, v2.z*sc, v2.w*sc);
    *(float4*)(rp + 12) = make_float4(v3.x*sc, v3.y*sc, v3.z*sc, v3.w*sc);
  }
  __syncthreads();
  // fused layer-0 msg: wave handles 16 rows of the tile (all in st, scaled)
  {
    bf16x8 Bm0[4], Bm1[4];
    float vbm[4];
#pragma unroll
    for (int jt = 0; jt < 4; ++jt) {
      Bm0[jt] = *(const bf16x8*)&WmpPk[((jt * 2 + 0) * 64 + lane) * 8];
      Bm1[jt] = *(const bf16x8*)&WmpPk[((jt * 2 + 1) * 64 + lane) * 8];
      vbm[jt] = bmp0[jt * 16 + lane15];
    }
    int mrow = wv * 16 + lane15;
    bf16x8 A0 = frag_f32(&st[mrow * PST + quad * 8]);
    bf16x8 A1 = frag_f32(&st[mrow * PST + 32 + quad * 8]);
#pragma unroll
    for (int jt = 0; jt < 4; ++jt) {
      f32x4 z = {0.f, 0.f, 0.f, 0.f};
      z = __builtin_amdgcn_mfma_f32_16x16x32_bf16(A0, Bm0[jt], z, 0, 0, 0);
      z = __builtin_amdgcn_mfma_f32_16x16x32_bf16(A1, Bm1[jt], z, 0, 0, 0);
#pragma unroll
      for (int i = 0; i < 4; ++i) {
        int r = n0 + wv * 16 + quad * 4 + i;
        if (r < NN) msgbf[(size_t)r * HD + jt * 16 + lane15] = f2bf(z[i] + vbm[jt]);
      }
    }
    float4 a1l = *(const float4*)&attn0[quad * 8];
    float4 a1h = *(const float4*)&attn0[quad * 8 + 4];
    float4 a1l2 = *(const float4*)&attn0[32 + quad * 8];
    float4 a1h2 = *(const float4*)&attn0[32 + quad * 8 + 4];
    float4 a2l = *(const float4*)&attn0[64 + quad * 8];
    float4 a2h = *(const float4*)&attn0[64 + quad * 8 + 4];
    float4 a2l2 = *(const float4*)&attn0[96 + quad * 8];
    float4 a2h2 = *(const float4*)&attn0[96 + quad * 8 + 4];
    float p1 = bf2f(A0[0])*a1l.x + bf2f(A0[1])*a1l.y + bf2f(A0[2])*a1l.z + bf2f(A0[3])*a1l.w
             + bf2f(A0[4])*a1h.x + bf2f(A0[5])*a1h.y + bf2f(A0[6])*a1h.z + bf2f(A0[7])*a1h.w
             + bf2f(A1[0])*a1l2.x + bf2f(A1[1])*a1l2.y + bf2f(A1[2])*a1l2.z + bf2f(A1[3])*a1l2.w
             + bf2f(A1[4])*a1h2.x + bf2f(A1[5])*a1h2.y + bf2f(A1[6])*a1h2.z + bf2f(A1[7])*a1h2.w;
    float p2 = bf2f(A0[0])*a2l.x + bf2f(A0[1])*a2l.y + bf2f(A0[2])*a2l.z + bf2f(A0[3])*a2l.w
             + bf2f(A0[4])*a2h.x + bf2f(A0[5])*a2h.y + bf2f(A0[6])*a2h.z + bf2f(A0[7])*a2h.w
             + bf2f(A1[0])*a2l2.x + bf2f(A1[1])*a2l2.y + bf2f(A1[2])*a2l2.z + bf2f(A1[3])*a2l2.w
             + bf2f(A1[4])*a2h2.x + bf2f(A1[5])*a2h2.y + bf2f(A1[6])*a2h2.z + bf2f(A1[7])*a2h2.w;
    p1 += __shfl_xor(p1, 16, 64); p1 += __shfl_xor(p1, 32, 64);
    p2 += __shfl_xor(p2, 16, 64); p2 += __shfl_xor(p2, 32, 64);
    int prow = n0 + mrow;
    if (quad == 0 && prow < NN) { p_src[prow] = p1; p_dst[prow] = p2; }
  }
}

// ---------------------------------------------------------------- merged front kernels
// kA: blocks 0..3124 = hist, block 3125 = setup
__global__ void __launch_bounds__(256) kA(const int* __restrict__ dst, int* __restrict__ cnt,
                                          const float* __restrict__ edge_desc, const float* __restrict__ query,
                                          const float* __restrict__ Wq, const float* __restrict__ bq,
                                          const float* __restrict__ Ws, const float* __restrict__ bs,
                                          const float* __restrict__ attn_a,
                                          const float* __restrict__ Wns1, const float* __restrict__ bns1,
                                          const float* __restrict__ Wes1, const float* __restrict__ bes1,
                                          const float* __restrict__ Wmp,
                                          float* __restrict__ out_type_emb,
                                          float* __restrict__ qb, float* __restrict__ ta3,
                                          float* __restrict__ qe, ushort* __restrict__ WmpPk) {
  if (blockIdx.x < NE / 256) {
    int e = blockIdx.x * 256 + threadIdx.x;
    atomicAdd(&cnt[dst[e]], 1);
  } else {
    d_setup(edge_desc, query, Wq, bq, Ws, bs, attn_a, Wns1, bns1, Wes1, bes1, Wmp,
            out_type_emb, qb, ta3, qe, WmpPk);
  }
}

// kB: blocks 0..15 = te2, blocks 16..64 = scanA
__global__ void __launch_bounds__(256) kB(const float* __restrict__ te, const float* __restrict__ qe,
                                          const float* __restrict__ Wes1, ushort* __restrict__ Te2bf,
                                          const int* __restrict__ cnt, int* __restrict__ bsum) {
  int t = threadIdx.x;
  if (blockIdx.x < 16) {
    int idx = blockIdx.x * 256 + t;
    int ty = idx >> 6, j = idx & 63;
    float acc = qe[j];
#pragma unroll
    for (int d = 0; d < TDD; ++d) acc += te[ty * TDD + d] * Wes1[(2 * HD + d) * HD + j];
    Te2bf[idx] = f2bf(acc);
  } else {
    __shared__ int ws[4];
    int abid = blockIdx.x - 16;
    int c0 = abid * CHUNK;
    int s = 0;
#pragma unroll
    for (int it = 0; it < 4; ++it) {
      int i = c0 + it * 256 + t;
      if (i < NN) s += cnt[i];
    }
#pragma unroll
    for (int off = 1; off < 64; off <<= 1) s += __shfl_xor(s, off, 64);
    if ((t & 63) == 0) ws[t >> 6] = s;
    __syncthreads();
    if (t == 0) bsum[abid] = ws[0] + ws[1] + ws[2] + ws[3];
  }
}

__global__ void k_scanB(const int* __restrict__ bsum, int* __restrict__ boff,
                        int* __restrict__ row_ptr) {
  int t = threadIdx.x;  // 64 threads
  int v = (t < NCHUNK) ? bsum[t] : 0;
  int x = v;
#pragma unroll
  for (int off = 1; off < 64; off <<= 1) {
    int y = __shfl_up(x, off, 64);
    if (t >= off) x += y;
  }
  if (t < NCHUNK) boff[t] = x - v;
  if (t == 63) row_ptr[NN] = x;
}

// kD: blocks 0..48 = scanC, blocks 49..830 = proj (+fused layer-0 msg)
__global__ void __launch_bounds__(256) kD(const int* __restrict__ cnt, const int* __restrict__ boff,
                                          int* __restrict__ row_ptr, int* __restrict__ bucket_cursor,
                                          const float* __restrict__ X, const float* __restrict__ Wn,
                                          const float* __restrict__ bn, const float* __restrict__ ts_p,
                                          const ushort* __restrict__ WmpPk, const float* __restrict__ bmp0,
                                          const float* __restrict__ attn0,
                                          ushort* __restrict__ msgbf,
                                          float* __restrict__ p_src, float* __restrict__ p_dst) {
  if (blockIdx.x < NCHUNK) {
    __shared__ int wsum[4], woff_s[4];
    int t = threadIdx.x;
    int c0 = blockIdx.x * CHUNK;
    int i0 = c0 + t * 4;
    int v0 = (i0 + 0 < NN) ? cnt[i0 + 0] : 0;
    int v1 = (i0 + 1 < NN) ? cnt[i0 + 1] : 0;
    int v2 = (i0 + 2 < NN) ? cnt[i0 + 2] : 0;
    int v3 = (i0 + 3 < NN) ? cnt[i0 + 3] : 0;
    int s4 = v0 + v1 + v2 + v3;
    int lane = t & 63, wid = t >> 6;
    int x = s4;
#pragma unroll
    for (int off = 1; off < 64; off <<= 1) {
      int y = __shfl_up(x, off, 64);
      if (lane >= off) x += y;
    }
    if (lane == 63) wsum[wid] = x;
    __syncthreads();
    if (t == 0) {
      int a = 0;
      for (int i = 0; i < 4; ++i) { woff_s[i] = a; a += wsum[i]; }
    }
    __syncthreads();
    int base = boff[blockIdx.x] + woff_s[wid] + (x - s4);
    int r0 = base, r1 = base + v0, r2 = r1 + v1, r3 = r2 + v2;
    if (i0 + 0 < NN) {
      row_ptr[i0 + 0] = r0;
      if ((i0 & 255) == 0) bucket_cursor[i0 >> 8] = r0;
    }
    if (i0 + 1 < NN) row_ptr[i0 + 1] = r1;
    if (i0 + 2 < NN) row_ptr[i0 + 2] = r2;
    if (i0 + 3 < NN) row_ptr[i0 + 3] = r3;
  } else {
    d_proj(blockIdx.x - NCHUNK, X, Wn, bn, ts_p, WmpPk, bmp0, attn0, msgbf, p_src, p_dst);
  }
}

// phase B: bin edges by coarse bucket (dst>>8) into packed ebuf (uint2: pk, eid).
__global__ void __launch_bounds__(256) k_bin(const int* __restrict__ src,
                                             const int* __restrict__ dst,
                                             const int* __restrict__ etype,
                                             int* __restrict__ bucket_cursor,
                                             uint2* __restrict__ ebuf) {
  __shared__ int cntl[NBUCK];
  __shared__ int gbase[NBUCK];
  int t = threadIdx.x;
  for (int i = t; i < NBUCK; i += 256) cntl[i] = 0;
  __syncthreads();
  int e0 = blockIdx.x * EPB;
  int dd[16];
  uint pk[16];
  int rk[16];
#pragma unroll
  for (int c = 0; c < 4; ++c) {
    int eb = e0 + c * 1024 + t * 4;
    if (eb < NE) {
      int4 s4 = *(const int4*)&src[eb];
      int4 d4 = *(const int4*)&dst[eb];
      int4 y4 = *(const int4*)&etype[eb];
      int ds[4] = {d4.x, d4.y, d4.z, d4.w};
      int ss[4] = {s4.x, s4.y, s4.z, s4.w};
      int ys[4] = {y4.x, y4.y, y4.z, y4.w};
#pragma unroll
      for (int j = 0; j < 4; ++j) {
        int idx = c * 4 + j;
        int d = ds[j];
        dd[idx] = d;
        pk[idx] = (uint)ss[j] | ((uint)ys[j] << 16) | ((uint)(d & 255) << 22);
        rk[idx] = atomicAdd(&cntl[d >> 8], 1);
      }
    } else {
#pragma unroll
      for (int j = 0; j < 4; ++j) dd[c * 4 + j] = -1;
    }
  }
  __syncthreads();
  if (t < NBUCK && cntl[t] > 0) gbase[t] = atomicAdd(&bucket_cursor[t], cntl[t]);
  __syncthreads();
#pragma unroll
  for (int i = 0; i < 16; ++i) {
    if (dd[i] >= 0) {
      uint eid = (uint)(e0 + ((i >> 2) << 10) + t * 4 + (i & 3));
      ebuf[gbase[dd[i] >> 8] + rk[i]] = make_uint2(pk[i], eid);
    }
  }
}

// phase C: per-bucket scatter to final CSR slot
__global__ void __launch_bounds__(256) k_scatter2(const int* __restrict__ row_ptr,
                                                  const uint2* __restrict__ ebuf,
                                                  uint* __restrict__ csr,
                                                  uint* __restrict__ csr_eid) {
  __shared__ int curs[256];
  int b = blockIdx.x;
  int n0 = b << 8;
  int t = threadIdx.x;
  int n = n0 + t;
  curs[t] = (n < NN) ? row_ptr[n] : 0;
  __syncthreads();
  int n1 = n0 + 256; if (n1 > NN) n1 = NN;
  int lo = row_ptr[n0];
  int hi = row_ptr[n1];
  for (int i = lo + t; i < hi; i += 256) {
    uint2 v = ebuf[i];
    int j = (v.x >> 22) & 255;
    int pos = atomicAdd(&curs[j], 1);
    csr[pos] = v.x & 0x3FFFFFu;
    csr_eid[pos] = v.y;
  }
}

// ---------------------------------------------------------------- softmax-aggregate (wave/node)
// FUSE=1: epilogue also computes next-layer msg (MFMA over the block's 4 nodes)
//         and next-layer p_src/p_dst. No ht materialization at all.
// FUSE=0: final layer — write f32 ht for k_score.
template <int FUSE>
__global__ void __launch_bounds__(256) k_agg(const int* __restrict__ row_ptr,
                                             const uint* __restrict__ csr,
                                             const float* __restrict__ p_src,
                                             const float* __restrict__ p_dst,
                                             const float* __restrict__ ta_l,
                                             const ushort* __restrict__ msgbf,
                                             float* __restrict__ s_buf,
                                             const ushort* __restrict__ WmpPk_next,
                                             const float* __restrict__ bmp_next,
                                             const float* __restrict__ attn_next,
                                             ushort* __restrict__ msg_out,
                                             float* __restrict__ p_src_out,
                                             float* __restrict__ p_dst_out,
                                             float* __restrict__ ht_out) {
  __shared__ float v_lds[16][64];   // rows 0..3 = block's nodes (4..15 unused)
  int t = threadIdx.x;
  int lane = t & 63, wv = t >> 6;
  int n = blockIdx.x * 4 + wv;      // grid exactly NN/4 — always valid
  int start = row_ptr[n], end = row_ptr[n + 1];
  int deg = end - start;
  float pd = p_dst[n];
  int lq = lane & 7, lg = lane >> 3;
  float acc[8];
#pragma unroll
  for (int u = 0; u < 8; ++u) acc[u] = 0.f;
  float exsum = 0.f;

  if (deg <= 64) {
    bool valid = lane < deg;
    float s = -3.4e38f;
    int sidx = 0;
    if (valid) {
      uint pk = csr[start + lane];
      sidx = (int)(pk & 0xFFFFu);
      int ty = (int)(pk >> 16);
      float v = p_src[sidx] + pd + ta_l[ty];
      s = (v > 0.f) ? v : 0.2f * v;
    }
    float m = s;
#pragma unroll
    for (int off = 32; off >= 1; off >>= 1) m = fmaxf(m, __shfl_xor(m, off, 64));
    float ex = valid ? __expf(s - m) : 0.f;
    exsum = ex;
    for (int it = 0; it < deg; it += 8) {
      int el = it + lg;
      float exk = __shfl(ex, el, 64);
      int sk = __shfl(sidx, el, 64);
      if (el < deg) {
        uint4 mv = *(const uint4*)&msgbf[(size_t)sk * HD + lq * 8];
        acc[0] += exk * bflo(mv.x); acc[1] += exk * bfhi(mv.x);
        acc[2] += exk * bflo(mv.y); acc[3] += exk * bfhi(mv.y);
        acc[4] += exk * bflo(mv.z); acc[5] += exk * bfhi(mv.z);
        acc[6] += exk * bflo(mv.w); acc[7] += exk * bfhi(mv.w);
      }
    }
  } else {
    float m = -3.4e38f;
    for (int base = start; base < end; base += 64) {
      int i = base + lane;
      float s = -3.4e38f;
      if (i < end) {
        uint pk = csr[i];
        int sidx = (int)(pk & 0xFFFFu);
        int ty = (int)(pk >> 16);
        float v = p_src[sidx] + pd + ta_l[ty];
        s = (v > 0.f) ? v : 0.2f * v;
        s_buf[i] = s;
      }
      m = fmaxf(m, s);
    }
#pragma unroll
    for (int off = 32; off >= 1; off >>= 1) m = fmaxf(m, __shfl_xor(m, off, 64));
    for (int base = start; base < end; base += 64) {
      int i = base + lane;
      if (i < end) {
        float ex = __expf(s_buf[i] - m);
        s_buf[i] = ex;
        exsum += ex;
      }
    }
    for (int it = start; it < end; it += 8) {
      int el = it + lg;
      if (el < end) {
        float exk = s_buf[el];
        int sk = (int)(csr[el] & 0xFFFFu);
        uint4 mv = *(const uint4*)&msgbf[(size_t)sk * HD + lq * 8];
        acc[0] += exk * bflo(mv.x); acc[1] += exk * bfhi(mv.x);
        acc[2] += exk * bflo(mv.y); acc[3] += exk * bfhi(mv.y);
        acc[4] += exk * bflo(mv.z); acc[5] += exk * bfhi(mv.z);
        acc[6] += exk * bflo(mv.w); acc[7] += exk * bfhi(mv.w);
      }
    }
  }
#pragma unroll
  for (int u = 0; u < 8; ++u) {
    acc[u] += __shfl_xor(acc[u], 8, 64);
    acc[u] += __shfl_xor(acc[u], 16, 64);
    acc[u] += __shfl_xor(acc[u], 32, 64);
  }
#pragma unroll
  for (int off = 32; off >= 1; off >>= 1) exsum += __shfl_xor(exsum, off, 64);
  float inv = 1.f / (exsum + 1e-15f);
  float ss = 0.f;
#pragma unroll
  for (int u = 0; u < 8; ++u) {
    float v = fmaxf(acc[u] * inv, 0.f);
    acc[u] = v;
    ss += v * v;
  }
  ss += __shfl_xor(ss, 1, 64);
  ss += __shfl_xor(ss, 2, 64);
  ss += __shfl_xor(ss, 4, 64);
  float nu = fmaxf(sqrtf(ss), 1e-15f);
  float sc = fminf(nu, LCLAMP) / nu;

  if constexpr (FUSE == 0) {
    if (lane < 8) {
      *(float4*)&ht_out[(size_t)n * HD + lane * 8] =
          make_float4(acc[0] * sc, acc[1] * sc, acc[2] * sc, acc[3] * sc);
      *(float4*)&ht_out[(size_t)n * HD + lane * 8 + 4] =
          make_float4(acc[4] * sc, acc[5] * sc, acc[6] * sc, acc[7] * sc);
    }
  } else {
    // next-layer p from bf16-rounded ht (element index = lq*8+u)
    float hb[8];
#pragma unroll
    for (int u = 0; u < 8; ++u) hb[u] = bf2f((short)f2bf(acc[u] * sc));
    float4 a1a = *(const float4*)&attn_next[lq * 8];
    float4 a1b = *(const float4*)&attn_next[lq * 8 + 4];
    float4 a2a = *(const float4*)&attn_next[64 + lq * 8];
    float4 a2b = *(const float4*)&attn_next[64 + lq * 8 + 4];
    float p1 = hb[0]*a1a.x + hb[1]*a1a.y + hb[2]*a1a.z + hb[3]*a1a.w
             + hb[4]*a1b.x + hb[5]*a1b.y + hb[6]*a1b.z + hb[7]*a1b.w;
    float p2 = hb[0]*a2a.x + hb[1]*a2a.y + hb[2]*a2a.z + hb[3]*a2a.w
             + hb[4]*a2b.x + hb[5]*a2b.y + hb[6]*a2b.z + hb[7]*a2b.w;
    p1 += __shfl_xor(p1, 1, 64); p1 += __shfl_xor(p1, 2, 64); p1 += __shfl_xor(p1, 4, 64);
    p2 += __shfl_xor(p2, 1, 64); p2 += __shfl_xor(p2, 2, 64); p2 += __shfl_xor(p2, 4, 64);
    if (lane == 0) { p_src_out[n] = p1; p_dst_out[n] = p2; }
    // stage ht row into LDS for the block-wide msg GEMM
    if (lane < 8) {
      *(float4*)&v_lds[wv][lane * 8] =
          make_float4(acc[0] * sc, acc[1] * sc, acc[2] * sc, acc[3] * sc);
      *(float4*)&v_lds[wv][lane * 8 + 4] =
          make_float4(acc[4] * sc, acc[5] * sc, acc[6] * sc, acc[7] * sc);
    }
    __syncthreads();
    // msg = ht @ Wmp_next + bmp_next for the block's 4 nodes; wave wv computes cols wv*16..+15
    int lane15 = lane & 15, quad = lane >> 4;
    bf16x8 A0 = frag_f32(&v_lds[lane15][quad * 8]);        // rows 4..15 junk, discarded
    bf16x8 A1 = frag_f32(&v_lds[lane15][32 + quad * 8]);
    bf16x8 B0 = *(const bf16x8*)&WmpPk_next[(wv * 2 + 0) * 512 + lane * 8];
    bf16x8 B1 = *(const bf16x8*)&WmpPk_next[(wv * 2 + 1) * 512 + lane * 8];
    f32x4 z = {0.f, 0.f, 0.f, 0.f};
    z = __builtin_amdgcn_mfma_f32_16x16x32_bf16(A0, B0, z, 0, 0, 0);
    z = __builtin_amdgcn_mfma_f32_16x16x32_bf16(A1, B1, z, 0, 0, 0);
    float vbm = bmp_next[wv * 16 + lane15];
    if (quad == 0) {
      int nb = blockIdx.x * 4;
#pragma unroll
      for (int i = 0; i < 4; ++i)
        msg_out[(size_t)(nb + i) * HD + wv * 16 + lane15] = f2bf(z[i] + vbm);
    }
  }
}

// ---------------------------------------------------------------- heads (MFMA)
__global__ void __launch_bounds__(256) k_score(const float* __restrict__ ht,
                                               const float* __restrict__ Wns1,
                                               const float* __restrict__ qb,
                                               const float* __restrict__ Wns2,
                                               const float* __restrict__ bns2,
                                               const float* __restrict__ Wes1,
                                               float* __restrict__ node_scores,
                                               float* __restrict__ h_out,
                                               ushort* __restrict__ Asrc,
                                               ushort* __restrict__ Adst) {
  int t = threadIdx.x;
  int lane = t & 63, wv = t >> 6;
  int lane15 = lane & 15, quad = lane >> 4;
  int n0 = blockIdx.x * 64;
  int m0 = n0 + wv * 16;
  int row = m0 + lane15;
  int rowc = row < NN ? row : NN - 1;
  bf16x8 A0 = frag_f32(ht + (size_t)rowc * HD + quad * 8);
  bf16x8 A1 = frag_f32(ht + (size_t)rowc * HD + 32 + quad * 8);

  // node head
  {
    f32x4 acc[4];
#pragma unroll
    for (int jt = 0; jt < 4; ++jt) {
      bf16x8 b0 = bfrag_w(Wns1, 0, jt * 16, lane15, quad);
      bf16x8 b1 = bfrag_w(Wns1, 32, jt * 16, lane15, quad);
      f32x4 z = {0.f, 0.f, 0.f, 0.f};
      z = __builtin_amdgcn_mfma_f32_16x16x32_bf16(A0, b0, z, 0, 0, 0);
      z = __builtin_amdgcn_mfma_f32_16x16x32_bf16(A1, b1, z, 0, 0, 0);
      acc[jt] = z;
    }
    float vqb[4], vw2[4];
#pragma unroll
    for (int jt = 0; jt < 4; ++jt) { vqb[jt] = qb[jt * 16 + lane15]; vw2[jt] = Wns2[jt * 16 + lane15]; }
    float b2 = bns2[0];
#pragma unroll
    for (int i = 0; i < 4; ++i) {
      float si = 0.f;
#pragma unroll
      for (int jt = 0; jt < 4; ++jt) si += fmaxf(acc[jt][i] + vqb[jt], 0.f) * vw2[jt];
      si += __shfl_xor(si, 1, 64);
      si += __shfl_xor(si, 2, 64);
      si += __shfl_xor(si, 4, 64);
      si += __shfl_xor(si, 8, 64);
      int r = m0 + quad * 4 + i;
      if (lane15 == 0 && r < NN) node_scores[r] = 1.f / (1.f + __expf(-(si + b2)));
    }
  }
  // Asrc
  {
#pragma unroll
    for (int jt = 0; jt < 4; ++jt) {
      bf16x8 b0 = bfrag_w(Wes1, 0, jt * 16, lane15, quad);
      bf16x8 b1 = bfrag_w(Wes1, 32, jt * 16, lane15, quad);
      f32x4 z = {0.f, 0.f, 0.f, 0.f};
      z = __builtin_amdgcn_mfma_f32_16x16x32_bf16(A0, b0, z, 0, 0, 0);
      z = __builtin_amdgcn_mfma_f32_16x16x32_bf16(A1, b1, z, 0, 0, 0);
#pragma unroll
      for (int i = 0; i < 4; ++i) {
        int r = m0 + quad * 4 + i;
        if (r < NN) Asrc[(size_t)r * HD + jt * 16 + lane15] = f2bf(z[i]);
      }
    }
  }
  // Adst
  {
    const float* W = Wes1 + 64 * HD;
#pragma unroll
    for (int jt = 0; jt < 4; ++jt) {
      bf16x8 b0 = bfrag_w(W, 0, jt * 16, lane15, quad);
      bf16x8 b1 = bfrag_w(W, 32, jt * 16, lane15, quad);
      f32x4 z = {0.f, 0.f, 0.f, 0.f};
      z = __builtin_amdgcn_mfma_f32_16x16x32_bf16(A0, b0, z, 0, 0, 0);
      z = __builtin_amdgcn_mfma_f32_16x16x32_bf16(A1, b1, z, 0, 0, 0);
#pragma unroll
      for (int i = 0; i < 4; ++i) {
        int r = m0 + quad * 4 + i;
        if (r < NN) Adst[(size_t)r * HD + jt * 16 + lane15] = f2bf(z[i]);
      }
    }
  }
  // h_out: exact f32 pass
  {
    int r = t >> 2, p = t & 3;
    int gr = n0 + r;
    int grc = gr < NN ? gr : NN - 1;
    const float* rp = ht + (size_t)grc * HD + p * 16;
    float4 v0 = *(const float4*)(rp + 0);
    float4 v1 = *(const float4*)(rp + 4);
    float4 v2 = *(const float4*)(rp + 8);
    float4 v3 = *(const float4*)(rp + 12);
    float ssq = v0.x*v0.x + v0.y*v0.y + v0.z*v0.z + v0.w*v0.w
              + v1.x*v1.x + v1.y*v1.y + v1.z*v1.z + v1.w*v1.w
              + v2.x*v2.x + v2.y*v2.y + v2.z*v2.z + v2.w*v2.w
              + v3.x*v3.x + v3.y*v3.y + v3.z*v3.z + v3.w*v3.w;
    ssq += __shfl_xor(ssq, 1, 64);
    ssq += __shfl_xor(ssq, 2, 64);
    float nu = fmaxf(sqrtf(ssq), 1e-15f);
    float hs = tanhf(nu) / nu;
    if (gr < NN) {
      float* op = h_out + (size_t)gr * HD + p * 16;
      *(float4*)(op + 0)  = make_float4(v0.x*hs, v0.y*hs, v0.z*hs, v0.w*hs);
      *(float4*)(op + 4)  = make_float4(v1.x*hs, v1.y*hs, v1.z*hs, v1.w*hs);
      *(float4*)(op + 8)  = make_float4(v2.x*hs, v2.y*hs, v2.z*hs, v2.w*hs);
      *(float4*)(op + 12) = make_float4(v3.x*hs, v3.y*hs, v3.z*hs, v3.w*hs);
    }
  }
}

// ---------------------------------------------------------------- edge scores (CSR order)
__global__ void __launch_bounds__(256) k_edge(const int* __restrict__ row_ptr,
                                              const uint* __restrict__ csr,
                                              const uint* __restrict__ csr_eid,
                                              const ushort* __restrict__ Asrc,
                                              const ushort* __restrict__ Adst,
                                              const ushort* __restrict__ Te2bf,
                                              const float* __restrict__ Wes2,
                                              const float* __restrict__ bes2,
                                              float* __restrict__ edge_scores) {
  int t = threadIdx.x;
  int lane = t & 63;
  int n = (blockIdx.x * 256 + t) >> 6;
  if (n >= NN) return;
  int lq = lane & 7, lg = lane >> 3;
  int start = row_ptr[n], end = row_ptr[n + 1];
  if (start >= end) return;
  uint4 bv = *(const uint4*)&Adst[(size_t)n * HD + lq * 8];
  const float* wp = &Wes2[lq * 8];
  float4 w0 = *(const float4*)wp;
  float4 w1 = *(const float4*)(wp + 4);
  float b2 = bes2[0];
  for (int it = start; it < end; it += 8) {
    int e = it + lg;
    bool valid = e < end;
    float p = 0.f;
    if (valid) {
      uint pk = csr[e];
      int si = (int)(pk & 0xFFFFu);
      int ty = (int)((pk >> 16) & 0x3Fu);
      uint4 av = *(const uint4*)&Asrc[(size_t)si * HD + lq * 8];
      uint4 tv = *(const uint4*)&Te2bf[ty * HD + lq * 8];
      p += fmaxf(bflo(av.x) + bflo(bv.x) + bflo(tv.x), 0.f) * w0.x;
      p += fmaxf(bfhi(av.x) + bfhi(bv.x) + bfhi(tv.x), 0.f) * w0.y;
      p += fmaxf(bflo(av.y) + bflo(bv.y) + bflo(tv.y), 0.f) * w0.z;
      p += fmaxf(bfhi(av.y) + bfhi(bv.y) + bfhi(tv.y), 0.f) * w0.w;
      p += fmaxf(bflo(av.z) + bflo(bv.z) + bflo(tv.z), 0.f) * w1.x;
      p += fmaxf(bfhi(av.z) + bfhi(bv.z) + bfhi(tv.z), 0.f) * w1.y;
      p += fmaxf(bflo(av.w) + bflo(bv.w) + bflo(tv.w), 0.f) * w1.z;
      p += fmaxf(bfhi(av.w) + bfhi(bv.w) + bfhi(tv.w), 0.f) * w1.w;
    }
    p += __shfl_xor(p, 1, 64);
    p += __shfl_xor(p, 2, 64);
    p += __shfl_xor(p, 4, 64);
    if (valid && lq == 0) edge_scores[csr_eid[e]] = 1.f / (1.f + __expf(-(p + b2)));
  }
}

// ---------------------------------------------------------------- launch
extern "C" void kernel_launch(void* const* d_in, const int* in_sizes, int n_in,
                              void* d_out, int out_size, void* d_ws, size_t ws_size,
                              hipStream_t stream) {
  const float* node_features = (const float*)d_in[0];
  const float* edge_desc = (const float*)d_in[1];
  const float* query = (const float*)d_in[2];
  const float* Wn = (const float*)d_in[3];
  const float* bn = (const float*)d_in[4];
  const float* ts = (const float*)d_in[5];
  const float* Wq = (const float*)d_in[6];
  const float* bq = (const float*)d_in[7];
  const float* Ws_ = (const float*)d_in[8];
  const float* bs = (const float*)d_in[9];
  const float* attn_a = (const float*)d_in[10];
  const float* Wmp = (const float*)d_in[11];
  const float* bmp = (const float*)d_in[12];
  const float* Wns1 = (const float*)d_in[13];
  const float* bns1 = (const float*)d_in[14];
  const float* Wns2 = (const float*)d_in[15];
  const float* bns2 = (const float*)d_in[16];
  const float* Wes1 = (const float*)d_in[17];
  const float* bes1 = (const float*)d_in[18];
  const float* Wes2 = (const float*)d_in[19];
  const float* bes2 = (const float*)d_in[20];
  const int* edge_index = (const int*)d_in[21];
  const int* etype = (const int*)d_in[22];
  const int* src = edge_index;
  const int* dst = edge_index + NE;

  float* out_ns = (float*)d_out;
  float* out_es = out_ns + NN;
  float* out_h = out_es + NE;
  float* out_te = out_h + (size_t)NN * HD;

  char* w = (char*)d_ws;
  auto alloc = [&](size_t bytes) {
    char* p = w;
    w += (bytes + 1023) & ~(size_t)1023;
    return p;
  };
  float* ht_f = (float*)alloc((size_t)NN * HD * 4);        // final-layer f32 ht
  ushort* msg0 = (ushort*)alloc((size_t)NN * HD * 2);      // msg ping
  ushort* msg1 = (ushort*)alloc((size_t)NN * HD * 2);      // msg pong
  ushort* Asrc = (ushort*)alloc((size_t)NN * HD * 2);
  ushort* Adst = (ushort*)alloc((size_t)NN * HD * 2);
  float* pA = (float*)alloc(NN * 4);
  float* pdA = (float*)alloc(NN * 4);
  float* pB = (float*)alloc(NN * 4);
  float* pdB = (float*)alloc(NN * 4);
  float* s_buf = (float*)alloc(NE * 4);
  float* qb = (float*)alloc(HD * 4);
  float* qe = (float*)alloc(HD * 4);
  float* ta3 = (float*)alloc(NLAY * NTT * 4);
  ushort* Te2bf = (ushort*)alloc(NTT * HD * 2);
  ushort* WmpPk = (ushort*)alloc(NLAY * 4096 * 2);
  int* cnt = (int*)alloc(NN * 4);
  int* row_ptr = (int*)alloc((NN + 1) * 4);
  int* bsum = (int*)alloc(NCHUNK * 4);
  int* boff = (int*)alloc(NCHUNK * 4);
  int* bucket_cursor = (int*)alloc(NBUCK * 4);
  uint* csr = (uint*)alloc(NE * 4);
  uint* csr_eid = (uint*)alloc(NE * 4);
  // ebuf (NE x 8B = 6.4 MB) aliases Asrc (6.4 MB): CSR build finishes before
  // k_score writes Asrc. No overlap in stream order.
  uint2* ebuf = (uint2*)Asrc;

  hipMemsetAsync(cnt, 0, NN * 4, stream);
  // kA: hist (3125 blocks) + setup (1 block)
  kA<<<NE / 256 + 1, 256, 0, stream>>>(dst, cnt, edge_desc, query, Wq, bq, Ws_, bs, attn_a,
                                       Wns1, bns1, Wes1, bes1, Wmp, out_te, qb, ta3, qe, WmpPk);
  // kB: te2 (16) + scanA (49)
  kB<<<16 + NCHUNK, 256, 0, stream>>>(out_te, qe, Wes1, Te2bf, cnt, bsum);
  k_scanB<<<1, 64, 0, stream>>>(bsum, boff, row_ptr);
  // kD: scanC (49) + proj w/ fused layer-0 msg (782)
  kD<<<NCHUNK + (NN + 63) / 64, 256, 0, stream>>>(cnt, boff, row_ptr, bucket_cursor,
                                                  node_features, Wn, bn, ts, WmpPk,
                                                  bmp, attn_a, msg0, pA, pdA);
  k_bin<<<NBINBLK, 256, 0, stream>>>(src, dst, etype, bucket_cursor, ebuf);
  k_scatter2<<<NBUCK, 256, 0, stream>>>(row_ptr, ebuf, csr, csr_eid);

  const int AGG_GRID = NN / 4;   // NN % 4 == 0
  // layer 0: gather msg0 (from proj), emit msg1 = ht1 @ Wmp1 and p's for layer 1
  k_agg<1><<<AGG_GRID, 256, 0, stream>>>(row_ptr, csr, pA, pdA, ta3 + 0 * NTT, msg0, s_buf,
                                         WmpPk + 1 * 4096, bmp + 1 * HD,
                                         attn_a + 1 * (2 * HD + TDD),
                                         msg1, pB, pdB, nullptr);
  // layer 1: gather msg1, emit msg0 = ht2 @ Wmp2 and p's for layer 2
  k_agg<1><<<AGG_GRID, 256, 0, stream>>>(row_ptr, csr, pB, pdB, ta3 + 1 * NTT, msg1, s_buf,
                                         WmpPk + 2 * 4096, bmp + 2 * HD,
                                         attn_a + 2 * (2 * HD + TDD),
                                         msg0, pA, pdA, nullptr);
  // layer 2: gather msg0, write final f32 ht
  k_agg<0><<<AGG_GRID, 256, 0, stream>>>(row_ptr, csr, pA, pdA, ta3 + 2 * NTT, msg0, s_buf,
                                         nullptr, nullptr, nullptr,
                                         nullptr, nullptr, nullptr, ht_f);

  k_score<<<(NN + 63) / 64, 256, 0, stream>>>(ht_f, Wns1, qb, Wns2, bns2, Wes1,
                                              out_ns, out_h, Asrc, Adst);
  k_edge<<<(NN + 3) / 4, 256, 0, stream>>>(row_ptr, csr, csr_eid, Asrc, Adst, Te2bf,
                                           Wes2, bes2, out_es);
}

// Round 3
// 358.516 us; speedup vs baseline: 1.1070x; 1.0949x over previous
//
#include <hip/hip_runtime.h>
#include <math.h>

#define NN 50000
#define NE 800000
#define NFD 256
#define HD 64
#define QDD 128
#define TDD 32
#define NTT 64
#define NLAY 3
#define LCLAMP 6.1030340f   // atanh(1 - 1e-5)
#define NBUCK 196           // ceil(50000/256) coarse buckets (dst >> 8)
#define SBUCK 6144          // padded slots per bucket (expected 4096, sigma ~64)
#define NPAD (NBUCK * SBUCK)
#define EPB 4096            // edges per bin block
#define NBINBLK 196         // ceil(800000/4096)
#define PST 72              // proj LDS tile stride

typedef unsigned int uint;
typedef unsigned short ushort;
typedef __attribute__((ext_vector_type(8))) short bf16x8;
typedef __attribute__((ext_vector_type(4))) float f32x4;

__device__ __forceinline__ ushort f2bf(float f) {
  uint u = __float_as_uint(f);
  uint r = (u + 0x7FFFu + ((u >> 16) & 1u)) >> 16;
  return (ushort)r;
}
__device__ __forceinline__ short f2bfs(float f) { return (short)f2bf(f); }
__device__ __forceinline__ float bf2f(short s) { return __uint_as_float(((uint)(ushort)s) << 16); }
__device__ __forceinline__ float bflo(uint w) { return __uint_as_float(w << 16); }
__device__ __forceinline__ float bfhi(uint w) { return __uint_as_float(w & 0xFFFF0000u); }

// A-frag from 8 consecutive f32
__device__ __forceinline__ bf16x8 frag_f32(const float* p) {
  float4 a = *(const float4*)p;
  float4 b = *(const float4*)(p + 4);
  bf16x8 r;
  r[0] = f2bfs(a.x); r[1] = f2bfs(a.y); r[2] = f2bfs(a.z); r[3] = f2bfs(a.w);
  r[4] = f2bfs(b.x); r[5] = f2bfs(b.y); r[6] = f2bfs(b.z); r[7] = f2bfs(b.w);
  return r;
}
// B-frag from row-major W[K][64]: k=k0+quad*8+j, n=j0+lane15
__device__ __forceinline__ bf16x8 bfrag_w(const float* W, int k0, int j0, int lane15, int quad) {
  bf16x8 r;
#pragma unroll
  for (int j = 0; j < 8; ++j) r[j] = f2bfs(W[(k0 + quad * 8 + j) * HD + j0 + lane15]);
  return r;
}

// ---------------------------------------------------------------- setup (1 block): te, q-projs, ta3, WmpPk, Te2bf
__global__ void __launch_bounds__(256) kA(const float* __restrict__ edge_desc, const float* __restrict__ query,
                                          const float* __restrict__ Wq, const float* __restrict__ bq,
                                          const float* __restrict__ Ws, const float* __restrict__ bs,
                                          const float* __restrict__ attn_a,
                                          const float* __restrict__ Wns1, const float* __restrict__ bns1,
                                          const float* __restrict__ Wes1, const float* __restrict__ bes1,
                                          const float* __restrict__ Wmp,
                                          float* __restrict__ out_type_emb,
                                          float* __restrict__ qb, float* __restrict__ ta3,
                                          ushort* __restrict__ Te2bf, ushort* __restrict__ WmpPk) {
  __shared__ float te_l[NTT * TDD];
  __shared__ float q_l[HD];
  __shared__ float qe_l[HD];
  int t = threadIdx.x;
  if (t < HD) {
    float acc = bq[t];
    for (int k = 0; k < QDD; ++k) acc += query[k] * Wq[k * HD + t];
    q_l[t] = acc;
  }
  for (int idx = t; idx < NTT * TDD; idx += 256) {
    int ty = idx / TDD, d = idx % TDD;
    float acc = bs[d];
    for (int k = 0; k < 64; ++k) acc += edge_desc[ty * 64 + k] * Ws[k * TDD + d];
    float v = tanhf(acc);
    te_l[idx] = v;
    out_type_emb[idx] = v;
  }
  __syncthreads();
  if (t < NLAY * NTT) {
    int l = t / NTT, ty = t % NTT;
    float acc = 0.f;
    for (int d = 0; d < TDD; ++d) acc += te_l[ty * TDD + d] * attn_a[l * (2 * HD + TDD) + 2 * HD + d];
    ta3[t] = acc;
  }
  if (t < HD) {
    float a1 = bns1[t], a2 = bes1[t];
    for (int k = 0; k < HD; ++k) {
      a1 += q_l[k] * Wns1[(HD + k) * HD + t];
      a2 += q_l[k] * Wes1[(2 * HD + TDD + k) * HD + t];
    }
    qb[t] = a1;
    qe_l[t] = a2;
  }
  // pack Wmp B-frags: WmpPk[(((l*4+jt)*2+f)*64 + lane)*8 + j]
  //   = bf16(Wmp[l][(f*32 + quad*8 + j)][jt*16 + lane15])
  for (int idx = t; idx < NLAY * 4 * 2 * 64 * 8; idx += 256) {
    int j = idx & 7, lane = (idx >> 3) & 63, f = (idx >> 9) & 1, jl = idx >> 10;
    int l = jl >> 2, jt = jl & 3, q = lane >> 4, l15 = lane & 15;
    WmpPk[idx] = f2bf(Wmp[l * HD * HD + (f * 32 + q * 8 + j) * HD + jt * 16 + l15]);
  }
  __syncthreads();
  // Te2bf[ty][j] = bf16(type_emb[ty] @ Wes1[te-part] + qe)
  for (int idx = t; idx < NTT * HD; idx += 256) {
    int ty = idx >> 6, j = idx & 63;
    float acc = qe_l[j];
#pragma unroll
    for (int d = 0; d < TDD; ++d) acc += te_l[ty * TDD + d] * Wes1[(2 * HD + d) * HD + j];
    Te2bf[idx] = f2bf(acc);
  }
}

// ---------------------------------------------------------------- bin (device): append edges to padded bucket regions
// pk: src(16) | type(6)<<16 | (dst&255)<<22
__device__ void d_bin(int bbid,
                      const int* __restrict__ src,
                      const int* __restrict__ dst,
                      const int* __restrict__ etype,
                      int* __restrict__ bucket_cursor,
                      uint2* __restrict__ ebuf) {
  __shared__ int cntl[NBUCK];
  __shared__ int gbase[NBUCK];
  int t = threadIdx.x;
  for (int i = t; i < NBUCK; i += 256) cntl[i] = 0;
  __syncthreads();
  int e0 = bbid * EPB;
  int dd[16];
  uint pk[16];
  int rk[16];
#pragma unroll
  for (int c = 0; c < 4; ++c) {
    int eb = e0 + c * 1024 + t * 4;
    if (eb < NE) {   // NE%4==0 => eb<NE implies eb+3<NE
      int4 s4 = *(const int4*)&src[eb];
      int4 d4 = *(const int4*)&dst[eb];
      int4 y4 = *(const int4*)&etype[eb];
      int ds[4] = {d4.x, d4.y, d4.z, d4.w};
      int ss[4] = {s4.x, s4.y, s4.z, s4.w};
      int ys[4] = {y4.x, y4.y, y4.z, y4.w};
#pragma unroll
      for (int j = 0; j < 4; ++j) {
        int idx = c * 4 + j;
        int d = ds[j];
        dd[idx] = d;
        pk[idx] = (uint)ss[j] | ((uint)ys[j] << 16) | ((uint)(d & 255) << 22);
        rk[idx] = atomicAdd(&cntl[d >> 8], 1);
      }
    } else {
#pragma unroll
      for (int j = 0; j < 4; ++j) dd[c * 4 + j] = -1;
    }
  }
  __syncthreads();
  if (t < NBUCK && cntl[t] > 0)
    gbase[t] = t * SBUCK + atomicAdd(&bucket_cursor[t], cntl[t]);
  __syncthreads();
#pragma unroll
  for (int i = 0; i < 16; ++i) {
    if (dd[i] >= 0) {
      uint eid = (uint)(e0 + ((i >> 2) << 10) + t * 4 + (i & 3));
      ebuf[gbase[dd[i] >> 8] + rk[i]] = make_uint2(pk[i], eid);
    }
  }
}

// ---------------------------------------------------------------- proj (device) + fused layer-0 msg
__device__ void d_proj(int pbid,
                       const float* __restrict__ X,
                       const float* __restrict__ Wn,
                       const float* __restrict__ bn,
                       const float* __restrict__ ts_p,
                       const ushort* __restrict__ WmpPk,   // layer-0 frags at offset 0
                       const float* __restrict__ bmp0,
                       const float* __restrict__ attn0,
                       ushort* __restrict__ msgbf,
                       float* __restrict__ p_src,
                       float* __restrict__ p_dst) {
  __shared__ ushort buf[2][64 * PST];            // 2 x 9216 B
  float* st = (float*)&buf[0][0];                // epilogue alias: 64 x 72 f32
  int t = threadIdx.x;
  int lane = t & 63, wv = t >> 6;
  int lane15 = lane & 15, quad = lane >> 4;
  int n0 = pbid * 64;
  int j0 = wv * 16;
  bf16x8 B[8];
#pragma unroll
  for (int fb = 0; fb < 8; ++fb) B[fb] = bfrag_w(Wn, fb * 32, j0, lane15, quad);

  int srow = t >> 2;
  int scg = (t & 3) * 16;
  int grow = n0 + srow; if (grow >= NN) grow = NN - 1;
  const float* xrow = X + (size_t)grow * NFD + scg;

  f32x4 acc[4];
#pragma unroll
  for (int mt = 0; mt < 4; ++mt) acc[mt] = (f32x4){0.f, 0.f, 0.f, 0.f};

  float4 r0 = *(const float4*)(xrow + 0);
  float4 r1 = *(const float4*)(xrow + 4);
  float4 r2 = *(const float4*)(xrow + 8);
  float4 r3 = *(const float4*)(xrow + 12);

  for (int c = 0; c < 4; ++c) {
    ushort* wp = &buf[c & 1][srow * PST + scg];
    uint4 o0, o1;
    o0.x = (uint)f2bf(r0.x) | ((uint)f2bf(r0.y) << 16);
    o0.y = (uint)f2bf(r0.z) | ((uint)f2bf(r0.w) << 16);
    o0.z = (uint)f2bf(r1.x) | ((uint)f2bf(r1.y) << 16);
    o0.w = (uint)f2bf(r1.z) | ((uint)f2bf(r1.w) << 16);
    o1.x = (uint)f2bf(r2.x) | ((uint)f2bf(r2.y) << 16);
    o1.y = (uint)f2bf(r2.z) | ((uint)f2bf(r2.w) << 16);
    o1.z = (uint)f2bf(r3.x) | ((uint)f2bf(r3.y) << 16);
    o1.w = (uint)f2bf(r3.z) | ((uint)f2bf(r3.w) << 16);
    *(uint4*)wp = o0;
    *(uint4*)(wp + 8) = o1;
    if (c < 3) {
      const float* nx = xrow + (c + 1) * 64;
      r0 = *(const float4*)(nx + 0);
      r1 = *(const float4*)(nx + 4);
      r2 = *(const float4*)(nx + 8);
      r3 = *(const float4*)(nx + 12);
    }
    __syncthreads();
    const ushort* bp = &buf[c & 1][0];
#pragma unroll
    for (int mt = 0; mt < 4; ++mt) {
#pragma unroll
      for (int ks = 0; ks < 2; ++ks) {
        bf16x8 A = *(const bf16x8*)&bp[(mt * 16 + lane15) * PST + ks * 32 + quad * 8];
        acc[mt] = __builtin_amdgcn_mfma_f32_16x16x32_bf16(A, B[c * 2 + ks], acc[mt], 0, 0, 0);
      }
    }
  }
  __syncthreads();
  float ts = ts_p[0];
  float vb = bn[j0 + lane15];
#pragma unroll
  for (int mt = 0; mt < 4; ++mt)
#pragma unroll
    for (int i = 0; i < 4; ++i)
      st[(mt * 16 + quad * 4 + i) * PST + j0 + lane15] = (acc[mt][i] + vb) * ts;
  __syncthreads();
  {
    int r = t >> 2, p = t & 3;
    float* rp = &st[r * PST + p * 16];
    float4 v0 = *(const float4*)(rp + 0);
    float4 v1 = *(const float4*)(rp + 4);
    float4 v2 = *(const float4*)(rp + 8);
    float4 v3 = *(const float4*)(rp + 12);
    float ssq = v0.x*v0.x + v0.y*v0.y + v0.z*v0.z + v0.w*v0.w
              + v1.x*v1.x + v1.y*v1.y + v1.z*v1.z + v1.w*v1.w
              + v2.x*v2.x + v2.y*v2.y + v2.z*v2.z + v2.w*v2.w
              + v3.x*v3.x + v3.y*v3.y + v3.z*v3.z + v3.w*v3.w;
    ssq += __shfl_xor(ssq, 1, 64);
    ssq += __shfl_xor(ssq, 2, 64);
    float nu = fmaxf(sqrtf(ssq), 1e-15f);
    float sc = fminf(nu, LCLAMP) / nu;
    *(float4*)(rp + 0) = make_float4(v0.x*sc, v0.y*sc, v0.z*sc, v0.w*sc);
    *(float4*)(rp + 4) = make_float4(v1.x*sc, v1.y*sc, v1.z*sc, v1.w*sc);
    *(float4*)(rp + 8) = make_float4(v2.x*sc, v2.y*sc, v2.z*sc, v2.w*sc);
    *(float4*)(rp + 12) = make_float4(v3.x*sc, v3.y*sc, v3.z*sc, v3.w*sc);
  }
  __syncthreads();
  // fused layer-0 msg
  {
    bf16x8 Bm0[4], Bm1[4];
    float vbm[4];
#pragma unroll
    for (int jt = 0; jt < 4; ++jt) {
      Bm0[jt] = *(const bf16x8*)&WmpPk[((jt * 2 + 0) * 64 + lane) * 8];
      Bm1[jt] = *(const bf16x8*)&WmpPk[((jt * 2 + 1) * 64 + lane) * 8];
      vbm[jt] = bmp0[jt * 16 + lane15];
    }
    int mrow = wv * 16 + lane15;
    bf16x8 A0 = frag_f32(&st[mrow * PST + quad * 8]);
    bf16x8 A1 = frag_f32(&st[mrow * PST + 32 + quad * 8]);
#pragma unroll
    for (int jt = 0; jt < 4; ++jt) {
      f32x4 z = {0.f, 0.f, 0.f, 0.f};
      z = __builtin_amdgcn_mfma_f32_16x16x32_bf16(A0, Bm0[jt], z, 0, 0, 0);
      z = __builtin_amdgcn_mfma_f32_16x16x32_bf16(A1, Bm1[jt], z, 0, 0, 0);
#pragma unroll
      for (int i = 0; i < 4; ++i) {
        int r = n0 + wv * 16 + quad * 4 + i;
        if (r < NN) msgbf[(size_t)r * HD + jt * 16 + lane15] = f2bf(z[i] + vbm[jt]);
      }
    }
    float4 a1l = *(const float4*)&attn0[quad * 8];
    float4 a1h = *(const float4*)&attn0[quad * 8 + 4];
    float4 a1l2 = *(const float4*)&attn0[32 + quad * 8];
    float4 a1h2 = *(const float4*)&attn0[32 + quad * 8 + 4];
    float4 a2l = *(const float4*)&attn0[64 + quad * 8];
    float4 a2h = *(const float4*)&attn0[64 + quad * 8 + 4];
    float4 a2l2 = *(const float4*)&attn0[96 + quad * 8];
    float4 a2h2 = *(const float4*)&attn0[96 + quad * 8 + 4];
    float p1 = bf2f(A0[0])*a1l.x + bf2f(A0[1])*a1l.y + bf2f(A0[2])*a1l.z + bf2f(A0[3])*a1l.w
             + bf2f(A0[4])*a1h.x + bf2f(A0[5])*a1h.y + bf2f(A0[6])*a1h.z + bf2f(A0[7])*a1h.w
             + bf2f(A1[0])*a1l2.x + bf2f(A1[1])*a1l2.y + bf2f(A1[2])*a1l2.z + bf2f(A1[3])*a1l2.w
             + bf2f(A1[4])*a1h2.x + bf2f(A1[5])*a1h2.y + bf2f(A1[6])*a1h2.z + bf2f(A1[7])*a1h2.w;
    float p2 = bf2f(A0[0])*a2l.x + bf2f(A0[1])*a2l.y + bf2f(A0[2])*a2l.z + bf2f(A0[3])*a2l.w
             + bf2f(A0[4])*a2h.x + bf2f(A0[5])*a2h.y + bf2f(A0[6])*a2h.z + bf2f(A0[7])*a2h.w
             + bf2f(A1[0])*a2l2.x + bf2f(A1[1])*a2l2.y + bf2f(A1[2])*a2l2.z + bf2f(A1[3])*a2l2.w
             + bf2f(A1[4])*a2h2.x + bf2f(A1[5])*a2h2.y + bf2f(A1[6])*a2h2.z + bf2f(A1[7])*a2h2.w;
    p1 += __shfl_xor(p1, 16, 64); p1 += __shfl_xor(p1, 32, 64);
    p2 += __shfl_xor(p2, 16, 64); p2 += __shfl_xor(p2, 32, 64);
    int prow = n0 + mrow;
    if (quad == 0 && prow < NN) { p_src[prow] = p1; p_dst[prow] = p2; }
  }
}

// kE: blocks 0..195 = bin, rest = proj (independent work, co-scheduled)
__global__ void __launch_bounds__(256) kE(const int* __restrict__ src, const int* __restrict__ dst,
                                          const int* __restrict__ etype, int* __restrict__ bucket_cursor,
                                          uint2* __restrict__ ebuf,
                                          const float* __restrict__ X, const float* __restrict__ Wn,
                                          const float* __restrict__ bn, const float* __restrict__ ts_p,
                                          const ushort* __restrict__ WmpPk, const float* __restrict__ bmp0,
                                          const float* __restrict__ attn0,
                                          ushort* __restrict__ msgbf,
                                          float* __restrict__ p_src, float* __restrict__ p_dst) {
  if (blockIdx.x < NBINBLK)
    d_bin(blockIdx.x, src, dst, etype, bucket_cursor, ebuf);
  else
    d_proj(blockIdx.x - NBINBLK, X, Wn, bn, ts_p, WmpPk, bmp0, attn0, msgbf, p_src, p_dst);
}

// ---------------------------------------------------------------- scatter: order bucket by node, emit rdeg + csr
__global__ void __launch_bounds__(256) k_scatter2(const int* __restrict__ bucket_cursor,
                                                  const uint2* __restrict__ ebuf,
                                                  uint* __restrict__ csr,
                                                  uint* __restrict__ csr_eid,
                                                  uint2* __restrict__ rdeg) {
  __shared__ int cnt_l[256];
  __shared__ int curs[256];
  __shared__ int wsum[4], woff[4];
  int b = blockIdx.x;
  int t = threadIdx.x;
  int base = b * SBUCK;
  int cb = bucket_cursor[b];           // edges in this bucket
  cnt_l[t] = 0;
  __syncthreads();
  for (int i = t; i < cb; i += 256)
    atomicAdd(&cnt_l[(ebuf[base + i].x >> 22) & 255], 1);
  __syncthreads();
  int v = cnt_l[t];
  int lane = t & 63, wid = t >> 6;
  int x = v;
#pragma unroll
  for (int off = 1; off < 64; off <<= 1) {
    int y = __shfl_up(x, off, 64);
    if (lane >= off) x += y;
  }
  if (lane == 63) wsum[wid] = x;
  __syncthreads();
  if (t == 0) {
    int a = 0;
    for (int i = 0; i < 4; ++i) { woff[i] = a; a += wsum[i]; }
  }
  __syncthreads();
  int loff = woff[wid] + (x - v);      // exclusive prefix
  int n = (b << 8) + t;
  if (n < NN) rdeg[n] = make_uint2((uint)(base + loff), (uint)v);
  curs[t] = base + loff;
  __syncthreads();
  for (int i = t; i < cb; i += 256) {
    uint2 e = ebuf[base + i];
    int j = (e.x >> 22) & 255;
    int pos = atomicAdd(&curs[j], 1);
    csr[pos] = e.x & 0x3FFFFFu;
    csr_eid[pos] = e.y;
  }
}

// ---------------------------------------------------------------- softmax-aggregate (wave/node)
// FUSE=1: epilogue also computes next-layer msg + p's. FUSE=0: final layer, f32 ht out.
template <int FUSE>
__global__ void __launch_bounds__(256) k_agg(const uint2* __restrict__ rdeg,
                                             const uint* __restrict__ csr,
                                             const float* __restrict__ p_src,
                                             const float* __restrict__ p_dst,
                                             const float* __restrict__ ta_l,
                                             const ushort* __restrict__ msgbf,
                                             float* __restrict__ s_buf,
                                             const ushort* __restrict__ WmpPk_next,
                                             const float* __restrict__ bmp_next,
                                             const float* __restrict__ attn_next,
                                             ushort* __restrict__ msg_out,
                                             float* __restrict__ p_src_out,
                                             float* __restrict__ p_dst_out,
                                             float* __restrict__ ht_out) {
  __shared__ float v_lds[16][64];   // rows 0..3 = block's nodes (4..15 unused)
  int t = threadIdx.x;
  int lane = t & 63, wv = t >> 6;
  int n = blockIdx.x * 4 + wv;      // grid exactly NN/4
  uint2 rd = rdeg[n];
  int start = (int)rd.x;
  int deg = (int)rd.y;
  int end = start + deg;
  float pd = p_dst[n];
  int lq = lane & 7, lg = lane >> 3;
  float acc[8];
#pragma unroll
  for (int u = 0; u < 8; ++u) acc[u] = 0.f;
  float exsum = 0.f;

  if (deg <= 64) {
    bool valid = lane < deg;
    float s = -3.4e38f;
    int sidx = 0;
    if (valid) {
      uint pk = csr[start + lane];
      sidx = (int)(pk & 0xFFFFu);
      int ty = (int)(pk >> 16);
      float v = p_src[sidx] + pd + ta_l[ty];
      s = (v > 0.f) ? v : 0.2f * v;
    }
    float m = s;
#pragma unroll
    for (int off = 32; off >= 1; off >>= 1) m = fmaxf(m, __shfl_xor(m, off, 64));
    float ex = valid ? __expf(s - m) : 0.f;
    exsum = ex;
    for (int it = 0; it < deg; it += 8) {
      int el = it + lg;
      float exk = __shfl(ex, el, 64);
      int sk = __shfl(sidx, el, 64);
      if (el < deg) {
        uint4 mv = *(const uint4*)&msgbf[(size_t)sk * HD + lq * 8];
        acc[0] += exk * bflo(mv.x); acc[1] += exk * bfhi(mv.x);
        acc[2] += exk * bflo(mv.y); acc[3] += exk * bfhi(mv.y);
        acc[4] += exk * bflo(mv.z); acc[5] += exk * bfhi(mv.z);
        acc[6] += exk * bflo(mv.w); acc[7] += exk * bfhi(mv.w);
      }
    }
  } else {
    float m = -3.4e38f;
    for (int base = start; base < end; base += 64) {
      int i = base + lane;
      float s = -3.4e38f;
      if (i < end) {
        uint pk = csr[i];
        int sidx = (int)(pk & 0xFFFFu);
        int ty = (int)(pk >> 16);
        float v = p_src[sidx] + pd + ta_l[ty];
        s = (v > 0.f) ? v : 0.2f * v;
        s_buf[i] = s;
      }
      m = fmaxf(m, s);
    }
#pragma unroll
    for (int off = 32; off >= 1; off >>= 1) m = fmaxf(m, __shfl_xor(m, off, 64));
    for (int base = start; base < end; base += 64) {
      int i = base + lane;
      if (i < end) {
        float ex = __expf(s_buf[i] - m);
        s_buf[i] = ex;
        exsum += ex;
      }
    }
    for (int it = start; it < end; it += 8) {
      int el = it + lg;
      if (el < end) {
        float exk = s_buf[el];
        int sk = (int)(csr[el] & 0xFFFFu);
        uint4 mv = *(const uint4*)&msgbf[(size_t)sk * HD + lq * 8];
        acc[0] += exk * bflo(mv.x); acc[1] += exk * bfhi(mv.x);
        acc[2] += exk * bflo(mv.y); acc[3] += exk * bfhi(mv.y);
        acc[4] += exk * bflo(mv.z); acc[5] += exk * bfhi(mv.z);
        acc[6] += exk * bflo(mv.w); acc[7] += exk * bfhi(mv.w);
      }
    }
  }
#pragma unroll
  for (int u = 0; u < 8; ++u) {
    acc[u] += __shfl_xor(acc[u], 8, 64);
    acc[u] += __shfl_xor(acc[u], 16, 64);
    acc[u] += __shfl_xor(acc[u], 32, 64);
  }
#pragma unroll
  for (int off = 32; off >= 1; off >>= 1) exsum += __shfl_xor(exsum, off, 64);
  float inv = 1.f / (exsum + 1e-15f);
  float ss = 0.f;
#pragma unroll
  for (int u = 0; u < 8; ++u) {
    float v = fmaxf(acc[u] * inv, 0.f);
    acc[u] = v;
    ss += v * v;
  }
  ss += __shfl_xor(ss, 1, 64);
  ss += __shfl_xor(ss, 2, 64);
  ss += __shfl_xor(ss, 4, 64);
  float nu = fmaxf(sqrtf(ss), 1e-15f);
  float sc = fminf(nu, LCLAMP) / nu;

  if constexpr (FUSE == 0) {
    if (lane < 8) {
      *(float4*)&ht_out[(size_t)n * HD + lane * 8] =
          make_float4(acc[0] * sc, acc[1] * sc, acc[2] * sc, acc[3] * sc);
      *(float4*)&ht_out[(size_t)n * HD + lane * 8 + 4] =
          make_float4(acc[4] * sc, acc[5] * sc, acc[6] * sc, acc[7] * sc);
    }
  } else {
    // next-layer p from bf16-rounded ht (element index = lq*8+u)
    float hb[8];
#pragma unroll
    for (int u = 0; u < 8; ++u) hb[u] = bf2f((short)f2bf(acc[u] * sc));
    float4 a1a = *(const float4*)&attn_next[lq * 8];
    float4 a1b = *(const float4*)&attn_next[lq * 8 + 4];
    float4 a2a = *(const float4*)&attn_next[64 + lq * 8];
    float4 a2b = *(const float4*)&attn_next[64 + lq * 8 + 4];
    float p1 = hb[0]*a1a.x + hb[1]*a1a.y + hb[2]*a1a.z + hb[3]*a1a.w
             + hb[4]*a1b.x + hb[5]*a1b.y + hb[6]*a1b.z + hb[7]*a1b.w;
    float p2 = hb[0]*a2a.x + hb[1]*a2a.y + hb[2]*a2a.z + hb[3]*a2a.w
             + hb[4]*a2b.x + hb[5]*a2b.y + hb[6]*a2b.z + hb[7]*a2b.w;
    p1 += __shfl_xor(p1, 1, 64); p1 += __shfl_xor(p1, 2, 64); p1 += __shfl_xor(p1, 4, 64);
    p2 += __shfl_xor(p2, 1, 64); p2 += __shfl_xor(p2, 2, 64); p2 += __shfl_xor(p2, 4, 64);
    if (lane == 0) { p_src_out[n] = p1; p_dst_out[n] = p2; }
    if (lane < 8) {
      *(float4*)&v_lds[wv][lane * 8] =
          make_float4(acc[0] * sc, acc[1] * sc, acc[2] * sc, acc[3] * sc);
      *(float4*)&v_lds[wv][lane * 8 + 4] =
          make_float4(acc[4] * sc, acc[5] * sc, acc[6] * sc, acc[7] * sc);
    }
    __syncthreads();
    // msg = ht @ Wmp_next + bmp_next; wave wv computes cols wv*16..+15
    int lane15 = lane & 15, quad = lane >> 4;
    bf16x8 A0 = frag_f32(&v_lds[lane15][quad * 8]);
    bf16x8 A1 = frag_f32(&v_lds[lane15][32 + quad * 8]);
    bf16x8 B0 = *(const bf16x8*)&WmpPk_next[(wv * 2 + 0) * 512 + lane * 8];
    bf16x8 B1 = *(const bf16x8*)&WmpPk_next[(wv * 2 + 1) * 512 + lane * 8];
    f32x4 z = {0.f, 0.f, 0.f, 0.f};
    z = __builtin_amdgcn_mfma_f32_16x16x32_bf16(A0, B0, z, 0, 0, 0);
    z = __builtin_amdgcn_mfma_f32_16x16x32_bf16(A1, B1, z, 0, 0, 0);
    float vbm = bmp_next[wv * 16 + lane15];
    if (quad == 0) {
      int nb = blockIdx.x * 4;
#pragma unroll
      for (int i = 0; i < 4; ++i)
        msg_out[(size_t)(nb + i) * HD + wv * 16 + lane15] = f2bf(z[i] + vbm);
    }
  }
}

// ---------------------------------------------------------------- heads (MFMA)
__global__ void __launch_bounds__(256) k_score(const float* __restrict__ ht,
                                               const float* __restrict__ Wns1,
                                               const float* __restrict__ qb,
                                               const float* __restrict__ Wns2,
                                               const float* __restrict__ bns2,
                                               const float* __restrict__ Wes1,
                                               float* __restrict__ node_scores,
                                               float* __restrict__ h_out,
                                               ushort* __restrict__ Asrc,
                                               ushort* __restrict__ Adst) {
  int t = threadIdx.x;
  int lane = t & 63, wv = t >> 6;
  int lane15 = lane & 15, quad = lane >> 4;
  int n0 = blockIdx.x * 64;
  int m0 = n0 + wv * 16;
  int row = m0 + lane15;
  int rowc = row < NN ? row : NN - 1;
  bf16x8 A0 = frag_f32(ht + (size_t)rowc * HD + quad * 8);
  bf16x8 A1 = frag_f32(ht + (size_t)rowc * HD + 32 + quad * 8);

  // node head
  {
    f32x4 acc[4];
#pragma unroll
    for (int jt = 0; jt < 4; ++jt) {
      bf16x8 b0 = bfrag_w(Wns1, 0, jt * 16, lane15, quad);
      bf16x8 b1 = bfrag_w(Wns1, 32, jt * 16, lane15, quad);
      f32x4 z = {0.f, 0.f, 0.f, 0.f};
      z = __builtin_amdgcn_mfma_f32_16x16x32_bf16(A0, b0, z, 0, 0, 0);
      z = __builtin_amdgcn_mfma_f32_16x16x32_bf16(A1, b1, z, 0, 0, 0);
      acc[jt] = z;
    }
    float vqb[4], vw2[4];
#pragma unroll
    for (int jt = 0; jt < 4; ++jt) { vqb[jt] = qb[jt * 16 + lane15]; vw2[jt] = Wns2[jt * 16 + lane15]; }
    float b2 = bns2[0];
#pragma unroll
    for (int i = 0; i < 4; ++i) {
      float si = 0.f;
#pragma unroll
      for (int jt = 0; jt < 4; ++jt) si += fmaxf(acc[jt][i] + vqb[jt], 0.f) * vw2[jt];
      si += __shfl_xor(si, 1, 64);
      si += __shfl_xor(si, 2, 64);
      si += __shfl_xor(si, 4, 64);
      si += __shfl_xor(si, 8, 64);
      int r = m0 + quad * 4 + i;
      if (lane15 == 0 && r < NN) node_scores[r] = 1.f / (1.f + __expf(-(si + b2)));
    }
  }
  // Asrc
  {
#pragma unroll
    for (int jt = 0; jt < 4; ++jt) {
      bf16x8 b0 = bfrag_w(Wes1, 0, jt * 16, lane15, quad);
      bf16x8 b1 = bfrag_w(Wes1, 32, jt * 16, lane15, quad);
      f32x4 z = {0.f, 0.f, 0.f, 0.f};
      z = __builtin_amdgcn_mfma_f32_16x16x32_bf16(A0, b0, z, 0, 0, 0);
      z = __builtin_amdgcn_mfma_f32_16x16x32_bf16(A1, b1, z, 0, 0, 0);
#pragma unroll
      for (int i = 0; i < 4; ++i) {
        int r = m0 + quad * 4 + i;
        if (r < NN) Asrc[(size_t)r * HD + jt * 16 + lane15] = f2bf(z[i]);
      }
    }
  }
  // Adst
  {
    const float* W = Wes1 + 64 * HD;
#pragma unroll
    for (int jt = 0; jt < 4; ++jt) {
      bf16x8 b0 = bfrag_w(W, 0, jt * 16, lane15, quad);
      bf16x8 b1 = bfrag_w(W, 32, jt * 16, lane15, quad);
      f32x4 z = {0.f, 0.f, 0.f, 0.f};
      z = __builtin_amdgcn_mfma_f32_16x16x32_bf16(A0, b0, z, 0, 0, 0);
      z = __builtin_amdgcn_mfma_f32_16x16x32_bf16(A1, b1, z, 0, 0, 0);
#pragma unroll
      for (int i = 0; i < 4; ++i) {
        int r = m0 + quad * 4 + i;
        if (r < NN) Adst[(size_t)r * HD + jt * 16 + lane15] = f2bf(z[i]);
      }
    }
  }
  // h_out: exact f32 pass
  {
    int r = t >> 2, p = t & 3;
    int gr = n0 + r;
    int grc = gr < NN ? gr : NN - 1;
    const float* rp = ht + (size_t)grc * HD + p * 16;
    float4 v0 = *(const float4*)(rp + 0);
    float4 v1 = *(const float4*)(rp + 4);
    float4 v2 = *(const float4*)(rp + 8);
    float4 v3 = *(const float4*)(rp + 12);
    float ssq = v0.x*v0.x + v0.y*v0.y + v0.z*v0.z + v0.w*v0.w
              + v1.x*v1.x + v1.y*v1.y + v1.z*v1.z + v1.w*v1.w
              + v2.x*v2.x + v2.y*v2.y + v2.z*v2.z + v2.w*v2.w
              + v3.x*v3.x + v3.y*v3.y + v3.z*v3.z + v3.w*v3.w;
    ssq += __shfl_xor(ssq, 1, 64);
    ssq += __shfl_xor(ssq, 2, 64);
    float nu = fmaxf(sqrtf(ssq), 1e-15f);
    float hs = tanhf(nu) / nu;
    if (gr < NN) {
      float* op = h_out + (size_t)gr * HD + p * 16;
      *(float4*)(op + 0)  = make_float4(v0.x*hs, v0.y*hs, v0.z*hs, v0.w*hs);
      *(float4*)(op + 4)  = make_float4(v1.x*hs, v1.y*hs, v1.z*hs, v1.w*hs);
      *(float4*)(op + 8)  = make_float4(v2.x*hs, v2.y*hs, v2.z*hs, v2.w*hs);
      *(float4*)(op + 12) = make_float4(v3.x*hs, v3.y*hs, v3.z*hs, v3.w*hs);
    }
  }
}

// ---------------------------------------------------------------- edge scores (CSR order)
__global__ void __launch_bounds__(256) k_edge(const uint2* __restrict__ rdeg,
                                              const uint* __restrict__ csr,
                                              const uint* __restrict__ csr_eid,
                                              const ushort* __restrict__ Asrc,
                                              const ushort* __restrict__ Adst,
                                              const ushort* __restrict__ Te2bf,
                                              const float* __restrict__ Wes2,
                                              const float* __restrict__ bes2,
                                              float* __restrict__ edge_scores) {
  int t = threadIdx.x;
  int lane = t & 63;
  int n = (blockIdx.x * 256 + t) >> 6;
  if (n >= NN) return;
  int lq = lane & 7, lg = lane >> 3;
  uint2 rd = rdeg[n];
  int start = (int)rd.x;
  int deg = (int)rd.y;
  if (deg == 0) return;
  int end = start + deg;
  uint4 bv = *(const uint4*)&Adst[(size_t)n * HD + lq * 8];
  const float* wp = &Wes2[lq * 8];
  float4 w0 = *(const float4*)wp;
  float4 w1 = *(const float4*)(wp + 4);
  float b2 = bes2[0];
  for (int it = start; it < end; it += 8) {
    int e = it + lg;
    bool valid = e < end;
    float p = 0.f;
    if (valid) {
      uint pk = csr[e];
      int si = (int)(pk & 0xFFFFu);
      int ty = (int)((pk >> 16) & 0x3Fu);
      uint4 av = *(const uint4*)&Asrc[(size_t)si * HD + lq * 8];
      uint4 tv = *(const uint4*)&Te2bf[ty * HD + lq * 8];
      p += fmaxf(bflo(av.x) + bflo(bv.x) + bflo(tv.x), 0.f) * w0.x;
      p += fmaxf(bfhi(av.x) + bfhi(bv.x) + bfhi(tv.x), 0.f) * w0.y;
      p += fmaxf(bflo(av.y) + bflo(bv.y) + bflo(tv.y), 0.f) * w0.z;
      p += fmaxf(bfhi(av.y) + bfhi(bv.y) + bfhi(tv.y), 0.f) * w0.w;
      p += fmaxf(bflo(av.z) + bflo(bv.z) + bflo(tv.z), 0.f) * w1.x;
      p += fmaxf(bfhi(av.z) + bfhi(bv.z) + bfhi(tv.z), 0.f) * w1.y;
      p += fmaxf(bflo(av.w) + bflo(bv.w) + bflo(tv.w), 0.f) * w1.z;
      p += fmaxf(bfhi(av.w) + bfhi(bv.w) + bfhi(tv.w), 0.f) * w1.w;
    }
    p += __shfl_xor(p, 1, 64);
    p += __shfl_xor(p, 2, 64);
    p += __shfl_xor(p, 4, 64);
    if (valid && lq == 0) edge_scores[csr_eid[e]] = 1.f / (1.f + __expf(-(p + b2)));
  }
}

// ---------------------------------------------------------------- launch
extern "C" void kernel_launch(void* const* d_in, const int* in_sizes, int n_in,
                              void* d_out, int out_size, void* d_ws, size_t ws_size,
                              hipStream_t stream) {
  const float* node_features = (const float*)d_in[0];
  const float* edge_desc = (const float*)d_in[1];
  const float* query = (const float*)d_in[2];
  const float* Wn = (const float*)d_in[3];
  const float* bn = (const float*)d_in[4];
  const float* ts = (const float*)d_in[5];
  const float* Wq = (const float*)d_in[6];
  const float* bq = (const float*)d_in[7];
  const float* Ws_ = (const float*)d_in[8];
  const float* bs = (const float*)d_in[9];
  const float* attn_a = (const float*)d_in[10];
  const float* Wmp = (const float*)d_in[11];
  const float* bmp = (const float*)d_in[12];
  const float* Wns1 = (const float*)d_in[13];
  const float* bns1 = (const float*)d_in[14];
  const float* Wns2 = (const float*)d_in[15];
  const float* bns2 = (const float*)d_in[16];
  const float* Wes1 = (const float*)d_in[17];
  const float* bes1 = (const float*)d_in[18];
  const float* Wes2 = (const float*)d_in[19];
  const float* bes2 = (const float*)d_in[20];
  const int* edge_index = (const int*)d_in[21];
  const int* etype = (const int*)d_in[22];
  const int* src = edge_index;
  const int* dst = edge_index + NE;

  float* out_ns = (float*)d_out;
  float* out_es = out_ns + NN;
  float* out_h = out_es + NE;
  float* out_te = out_h + (size_t)NN * HD;

  char* w = (char*)d_ws;
  auto alloc = [&](size_t bytes) {
    char* p = w;
    w += (bytes + 1023) & ~(size_t)1023;
    return p;
  };
  float* ht_f = (float*)alloc((size_t)NN * HD * 4);        // final-layer f32 ht
  ushort* msg0 = (ushort*)alloc((size_t)NN * HD * 2);      // msg ping
  ushort* msg1 = (ushort*)alloc((size_t)NN * HD * 2);      // msg pong
  ushort* Asrc = (ushort*)alloc((size_t)NN * HD * 2);      // } adjacent: ebuf alias spans both
  ushort* Adst = (ushort*)alloc((size_t)NN * HD * 2);      // }
  float* pA = (float*)alloc(NN * 4);
  float* pdA = (float*)alloc(NN * 4);
  float* pB = (float*)alloc(NN * 4);
  float* pdB = (float*)alloc(NN * 4);
  float* s_buf = (float*)alloc((size_t)NPAD * 4);
  float* qb = (float*)alloc(HD * 4);
  float* ta3 = (float*)alloc(NLAY * NTT * 4);
  ushort* Te2bf = (ushort*)alloc(NTT * HD * 2);
  ushort* WmpPk = (ushort*)alloc(NLAY * 4096 * 2);
  int* bucket_cursor = (int*)alloc(NBUCK * 4);
  uint2* rdeg = (uint2*)alloc((size_t)NN * 8);
  uint* csr = (uint*)alloc((size_t)NPAD * 4);
  uint* csr_eid = (uint*)alloc((size_t)NPAD * 4);
  // ebuf (NPAD x 8B = 9.6 MB) aliases Asrc+Adst (12.8 MB contiguous): CSR build
  // finishes (k_scatter2) before k_score writes Asrc/Adst. No overlap in stream order.
  uint2* ebuf = (uint2*)Asrc;

  hipMemsetAsync(bucket_cursor, 0, NBUCK * 4, stream);
  // setup: te, q-projections, ta3, WmpPk pack, Te2bf (1 block)
  kA<<<1, 256, 0, stream>>>(edge_desc, query, Wq, bq, Ws_, bs, attn_a,
                            Wns1, bns1, Wes1, bes1, Wmp, out_te, qb, ta3, Te2bf, WmpPk);
  // bin (196) + proj w/ fused layer-0 msg (782), co-scheduled
  kE<<<NBINBLK + (NN + 63) / 64, 256, 0, stream>>>(src, dst, etype, bucket_cursor, ebuf,
                                                   node_features, Wn, bn, ts, WmpPk,
                                                   bmp, attn_a, msg0, pA, pdA);
  // order within bucket by node; emit rdeg + csr/csr_eid
  k_scatter2<<<NBUCK, 256, 0, stream>>>(bucket_cursor, ebuf, csr, csr_eid, rdeg);

  const int AGG_GRID = NN / 4;   // NN % 4 == 0
  // layer 0: gather msg0, emit msg1 = ht1 @ Wmp1 and p's for layer 1
  k_agg<1><<<AGG_GRID, 256, 0, stream>>>(rdeg, csr, pA, pdA, ta3 + 0 * NTT, msg0, s_buf,
                                         WmpPk + 1 * 4096, bmp + 1 * HD,
                                         attn_a + 1 * (2 * HD + TDD),
                                         msg1, pB, pdB, nullptr);
  // layer 1: gather msg1, emit msg0 = ht2 @ Wmp2 and p's for layer 2
  k_agg<1><<<AGG_GRID, 256, 0, stream>>>(rdeg, csr, pB, pdB, ta3 + 1 * NTT, msg1, s_buf,
                                         WmpPk + 2 * 4096, bmp + 2 * HD,
                                         attn_a + 2 * (2 * HD + TDD),
                                         msg0, pA, pdA, nullptr);
  // layer 2: gather msg0, write final f32 ht
  k_agg<0><<<AGG_GRID, 256, 0, stream>>>(rdeg, csr, pA, pdA, ta3 + 2 * NTT, msg0, s_buf,
                                         nullptr, nullptr, nullptr,
                                         nullptr, nullptr, nullptr, ht_f);

  k_score<<<(NN + 63) / 64, 256, 0, stream>>>(ht_f, Wns1, qb, Wns2, bns2, Wes1,
                                              out_ns, out_h, Asrc, Adst);
  k_edge<<<(NN + 3) / 4, 256, 0, stream>>>(rdeg, csr, csr_eid, Asrc, Adst, Te2bf,
                                           Wes2, bes2, out_es);
}

// Round 4
// 322.259 us; speedup vs baseline: 1.2316x; 1.1125x over previous
//
#include <hip/hip_runtime.h>
#include <math.h>

#define NN 50000
#define NE 800000
#define NFD 256
#define HD 64
#define QDD 128
#define TDD 32
#define NTT 64
#define NLAY 3
#define LCLAMP 6.1030340f   // atanh(1 - 1e-5)
#define NBUCK 196           // ceil(50000/256) coarse buckets (dst >> 8)
#define SBUCK 6144          // padded slots per bucket (expected 4096, sigma ~64)
#define NPAD (NBUCK * SBUCK)
#define EPB 4096            // edges per bin block
#define NBINBLK 196         // ceil(800000/4096)
#define PST 72              // proj LDS tile stride

typedef unsigned int uint;
typedef unsigned short ushort;
typedef __attribute__((ext_vector_type(8))) short bf16x8;
typedef __attribute__((ext_vector_type(4))) float f32x4;

__device__ __forceinline__ ushort f2bf(float f) {
  uint u = __float_as_uint(f);
  uint r = (u + 0x7FFFu + ((u >> 16) & 1u)) >> 16;
  return (ushort)r;
}
__device__ __forceinline__ short f2bfs(float f) { return (short)f2bf(f); }
__device__ __forceinline__ float bf2f(short s) { return __uint_as_float(((uint)(ushort)s) << 16); }
__device__ __forceinline__ float bflo(uint w) { return __uint_as_float(w << 16); }
__device__ __forceinline__ float bfhi(uint w) { return __uint_as_float(w & 0xFFFF0000u); }

// A-frag from 8 consecutive f32
__device__ __forceinline__ bf16x8 frag_f32(const float* p) {
  float4 a = *(const float4*)p;
  float4 b = *(const float4*)(p + 4);
  bf16x8 r;
  r[0] = f2bfs(a.x); r[1] = f2bfs(a.y); r[2] = f2bfs(a.z); r[3] = f2bfs(a.w);
  r[4] = f2bfs(b.x); r[5] = f2bfs(b.y); r[6] = f2bfs(b.z); r[7] = f2bfs(b.w);
  return r;
}
// B-frag from row-major W[K][64]: k=k0+quad*8+j, n=j0+lane15
__device__ __forceinline__ bf16x8 bfrag_w(const float* W, int k0, int j0, int lane15, int quad) {
  bf16x8 r;
#pragma unroll
  for (int j = 0; j < 8; ++j) r[j] = f2bfs(W[(k0 + quad * 8 + j) * HD + j0 + lane15]);
  return r;
}

// ---------------------------------------------------------------- setup (1 block): te, q-projs, ta3, WmpPk, Te2bf
__global__ void __launch_bounds__(256) kA(const float* __restrict__ edge_desc, const float* __restrict__ query,
                                          const float* __restrict__ Wq, const float* __restrict__ bq,
                                          const float* __restrict__ Ws, const float* __restrict__ bs,
                                          const float* __restrict__ attn_a,
                                          const float* __restrict__ Wns1, const float* __restrict__ bns1,
                                          const float* __restrict__ Wes1, const float* __restrict__ bes1,
                                          const float* __restrict__ Wmp,
                                          float* __restrict__ out_type_emb,
                                          float* __restrict__ qb, float* __restrict__ ta3,
                                          ushort* __restrict__ Te2bf, ushort* __restrict__ WmpPk) {
  __shared__ float te_l[NTT * TDD];
  __shared__ float q_l[HD];
  __shared__ float qe_l[HD];
  int t = threadIdx.x;
  if (t < HD) {
    float acc = bq[t];
    for (int k = 0; k < QDD; ++k) acc += query[k] * Wq[k * HD + t];
    q_l[t] = acc;
  }
  for (int idx = t; idx < NTT * TDD; idx += 256) {
    int ty = idx / TDD, d = idx % TDD;
    float acc = bs[d];
    for (int k = 0; k < 64; ++k) acc += edge_desc[ty * 64 + k] * Ws[k * TDD + d];
    float v = tanhf(acc);
    te_l[idx] = v;
    out_type_emb[idx] = v;
  }
  __syncthreads();
  if (t < NLAY * NTT) {
    int l = t / NTT, ty = t % NTT;
    float acc = 0.f;
    for (int d = 0; d < TDD; ++d) acc += te_l[ty * TDD + d] * attn_a[l * (2 * HD + TDD) + 2 * HD + d];
    ta3[t] = acc;
  }
  if (t < HD) {
    float a1 = bns1[t], a2 = bes1[t];
    for (int k = 0; k < HD; ++k) {
      a1 += q_l[k] * Wns1[(HD + k) * HD + t];
      a2 += q_l[k] * Wes1[(2 * HD + TDD + k) * HD + t];
    }
    qb[t] = a1;
    qe_l[t] = a2;
  }
  // pack Wmp B-frags: WmpPk[(((l*4+jt)*2+f)*64 + lane)*8 + j]
  //   = bf16(Wmp[l][(f*32 + quad*8 + j)][jt*16 + lane15])
  for (int idx = t; idx < NLAY * 4 * 2 * 64 * 8; idx += 256) {
    int j = idx & 7, lane = (idx >> 3) & 63, f = (idx >> 9) & 1, jl = idx >> 10;
    int l = jl >> 2, jt = jl & 3, q = lane >> 4, l15 = lane & 15;
    WmpPk[idx] = f2bf(Wmp[l * HD * HD + (f * 32 + q * 8 + j) * HD + jt * 16 + l15]);
  }
  __syncthreads();
  // Te2bf[ty][j] = bf16(type_emb[ty] @ Wes1[te-part] + qe)
  for (int idx = t; idx < NTT * HD; idx += 256) {
    int ty = idx >> 6, j = idx & 63;
    float acc = qe_l[j];
#pragma unroll
    for (int d = 0; d < TDD; ++d) acc += te_l[ty * TDD + d] * Wes1[(2 * HD + d) * HD + j];
    Te2bf[idx] = f2bf(acc);
  }
}

// ---------------------------------------------------------------- bin (device): append edges to padded bucket regions
// pk: src(16) | type(6)<<16 | (dst&255)<<22
__device__ void d_bin(int bbid,
                      const int* __restrict__ src,
                      const int* __restrict__ dst,
                      const int* __restrict__ etype,
                      int* __restrict__ bucket_cursor,
                      uint2* __restrict__ ebuf) {
  __shared__ int cntl[NBUCK];
  __shared__ int gbase[NBUCK];
  int t = threadIdx.x;
  for (int i = t; i < NBUCK; i += 256) cntl[i] = 0;
  __syncthreads();
  int e0 = bbid * EPB;
  int dd[16];
  uint pk[16];
  int rk[16];
#pragma unroll
  for (int c = 0; c < 4; ++c) {
    int eb = e0 + c * 1024 + t * 4;
    if (eb < NE) {   // NE%4==0 => eb<NE implies eb+3<NE
      int4 s4 = *(const int4*)&src[eb];
      int4 d4 = *(const int4*)&dst[eb];
      int4 y4 = *(const int4*)&etype[eb];
      int ds[4] = {d4.x, d4.y, d4.z, d4.w};
      int ss[4] = {s4.x, s4.y, s4.z, s4.w};
      int ys[4] = {y4.x, y4.y, y4.z, y4.w};
#pragma unroll
      for (int j = 0; j < 4; ++j) {
        int idx = c * 4 + j;
        int d = ds[j];
        dd[idx] = d;
        pk[idx] = (uint)ss[j] | ((uint)ys[j] << 16) | ((uint)(d & 255) << 22);
        rk[idx] = atomicAdd(&cntl[d >> 8], 1);
      }
    } else {
#pragma unroll
      for (int j = 0; j < 4; ++j) dd[c * 4 + j] = -1;
    }
  }
  __syncthreads();
  if (t < NBUCK && cntl[t] > 0)
    gbase[t] = t * SBUCK + atomicAdd(&bucket_cursor[t], cntl[t]);
  __syncthreads();
#pragma unroll
  for (int i = 0; i < 16; ++i) {
    if (dd[i] >= 0) {
      uint eid = (uint)(e0 + ((i >> 2) << 10) + t * 4 + (i & 3));
      ebuf[gbase[dd[i] >> 8] + rk[i]] = make_uint2(pk[i], eid);
    }
  }
}

// ---------------------------------------------------------------- proj (device) + fused layer-0 msg
__device__ void d_proj(int pbid,
                       const float* __restrict__ X,
                       const float* __restrict__ Wn,
                       const float* __restrict__ bn,
                       const float* __restrict__ ts_p,
                       const ushort* __restrict__ WmpPk,   // layer-0 frags at offset 0
                       const float* __restrict__ bmp0,
                       const float* __restrict__ attn0,
                       ushort* __restrict__ msgbf,
                       float* __restrict__ p_src,
                       float* __restrict__ p_dst) {
  __shared__ ushort buf[2][64 * PST];            // 2 x 9216 B
  float* st = (float*)&buf[0][0];                // epilogue alias: 64 x 72 f32
  int t = threadIdx.x;
  int lane = t & 63, wv = t >> 6;
  int lane15 = lane & 15, quad = lane >> 4;
  int n0 = pbid * 64;
  int j0 = wv * 16;
  bf16x8 B[8];
#pragma unroll
  for (int fb = 0; fb < 8; ++fb) B[fb] = bfrag_w(Wn, fb * 32, j0, lane15, quad);

  int srow = t >> 2;
  int scg = (t & 3) * 16;
  int grow = n0 + srow; if (grow >= NN) grow = NN - 1;
  const float* xrow = X + (size_t)grow * NFD + scg;

  f32x4 acc[4];
#pragma unroll
  for (int mt = 0; mt < 4; ++mt) acc[mt] = (f32x4){0.f, 0.f, 0.f, 0.f};

  float4 r0 = *(const float4*)(xrow + 0);
  float4 r1 = *(const float4*)(xrow + 4);
  float4 r2 = *(const float4*)(xrow + 8);
  float4 r3 = *(const float4*)(xrow + 12);

  for (int c = 0; c < 4; ++c) {
    ushort* wp = &buf[c & 1][srow * PST + scg];
    uint4 o0, o1;
    o0.x = (uint)f2bf(r0.x) | ((uint)f2bf(r0.y) << 16);
    o0.y = (uint)f2bf(r0.z) | ((uint)f2bf(r0.w) << 16);
    o0.z = (uint)f2bf(r1.x) | ((uint)f2bf(r1.y) << 16);
    o0.w = (uint)f2bf(r1.z) | ((uint)f2bf(r1.w) << 16);
    o1.x = (uint)f2bf(r2.x) | ((uint)f2bf(r2.y) << 16);
    o1.y = (uint)f2bf(r2.z) | ((uint)f2bf(r2.w) << 16);
    o1.z = (uint)f2bf(r3.x) | ((uint)f2bf(r3.y) << 16);
    o1.w = (uint)f2bf(r3.z) | ((uint)f2bf(r3.w) << 16);
    *(uint4*)wp = o0;
    *(uint4*)(wp + 8) = o1;
    if (c < 3) {
      const float* nx = xrow + (c + 1) * 64;
      r0 = *(const float4*)(nx + 0);
      r1 = *(const float4*)(nx + 4);
      r2 = *(const float4*)(nx + 8);
      r3 = *(const float4*)(nx + 12);
    }
    __syncthreads();
    const ushort* bp = &buf[c & 1][0];
#pragma unroll
    for (int mt = 0; mt < 4; ++mt) {
#pragma unroll
      for (int ks = 0; ks < 2; ++ks) {
        bf16x8 A = *(const bf16x8*)&bp[(mt * 16 + lane15) * PST + ks * 32 + quad * 8];
        acc[mt] = __builtin_amdgcn_mfma_f32_16x16x32_bf16(A, B[c * 2 + ks], acc[mt], 0, 0, 0);
      }
    }
  }
  __syncthreads();
  float ts = ts_p[0];
  float vb = bn[j0 + lane15];
#pragma unroll
  for (int mt = 0; mt < 4; ++mt)
#pragma unroll
    for (int i = 0; i < 4; ++i)
      st[(mt * 16 + quad * 4 + i) * PST + j0 + lane15] = (acc[mt][i] + vb) * ts;
  __syncthreads();
  {
    int r = t >> 2, p = t & 3;
    float* rp = &st[r * PST + p * 16];
    float4 v0 = *(const float4*)(rp + 0);
    float4 v1 = *(const float4*)(rp + 4);
    float4 v2 = *(const float4*)(rp + 8);
    float4 v3 = *(const float4*)(rp + 12);
    float ssq = v0.x*v0.x + v0.y*v0.y + v0.z*v0.z + v0.w*v0.w
              + v1.x*v1.x + v1.y*v1.y + v1.z*v1.z + v1.w*v1.w
              + v2.x*v2.x + v2.y*v2.y + v2.z*v2.z + v2.w*v2.w
              + v3.x*v3.x + v3.y*v3.y + v3.z*v3.z + v3.w*v3.w;
    ssq += __shfl_xor(ssq, 1, 64);
    ssq += __shfl_xor(ssq, 2, 64);
    float nu = fmaxf(sqrtf(ssq), 1e-15f);
    float sc = fminf(nu, LCLAMP) / nu;
    *(float4*)(rp + 0) = make_float4(v0.x*sc, v0.y*sc, v0.z*sc, v0.w*sc);
    *(float4*)(rp + 4) = make_float4(v1.x*sc, v1.y*sc, v1.z*sc, v1.w*sc);
    *(float4*)(rp + 8) = make_float4(v2.x*sc, v2.y*sc, v2.z*sc, v2.w*sc);
    *(float4*)(rp + 12) = make_float4(v3.x*sc, v3.y*sc, v3.z*sc, v3.w*sc);
  }
  __syncthreads();
  // fused layer-0 msg
  {
    bf16x8 Bm0[4], Bm1[4];
    float vbm[4];
#pragma unroll
    for (int jt = 0; jt < 4; ++jt) {
      Bm0[jt] = *(const bf16x8*)&WmpPk[((jt * 2 + 0) * 64 + lane) * 8];
      Bm1[jt] = *(const bf16x8*)&WmpPk[((jt * 2 + 1) * 64 + lane) * 8];
      vbm[jt] = bmp0[jt * 16 + lane15];
    }
    int mrow = wv * 16 + lane15;
    bf16x8 A0 = frag_f32(&st[mrow * PST + quad * 8]);
    bf16x8 A1 = frag_f32(&st[mrow * PST + 32 + quad * 8]);
#pragma unroll
    for (int jt = 0; jt < 4; ++jt) {
      f32x4 z = {0.f, 0.f, 0.f, 0.f};
      z = __builtin_amdgcn_mfma_f32_16x16x32_bf16(A0, Bm0[jt], z, 0, 0, 0);
      z = __builtin_amdgcn_mfma_f32_16x16x32_bf16(A1, Bm1[jt], z, 0, 0, 0);
#pragma unroll
      for (int i = 0; i < 4; ++i) {
        int r = n0 + wv * 16 + quad * 4 + i;
        if (r < NN) msgbf[(size_t)r * HD + jt * 16 + lane15] = f2bf(z[i] + vbm[jt]);
      }
    }
    float4 a1l = *(const float4*)&attn0[quad * 8];
    float4 a1h = *(const float4*)&attn0[quad * 8 + 4];
    float4 a1l2 = *(const float4*)&attn0[32 + quad * 8];
    float4 a1h2 = *(const float4*)&attn0[32 + quad * 8 + 4];
    float4 a2l = *(const float4*)&attn0[64 + quad * 8];
    float4 a2h = *(const float4*)&attn0[64 + quad * 8 + 4];
    float4 a2l2 = *(const float4*)&attn0[96 + quad * 8];
    float4 a2h2 = *(const float4*)&attn0[96 + quad * 8 + 4];
    float p1 = bf2f(A0[0])*a1l.x + bf2f(A0[1])*a1l.y + bf2f(A0[2])*a1l.z + bf2f(A0[3])*a1l.w
             + bf2f(A0[4])*a1h.x + bf2f(A0[5])*a1h.y + bf2f(A0[6])*a1h.z + bf2f(A0[7])*a1h.w
             + bf2f(A1[0])*a1l2.x + bf2f(A1[1])*a1l2.y + bf2f(A1[2])*a1l2.z + bf2f(A1[3])*a1l2.w
             + bf2f(A1[4])*a1h2.x + bf2f(A1[5])*a1h2.y + bf2f(A1[6])*a1h2.z + bf2f(A1[7])*a1h2.w;
    float p2 = bf2f(A0[0])*a2l.x + bf2f(A0[1])*a2l.y + bf2f(A0[2])*a2l.z + bf2f(A0[3])*a2l.w
             + bf2f(A0[4])*a2h.x + bf2f(A0[5])*a2h.y + bf2f(A0[6])*a2h.z + bf2f(A0[7])*a2h.w
             + bf2f(A1[0])*a2l2.x + bf2f(A1[1])*a2l2.y + bf2f(A1[2])*a2l2.z + bf2f(A1[3])*a2l2.w
             + bf2f(A1[4])*a2h2.x + bf2f(A1[5])*a2h2.y + bf2f(A1[6])*a2h2.z + bf2f(A1[7])*a2h2.w;
    p1 += __shfl_xor(p1, 16, 64); p1 += __shfl_xor(p1, 32, 64);
    p2 += __shfl_xor(p2, 16, 64); p2 += __shfl_xor(p2, 32, 64);
    int prow = n0 + mrow;
    if (quad == 0 && prow < NN) { p_src[prow] = p1; p_dst[prow] = p2; }
  }
}

// kE: blocks 0..195 = bin, rest = proj (independent work, co-scheduled)
__global__ void __launch_bounds__(256) kE(const int* __restrict__ src, const int* __restrict__ dst,
                                          const int* __restrict__ etype, int* __restrict__ bucket_cursor,
                                          uint2* __restrict__ ebuf,
                                          const float* __restrict__ X, const float* __restrict__ Wn,
                                          const float* __restrict__ bn, const float* __restrict__ ts_p,
                                          const ushort* __restrict__ WmpPk, const float* __restrict__ bmp0,
                                          const float* __restrict__ attn0,
                                          ushort* __restrict__ msgbf,
                                          float* __restrict__ p_src, float* __restrict__ p_dst) {
  if (blockIdx.x < NBINBLK)
    d_bin(blockIdx.x, src, dst, etype, bucket_cursor, ebuf);
  else
    d_proj(blockIdx.x - NBINBLK, X, Wn, bn, ts_p, WmpPk, bmp0, attn0, msgbf, p_src, p_dst);
}

// ---------------------------------------------------------------- scatter: order bucket by node, emit rdeg + csr
__global__ void __launch_bounds__(256) k_scatter2(const int* __restrict__ bucket_cursor,
                                                  const uint2* __restrict__ ebuf,
                                                  uint* __restrict__ csr,
                                                  uint* __restrict__ csr_eid,
                                                  uint2* __restrict__ rdeg) {
  __shared__ int cnt_l[256];
  __shared__ int curs[256];
  __shared__ int wsum[4], woff[4];
  int b = blockIdx.x;
  int t = threadIdx.x;
  int base = b * SBUCK;
  int cb = bucket_cursor[b];           // edges in this bucket
  cnt_l[t] = 0;
  __syncthreads();
  for (int i = t; i < cb; i += 256)
    atomicAdd(&cnt_l[(ebuf[base + i].x >> 22) & 255], 1);
  __syncthreads();
  int v = cnt_l[t];
  int lane = t & 63, wid = t >> 6;
  int x = v;
#pragma unroll
  for (int off = 1; off < 64; off <<= 1) {
    int y = __shfl_up(x, off, 64);
    if (lane >= off) x += y;
  }
  if (lane == 63) wsum[wid] = x;
  __syncthreads();
  if (t == 0) {
    int a = 0;
    for (int i = 0; i < 4; ++i) { woff[i] = a; a += wsum[i]; }
  }
  __syncthreads();
  int loff = woff[wid] + (x - v);      // exclusive prefix
  int n = (b << 8) + t;
  if (n < NN) rdeg[n] = make_uint2((uint)(base + loff), (uint)v);
  curs[t] = base + loff;
  __syncthreads();
  for (int i = t; i < cb; i += 256) {
    uint2 e = ebuf[base + i];
    int j = (e.x >> 22) & 255;
    int pos = atomicAdd(&curs[j], 1);
    csr[pos] = e.x & 0x3FFFFFu;
    csr_eid[pos] = e.y;
  }
}

// ---------------------------------------------------------------- softmax-aggregate (2 nodes/wave, 32 lanes each)
// FUSE=1: epilogue also computes next-layer msg + p's. FUSE=0: final layer, f32 ht out.
template <int FUSE>
__global__ void __launch_bounds__(256) k_agg(const uint2* __restrict__ rdeg,
                                             const uint* __restrict__ csr,
                                             const float* __restrict__ p_src,
                                             const float* __restrict__ p_dst,
                                             const float* __restrict__ ta_l,
                                             const ushort* __restrict__ msgbf,
                                             float* __restrict__ s_buf,
                                             const ushort* __restrict__ WmpPk_next,
                                             const float* __restrict__ bmp_next,
                                             const float* __restrict__ attn_next,
                                             ushort* __restrict__ msg_out,
                                             float* __restrict__ p_src_out,
                                             float* __restrict__ p_dst_out,
                                             float* __restrict__ ht_out) {
  __shared__ float v_lds[16][68];   // +4 pad: b128 reads 2-way max (was 16-way at stride 64)
  __shared__ float exs[4][64];      // per-wave staged exp(score) (replaces ds_bpermute)
  __shared__ uint  sis[4][64];      // per-wave staged src index
  int t = threadIdx.x;
  int lane = t & 63, wv = t >> 6;
  int nloc = t >> 5;                 // 0..7: node slot within block
  int half = (lane >> 5) & 1;        // which node within wave
  int l32 = lane & 31;               // lane within node's 32-group
  int lq = lane & 7;                 // dim group: owns dims lq*8..lq*8+7
  int lg32 = (lane >> 3) & 3;        // gather group within node (4 groups of 8)
  int n = blockIdx.x * 8 + nloc;     // grid exactly NN/8
  uint2 rd = rdeg[n];
  int start = (int)rd.x;
  int deg = (int)rd.y;
  int end = start + deg;
  float pd = p_dst[n];
  float acc[8];
#pragma unroll
  for (int u = 0; u < 8; ++u) acc[u] = 0.f;
  float exsum = 0.f;

  if (deg <= 32) {
    bool valid = l32 < deg;
    float s = -3.4e38f;
    int sidx = 0;
    if (valid) {
      uint pk = csr[start + l32];
      sidx = (int)(pk & 0xFFFFu);
      int ty = (int)(pk >> 16);
      float v = p_src[sidx] + pd + ta_l[ty];
      s = (v > 0.f) ? v : 0.2f * v;
    }
    float m = s;
#pragma unroll
    for (int off = 16; off >= 1; off >>= 1) m = fmaxf(m, __shfl_xor(m, off, 64));
    float ex = valid ? __expf(s - m) : 0.f;
    exsum = ex;
    if (valid) { exs[wv][lane] = ex; sis[wv][lane] = (uint)sidx; }
    for (int it = 0; it < deg; it += 4) {
      int el = it + lg32;
      if (el < deg) {
        float exk = exs[wv][half * 32 + el];       // 8 lanes same addr -> broadcast
        int sk = (int)sis[wv][half * 32 + el];
        uint4 mv = *(const uint4*)&msgbf[(size_t)sk * HD + lq * 8];
        acc[0] += exk * bflo(mv.x); acc[1] += exk * bfhi(mv.x);
        acc[2] += exk * bflo(mv.y); acc[3] += exk * bfhi(mv.y);
        acc[4] += exk * bflo(mv.z); acc[5] += exk * bfhi(mv.z);
        acc[6] += exk * bflo(mv.w); acc[7] += exk * bfhi(mv.w);
      }
    }
  } else {
    // rare path (deg>32): chunked at 32-lane width via s_buf
    float m = -3.4e38f;
    for (int base = start; base < end; base += 32) {
      int i = base + l32;
      float s = -3.4e38f;
      if (i < end) {
        uint pk = csr[i];
        int sidx = (int)(pk & 0xFFFFu);
        int ty = (int)(pk >> 16);
        float v = p_src[sidx] + pd + ta_l[ty];
        s = (v > 0.f) ? v : 0.2f * v;
        s_buf[i] = s;
      }
      m = fmaxf(m, s);
    }
#pragma unroll
    for (int off = 16; off >= 1; off >>= 1) m = fmaxf(m, __shfl_xor(m, off, 64));
    for (int base = start; base < end; base += 32) {
      int i = base + l32;
      if (i < end) {
        float ex = __expf(s_buf[i] - m);
        s_buf[i] = ex;
        exsum += ex;
      }
    }
    for (int it = start; it < end; it += 4) {
      int el = it + lg32;
      if (el < end) {
        float exk = s_buf[el];
        int sk = (int)(csr[el] & 0xFFFFu);
        uint4 mv = *(const uint4*)&msgbf[(size_t)sk * HD + lq * 8];
        acc[0] += exk * bflo(mv.x); acc[1] += exk * bfhi(mv.x);
        acc[2] += exk * bflo(mv.y); acc[3] += exk * bfhi(mv.y);
        acc[4] += exk * bflo(mv.z); acc[5] += exk * bfhi(mv.z);
        acc[6] += exk * bflo(mv.w); acc[7] += exk * bfhi(mv.w);
      }
    }
  }
  // reduce over the 4 gather groups (within each 32-half)
#pragma unroll
  for (int u = 0; u < 8; ++u) {
    acc[u] += __shfl_xor(acc[u], 8, 64);
    acc[u] += __shfl_xor(acc[u], 16, 64);
  }
#pragma unroll
  for (int off = 16; off >= 1; off >>= 1) exsum += __shfl_xor(exsum, off, 64);
  float inv = 1.f / (exsum + 1e-15f);
  float ss = 0.f;
#pragma unroll
  for (int u = 0; u < 8; ++u) {
    float v = fmaxf(acc[u] * inv, 0.f);
    acc[u] = v;
    ss += v * v;
  }
  ss += __shfl_xor(ss, 1, 64);
  ss += __shfl_xor(ss, 2, 64);
  ss += __shfl_xor(ss, 4, 64);
  float nu = fmaxf(sqrtf(ss), 1e-15f);
  float sc = fminf(nu, LCLAMP) / nu;

  if constexpr (FUSE == 0) {
    if (l32 < 8) {
      *(float4*)&ht_out[(size_t)n * HD + l32 * 8] =
          make_float4(acc[0] * sc, acc[1] * sc, acc[2] * sc, acc[3] * sc);
      *(float4*)&ht_out[(size_t)n * HD + l32 * 8 + 4] =
          make_float4(acc[4] * sc, acc[5] * sc, acc[6] * sc, acc[7] * sc);
    }
  } else {
    // next-layer p from bf16-rounded ht (element index = lq*8+u)
    float hb[8];
#pragma unroll
    for (int u = 0; u < 8; ++u) hb[u] = bf2f((short)f2bf(acc[u] * sc));
    float4 a1a = *(const float4*)&attn_next[lq * 8];
    float4 a1b = *(const float4*)&attn_next[lq * 8 + 4];
    float4 a2a = *(const float4*)&attn_next[64 + lq * 8];
    float4 a2b = *(const float4*)&attn_next[64 + lq * 8 + 4];
    float p1 = hb[0]*a1a.x + hb[1]*a1a.y + hb[2]*a1a.z + hb[3]*a1a.w
             + hb[4]*a1b.x + hb[5]*a1b.y + hb[6]*a1b.z + hb[7]*a1b.w;
    float p2 = hb[0]*a2a.x + hb[1]*a2a.y + hb[2]*a2a.z + hb[3]*a2a.w
             + hb[4]*a2b.x + hb[5]*a2b.y + hb[6]*a2b.z + hb[7]*a2b.w;
    p1 += __shfl_xor(p1, 1, 64); p1 += __shfl_xor(p1, 2, 64); p1 += __shfl_xor(p1, 4, 64);
    p2 += __shfl_xor(p2, 1, 64); p2 += __shfl_xor(p2, 2, 64); p2 += __shfl_xor(p2, 4, 64);
    if (l32 == 0) { p_src_out[n] = p1; p_dst_out[n] = p2; }
    if (l32 < 8) {
      *(float4*)&v_lds[nloc][l32 * 8] =
          make_float4(acc[0] * sc, acc[1] * sc, acc[2] * sc, acc[3] * sc);
      *(float4*)&v_lds[nloc][l32 * 8 + 4] =
          make_float4(acc[4] * sc, acc[5] * sc, acc[6] * sc, acc[7] * sc);
    }
    __syncthreads();
    // msg = ht @ Wmp_next + bmp_next for the block's 8 nodes; wave wv computes cols wv*16..+15
    int lane15 = lane & 15, quad = lane >> 4;
    bf16x8 A0 = frag_f32(&v_lds[lane15][quad * 8]);      // rows 8..15 junk, discarded
    bf16x8 A1 = frag_f32(&v_lds[lane15][32 + quad * 8]);
    bf16x8 B0 = *(const bf16x8*)&WmpPk_next[(wv * 2 + 0) * 512 + lane * 8];
    bf16x8 B1 = *(const bf16x8*)&WmpPk_next[(wv * 2 + 1) * 512 + lane * 8];
    f32x4 z = {0.f, 0.f, 0.f, 0.f};
    z = __builtin_amdgcn_mfma_f32_16x16x32_bf16(A0, B0, z, 0, 0, 0);
    z = __builtin_amdgcn_mfma_f32_16x16x32_bf16(A1, B1, z, 0, 0, 0);
    float vbm = bmp_next[wv * 16 + lane15];
    if (quad < 2) {
      int nb = blockIdx.x * 8;
#pragma unroll
      for (int i = 0; i < 4; ++i)
        msg_out[(size_t)(nb + quad * 4 + i) * HD + wv * 16 + lane15] = f2bf(z[i] + vbm);
    }
  }
}

// ---------------------------------------------------------------- heads (MFMA)
__global__ void __launch_bounds__(256) k_score(const float* __restrict__ ht,
                                               const float* __restrict__ Wns1,
                                               const float* __restrict__ qb,
                                               const float* __restrict__ Wns2,
                                               const float* __restrict__ bns2,
                                               const float* __restrict__ Wes1,
                                               float* __restrict__ node_scores,
                                               float* __restrict__ h_out,
                                               ushort* __restrict__ Asrc,
                                               ushort* __restrict__ Adst) {
  int t = threadIdx.x;
  int lane = t & 63, wv = t >> 6;
  int lane15 = lane & 15, quad = lane >> 4;
  int n0 = blockIdx.x * 64;
  int m0 = n0 + wv * 16;
  int row = m0 + lane15;
  int rowc = row < NN ? row : NN - 1;
  bf16x8 A0 = frag_f32(ht + (size_t)rowc * HD + quad * 8);
  bf16x8 A1 = frag_f32(ht + (size_t)rowc * HD + 32 + quad * 8);

  // node head
  {
    f32x4 acc[4];
#pragma unroll
    for (int jt = 0; jt < 4; ++jt) {
      bf16x8 b0 = bfrag_w(Wns1, 0, jt * 16, lane15, quad);
      bf16x8 b1 = bfrag_w(Wns1, 32, jt * 16, lane15, quad);
      f32x4 z = {0.f, 0.f, 0.f, 0.f};
      z = __builtin_amdgcn_mfma_f32_16x16x32_bf16(A0, b0, z, 0, 0, 0);
      z = __builtin_amdgcn_mfma_f32_16x16x32_bf16(A1, b1, z, 0, 0, 0);
      acc[jt] = z;
    }
    float vqb[4], vw2[4];
#pragma unroll
    for (int jt = 0; jt < 4; ++jt) { vqb[jt] = qb[jt * 16 + lane15]; vw2[jt] = Wns2[jt * 16 + lane15]; }
    float b2 = bns2[0];
#pragma unroll
    for (int i = 0; i < 4; ++i) {
      float si = 0.f;
#pragma unroll
      for (int jt = 0; jt < 4; ++jt) si += fmaxf(acc[jt][i] + vqb[jt], 0.f) * vw2[jt];
      si += __shfl_xor(si, 1, 64);
      si += __shfl_xor(si, 2, 64);
      si += __shfl_xor(si, 4, 64);
      si += __shfl_xor(si, 8, 64);
      int r = m0 + quad * 4 + i;
      if (lane15 == 0 && r < NN) node_scores[r] = 1.f / (1.f + __expf(-(si + b2)));
    }
  }
  // Asrc
  {
#pragma unroll
    for (int jt = 0; jt < 4; ++jt) {
      bf16x8 b0 = bfrag_w(Wes1, 0, jt * 16, lane15, quad);
      bf16x8 b1 = bfrag_w(Wes1, 32, jt * 16, lane15, quad);
      f32x4 z = {0.f, 0.f, 0.f, 0.f};
      z = __builtin_amdgcn_mfma_f32_16x16x32_bf16(A0, b0, z, 0, 0, 0);
      z = __builtin_amdgcn_mfma_f32_16x16x32_bf16(A1, b1, z, 0, 0, 0);
#pragma unroll
      for (int i = 0; i < 4; ++i) {
        int r = m0 + quad * 4 + i;
        if (r < NN) Asrc[(size_t)r * HD + jt * 16 + lane15] = f2bf(z[i]);
      }
    }
  }
  // Adst
  {
    const float* W = Wes1 + 64 * HD;
#pragma unroll
    for (int jt = 0; jt < 4; ++jt) {
      bf16x8 b0 = bfrag_w(W, 0, jt * 16, lane15, quad);
      bf16x8 b1 = bfrag_w(W, 32, jt * 16, lane15, quad);
      f32x4 z = {0.f, 0.f, 0.f, 0.f};
      z = __builtin_amdgcn_mfma_f32_16x16x32_bf16(A0, b0, z, 0, 0, 0);
      z = __builtin_amdgcn_mfma_f32_16x16x32_bf16(A1, b1, z, 0, 0, 0);
#pragma unroll
      for (int i = 0; i < 4; ++i) {
        int r = m0 + quad * 4 + i;
        if (r < NN) Adst[(size_t)r * HD + jt * 16 + lane15] = f2bf(z[i]);
      }
    }
  }
  // h_out: exact f32 pass
  {
    int r = t >> 2, p = t & 3;
    int gr = n0 + r;
    int grc = gr < NN ? gr : NN - 1;
    const float* rp = ht + (size_t)grc * HD + p * 16;
    float4 v0 = *(const float4*)(rp + 0);
    float4 v1 = *(const float4*)(rp + 4);
    float4 v2 = *(const float4*)(rp + 8);
    float4 v3 = *(const float4*)(rp + 12);
    float ssq = v0.x*v0.x + v0.y*v0.y + v0.z*v0.z + v0.w*v0.w
              + v1.x*v1.x + v1.y*v1.y + v1.z*v1.z + v1.w*v1.w
              + v2.x*v2.x + v2.y*v2.y + v2.z*v2.z + v2.w*v2.w
              + v3.x*v3.x + v3.y*v3.y + v3.z*v3.z + v3.w*v3.w;
    ssq += __shfl_xor(ssq, 1, 64);
    ssq += __shfl_xor(ssq, 2, 64);
    float nu = fmaxf(sqrtf(ssq), 1e-15f);
    float hs = tanhf(nu) / nu;
    if (gr < NN) {
      float* op = h_out + (size_t)gr * HD + p * 16;
      *(float4*)(op + 0)  = make_float4(v0.x*hs, v0.y*hs, v0.z*hs, v0.w*hs);
      *(float4*)(op + 4)  = make_float4(v1.x*hs, v1.y*hs, v1.z*hs, v1.w*hs);
      *(float4*)(op + 8)  = make_float4(v2.x*hs, v2.y*hs, v2.z*hs, v2.w*hs);
      *(float4*)(op + 12) = make_float4(v3.x*hs, v3.y*hs, v3.z*hs, v3.w*hs);
    }
  }
}

// ---------------------------------------------------------------- edge scores (CSR order)
__global__ void __launch_bounds__(256) k_edge(const uint2* __restrict__ rdeg,
                                              const uint* __restrict__ csr,
                                              const uint* __restrict__ csr_eid,
                                              const ushort* __restrict__ Asrc,
                                              const ushort* __restrict__ Adst,
                                              const ushort* __restrict__ Te2bf,
                                              const float* __restrict__ Wes2,
                                              const float* __restrict__ bes2,
                                              float* __restrict__ edge_scores) {
  int t = threadIdx.x;
  int lane = t & 63;
  int n = (blockIdx.x * 256 + t) >> 6;
  if (n >= NN) return;
  int lq = lane & 7, lg = lane >> 3;
  uint2 rd = rdeg[n];
  int start = (int)rd.x;
  int deg = (int)rd.y;
  if (deg == 0) return;
  int end = start + deg;
  uint4 bv = *(const uint4*)&Adst[(size_t)n * HD + lq * 8];
  const float* wp = &Wes2[lq * 8];
  float4 w0 = *(const float4*)wp;
  float4 w1 = *(const float4*)(wp + 4);
  float b2 = bes2[0];
  for (int it = start; it < end; it += 8) {
    int e = it + lg;
    bool valid = e < end;
    float p = 0.f;
    if (valid) {
      uint pk = csr[e];
      int si = (int)(pk & 0xFFFFu);
      int ty = (int)((pk >> 16) & 0x3Fu);
      uint4 av = *(const uint4*)&Asrc[(size_t)si * HD + lq * 8];
      uint4 tv = *(const uint4*)&Te2bf[ty * HD + lq * 8];
      p += fmaxf(bflo(av.x) + bflo(bv.x) + bflo(tv.x), 0.f) * w0.x;
      p += fmaxf(bfhi(av.x) + bfhi(bv.x) + bfhi(tv.x), 0.f) * w0.y;
      p += fmaxf(bflo(av.y) + bflo(bv.y) + bflo(tv.y), 0.f) * w0.z;
      p += fmaxf(bfhi(av.y) + bfhi(bv.y) + bfhi(tv.y), 0.f) * w0.w;
      p += fmaxf(bflo(av.z) + bflo(bv.z) + bflo(tv.z), 0.f) * w1.x;
      p += fmaxf(bfhi(av.z) + bfhi(bv.z) + bfhi(tv.z), 0.f) * w1.y;
      p += fmaxf(bflo(av.w) + bflo(bv.w) + bflo(tv.w), 0.f) * w1.z;
      p += fmaxf(bfhi(av.w) + bfhi(bv.w) + bfhi(tv.w), 0.f) * w1.w;
    }
    p += __shfl_xor(p, 1, 64);
    p += __shfl_xor(p, 2, 64);
    p += __shfl_xor(p, 4, 64);
    if (valid && lq == 0) edge_scores[csr_eid[e]] = 1.f / (1.f + __expf(-(p + b2)));
  }
}

// ---------------------------------------------------------------- launch
extern "C" void kernel_launch(void* const* d_in, const int* in_sizes, int n_in,
                              void* d_out, int out_size, void* d_ws, size_t ws_size,
                              hipStream_t stream) {
  const float* node_features = (const float*)d_in[0];
  const float* edge_desc = (const float*)d_in[1];
  const float* query = (const float*)d_in[2];
  const float* Wn = (const float*)d_in[3];
  const float* bn = (const float*)d_in[4];
  const float* ts = (const float*)d_in[5];
  const float* Wq = (const float*)d_in[6];
  const float* bq = (const float*)d_in[7];
  const float* Ws_ = (const float*)d_in[8];
  const float* bs = (const float*)d_in[9];
  const float* attn_a = (const float*)d_in[10];
  const float* Wmp = (const float*)d_in[11];
  const float* bmp = (const float*)d_in[12];
  const float* Wns1 = (const float*)d_in[13];
  const float* bns1 = (const float*)d_in[14];
  const float* Wns2 = (const float*)d_in[15];
  const float* bns2 = (const float*)d_in[16];
  const float* Wes1 = (const float*)d_in[17];
  const float* bes1 = (const float*)d_in[18];
  const float* Wes2 = (const float*)d_in[19];
  const float* bes2 = (const float*)d_in[20];
  const int* edge_index = (const int*)d_in[21];
  const int* etype = (const int*)d_in[22];
  const int* src = edge_index;
  const int* dst = edge_index + NE;

  float* out_ns = (float*)d_out;
  float* out_es = out_ns + NN;
  float* out_h = out_es + NE;
  float* out_te = out_h + (size_t)NN * HD;

  char* w = (char*)d_ws;
  auto alloc = [&](size_t bytes) {
    char* p = w;
    w += (bytes + 1023) & ~(size_t)1023;
    return p;
  };
  float* ht_f = (float*)alloc((size_t)NN * HD * 4);        // final-layer f32 ht
  ushort* msg0 = (ushort*)alloc((size_t)NN * HD * 2);      // msg ping
  ushort* msg1 = (ushort*)alloc((size_t)NN * HD * 2);      // msg pong
  ushort* Asrc = (ushort*)alloc((size_t)NN * HD * 2);      // } adjacent: ebuf alias spans both
  ushort* Adst = (ushort*)alloc((size_t)NN * HD * 2);      // }
  float* pA = (float*)alloc(NN * 4);
  float* pdA = (float*)alloc(NN * 4);
  float* pB = (float*)alloc(NN * 4);
  float* pdB = (float*)alloc(NN * 4);
  float* s_buf = (float*)alloc((size_t)NPAD * 4);
  float* qb = (float*)alloc(HD * 4);
  float* ta3 = (float*)alloc(NLAY * NTT * 4);
  ushort* Te2bf = (ushort*)alloc(NTT * HD * 2);
  ushort* WmpPk = (ushort*)alloc(NLAY * 4096 * 2);
  int* bucket_cursor = (int*)alloc(NBUCK * 4);
  uint2* rdeg = (uint2*)alloc((size_t)NN * 8);
  uint* csr = (uint*)alloc((size_t)NPAD * 4);
  uint* csr_eid = (uint*)alloc((size_t)NPAD * 4);
  // ebuf (NPAD x 8B = 9.6 MB) aliases Asrc+Adst (12.8 MB contiguous): CSR build
  // finishes (k_scatter2) before k_score writes Asrc/Adst. No overlap in stream order.
  uint2* ebuf = (uint2*)Asrc;

  hipMemsetAsync(bucket_cursor, 0, NBUCK * 4, stream);
  // setup: te, q-projections, ta3, WmpPk pack, Te2bf (1 block)
  kA<<<1, 256, 0, stream>>>(edge_desc, query, Wq, bq, Ws_, bs, attn_a,
                            Wns1, bns1, Wes1, bes1, Wmp, out_te, qb, ta3, Te2bf, WmpPk);
  // bin (196) + proj w/ fused layer-0 msg (782), co-scheduled
  kE<<<NBINBLK + (NN + 63) / 64, 256, 0, stream>>>(src, dst, etype, bucket_cursor, ebuf,
                                                   node_features, Wn, bn, ts, WmpPk,
                                                   bmp, attn_a, msg0, pA, pdA);
  // order within bucket by node; emit rdeg + csr/csr_eid
  k_scatter2<<<NBUCK, 256, 0, stream>>>(bucket_cursor, ebuf, csr, csr_eid, rdeg);

  const int AGG_GRID = NN / 8;   // NN % 8 == 0 -> 6250 blocks, 8 nodes each
  // layer 0: gather msg0, emit msg1 = ht1 @ Wmp1 and p's for layer 1
  k_agg<1><<<AGG_GRID, 256, 0, stream>>>(rdeg, csr, pA, pdA, ta3 + 0 * NTT, msg0, s_buf,
                                         WmpPk + 1 * 4096, bmp + 1 * HD,
                                         attn_a + 1 * (2 * HD + TDD),
                                         msg1, pB, pdB, nullptr);
  // layer 1: gather msg1, emit msg0 = ht2 @ Wmp2 and p's for layer 2
  k_agg<1><<<AGG_GRID, 256, 0, stream>>>(rdeg, csr, pB, pdB, ta3 + 1 * NTT, msg1, s_buf,
                                         WmpPk + 2 * 4096, bmp + 2 * HD,
                                         attn_a + 2 * (2 * HD + TDD),
                                         msg0, pA, pdA, nullptr);
  // layer 2: gather msg0, write final f32 ht
  k_agg<0><<<AGG_GRID, 256, 0, stream>>>(rdeg, csr, pA, pdA, ta3 + 2 * NTT, msg0, s_buf,
                                         nullptr, nullptr, nullptr,
                                         nullptr, nullptr, nullptr, ht_f);

  k_score<<<(NN + 63) / 64, 256, 0, stream>>>(ht_f, Wns1, qb, Wns2, bns2, Wes1,
                                              out_ns, out_h, Asrc, Adst);
  k_edge<<<(NN + 3) / 4, 256, 0, stream>>>(rdeg, csr, csr_eid, Asrc, Adst, Te2bf,
                                           Wes2, bes2, out_es);
}

// Round 5
// 313.739 us; speedup vs baseline: 1.2650x; 1.0272x over previous
//
#include <hip/hip_runtime.h>
#include <math.h>

#define NN 50000
#define NE 800000
#define NFD 256
#define HD 64
#define QDD 128
#define TDD 32
#define NTT 64
#define NLAY 3
#define LCLAMP 6.1030340f   // atanh(1 - 1e-5)
#define NBUCK 196           // ceil(50000/256) coarse buckets (dst >> 8)
#define SBUCK 6144          // padded slots per bucket (expected 4096, sigma ~64)
#define NPAD (NBUCK * SBUCK)
#define EPB 4096            // edges per bin block
#define NBINBLK 196         // ceil(800000/4096)
#define NPROJ 782           // ceil(50000/64)
#define PST 72              // proj LDS tile stride

typedef unsigned int uint;
typedef unsigned short ushort;
typedef __attribute__((ext_vector_type(8))) short bf16x8;
typedef __attribute__((ext_vector_type(4))) float f32x4;

__device__ __forceinline__ ushort f2bf(float f) {
  uint u = __float_as_uint(f);
  uint r = (u + 0x7FFFu + ((u >> 16) & 1u)) >> 16;
  return (ushort)r;
}
__device__ __forceinline__ short f2bfs(float f) { return (short)f2bf(f); }
__device__ __forceinline__ float bf2f(short s) { return __uint_as_float(((uint)(ushort)s) << 16); }
__device__ __forceinline__ float bflo(uint w) { return __uint_as_float(w << 16); }
__device__ __forceinline__ float bfhi(uint w) { return __uint_as_float(w & 0xFFFF0000u); }

// A-frag from 8 consecutive f32
__device__ __forceinline__ bf16x8 frag_f32(const float* p) {
  float4 a = *(const float4*)p;
  float4 b = *(const float4*)(p + 4);
  bf16x8 r;
  r[0] = f2bfs(a.x); r[1] = f2bfs(a.y); r[2] = f2bfs(a.z); r[3] = f2bfs(a.w);
  r[4] = f2bfs(b.x); r[5] = f2bfs(b.y); r[6] = f2bfs(b.z); r[7] = f2bfs(b.w);
  return r;
}
// B-frag from row-major W[K][64]: k=k0+quad*8+j, n=j0+lane15
__device__ __forceinline__ bf16x8 bfrag_w(const float* W, int k0, int j0, int lane15, int quad) {
  bf16x8 r;
#pragma unroll
  for (int j = 0; j < 8; ++j) r[j] = f2bfs(W[(k0 + quad * 8 + j) * HD + j0 + lane15]);
  return r;
}

// ---------------------------------------------------------------- setup (device, 1 block)
__device__ void d_setup(const float* __restrict__ edge_desc, const float* __restrict__ query,
                        const float* __restrict__ Wq, const float* __restrict__ bq,
                        const float* __restrict__ Ws, const float* __restrict__ bs,
                        const float* __restrict__ attn_a,
                        const float* __restrict__ Wns1, const float* __restrict__ bns1,
                        const float* __restrict__ Wes1, const float* __restrict__ bes1,
                        const float* __restrict__ Wmp,
                        float* __restrict__ out_type_emb,
                        float* __restrict__ qb, float* __restrict__ ta3,
                        ushort* __restrict__ Te2bf, ushort* __restrict__ WmpPk,
                        ushort* __restrict__ WnsPk, ushort* __restrict__ WesaPk,
                        ushort* __restrict__ WesbPk) {
  __shared__ float te_l[NTT * TDD];
  __shared__ float q_l[HD];
  __shared__ float qe_l[HD];
  int t = threadIdx.x;
  if (t < HD) {
    float acc = bq[t];
    for (int k = 0; k < QDD; ++k) acc += query[k] * Wq[k * HD + t];
    q_l[t] = acc;
  }
  for (int idx = t; idx < NTT * TDD; idx += 256) {
    int ty = idx / TDD, d = idx % TDD;
    float acc = bs[d];
    for (int k = 0; k < 64; ++k) acc += edge_desc[ty * 64 + k] * Ws[k * TDD + d];
    float v = tanhf(acc);
    te_l[idx] = v;
    out_type_emb[idx] = v;
  }
  __syncthreads();
  if (t < NLAY * NTT) {
    int l = t / NTT, ty = t % NTT;
    float acc = 0.f;
    for (int d = 0; d < TDD; ++d) acc += te_l[ty * TDD + d] * attn_a[l * (2 * HD + TDD) + 2 * HD + d];
    ta3[t] = acc;
  }
  if (t < HD) {
    float a1 = bns1[t], a2 = bes1[t];
    for (int k = 0; k < HD; ++k) {
      a1 += q_l[k] * Wns1[(HD + k) * HD + t];
      a2 += q_l[k] * Wes1[(2 * HD + TDD + k) * HD + t];
    }
    qb[t] = a1;
    qe_l[t] = a2;
  }
  // pack Wmp B-frags: WmpPk[(((l*4+jt)*2+f)*64 + lane)*8 + j]
  //   = bf16(Wmp[l][(f*32 + quad*8 + j)][jt*16 + lane15])
  for (int idx = t; idx < NLAY * 4 * 2 * 64 * 8; idx += 256) {
    int j = idx & 7, lane = (idx >> 3) & 63, f = (idx >> 9) & 1, jl = idx >> 10;
    int l = jl >> 2, jt = jl & 3, q = lane >> 4, l15 = lane & 15;
    WmpPk[idx] = f2bf(Wmp[l * HD * HD + (f * 32 + q * 8 + j) * HD + jt * 16 + l15]);
  }
  // pack head weights (same layout, single "layer" each)
  for (int idx = t; idx < 4 * 2 * 64 * 8; idx += 256) {
    int j = idx & 7, lane = (idx >> 3) & 63, f = (idx >> 9) & 1, jt = (idx >> 10) & 3;
    int q = lane >> 4, l15 = lane & 15;
    int row = f * 32 + q * 8 + j, col = jt * 16 + l15;
    WnsPk[idx]  = f2bf(Wns1[row * HD + col]);
    WesaPk[idx] = f2bf(Wes1[row * HD + col]);
    WesbPk[idx] = f2bf(Wes1[(64 + row) * HD + col]);
  }
  __syncthreads();
  // Te2bf[ty][j] = bf16(type_emb[ty] @ Wes1[te-part] + qe)
  for (int idx = t; idx < NTT * HD; idx += 256) {
    int ty = idx >> 6, j = idx & 63;
    float acc = qe_l[j];
#pragma unroll
    for (int d = 0; d < TDD; ++d) acc += te_l[ty * TDD + d] * Wes1[(2 * HD + d) * HD + j];
    Te2bf[idx] = f2bf(acc);
  }
}

// ---------------------------------------------------------------- bin (device): append edges to padded bucket regions
// pk: src(16) | type(6)<<16 | (dst&255)<<22
__device__ void d_bin(int bbid,
                      const int* __restrict__ src,
                      const int* __restrict__ dst,
                      const int* __restrict__ etype,
                      int* __restrict__ bucket_cursor,
                      uint2* __restrict__ ebuf) {
  __shared__ int cntl[NBUCK];
  __shared__ int gbase[NBUCK];
  int t = threadIdx.x;
  for (int i = t; i < NBUCK; i += 256) cntl[i] = 0;
  __syncthreads();
  int e0 = bbid * EPB;
  int dd[16];
  uint pk[16];
  int rk[16];
#pragma unroll
  for (int c = 0; c < 4; ++c) {
    int eb = e0 + c * 1024 + t * 4;
    if (eb < NE) {   // NE%4==0 => eb<NE implies eb+3<NE
      int4 s4 = *(const int4*)&src[eb];
      int4 d4 = *(const int4*)&dst[eb];
      int4 y4 = *(const int4*)&etype[eb];
      int ds[4] = {d4.x, d4.y, d4.z, d4.w};
      int ss[4] = {s4.x, s4.y, s4.z, s4.w};
      int ys[4] = {y4.x, y4.y, y4.z, y4.w};
#pragma unroll
      for (int j = 0; j < 4; ++j) {
        int idx = c * 4 + j;
        int d = ds[j];
        dd[idx] = d;
        pk[idx] = (uint)ss[j] | ((uint)ys[j] << 16) | ((uint)(d & 255) << 22);
        rk[idx] = atomicAdd(&cntl[d >> 8], 1);
      }
    } else {
#pragma unroll
      for (int j = 0; j < 4; ++j) dd[c * 4 + j] = -1;
    }
  }
  __syncthreads();
  if (t < NBUCK && cntl[t] > 0)
    gbase[t] = t * SBUCK + atomicAdd(&bucket_cursor[t], cntl[t]);
  __syncthreads();
#pragma unroll
  for (int i = 0; i < 16; ++i) {
    if (dd[i] >= 0) {
      uint eid = (uint)(e0 + ((i >> 2) << 10) + t * 4 + (i & 3));
      ebuf[gbase[dd[i] >> 8] + rk[i]] = make_uint2(pk[i], eid);
    }
  }
}

// ---------------------------------------------------------------- proj (device) + fused layer-0 msg
// (Wmp0 B-frags loaded direct from f32 — no dependency on setup block)
__device__ void d_proj(int pbid,
                       const float* __restrict__ X,
                       const float* __restrict__ Wn,
                       const float* __restrict__ bn,
                       const float* __restrict__ ts_p,
                       const float* __restrict__ Wmp0,
                       const float* __restrict__ bmp0,
                       const float* __restrict__ attn0,
                       ushort* __restrict__ msgbf,
                       float* __restrict__ p_src,
                       float* __restrict__ p_dst) {
  __shared__ ushort buf[2][64 * PST];            // 2 x 9216 B
  float* st = (float*)&buf[0][0];                // epilogue alias: 64 x 72 f32
  int t = threadIdx.x;
  int lane = t & 63, wv = t >> 6;
  int lane15 = lane & 15, quad = lane >> 4;
  int n0 = pbid * 64;
  int j0 = wv * 16;
  bf16x8 B[8];
#pragma unroll
  for (int fb = 0; fb < 8; ++fb) B[fb] = bfrag_w(Wn, fb * 32, j0, lane15, quad);

  int srow = t >> 2;
  int scg = (t & 3) * 16;
  int grow = n0 + srow; if (grow >= NN) grow = NN - 1;
  const float* xrow = X + (size_t)grow * NFD + scg;

  f32x4 acc[4];
#pragma unroll
  for (int mt = 0; mt < 4; ++mt) acc[mt] = (f32x4){0.f, 0.f, 0.f, 0.f};

  float4 r0 = *(const float4*)(xrow + 0);
  float4 r1 = *(const float4*)(xrow + 4);
  float4 r2 = *(const float4*)(xrow + 8);
  float4 r3 = *(const float4*)(xrow + 12);

  for (int c = 0; c < 4; ++c) {
    ushort* wp = &buf[c & 1][srow * PST + scg];
    uint4 o0, o1;
    o0.x = (uint)f2bf(r0.x) | ((uint)f2bf(r0.y) << 16);
    o0.y = (uint)f2bf(r0.z) | ((uint)f2bf(r0.w) << 16);
    o0.z = (uint)f2bf(r1.x) | ((uint)f2bf(r1.y) << 16);
    o0.w = (uint)f2bf(r1.z) | ((uint)f2bf(r1.w) << 16);
    o1.x = (uint)f2bf(r2.x) | ((uint)f2bf(r2.y) << 16);
    o1.y = (uint)f2bf(r2.z) | ((uint)f2bf(r2.w) << 16);
    o1.z = (uint)f2bf(r3.x) | ((uint)f2bf(r3.y) << 16);
    o1.w = (uint)f2bf(r3.z) | ((uint)f2bf(r3.w) << 16);
    *(uint4*)wp = o0;
    *(uint4*)(wp + 8) = o1;
    if (c < 3) {
      const float* nx = xrow + (c + 1) * 64;
      r0 = *(const float4*)(nx + 0);
      r1 = *(const float4*)(nx + 4);
      r2 = *(const float4*)(nx + 8);
      r3 = *(const float4*)(nx + 12);
    }
    __syncthreads();
    const ushort* bp = &buf[c & 1][0];
#pragma unroll
    for (int mt = 0; mt < 4; ++mt) {
#pragma unroll
      for (int ks = 0; ks < 2; ++ks) {
        bf16x8 A = *(const bf16x8*)&bp[(mt * 16 + lane15) * PST + ks * 32 + quad * 8];
        acc[mt] = __builtin_amdgcn_mfma_f32_16x16x32_bf16(A, B[c * 2 + ks], acc[mt], 0, 0, 0);
      }
    }
  }
  __syncthreads();
  float ts = ts_p[0];
  float vb = bn[j0 + lane15];
#pragma unroll
  for (int mt = 0; mt < 4; ++mt)
#pragma unroll
    for (int i = 0; i < 4; ++i)
      st[(mt * 16 + quad * 4 + i) * PST + j0 + lane15] = (acc[mt][i] + vb) * ts;
  __syncthreads();
  {
    int r = t >> 2, p = t & 3;
    float* rp = &st[r * PST + p * 16];
    float4 v0 = *(const float4*)(rp + 0);
    float4 v1 = *(const float4*)(rp + 4);
    float4 v2 = *(const float4*)(rp + 8);
    float4 v3 = *(const float4*)(rp + 12);
    float ssq = v0.x*v0.x + v0.y*v0.y + v0.z*v0.z + v0.w*v0.w
              + v1.x*v1.x + v1.y*v1.y + v1.z*v1.z + v1.w*v1.w
              + v2.x*v2.x + v2.y*v2.y + v2.z*v2.z + v2.w*v2.w
              + v3.x*v3.x + v3.y*v3.y + v3.z*v3.z + v3.w*v3.w;
    ssq += __shfl_xor(ssq, 1, 64);
    ssq += __shfl_xor(ssq, 2, 64);
    float nu = fmaxf(sqrtf(ssq), 1e-15f);
    float sc = fminf(nu, LCLAMP) / nu;
    *(float4*)(rp + 0) = make_float4(v0.x*sc, v0.y*sc, v0.z*sc, v0.w*sc);
    *(float4*)(rp + 4) = make_float4(v1.x*sc, v1.y*sc, v1.z*sc, v1.w*sc);
    *(float4*)(rp + 8) = make_float4(v2.x*sc, v2.y*sc, v2.z*sc, v2.w*sc);
    *(float4*)(rp + 12) = make_float4(v3.x*sc, v3.y*sc, v3.z*sc, v3.w*sc);
  }
  __syncthreads();
  // fused layer-0 msg
  {
    bf16x8 Bm0[4], Bm1[4];
    float vbm[4];
#pragma unroll
    for (int jt = 0; jt < 4; ++jt) {
      Bm0[jt] = bfrag_w(Wmp0, 0, jt * 16, lane15, quad);
      Bm1[jt] = bfrag_w(Wmp0, 32, jt * 16, lane15, quad);
      vbm[jt] = bmp0[jt * 16 + lane15];
    }
    int mrow = wv * 16 + lane15;
    bf16x8 A0 = frag_f32(&st[mrow * PST + quad * 8]);
    bf16x8 A1 = frag_f32(&st[mrow * PST + 32 + quad * 8]);
#pragma unroll
    for (int jt = 0; jt < 4; ++jt) {
      f32x4 z = {0.f, 0.f, 0.f, 0.f};
      z = __builtin_amdgcn_mfma_f32_16x16x32_bf16(A0, Bm0[jt], z, 0, 0, 0);
      z = __builtin_amdgcn_mfma_f32_16x16x32_bf16(A1, Bm1[jt], z, 0, 0, 0);
#pragma unroll
      for (int i = 0; i < 4; ++i) {
        int r = n0 + wv * 16 + quad * 4 + i;
        if (r < NN) msgbf[(size_t)r * HD + jt * 16 + lane15] = f2bf(z[i] + vbm[jt]);
      }
    }
    float4 a1l = *(const float4*)&attn0[quad * 8];
    float4 a1h = *(const float4*)&attn0[quad * 8 + 4];
    float4 a1l2 = *(const float4*)&attn0[32 + quad * 8];
    float4 a1h2 = *(const float4*)&attn0[32 + quad * 8 + 4];
    float4 a2l = *(const float4*)&attn0[64 + quad * 8];
    float4 a2h = *(const float4*)&attn0[64 + quad * 8 + 4];
    float4 a2l2 = *(const float4*)&attn0[96 + quad * 8];
    float4 a2h2 = *(const float4*)&attn0[96 + quad * 8 + 4];
    float p1 = bf2f(A0[0])*a1l.x + bf2f(A0[1])*a1l.y + bf2f(A0[2])*a1l.z + bf2f(A0[3])*a1l.w
             + bf2f(A0[4])*a1h.x + bf2f(A0[5])*a1h.y + bf2f(A0[6])*a1h.z + bf2f(A0[7])*a1h.w
             + bf2f(A1[0])*a1l2.x + bf2f(A1[1])*a1l2.y + bf2f(A1[2])*a1l2.z + bf2f(A1[3])*a1l2.w
             + bf2f(A1[4])*a1h2.x + bf2f(A1[5])*a1h2.y + bf2f(A1[6])*a1h2.z + bf2f(A1[7])*a1h2.w;
    float p2 = bf2f(A0[0])*a2l.x + bf2f(A0[1])*a2l.y + bf2f(A0[2])*a2l.z + bf2f(A0[3])*a2l.w
             + bf2f(A0[4])*a2h.x + bf2f(A0[5])*a2h.y + bf2f(A0[6])*a2h.z + bf2f(A0[7])*a2h.w
             + bf2f(A1[0])*a2l2.x + bf2f(A1[1])*a2l2.y + bf2f(A1[2])*a2l2.z + bf2f(A1[3])*a2l2.w
             + bf2f(A1[4])*a2h2.x + bf2f(A1[5])*a2h2.y + bf2f(A1[6])*a2h2.z + bf2f(A1[7])*a2h2.w;
    p1 += __shfl_xor(p1, 16, 64); p1 += __shfl_xor(p1, 32, 64);
    p2 += __shfl_xor(p2, 16, 64); p2 += __shfl_xor(p2, 32, 64);
    int prow = n0 + mrow;
    if (quad == 0 && prow < NN) { p_src[prow] = p1; p_dst[prow] = p2; }
  }
}

// kE: blocks 0..195 = bin, 196..977 = proj, 978 = setup (all independent)
__global__ void __launch_bounds__(256) kE(const int* __restrict__ src, const int* __restrict__ dst,
                                          const int* __restrict__ etype, int* __restrict__ bucket_cursor,
                                          uint2* __restrict__ ebuf,
                                          const float* __restrict__ X, const float* __restrict__ Wn,
                                          const float* __restrict__ bn, const float* __restrict__ ts_p,
                                          const float* __restrict__ Wmp, const float* __restrict__ bmp,
                                          const float* __restrict__ attn_a,
                                          ushort* __restrict__ msgbf,
                                          float* __restrict__ p_src, float* __restrict__ p_dst,
                                          const float* __restrict__ edge_desc, const float* __restrict__ query,
                                          const float* __restrict__ Wq, const float* __restrict__ bq,
                                          const float* __restrict__ Ws, const float* __restrict__ bs,
                                          const float* __restrict__ Wns1, const float* __restrict__ bns1,
                                          const float* __restrict__ Wes1, const float* __restrict__ bes1,
                                          float* __restrict__ out_type_emb,
                                          float* __restrict__ qb, float* __restrict__ ta3,
                                          ushort* __restrict__ Te2bf, ushort* __restrict__ WmpPk,
                                          ushort* __restrict__ WnsPk, ushort* __restrict__ WesaPk,
                                          ushort* __restrict__ WesbPk) {
  if (blockIdx.x < NBINBLK)
    d_bin(blockIdx.x, src, dst, etype, bucket_cursor, ebuf);
  else if (blockIdx.x < NBINBLK + NPROJ)
    d_proj(blockIdx.x - NBINBLK, X, Wn, bn, ts_p, Wmp, bmp, attn_a, msgbf, p_src, p_dst);
  else
    d_setup(edge_desc, query, Wq, bq, Ws, bs, attn_a, Wns1, bns1, Wes1, bes1, Wmp,
            out_type_emb, qb, ta3, Te2bf, WmpPk, WnsPk, WesaPk, WesbPk);
}

// ---------------------------------------------------------------- scatter: order bucket by node, emit rdeg + csr
__global__ void __launch_bounds__(256) k_scatter2(const int* __restrict__ bucket_cursor,
                                                  const uint2* __restrict__ ebuf,
                                                  uint* __restrict__ csr,
                                                  uint* __restrict__ csr_eid,
                                                  uint2* __restrict__ rdeg) {
  __shared__ int cnt_l[256];
  __shared__ int curs[256];
  __shared__ int wsum[4], woff[4];
  int b = blockIdx.x;
  int t = threadIdx.x;
  int base = b * SBUCK;
  int cb = bucket_cursor[b];           // edges in this bucket
  cnt_l[t] = 0;
  __syncthreads();
  for (int i = t; i < cb; i += 256)
    atomicAdd(&cnt_l[(ebuf[base + i].x >> 22) & 255], 1);
  __syncthreads();
  int v = cnt_l[t];
  int lane = t & 63, wid = t >> 6;
  int x = v;
#pragma unroll
  for (int off = 1; off < 64; off <<= 1) {
    int y = __shfl_up(x, off, 64);
    if (lane >= off) x += y;
  }
  if (lane == 63) wsum[wid] = x;
  __syncthreads();
  if (t == 0) {
    int a = 0;
    for (int i = 0; i < 4; ++i) { woff[i] = a; a += wsum[i]; }
  }
  __syncthreads();
  int loff = woff[wid] + (x - v);      // exclusive prefix
  int n = (b << 8) + t;
  if (n < NN) rdeg[n] = make_uint2((uint)(base + loff), (uint)v);
  curs[t] = base + loff;
  __syncthreads();
  for (int i = t; i < cb; i += 256) {
    uint2 e = ebuf[base + i];
    int j = (e.x >> 22) & 255;
    int pos = atomicAdd(&curs[j], 1);
    csr[pos] = e.x & 0x3FFFFFu;
    csr_eid[pos] = e.y;
  }
}

// ---------------------------------------------------------------- softmax-aggregate (2 nodes/wave, 32 lanes each)
// FUSE=1: epilogue computes next-layer msg + p's.
// FUSE=0: final layer — epilogue fuses the former k_score (node head, Asrc/Adst, h_out).
template <int FUSE>
__global__ void __launch_bounds__(256) k_agg(const uint2* __restrict__ rdeg,
                                             const uint* __restrict__ csr,
                                             const float* __restrict__ p_src,
                                             const float* __restrict__ p_dst,
                                             const float* __restrict__ ta_l,
                                             const ushort* __restrict__ msgbf,
                                             float* __restrict__ s_buf,
                                             const ushort* __restrict__ WmpPk_next,
                                             const float* __restrict__ bmp_next,
                                             const float* __restrict__ attn_next,
                                             ushort* __restrict__ msg_out,
                                             float* __restrict__ p_src_out,
                                             float* __restrict__ p_dst_out,
                                             const float* __restrict__ qb,
                                             const float* __restrict__ Wns2,
                                             const float* __restrict__ bns2,
                                             const ushort* __restrict__ WnsPk,
                                             const ushort* __restrict__ WesaPk,
                                             const ushort* __restrict__ WesbPk,
                                             float* __restrict__ node_scores,
                                             float* __restrict__ h_out,
                                             ushort* __restrict__ Asrc,
                                             ushort* __restrict__ Adst) {
  __shared__ float v_lds[16][68];   // +4 pad: b128 reads 2-way max
  __shared__ float exs[4][64];      // per-wave staged exp(score)
  __shared__ uint  sis[4][64];      // per-wave staged src index
  __shared__ float sc_part[8][4];   // FUSE=0: node-head partials per wave
  int t = threadIdx.x;
  int lane = t & 63, wv = t >> 6;
  int nloc = t >> 5;                 // 0..7: node slot within block
  int half = (lane >> 5) & 1;        // which node within wave
  int l32 = lane & 31;               // lane within node's 32-group
  int lq = lane & 7;                 // dim group: owns dims lq*8..lq*8+7
  int lg32 = (lane >> 3) & 3;        // gather group within node (4 groups of 8)
  int n = blockIdx.x * 8 + nloc;     // grid exactly NN/8
  uint2 rd = rdeg[n];
  int start = (int)rd.x;
  int deg = (int)rd.y;
  int end = start + deg;
  float pd = p_dst[n];
  float acc[8];
#pragma unroll
  for (int u = 0; u < 8; ++u) acc[u] = 0.f;
  float exsum = 0.f;

  if (deg <= 32) {
    bool valid = l32 < deg;
    float s = -3.4e38f;
    int sidx = 0;
    if (valid) {
      uint pk = csr[start + l32];
      sidx = (int)(pk & 0xFFFFu);
      int ty = (int)(pk >> 16);
      float v = p_src[sidx] + pd + ta_l[ty];
      s = (v > 0.f) ? v : 0.2f * v;
    }
    float m = s;
#pragma unroll
    for (int off = 16; off >= 1; off >>= 1) m = fmaxf(m, __shfl_xor(m, off, 64));
    float ex = valid ? __expf(s - m) : 0.f;
    exsum = ex;
    if (valid) { exs[wv][lane] = ex; sis[wv][lane] = (uint)sidx; }
    for (int it = 0; it < deg; it += 4) {
      int el = it + lg32;
      if (el < deg) {
        float exk = exs[wv][half * 32 + el];       // 8 lanes same addr -> broadcast
        int sk = (int)sis[wv][half * 32 + el];
        uint4 mv = *(const uint4*)&msgbf[(size_t)sk * HD + lq * 8];
        acc[0] += exk * bflo(mv.x); acc[1] += exk * bfhi(mv.x);
        acc[2] += exk * bflo(mv.y); acc[3] += exk * bfhi(mv.y);
        acc[4] += exk * bflo(mv.z); acc[5] += exk * bfhi(mv.z);
        acc[6] += exk * bflo(mv.w); acc[7] += exk * bfhi(mv.w);
      }
    }
  } else {
    // rare path (deg>32): chunked at 32-lane width via s_buf
    float m = -3.4e38f;
    for (int base = start; base < end; base += 32) {
      int i = base + l32;
      float s = -3.4e38f;
      if (i < end) {
        uint pk = csr[i];
        int sidx = (int)(pk & 0xFFFFu);
        int ty = (int)(pk >> 16);
        float v = p_src[sidx] + pd + ta_l[ty];
        s = (v > 0.f) ? v : 0.2f * v;
        s_buf[i] = s;
      }
      m = fmaxf(m, s);
    }
#pragma unroll
    for (int off = 16; off >= 1; off >>= 1) m = fmaxf(m, __shfl_xor(m, off, 64));
    for (int base = start; base < end; base += 32) {
      int i = base + l32;
      if (i < end) {
        float ex = __expf(s_buf[i] - m);
        s_buf[i] = ex;
        exsum += ex;
      }
    }
    for (int it = start; it < end; it += 4) {
      int el = it + lg32;
      if (el < end) {
        float exk = s_buf[el];
        int sk = (int)(csr[el] & 0xFFFFu);
        uint4 mv = *(const uint4*)&msgbf[(size_t)sk * HD + lq * 8];
        acc[0] += exk * bflo(mv.x); acc[1] += exk * bfhi(mv.x);
        acc[2] += exk * bflo(mv.y); acc[3] += exk * bfhi(mv.y);
        acc[4] += exk * bflo(mv.z); acc[5] += exk * bfhi(mv.z);
        acc[6] += exk * bflo(mv.w); acc[7] += exk * bfhi(mv.w);
      }
    }
  }
  // reduce over the 4 gather groups (within each 32-half)
#pragma unroll
  for (int u = 0; u < 8; ++u) {
    acc[u] += __shfl_xor(acc[u], 8, 64);
    acc[u] += __shfl_xor(acc[u], 16, 64);
  }
#pragma unroll
  for (int off = 16; off >= 1; off >>= 1) exsum += __shfl_xor(exsum, off, 64);
  float inv = 1.f / (exsum + 1e-15f);
  float ss = 0.f;
#pragma unroll
  for (int u = 0; u < 8; ++u) {
    float v = fmaxf(acc[u] * inv, 0.f);
    acc[u] = v;
    ss += v * v;
  }
  ss += __shfl_xor(ss, 1, 64);
  ss += __shfl_xor(ss, 2, 64);
  ss += __shfl_xor(ss, 4, 64);
  float nu = fmaxf(sqrtf(ss), 1e-15f);
  float sc = fminf(nu, LCLAMP) / nu;

  if constexpr (FUSE == 0) {
    // ---- fused k_score: stage final ht rows, then heads + h_out from LDS ----
    if (l32 < 8) {
      *(float4*)&v_lds[nloc][l32 * 8] =
          make_float4(acc[0] * sc, acc[1] * sc, acc[2] * sc, acc[3] * sc);
      *(float4*)&v_lds[nloc][l32 * 8 + 4] =
          make_float4(acc[4] * sc, acc[5] * sc, acc[6] * sc, acc[7] * sc);
    }
    __syncthreads();
    int lane15 = lane & 15, quad = lane >> 4;
    int nb = blockIdx.x * 8;
    // h_out: exact f32 pass (replicates former k_score lane pattern bitwise)
    if (t < 32) {
      int r = t >> 2, p = t & 3;
      const float* rp = &v_lds[r][p * 16];
      float4 v0 = *(const float4*)(rp + 0);
      float4 v1 = *(const float4*)(rp + 4);
      float4 v2 = *(const float4*)(rp + 8);
      float4 v3 = *(const float4*)(rp + 12);
      float ssq = v0.x*v0.x + v0.y*v0.y + v0.z*v0.z + v0.w*v0.w
                + v1.x*v1.x + v1.y*v1.y + v1.z*v1.z + v1.w*v1.w
                + v2.x*v2.x + v2.y*v2.y + v2.z*v2.z + v2.w*v2.w
                + v3.x*v3.x + v3.y*v3.y + v3.z*v3.z + v3.w*v3.w;
      ssq += __shfl_xor(ssq, 1, 64);
      ssq += __shfl_xor(ssq, 2, 64);
      float nu2 = fmaxf(sqrtf(ssq), 1e-15f);
      float hs = tanhf(nu2) / nu2;
      float* op = h_out + (size_t)(nb + r) * HD + p * 16;
      *(float4*)(op + 0)  = make_float4(v0.x*hs, v0.y*hs, v0.z*hs, v0.w*hs);
      *(float4*)(op + 4)  = make_float4(v1.x*hs, v1.y*hs, v1.z*hs, v1.w*hs);
      *(float4*)(op + 8)  = make_float4(v2.x*hs, v2.y*hs, v2.z*hs, v2.w*hs);
      *(float4*)(op + 12) = make_float4(v3.x*hs, v3.y*hs, v3.z*hs, v3.w*hs);
    }
    // 3 GEMMs (node-head y, Asrc, Adst): wave wv computes cols wv*16..+15 for 8 nodes
    bf16x8 A0 = frag_f32(&v_lds[lane15][quad * 8]);      // rows 8..15 junk, outputs discarded
    bf16x8 A1 = frag_f32(&v_lds[lane15][32 + quad * 8]);
    // node head
    {
      bf16x8 B0 = *(const bf16x8*)&WnsPk[(wv * 2 + 0) * 512 + lane * 8];
      bf16x8 B1 = *(const bf16x8*)&WnsPk[(wv * 2 + 1) * 512 + lane * 8];
      f32x4 z = {0.f, 0.f, 0.f, 0.f};
      z = __builtin_amdgcn_mfma_f32_16x16x32_bf16(A0, B0, z, 0, 0, 0);
      z = __builtin_amdgcn_mfma_f32_16x16x32_bf16(A1, B1, z, 0, 0, 0);
      float vqb = qb[wv * 16 + lane15];
      float vw2 = Wns2[wv * 16 + lane15];
      if (quad < 2) {
#pragma unroll
        for (int i = 0; i < 4; ++i) {
          float part = fmaxf(z[i] + vqb, 0.f) * vw2;
          part += __shfl_xor(part, 1, 64);
          part += __shfl_xor(part, 2, 64);
          part += __shfl_xor(part, 4, 64);
          part += __shfl_xor(part, 8, 64);
          if (lane15 == 0) sc_part[quad * 4 + i][wv] = part;
        }
      }
    }
    // Asrc
    {
      bf16x8 B0 = *(const bf16x8*)&WesaPk[(wv * 2 + 0) * 512 + lane * 8];
      bf16x8 B1 = *(const bf16x8*)&WesaPk[(wv * 2 + 1) * 512 + lane * 8];
      f32x4 z = {0.f, 0.f, 0.f, 0.f};
      z = __builtin_amdgcn_mfma_f32_16x16x32_bf16(A0, B0, z, 0, 0, 0);
      z = __builtin_amdgcn_mfma_f32_16x16x32_bf16(A1, B1, z, 0, 0, 0);
      if (quad < 2) {
#pragma unroll
        for (int i = 0; i < 4; ++i)
          Asrc[(size_t)(nb + quad * 4 + i) * HD + wv * 16 + lane15] = f2bf(z[i]);
      }
    }
    // Adst
    {
      bf16x8 B0 = *(const bf16x8*)&WesbPk[(wv * 2 + 0) * 512 + lane * 8];
      bf16x8 B1 = *(const bf16x8*)&WesbPk[(wv * 2 + 1) * 512 + lane * 8];
      f32x4 z = {0.f, 0.f, 0.f, 0.f};
      z = __builtin_amdgcn_mfma_f32_16x16x32_bf16(A0, B0, z, 0, 0, 0);
      z = __builtin_amdgcn_mfma_f32_16x16x32_bf16(A1, B1, z, 0, 0, 0);
      if (quad < 2) {
#pragma unroll
        for (int i = 0; i < 4; ++i)
          Adst[(size_t)(nb + quad * 4 + i) * HD + wv * 16 + lane15] = f2bf(z[i]);
      }
    }
    __syncthreads();
    if (t < 8) {
      float si = sc_part[t][0] + sc_part[t][1] + sc_part[t][2] + sc_part[t][3];
      node_scores[nb + t] = 1.f / (1.f + __expf(-(si + bns2[0])));
    }
  } else {
    // next-layer p from bf16-rounded ht (element index = lq*8+u)
    float hb[8];
#pragma unroll
    for (int u = 0; u < 8; ++u) hb[u] = bf2f((short)f2bf(acc[u] * sc));
    float4 a1a = *(const float4*)&attn_next[lq * 8];
    float4 a1b = *(const float4*)&attn_next[lq * 8 + 4];
    float4 a2a = *(const float4*)&attn_next[64 + lq * 8];
    float4 a2b = *(const float4*)&attn_next[64 + lq * 8 + 4];
    float p1 = hb[0]*a1a.x + hb[1]*a1a.y + hb[2]*a1a.z + hb[3]*a1a.w
             + hb[4]*a1b.x + hb[5]*a1b.y + hb[6]*a1b.z + hb[7]*a1b.w;
    float p2 = hb[0]*a2a.x + hb[1]*a2a.y + hb[2]*a2a.z + hb[3]*a2a.w
             + hb[4]*a2b.x + hb[5]*a2b.y + hb[6]*a2b.z + hb[7]*a2b.w;
    p1 += __shfl_xor(p1, 1, 64); p1 += __shfl_xor(p1, 2, 64); p1 += __shfl_xor(p1, 4, 64);
    p2 += __shfl_xor(p2, 1, 64); p2 += __shfl_xor(p2, 2, 64); p2 += __shfl_xor(p2, 4, 64);
    if (l32 == 0) { p_src_out[n] = p1; p_dst_out[n] = p2; }
    if (l32 < 8) {
      *(float4*)&v_lds[nloc][l32 * 8] =
          make_float4(acc[0] * sc, acc[1] * sc, acc[2] * sc, acc[3] * sc);
      *(float4*)&v_lds[nloc][l32 * 8 + 4] =
          make_float4(acc[4] * sc, acc[5] * sc, acc[6] * sc, acc[7] * sc);
    }
    __syncthreads();
    // msg = ht @ Wmp_next + bmp_next for the block's 8 nodes; wave wv computes cols wv*16..+15
    int lane15 = lane & 15, quad = lane >> 4;
    bf16x8 A0 = frag_f32(&v_lds[lane15][quad * 8]);      // rows 8..15 junk, discarded
    bf16x8 A1 = frag_f32(&v_lds[lane15][32 + quad * 8]);
    bf16x8 B0 = *(const bf16x8*)&WmpPk_next[(wv * 2 + 0) * 512 + lane * 8];
    bf16x8 B1 = *(const bf16x8*)&WmpPk_next[(wv * 2 + 1) * 512 + lane * 8];
    f32x4 z = {0.f, 0.f, 0.f, 0.f};
    z = __builtin_amdgcn_mfma_f32_16x16x32_bf16(A0, B0, z, 0, 0, 0);
    z = __builtin_amdgcn_mfma_f32_16x16x32_bf16(A1, B1, z, 0, 0, 0);
    float vbm = bmp_next[wv * 16 + lane15];
    if (quad < 2) {
      int nb = blockIdx.x * 8;
#pragma unroll
      for (int i = 0; i < 4; ++i)
        msg_out[(size_t)(nb + quad * 4 + i) * HD + wv * 16 + lane15] = f2bf(z[i] + vbm);
    }
  }
}

// ---------------------------------------------------------------- edge scores (CSR order)
__global__ void __launch_bounds__(256) k_edge(const uint2* __restrict__ rdeg,
                                              const uint* __restrict__ csr,
                                              const uint* __restrict__ csr_eid,
                                              const ushort* __restrict__ Asrc,
                                              const ushort* __restrict__ Adst,
                                              const ushort* __restrict__ Te2bf,
                                              const float* __restrict__ Wes2,
                                              const float* __restrict__ bes2,
                                              float* __restrict__ edge_scores) {
  int t = threadIdx.x;
  int lane = t & 63;
  int n = (blockIdx.x * 256 + t) >> 6;
  if (n >= NN) return;
  int lq = lane & 7, lg = lane >> 3;
  uint2 rd = rdeg[n];
  int start = (int)rd.x;
  int deg = (int)rd.y;
  if (deg == 0) return;
  int end = start + deg;
  uint4 bv = *(const uint4*)&Adst[(size_t)n * HD + lq * 8];
  const float* wp = &Wes2[lq * 8];
  float4 w0 = *(const float4*)wp;
  float4 w1 = *(const float4*)(wp + 4);
  float b2 = bes2[0];
  for (int it = start; it < end; it += 8) {
    int e = it + lg;
    bool valid = e < end;
    float p = 0.f;
    if (valid) {
      uint pk = csr[e];
      int si = (int)(pk & 0xFFFFu);
      int ty = (int)((pk >> 16) & 0x3Fu);
      uint4 av = *(const uint4*)&Asrc[(size_t)si * HD + lq * 8];
      uint4 tv = *(const uint4*)&Te2bf[ty * HD + lq * 8];
      p += fmaxf(bflo(av.x) + bflo(bv.x) + bflo(tv.x), 0.f) * w0.x;
      p += fmaxf(bfhi(av.x) + bfhi(bv.x) + bfhi(tv.x), 0.f) * w0.y;
      p += fmaxf(bflo(av.y) + bflo(bv.y) + bflo(tv.y), 0.f) * w0.z;
      p += fmaxf(bfhi(av.y) + bfhi(bv.y) + bfhi(tv.y), 0.f) * w0.w;
      p += fmaxf(bflo(av.z) + bflo(bv.z) + bflo(tv.z), 0.f) * w1.x;
      p += fmaxf(bfhi(av.z) + bfhi(bv.z) + bfhi(tv.z), 0.f) * w1.y;
      p += fmaxf(bflo(av.w) + bflo(bv.w) + bflo(tv.w), 0.f) * w1.z;
      p += fmaxf(bfhi(av.w) + bfhi(bv.w) + bfhi(tv.w), 0.f) * w1.w;
    }
    p += __shfl_xor(p, 1, 64);
    p += __shfl_xor(p, 2, 64);
    p += __shfl_xor(p, 4, 64);
    if (valid && lq == 0) edge_scores[csr_eid[e]] = 1.f / (1.f + __expf(-(p + b2)));
  }
}

// ---------------------------------------------------------------- launch
extern "C" void kernel_launch(void* const* d_in, const int* in_sizes, int n_in,
                              void* d_out, int out_size, void* d_ws, size_t ws_size,
                              hipStream_t stream) {
  const float* node_features = (const float*)d_in[0];
  const float* edge_desc = (const float*)d_in[1];
  const float* query = (const float*)d_in[2];
  const float* Wn = (const float*)d_in[3];
  const float* bn = (const float*)d_in[4];
  const float* ts = (const float*)d_in[5];
  const float* Wq = (const float*)d_in[6];
  const float* bq = (const float*)d_in[7];
  const float* Ws_ = (const float*)d_in[8];
  const float* bs = (const float*)d_in[9];
  const float* attn_a = (const float*)d_in[10];
  const float* Wmp = (const float*)d_in[11];
  const float* bmp = (const float*)d_in[12];
  const float* Wns1 = (const float*)d_in[13];
  const float* bns1 = (const float*)d_in[14];
  const float* Wns2 = (const float*)d_in[15];
  const float* bns2 = (const float*)d_in[16];
  const float* Wes1 = (const float*)d_in[17];
  const float* bes1 = (const float*)d_in[18];
  const float* Wes2 = (const float*)d_in[19];
  const float* bes2 = (const float*)d_in[20];
  const int* edge_index = (const int*)d_in[21];
  const int* etype = (const int*)d_in[22];
  const int* src = edge_index;
  const int* dst = edge_index + NE;

  float* out_ns = (float*)d_out;
  float* out_es = out_ns + NN;
  float* out_h = out_es + NE;
  float* out_te = out_h + (size_t)NN * HD;

  char* w = (char*)d_ws;
  auto alloc = [&](size_t bytes) {
    char* p = w;
    w += (bytes + 1023) & ~(size_t)1023;
    return p;
  };
  ushort* msg0 = (ushort*)alloc((size_t)NN * HD * 2);      // msg ping
  ushort* msg1 = (ushort*)alloc((size_t)NN * HD * 2);      // msg pong
  ushort* Asrc = (ushort*)alloc((size_t)NN * HD * 2);      // } adjacent: ebuf alias spans both
  ushort* Adst = (ushort*)alloc((size_t)NN * HD * 2);      // }
  float* pA = (float*)alloc(NN * 4);
  float* pdA = (float*)alloc(NN * 4);
  float* pB = (float*)alloc(NN * 4);
  float* pdB = (float*)alloc(NN * 4);
  float* s_buf = (float*)alloc((size_t)NPAD * 4);
  float* qb = (float*)alloc(HD * 4);
  float* ta3 = (float*)alloc(NLAY * NTT * 4);
  ushort* Te2bf = (ushort*)alloc(NTT * HD * 2);
  ushort* WmpPk = (ushort*)alloc(NLAY * 4096 * 2);
  ushort* WnsPk = (ushort*)alloc(4096 * 2);
  ushort* WesaPk = (ushort*)alloc(4096 * 2);
  ushort* WesbPk = (ushort*)alloc(4096 * 2);
  int* bucket_cursor = (int*)alloc(NBUCK * 4);
  uint2* rdeg = (uint2*)alloc((size_t)NN * 8);
  uint* csr = (uint*)alloc((size_t)NPAD * 4);
  uint* csr_eid = (uint*)alloc((size_t)NPAD * 4);
  // ebuf (NPAD x 8B = 9.6 MB) aliases Asrc+Adst (12.8 MB contiguous): CSR build
  // finishes (k_scatter2) before k_agg<0> writes Asrc/Adst. No overlap in stream order.
  uint2* ebuf = (uint2*)Asrc;

  hipMemsetAsync(bucket_cursor, 0, NBUCK * 4, stream);
  // bin (196) + proj w/ fused layer-0 msg (782) + setup (1), co-scheduled
  kE<<<NBINBLK + NPROJ + 1, 256, 0, stream>>>(src, dst, etype, bucket_cursor, ebuf,
                                              node_features, Wn, bn, ts, Wmp, bmp, attn_a,
                                              msg0, pA, pdA,
                                              edge_desc, query, Wq, bq, Ws_, bs,
                                              Wns1, bns1, Wes1, bes1,
                                              out_te, qb, ta3, Te2bf, WmpPk,
                                              WnsPk, WesaPk, WesbPk);
  // order within bucket by node; emit rdeg + csr/csr_eid
  k_scatter2<<<NBUCK, 256, 0, stream>>>(bucket_cursor, ebuf, csr, csr_eid, rdeg);

  const int AGG_GRID = NN / 8;   // 6250 blocks, 8 nodes each
  // layer 0: gather msg0, emit msg1 = ht1 @ Wmp1 and p's for layer 1
  k_agg<1><<<AGG_GRID, 256, 0, stream>>>(rdeg, csr, pA, pdA, ta3 + 0 * NTT, msg0, s_buf,
                                         WmpPk + 1 * 4096, bmp + 1 * HD,
                                         attn_a + 1 * (2 * HD + TDD),
                                         msg1, pB, pdB,
                                         nullptr, nullptr, nullptr, nullptr, nullptr,
                                         nullptr, nullptr, nullptr, nullptr, nullptr);
  // layer 1: gather msg1, emit msg0 = ht2 @ Wmp2 and p's for layer 2
  k_agg<1><<<AGG_GRID, 256, 0, stream>>>(rdeg, csr, pB, pdB, ta3 + 1 * NTT, msg1, s_buf,
                                         WmpPk + 2 * 4096, bmp + 2 * HD,
                                         attn_a + 2 * (2 * HD + TDD),
                                         msg0, pA, pdA,
                                         nullptr, nullptr, nullptr, nullptr, nullptr,
                                         nullptr, nullptr, nullptr, nullptr, nullptr);
  // layer 2: gather msg0, fused heads (node_scores, h_out, Asrc, Adst)
  k_agg<0><<<AGG_GRID, 256, 0, stream>>>(rdeg, csr, pA, pdA, ta3 + 2 * NTT, msg0, s_buf,
                                         nullptr, nullptr, nullptr,
                                         nullptr, nullptr, nullptr,
                                         qb, Wns2, bns2, WnsPk, WesaPk, WesbPk,
                                         out_ns, out_h, Asrc, Adst);

  k_edge<<<(NN + 3) / 4, 256, 0, stream>>>(rdeg, csr, csr_eid, Asrc, Adst, Te2bf,
                                           Wes2, bes2, out_es);
}

// Round 6
// 285.160 us; speedup vs baseline: 1.3918x; 1.1002x over previous
//
#include <hip/hip_runtime.h>
#include <math.h>

#define NN 50000
#define NE 800000
#define NFD 256
#define HD 64
#define QDD 128
#define TDD 32
#define NTT 64
#define NLAY 3
#define LCLAMP 6.1030340f   // atanh(1 - 1e-5)
#define NBUCK 196           // ceil(50000/256) coarse buckets (dst >> 8)
#define SBUCK 6144          // padded slots per bucket (expected 4096, sigma ~64)
#define NPAD (NBUCK * SBUCK)
#define EPB 4096            // edges per bin block
#define NBINBLK 196         // ceil(800000/4096)
#define NPROJ 782           // ceil(50000/64)
#define PST 72              // proj LDS tile stride

typedef unsigned int uint;
typedef unsigned short ushort;
typedef __attribute__((ext_vector_type(8))) short bf16x8;
typedef __attribute__((ext_vector_type(4))) float f32x4;

__device__ __forceinline__ ushort f2bf(float f) {
  uint u = __float_as_uint(f);
  uint r = (u + 0x7FFFu + ((u >> 16) & 1u)) >> 16;
  return (ushort)r;
}
__device__ __forceinline__ short f2bfs(float f) { return (short)f2bf(f); }
__device__ __forceinline__ float bf2f(short s) { return __uint_as_float(((uint)(ushort)s) << 16); }
__device__ __forceinline__ float bflo(uint w) { return __uint_as_float(w << 16); }
__device__ __forceinline__ float bfhi(uint w) { return __uint_as_float(w & 0xFFFF0000u); }

// A-frag from 8 consecutive f32
__device__ __forceinline__ bf16x8 frag_f32(const float* p) {
  float4 a = *(const float4*)p;
  float4 b = *(const float4*)(p + 4);
  bf16x8 r;
  r[0] = f2bfs(a.x); r[1] = f2bfs(a.y); r[2] = f2bfs(a.z); r[3] = f2bfs(a.w);
  r[4] = f2bfs(b.x); r[5] = f2bfs(b.y); r[6] = f2bfs(b.z); r[7] = f2bfs(b.w);
  return r;
}
// B-frag from row-major W[K][64]: k=k0+quad*8+j, n=j0+lane15
__device__ __forceinline__ bf16x8 bfrag_w(const float* W, int k0, int j0, int lane15, int quad) {
  bf16x8 r;
#pragma unroll
  for (int j = 0; j < 8; ++j) r[j] = f2bfs(W[(k0 + quad * 8 + j) * HD + j0 + lane15]);
  return r;
}

// ---------------------------------------------------------------- te blocks (4): q/qe redundant, 16 types each
// block tb handles types [tb*16, tb*16+16); block 0 also emits qb.
__device__ void d_te(int tb,
                     const float* __restrict__ edge_desc, const float* __restrict__ query,
                     const float* __restrict__ Wq, const float* __restrict__ bq,
                     const float* __restrict__ Ws, const float* __restrict__ bs,
                     const float* __restrict__ attn_a,
                     const float* __restrict__ Wns1, const float* __restrict__ bns1,
                     const float* __restrict__ Wes1, const float* __restrict__ bes1,
                     float* __restrict__ out_type_emb,
                     float* __restrict__ qb, float* __restrict__ ta3,
                     ushort* __restrict__ Te2bf) {
  __shared__ float te_s[16 * TDD];   // this block's 16 rows
  __shared__ float q_s[HD];
  __shared__ float qe_s[HD];
  int t = threadIdx.x;
  if (t < HD) {
    float acc = bq[t];
    for (int k = 0; k < QDD; ++k) acc += query[k] * Wq[k * HD + t];
    q_s[t] = acc;
  }
  for (int idx = t; idx < 16 * TDD; idx += 256) {   // 2 iters
    int tyl = idx / TDD, d = idx % TDD;
    int ty = tb * 16 + tyl;
    float acc = bs[d];
    for (int k = 0; k < 64; ++k) acc += edge_desc[ty * 64 + k] * Ws[k * TDD + d];
    float v = tanhf(acc);
    te_s[idx] = v;
    out_type_emb[ty * TDD + d] = v;
  }
  __syncthreads();
  // qe (needs q_s); qb only on block 0
  if (t < HD) {
    float a2 = bes1[t];
    for (int k = 0; k < HD; ++k) a2 += q_s[k] * Wes1[(2 * HD + TDD + k) * HD + t];
    qe_s[t] = a2;
    if (tb == 0) {
      float a1 = bns1[t];
      for (int k = 0; k < HD; ++k) a1 += q_s[k] * Wns1[(HD + k) * HD + t];
      qb[t] = a1;
    }
  }
  // ta3 for this block's 16 types x 3 layers
  if (t < NLAY * 16) {
    int l = t >> 4, tyl = t & 15;
    float acc = 0.f;
    for (int d = 0; d < TDD; ++d) acc += te_s[tyl * TDD + d] * attn_a[l * (2 * HD + TDD) + 2 * HD + d];
    ta3[l * NTT + tb * 16 + tyl] = acc;
  }
  __syncthreads();
  // Te2bf rows
  for (int idx = t; idx < 16 * HD; idx += 256) {    // 4 iters
    int tyl = idx >> 6, j = idx & 63;
    float acc = qe_s[j];
#pragma unroll
    for (int d = 0; d < TDD; ++d) acc += te_s[tyl * TDD + d] * Wes1[(2 * HD + d) * HD + j];
    Te2bf[(tb * 16 + tyl) * HD + j] = f2bf(acc);
  }
}

// ---------------------------------------------------------------- pack blocks (5): one 4096-elem array each
__device__ void d_pack(int pid,
                       const float* __restrict__ Wmp, const float* __restrict__ Wns1,
                       const float* __restrict__ Wes1,
                       ushort* __restrict__ WmpPk, ushort* __restrict__ WnsPk,
                       ushort* __restrict__ WesaPk, ushort* __restrict__ WesbPk) {
  int t = threadIdx.x;
  for (int i = t; i < 4096; i += 256) {   // 16 iters
    int j = i & 7, lane = (i >> 3) & 63, f = (i >> 9) & 1, jt = (i >> 10) & 3;
    int q = lane >> 4, l15 = lane & 15;
    int row = f * 32 + q * 8 + j, col = jt * 16 + l15;
    if (pid < 2) {
      int l = pid + 1;   // layers 1,2 (layer 0 unused: proj loads Wmp0 direct)
      WmpPk[l * 4096 + i] = f2bf(Wmp[l * HD * HD + row * HD + col]);
    } else if (pid == 2) {
      WnsPk[i] = f2bf(Wns1[row * HD + col]);
    } else if (pid == 3) {
      WesaPk[i] = f2bf(Wes1[row * HD + col]);
    } else {
      WesbPk[i] = f2bf(Wes1[(64 + row) * HD + col]);
    }
  }
}

// ---------------------------------------------------------------- bin (device): append edges to padded bucket regions
// pk: src(16) | type(6)<<16 | (dst&255)<<22
__device__ void d_bin(int bbid,
                      const int* __restrict__ src,
                      const int* __restrict__ dst,
                      const int* __restrict__ etype,
                      int* __restrict__ bucket_cursor,
                      uint2* __restrict__ ebuf) {
  __shared__ int cntl[NBUCK];
  __shared__ int gbase[NBUCK];
  int t = threadIdx.x;
  for (int i = t; i < NBUCK; i += 256) cntl[i] = 0;
  __syncthreads();
  int e0 = bbid * EPB;
  int dd[16];
  uint pk[16];
  int rk[16];
#pragma unroll
  for (int c = 0; c < 4; ++c) {
    int eb = e0 + c * 1024 + t * 4;
    if (eb < NE) {   // NE%4==0 => eb<NE implies eb+3<NE
      int4 s4 = *(const int4*)&src[eb];
      int4 d4 = *(const int4*)&dst[eb];
      int4 y4 = *(const int4*)&etype[eb];
      int ds[4] = {d4.x, d4.y, d4.z, d4.w};
      int ss[4] = {s4.x, s4.y, s4.z, s4.w};
      int ys[4] = {y4.x, y4.y, y4.z, y4.w};
#pragma unroll
      for (int j = 0; j < 4; ++j) {
        int idx = c * 4 + j;
        int d = ds[j];
        dd[idx] = d;
        pk[idx] = (uint)ss[j] | ((uint)ys[j] << 16) | ((uint)(d & 255) << 22);
        rk[idx] = atomicAdd(&cntl[d >> 8], 1);
      }
    } else {
#pragma unroll
      for (int j = 0; j < 4; ++j) dd[c * 4 + j] = -1;
    }
  }
  __syncthreads();
  if (t < NBUCK && cntl[t] > 0)
    gbase[t] = t * SBUCK + atomicAdd(&bucket_cursor[t], cntl[t]);
  __syncthreads();
#pragma unroll
  for (int i = 0; i < 16; ++i) {
    if (dd[i] >= 0) {
      uint eid = (uint)(e0 + ((i >> 2) << 10) + t * 4 + (i & 3));
      ebuf[gbase[dd[i] >> 8] + rk[i]] = make_uint2(pk[i], eid);
    }
  }
}

// ---------------------------------------------------------------- proj (device) + fused layer-0 msg
// (Wmp0 B-frags loaded direct from f32 — no dependency on the setup blocks)
__device__ void d_proj(int pbid,
                       const float* __restrict__ X,
                       const float* __restrict__ Wn,
                       const float* __restrict__ bn,
                       const float* __restrict__ ts_p,
                       const float* __restrict__ Wmp0,
                       const float* __restrict__ bmp0,
                       const float* __restrict__ attn0,
                       ushort* __restrict__ msgbf,
                       float* __restrict__ p_src,
                       float* __restrict__ p_dst) {
  __shared__ ushort buf[2][64 * PST];            // 2 x 9216 B
  float* st = (float*)&buf[0][0];                // epilogue alias: 64 x 72 f32
  int t = threadIdx.x;
  int lane = t & 63, wv = t >> 6;
  int lane15 = lane & 15, quad = lane >> 4;
  int n0 = pbid * 64;
  int j0 = wv * 16;
  bf16x8 B[8];
#pragma unroll
  for (int fb = 0; fb < 8; ++fb) B[fb] = bfrag_w(Wn, fb * 32, j0, lane15, quad);

  int srow = t >> 2;
  int scg = (t & 3) * 16;
  int grow = n0 + srow; if (grow >= NN) grow = NN - 1;
  const float* xrow = X + (size_t)grow * NFD + scg;

  f32x4 acc[4];
#pragma unroll
  for (int mt = 0; mt < 4; ++mt) acc[mt] = (f32x4){0.f, 0.f, 0.f, 0.f};

  float4 r0 = *(const float4*)(xrow + 0);
  float4 r1 = *(const float4*)(xrow + 4);
  float4 r2 = *(const float4*)(xrow + 8);
  float4 r3 = *(const float4*)(xrow + 12);

  for (int c = 0; c < 4; ++c) {
    ushort* wp = &buf[c & 1][srow * PST + scg];
    uint4 o0, o1;
    o0.x = (uint)f2bf(r0.x) | ((uint)f2bf(r0.y) << 16);
    o0.y = (uint)f2bf(r0.z) | ((uint)f2bf(r0.w) << 16);
    o0.z = (uint)f2bf(r1.x) | ((uint)f2bf(r1.y) << 16);
    o0.w = (uint)f2bf(r1.z) | ((uint)f2bf(r1.w) << 16);
    o1.x = (uint)f2bf(r2.x) | ((uint)f2bf(r2.y) << 16);
    o1.y = (uint)f2bf(r2.z) | ((uint)f2bf(r2.w) << 16);
    o1.z = (uint)f2bf(r3.x) | ((uint)f2bf(r3.y) << 16);
    o1.w = (uint)f2bf(r3.z) | ((uint)f2bf(r3.w) << 16);
    *(uint4*)wp = o0;
    *(uint4*)(wp + 8) = o1;
    if (c < 3) {
      const float* nx = xrow + (c + 1) * 64;
      r0 = *(const float4*)(nx + 0);
      r1 = *(const float4*)(nx + 4);
      r2 = *(const float4*)(nx + 8);
      r3 = *(const float4*)(nx + 12);
    }
    __syncthreads();
    const ushort* bp = &buf[c & 1][0];
#pragma unroll
    for (int mt = 0; mt < 4; ++mt) {
#pragma unroll
      for (int ks = 0; ks < 2; ++ks) {
        bf16x8 A = *(const bf16x8*)&bp[(mt * 16 + lane15) * PST + ks * 32 + quad * 8];
        acc[mt] = __builtin_amdgcn_mfma_f32_16x16x32_bf16(A, B[c * 2 + ks], acc[mt], 0, 0, 0);
      }
    }
  }
  __syncthreads();
  float ts = ts_p[0];
  float vb = bn[j0 + lane15];
#pragma unroll
  for (int mt = 0; mt < 4; ++mt)
#pragma unroll
    for (int i = 0; i < 4; ++i)
      st[(mt * 16 + quad * 4 + i) * PST + j0 + lane15] = (acc[mt][i] + vb) * ts;
  __syncthreads();
  {
    int r = t >> 2, p = t & 3;
    float* rp = &st[r * PST + p * 16];
    float4 v0 = *(const float4*)(rp + 0);
    float4 v1 = *(const float4*)(rp + 4);
    float4 v2 = *(const float4*)(rp + 8);
    float4 v3 = *(const float4*)(rp + 12);
    float ssq = v0.x*v0.x + v0.y*v0.y + v0.z*v0.z + v0.w*v0.w
              + v1.x*v1.x + v1.y*v1.y + v1.z*v1.z + v1.w*v1.w
              + v2.x*v2.x + v2.y*v2.y + v2.z*v2.z + v2.w*v2.w
              + v3.x*v3.x + v3.y*v3.y + v3.z*v3.z + v3.w*v3.w;
    ssq += __shfl_xor(ssq, 1, 64);
    ssq += __shfl_xor(ssq, 2, 64);
    float nu = fmaxf(sqrtf(ssq), 1e-15f);
    float sc = fminf(nu, LCLAMP) / nu;
    *(float4*)(rp + 0) = make_float4(v0.x*sc, v0.y*sc, v0.z*sc, v0.w*sc);
    *(float4*)(rp + 4) = make_float4(v1.x*sc, v1.y*sc, v1.z*sc, v1.w*sc);
    *(float4*)(rp + 8) = make_float4(v2.x*sc, v2.y*sc, v2.z*sc, v2.w*sc);
    *(float4*)(rp + 12) = make_float4(v3.x*sc, v3.y*sc, v3.z*sc, v3.w*sc);
  }
  __syncthreads();
  // fused layer-0 msg
  {
    bf16x8 Bm0[4], Bm1[4];
    float vbm[4];
#pragma unroll
    for (int jt = 0; jt < 4; ++jt) {
      Bm0[jt] = bfrag_w(Wmp0, 0, jt * 16, lane15, quad);
      Bm1[jt] = bfrag_w(Wmp0, 32, jt * 16, lane15, quad);
      vbm[jt] = bmp0[jt * 16 + lane15];
    }
    int mrow = wv * 16 + lane15;
    bf16x8 A0 = frag_f32(&st[mrow * PST + quad * 8]);
    bf16x8 A1 = frag_f32(&st[mrow * PST + 32 + quad * 8]);
#pragma unroll
    for (int jt = 0; jt < 4; ++jt) {
      f32x4 z = {0.f, 0.f, 0.f, 0.f};
      z = __builtin_amdgcn_mfma_f32_16x16x32_bf16(A0, Bm0[jt], z, 0, 0, 0);
      z = __builtin_amdgcn_mfma_f32_16x16x32_bf16(A1, Bm1[jt], z, 0, 0, 0);
#pragma unroll
      for (int i = 0; i < 4; ++i) {
        int r = n0 + wv * 16 + quad * 4 + i;
        if (r < NN) msgbf[(size_t)r * HD + jt * 16 + lane15] = f2bf(z[i] + vbm[jt]);
      }
    }
    float4 a1l = *(const float4*)&attn0[quad * 8];
    float4 a1h = *(const float4*)&attn0[quad * 8 + 4];
    float4 a1l2 = *(const float4*)&attn0[32 + quad * 8];
    float4 a1h2 = *(const float4*)&attn0[32 + quad * 8 + 4];
    float4 a2l = *(const float4*)&attn0[64 + quad * 8];
    float4 a2h = *(const float4*)&attn0[64 + quad * 8 + 4];
    float4 a2l2 = *(const float4*)&attn0[96 + quad * 8];
    float4 a2h2 = *(const float4*)&attn0[96 + quad * 8 + 4];
    float p1 = bf2f(A0[0])*a1l.x + bf2f(A0[1])*a1l.y + bf2f(A0[2])*a1l.z + bf2f(A0[3])*a1l.w
             + bf2f(A0[4])*a1h.x + bf2f(A0[5])*a1h.y + bf2f(A0[6])*a1h.z + bf2f(A0[7])*a1h.w
             + bf2f(A1[0])*a1l2.x + bf2f(A1[1])*a1l2.y + bf2f(A1[2])*a1l2.z + bf2f(A1[3])*a1l2.w
             + bf2f(A1[4])*a1h2.x + bf2f(A1[5])*a1h2.y + bf2f(A1[6])*a1h2.z + bf2f(A1[7])*a1h2.w;
    float p2 = bf2f(A0[0])*a2l.x + bf2f(A0[1])*a2l.y + bf2f(A0[2])*a2l.z + bf2f(A0[3])*a2l.w
             + bf2f(A0[4])*a2h.x + bf2f(A0[5])*a2h.y + bf2f(A0[6])*a2h.z + bf2f(A0[7])*a2h.w
             + bf2f(A1[0])*a2l2.x + bf2f(A1[1])*a2l2.y + bf2f(A1[2])*a2l2.z + bf2f(A1[3])*a2l2.w
             + bf2f(A1[4])*a2h2.x + bf2f(A1[5])*a2h2.y + bf2f(A1[6])*a2h2.z + bf2f(A1[7])*a2h2.w;
    p1 += __shfl_xor(p1, 16, 64); p1 += __shfl_xor(p1, 32, 64);
    p2 += __shfl_xor(p2, 16, 64); p2 += __shfl_xor(p2, 32, 64);
    int prow = n0 + mrow;
    if (quad == 0 && prow < NN) { p_src[prow] = p1; p_dst[prow] = p2; }
  }
}

// kE: blocks [0,196)=bin, [196,978)=proj, [978,982)=te, [982,987)=pack — all independent
__global__ void __launch_bounds__(256) kE(const int* __restrict__ src, const int* __restrict__ dst,
                                          const int* __restrict__ etype, int* __restrict__ bucket_cursor,
                                          uint2* __restrict__ ebuf,
                                          const float* __restrict__ X, const float* __restrict__ Wn,
                                          const float* __restrict__ bn, const float* __restrict__ ts_p,
                                          const float* __restrict__ Wmp, const float* __restrict__ bmp,
                                          const float* __restrict__ attn_a,
                                          ushort* __restrict__ msgbf,
                                          float* __restrict__ p_src, float* __restrict__ p_dst,
                                          const float* __restrict__ edge_desc, const float* __restrict__ query,
                                          const float* __restrict__ Wq, const float* __restrict__ bq,
                                          const float* __restrict__ Ws, const float* __restrict__ bs,
                                          const float* __restrict__ Wns1, const float* __restrict__ bns1,
                                          const float* __restrict__ Wes1, const float* __restrict__ bes1,
                                          float* __restrict__ out_type_emb,
                                          float* __restrict__ qb, float* __restrict__ ta3,
                                          ushort* __restrict__ Te2bf, ushort* __restrict__ WmpPk,
                                          ushort* __restrict__ WnsPk, ushort* __restrict__ WesaPk,
                                          ushort* __restrict__ WesbPk) {
  if (blockIdx.x < NBINBLK)
    d_bin(blockIdx.x, src, dst, etype, bucket_cursor, ebuf);
  else if (blockIdx.x < NBINBLK + NPROJ)
    d_proj(blockIdx.x - NBINBLK, X, Wn, bn, ts_p, Wmp, bmp, attn_a, msgbf, p_src, p_dst);
  else if (blockIdx.x < NBINBLK + NPROJ + 4)
    d_te(blockIdx.x - (NBINBLK + NPROJ), edge_desc, query, Wq, bq, Ws, bs, attn_a,
         Wns1, bns1, Wes1, bes1, out_type_emb, qb, ta3, Te2bf);
  else
    d_pack(blockIdx.x - (NBINBLK + NPROJ + 4), Wmp, Wns1, Wes1, WmpPk, WnsPk, WesaPk, WesbPk);
}

// ---------------------------------------------------------------- scatter: order bucket by node, emit rdeg + csr
__global__ void __launch_bounds__(256) k_scatter2(const int* __restrict__ bucket_cursor,
                                                  const uint2* __restrict__ ebuf,
                                                  uint* __restrict__ csr,
                                                  uint* __restrict__ csr_eid,
                                                  uint2* __restrict__ rdeg) {
  __shared__ int cnt_l[256];
  __shared__ int curs[256];
  __shared__ int wsum[4], woff[4];
  int b = blockIdx.x;
  int t = threadIdx.x;
  int base = b * SBUCK;
  int cb = bucket_cursor[b];           // edges in this bucket
  cnt_l[t] = 0;
  __syncthreads();
  for (int i = t; i < cb; i += 256)
    atomicAdd(&cnt_l[(ebuf[base + i].x >> 22) & 255], 1);
  __syncthreads();
  int v = cnt_l[t];
  int lane = t & 63, wid = t >> 6;
  int x = v;
#pragma unroll
  for (int off = 1; off < 64; off <<= 1) {
    int y = __shfl_up(x, off, 64);
    if (lane >= off) x += y;
  }
  if (lane == 63) wsum[wid] = x;
  __syncthreads();
  if (t == 0) {
    int a = 0;
    for (int i = 0; i < 4; ++i) { woff[i] = a; a += wsum[i]; }
  }
  __syncthreads();
  int loff = woff[wid] + (x - v);      // exclusive prefix
  int n = (b << 8) + t;
  if (n < NN) rdeg[n] = make_uint2((uint)(base + loff), (uint)v);
  curs[t] = base + loff;
  __syncthreads();
  for (int i = t; i < cb; i += 256) {
    uint2 e = ebuf[base + i];
    int j = (e.x >> 22) & 255;
    int pos = atomicAdd(&curs[j], 1);
    csr[pos] = e.x & 0x3FFFFFu;
    csr_eid[pos] = e.y;
  }
}

// ---------------------------------------------------------------- softmax-aggregate (2 nodes/wave, 32 lanes each)
// FUSE=1: epilogue computes next-layer msg + p's.
// FUSE=0: final layer — epilogue fuses the former k_score (node head, Asrc/Adst, h_out).
template <int FUSE>
__global__ void __launch_bounds__(256) k_agg(const uint2* __restrict__ rdeg,
                                             const uint* __restrict__ csr,
                                             const float* __restrict__ p_src,
                                             const float* __restrict__ p_dst,
                                             const float* __restrict__ ta_l,
                                             const ushort* __restrict__ msgbf,
                                             float* __restrict__ s_buf,
                                             const ushort* __restrict__ WmpPk_next,
                                             const float* __restrict__ bmp_next,
                                             const float* __restrict__ attn_next,
                                             ushort* __restrict__ msg_out,
                                             float* __restrict__ p_src_out,
                                             float* __restrict__ p_dst_out,
                                             const float* __restrict__ qb,
                                             const float* __restrict__ Wns2,
                                             const float* __restrict__ bns2,
                                             const ushort* __restrict__ WnsPk,
                                             const ushort* __restrict__ WesaPk,
                                             const ushort* __restrict__ WesbPk,
                                             float* __restrict__ node_scores,
                                             float* __restrict__ h_out,
                                             ushort* __restrict__ Asrc,
                                             ushort* __restrict__ Adst) {
  __shared__ float v_lds[16][68];   // +4 pad: b128 reads 2-way max
  __shared__ float exs[4][64];      // per-wave staged exp(score)
  __shared__ uint  sis[4][64];      // per-wave staged src index
  __shared__ float sc_part[8][4];   // FUSE=0: node-head partials per wave
  int t = threadIdx.x;
  int lane = t & 63, wv = t >> 6;
  int nloc = t >> 5;                 // 0..7: node slot within block
  int half = (lane >> 5) & 1;        // which node within wave
  int l32 = lane & 31;               // lane within node's 32-group
  int lq = lane & 7;                 // dim group: owns dims lq*8..lq*8+7
  int lg32 = (lane >> 3) & 3;        // gather group within node (4 groups of 8)
  int n = blockIdx.x * 8 + nloc;     // grid exactly NN/8
  uint2 rd = rdeg[n];
  int start = (int)rd.x;
  int deg = (int)rd.y;
  int end = start + deg;
  float pd = p_dst[n];
  float acc[8];
#pragma unroll
  for (int u = 0; u < 8; ++u) acc[u] = 0.f;
  float exsum = 0.f;

  if (deg <= 32) {
    bool valid = l32 < deg;
    float s = -3.4e38f;
    int sidx = 0;
    if (valid) {
      uint pk = csr[start + l32];
      sidx = (int)(pk & 0xFFFFu);
      int ty = (int)(pk >> 16);
      float v = p_src[sidx] + pd + ta_l[ty];
      s = (v > 0.f) ? v : 0.2f * v;
    }
    float m = s;
#pragma unroll
    for (int off = 16; off >= 1; off >>= 1) m = fmaxf(m, __shfl_xor(m, off, 64));
    float ex = valid ? __expf(s - m) : 0.f;
    exsum = ex;
    if (valid) { exs[wv][lane] = ex; sis[wv][lane] = (uint)sidx; }
    for (int it = 0; it < deg; it += 4) {
      int el = it + lg32;
      if (el < deg) {
        float exk = exs[wv][half * 32 + el];       // 8 lanes same addr -> broadcast
        int sk = (int)sis[wv][half * 32 + el];
        uint4 mv = *(const uint4*)&msgbf[(size_t)sk * HD + lq * 8];
        acc[0] += exk * bflo(mv.x); acc[1] += exk * bfhi(mv.x);
        acc[2] += exk * bflo(mv.y); acc[3] += exk * bfhi(mv.y);
        acc[4] += exk * bflo(mv.z); acc[5] += exk * bfhi(mv.z);
        acc[6] += exk * bflo(mv.w); acc[7] += exk * bfhi(mv.w);
      }
    }
  } else {
    // rare path (deg>32): chunked at 32-lane width via s_buf
    float m = -3.4e38f;
    for (int base = start; base < end; base += 32) {
      int i = base + l32;
      float s = -3.4e38f;
      if (i < end) {
        uint pk = csr[i];
        int sidx = (int)(pk & 0xFFFFu);
        int ty = (int)(pk >> 16);
        float v = p_src[sidx] + pd + ta_l[ty];
        s = (v > 0.f) ? v : 0.2f * v;
        s_buf[i] = s;
      }
      m = fmaxf(m, s);
    }
#pragma unroll
    for (int off = 16; off >= 1; off >>= 1) m = fmaxf(m, __shfl_xor(m, off, 64));
    for (int base = start; base < end; base += 32) {
      int i = base + l32;
      if (i < end) {
        float ex = __expf(s_buf[i] - m);
        s_buf[i] = ex;
        exsum += ex;
      }
    }
    for (int it = start; it < end; it += 4) {
      int el = it + lg32;
      if (el < end) {
        float exk = s_buf[el];
        int sk = (int)(csr[el] & 0xFFFFu);
        uint4 mv = *(const uint4*)&msgbf[(size_t)sk * HD + lq * 8];
        acc[0] += exk * bflo(mv.x); acc[1] += exk * bfhi(mv.x);
        acc[2] += exk * bflo(mv.y); acc[3] += exk * bfhi(mv.y);
        acc[4] += exk * bflo(mv.z); acc[5] += exk * bfhi(mv.z);
        acc[6] += exk * bflo(mv.w); acc[7] += exk * bfhi(mv.w);
      }
    }
  }
  // reduce over the 4 gather groups (within each 32-half)
#pragma unroll
  for (int u = 0; u < 8; ++u) {
    acc[u] += __shfl_xor(acc[u], 8, 64);
    acc[u] += __shfl_xor(acc[u], 16, 64);
  }
#pragma unroll
  for (int off = 16; off >= 1; off >>= 1) exsum += __shfl_xor(exsum, off, 64);
  float inv = 1.f / (exsum + 1e-15f);
  float ss = 0.f;
#pragma unroll
  for (int u = 0; u < 8; ++u) {
    float v = fmaxf(acc[u] * inv, 0.f);
    acc[u] = v;
    ss += v * v;
  }
  ss += __shfl_xor(ss, 1, 64);
  ss += __shfl_xor(ss, 2, 64);
  ss += __shfl_xor(ss, 4, 64);
  float nu = fmaxf(sqrtf(ss), 1e-15f);
  float sc = fminf(nu, LCLAMP) / nu;

  if constexpr (FUSE == 0) {
    // ---- fused k_score: stage final ht rows, then heads + h_out from LDS ----
    if (l32 < 8) {
      *(float4*)&v_lds[nloc][l32 * 8] =
          make_float4(acc[0] * sc, acc[1] * sc, acc[2] * sc, acc[3] * sc);
      *(float4*)&v_lds[nloc][l32 * 8 + 4] =
          make_float4(acc[4] * sc, acc[5] * sc, acc[6] * sc, acc[7] * sc);
    }
    __syncthreads();
    int lane15 = lane & 15, quad = lane >> 4;
    int nb = blockIdx.x * 8;
    // h_out: exact f32 pass (replicates former k_score lane pattern bitwise)
    if (t < 32) {
      int r = t >> 2, p = t & 3;
      const float* rp = &v_lds[r][p * 16];
      float4 v0 = *(const float4*)(rp + 0);
      float4 v1 = *(const float4*)(rp + 4);
      float4 v2 = *(const float4*)(rp + 8);
      float4 v3 = *(const float4*)(rp + 12);
      float ssq = v0.x*v0.x + v0.y*v0.y + v0.z*v0.z + v0.w*v0.w
                + v1.x*v1.x + v1.y*v1.y + v1.z*v1.z + v1.w*v1.w
                + v2.x*v2.x + v2.y*v2.y + v2.z*v2.z + v2.w*v2.w
                + v3.x*v3.x + v3.y*v3.y + v3.z*v3.z + v3.w*v3.w;
      ssq += __shfl_xor(ssq, 1, 64);
      ssq += __shfl_xor(ssq, 2, 64);
      float nu2 = fmaxf(sqrtf(ssq), 1e-15f);
      float hs = tanhf(nu2) / nu2;
      float* op = h_out + (size_t)(nb + r) * HD + p * 16;
      *(float4*)(op + 0)  = make_float4(v0.x*hs, v0.y*hs, v0.z*hs, v0.w*hs);
      *(float4*)(op + 4)  = make_float4(v1.x*hs, v1.y*hs, v1.z*hs, v1.w*hs);
      *(float4*)(op + 8)  = make_float4(v2.x*hs, v2.y*hs, v2.z*hs, v2.w*hs);
      *(float4*)(op + 12) = make_float4(v3.x*hs, v3.y*hs, v3.z*hs, v3.w*hs);
    }
    // 3 GEMMs (node-head y, Asrc, Adst): wave wv computes cols wv*16..+15 for 8 nodes
    bf16x8 A0 = frag_f32(&v_lds[lane15][quad * 8]);      // rows 8..15 junk, outputs discarded
    bf16x8 A1 = frag_f32(&v_lds[lane15][32 + quad * 8]);
    // node head
    {
      bf16x8 B0 = *(const bf16x8*)&WnsPk[(wv * 2 + 0) * 512 + lane * 8];
      bf16x8 B1 = *(const bf16x8*)&WnsPk[(wv * 2 + 1) * 512 + lane * 8];
      f32x4 z = {0.f, 0.f, 0.f, 0.f};
      z = __builtin_amdgcn_mfma_f32_16x16x32_bf16(A0, B0, z, 0, 0, 0);
      z = __builtin_amdgcn_mfma_f32_16x16x32_bf16(A1, B1, z, 0, 0, 0);
      float vqb = qb[wv * 16 + lane15];
      float vw2 = Wns2[wv * 16 + lane15];
      if (quad < 2) {
#pragma unroll
        for (int i = 0; i < 4; ++i) {
          float part = fmaxf(z[i] + vqb, 0.f) * vw2;
          part += __shfl_xor(part, 1, 64);
          part += __shfl_xor(part, 2, 64);
          part += __shfl_xor(part, 4, 64);
          part += __shfl_xor(part, 8, 64);
          if (lane15 == 0) sc_part[quad * 4 + i][wv] = part;
        }
      }
    }
    // Asrc
    {
      bf16x8 B0 = *(const bf16x8*)&WesaPk[(wv * 2 + 0) * 512 + lane * 8];
      bf16x8 B1 = *(const bf16x8*)&WesaPk[(wv * 2 + 1) * 512 + lane * 8];
      f32x4 z = {0.f, 0.f, 0.f, 0.f};
      z = __builtin_amdgcn_mfma_f32_16x16x32_bf16(A0, B0, z, 0, 0, 0);
      z = __builtin_amdgcn_mfma_f32_16x16x32_bf16(A1, B1, z, 0, 0, 0);
      if (quad < 2) {
#pragma unroll
        for (int i = 0; i < 4; ++i)
          Asrc[(size_t)(nb + quad * 4 + i) * HD + wv * 16 + lane15] = f2bf(z[i]);
      }
    }
    // Adst
    {
      bf16x8 B0 = *(const bf16x8*)&WesbPk[(wv * 2 + 0) * 512 + lane * 8];
      bf16x8 B1 = *(const bf16x8*)&WesbPk[(wv * 2 + 1) * 512 + lane * 8];
      f32x4 z = {0.f, 0.f, 0.f, 0.f};
      z = __builtin_amdgcn_mfma_f32_16x16x32_bf16(A0, B0, z, 0, 0, 0);
      z = __builtin_amdgcn_mfma_f32_16x16x32_bf16(A1, B1, z, 0, 0, 0);
      if (quad < 2) {
#pragma unroll
        for (int i = 0; i < 4; ++i)
          Adst[(size_t)(nb + quad * 4 + i) * HD + wv * 16 + lane15] = f2bf(z[i]);
      }
    }
    __syncthreads();
    if (t < 8) {
      float si = sc_part[t][0] + sc_part[t][1] + sc_part[t][2] + sc_part[t][3];
      node_scores[nb + t] = 1.f / (1.f + __expf(-(si + bns2[0])));
    }
  } else {
    // next-layer p from bf16-rounded ht (element index = lq*8+u)
    float hb[8];
#pragma unroll
    for (int u = 0; u < 8; ++u) hb[u] = bf2f((short)f2bf(acc[u] * sc));
    float4 a1a = *(const float4*)&attn_next[lq * 8];
    float4 a1b = *(const float4*)&attn_next[lq * 8 + 4];
    float4 a2a = *(const float4*)&attn_next[64 + lq * 8];
    float4 a2b = *(const float4*)&attn_next[64 + lq * 8 + 4];
    float p1 = hb[0]*a1a.x + hb[1]*a1a.y + hb[2]*a1a.z + hb[3]*a1a.w
             + hb[4]*a1b.x + hb[5]*a1b.y + hb[6]*a1b.z + hb[7]*a1b.w;
    float p2 = hb[0]*a2a.x + hb[1]*a2a.y + hb[2]*a2a.z + hb[3]*a2a.w
             + hb[4]*a2b.x + hb[5]*a2b.y + hb[6]*a2b.z + hb[7]*a2b.w;
    p1 += __shfl_xor(p1, 1, 64); p1 += __shfl_xor(p1, 2, 64); p1 += __shfl_xor(p1, 4, 64);
    p2 += __shfl_xor(p2, 1, 64); p2 += __shfl_xor(p2, 2, 64); p2 += __shfl_xor(p2, 4, 64);
    if (l32 == 0) { p_src_out[n] = p1; p_dst_out[n] = p2; }
    if (l32 < 8) {
      *(float4*)&v_lds[nloc][l32 * 8] =
          make_float4(acc[0] * sc, acc[1] * sc, acc[2] * sc, acc[3] * sc);
      *(float4*)&v_lds[nloc][l32 * 8 + 4] =
          make_float4(acc[4] * sc, acc[5] * sc, acc[6] * sc, acc[7] * sc);
    }
    __syncthreads();
    // msg = ht @ Wmp_next + bmp_next for the block's 8 nodes; wave wv computes cols wv*16..+15
    int lane15 = lane & 15, quad = lane >> 4;
    bf16x8 A0 = frag_f32(&v_lds[lane15][quad * 8]);      // rows 8..15 junk, discarded
    bf16x8 A1 = frag_f32(&v_lds[lane15][32 + quad * 8]);
    bf16x8 B0 = *(const bf16x8*)&WmpPk_next[(wv * 2 + 0) * 512 + lane * 8];
    bf16x8 B1 = *(const bf16x8*)&WmpPk_next[(wv * 2 + 1) * 512 + lane * 8];
    f32x4 z = {0.f, 0.f, 0.f, 0.f};
    z = __builtin_amdgcn_mfma_f32_16x16x32_bf16(A0, B0, z, 0, 0, 0);
    z = __builtin_amdgcn_mfma_f32_16x16x32_bf16(A1, B1, z, 0, 0, 0);
    float vbm = bmp_next[wv * 16 + lane15];
    if (quad < 2) {
      int nb = blockIdx.x * 8;
#pragma unroll
      for (int i = 0; i < 4; ++i)
        msg_out[(size_t)(nb + quad * 4 + i) * HD + wv * 16 + lane15] = f2bf(z[i] + vbm);
    }
  }
}

// ---------------------------------------------------------------- edge scores (CSR order)
__global__ void __launch_bounds__(256) k_edge(const uint2* __restrict__ rdeg,
                                              const uint* __restrict__ csr,
                                              const uint* __restrict__ csr_eid,
                                              const ushort* __restrict__ Asrc,
                                              const ushort* __restrict__ Adst,
                                              const ushort* __restrict__ Te2bf,
                                              const float* __restrict__ Wes2,
                                              const float* __restrict__ bes2,
                                              float* __restrict__ edge_scores) {
  int t = threadIdx.x;
  int lane = t & 63;
  int n = (blockIdx.x * 256 + t) >> 6;
  if (n >= NN) return;
  int lq = lane & 7, lg = lane >> 3;
  uint2 rd = rdeg[n];
  int start = (int)rd.x;
  int deg = (int)rd.y;
  if (deg == 0) return;
  int end = start + deg;
  uint4 bv = *(const uint4*)&Adst[(size_t)n * HD + lq * 8];
  const float* wp = &Wes2[lq * 8];
  float4 w0 = *(const float4*)wp;
  float4 w1 = *(const float4*)(wp + 4);
  float b2 = bes2[0];
  for (int it = start; it < end; it += 8) {
    int e = it + lg;
    bool valid = e < end;
    float p = 0.f;
    if (valid) {
      uint pk = csr[e];
      int si = (int)(pk & 0xFFFFu);
      int ty = (int)((pk >> 16) & 0x3Fu);
      uint4 av = *(const uint4*)&Asrc[(size_t)si * HD + lq * 8];
      uint4 tv = *(const uint4*)&Te2bf[ty * HD + lq * 8];
      p += fmaxf(bflo(av.x) + bflo(bv.x) + bflo(tv.x), 0.f) * w0.x;
      p += fmaxf(bfhi(av.x) + bfhi(bv.x) + bfhi(tv.x), 0.f) * w0.y;
      p += fmaxf(bflo(av.y) + bflo(bv.y) + bflo(tv.y), 0.f) * w0.z;
      p += fmaxf(bfhi(av.y) + bfhi(bv.y) + bfhi(tv.y), 0.f) * w0.w;
      p += fmaxf(bflo(av.z) + bflo(bv.z) + bflo(tv.z), 0.f) * w1.x;
      p += fmaxf(bfhi(av.z) + bfhi(bv.z) + bfhi(tv.z), 0.f) * w1.y;
      p += fmaxf(bflo(av.w) + bflo(bv.w) + bflo(tv.w), 0.f) * w1.z;
      p += fmaxf(bfhi(av.w) + bfhi(bv.w) + bfhi(tv.w), 0.f) * w1.w;
    }
    p += __shfl_xor(p, 1, 64);
    p += __shfl_xor(p, 2, 64);
    p += __shfl_xor(p, 4, 64);
    if (valid && lq == 0) edge_scores[csr_eid[e]] = 1.f / (1.f + __expf(-(p + b2)));
  }
}

// ---------------------------------------------------------------- launch
extern "C" void kernel_launch(void* const* d_in, const int* in_sizes, int n_in,
                              void* d_out, int out_size, void* d_ws, size_t ws_size,
                              hipStream_t stream) {
  const float* node_features = (const float*)d_in[0];
  const float* edge_desc = (const float*)d_in[1];
  const float* query = (const float*)d_in[2];
  const float* Wn = (const float*)d_in[3];
  const float* bn = (const float*)d_in[4];
  const float* ts = (const float*)d_in[5];
  const float* Wq = (const float*)d_in[6];
  const float* bq = (const float*)d_in[7];
  const float* Ws_ = (const float*)d_in[8];
  const float* bs = (const float*)d_in[9];
  const float* attn_a = (const float*)d_in[10];
  const float* Wmp = (const float*)d_in[11];
  const float* bmp = (const float*)d_in[12];
  const float* Wns1 = (const float*)d_in[13];
  const float* bns1 = (const float*)d_in[14];
  const float* Wns2 = (const float*)d_in[15];
  const float* bns2 = (const float*)d_in[16];
  const float* Wes1 = (const float*)d_in[17];
  const float* bes1 = (const float*)d_in[18];
  const float* Wes2 = (const float*)d_in[19];
  const float* bes2 = (const float*)d_in[20];
  const int* edge_index = (const int*)d_in[21];
  const int* etype = (const int*)d_in[22];
  const int* src = edge_index;
  const int* dst = edge_index + NE;

  float* out_ns = (float*)d_out;
  float* out_es = out_ns + NN;
  float* out_h = out_es + NE;
  float* out_te = out_h + (size_t)NN * HD;

  char* w = (char*)d_ws;
  auto alloc = [&](size_t bytes) {
    char* p = w;
    w += (bytes + 1023) & ~(size_t)1023;
    return p;
  };
  ushort* msg0 = (ushort*)alloc((size_t)NN * HD * 2);      // msg ping
  ushort* msg1 = (ushort*)alloc((size_t)NN * HD * 2);      // msg pong
  ushort* Asrc = (ushort*)alloc((size_t)NN * HD * 2);      // } adjacent: ebuf alias spans both
  ushort* Adst = (ushort*)alloc((size_t)NN * HD * 2);      // }
  float* pA = (float*)alloc(NN * 4);
  float* pdA = (float*)alloc(NN * 4);
  float* pB = (float*)alloc(NN * 4);
  float* pdB = (float*)alloc(NN * 4);
  float* s_buf = (float*)alloc((size_t)NPAD * 4);
  float* qb = (float*)alloc(HD * 4);
  float* ta3 = (float*)alloc(NLAY * NTT * 4);
  ushort* Te2bf = (ushort*)alloc(NTT * HD * 2);
  ushort* WmpPk = (ushort*)alloc(NLAY * 4096 * 2);
  ushort* WnsPk = (ushort*)alloc(4096 * 2);
  ushort* WesaPk = (ushort*)alloc(4096 * 2);
  ushort* WesbPk = (ushort*)alloc(4096 * 2);
  int* bucket_cursor = (int*)alloc(NBUCK * 4);
  uint2* rdeg = (uint2*)alloc((size_t)NN * 8);
  uint* csr = (uint*)alloc((size_t)NPAD * 4);
  uint* csr_eid = (uint*)alloc((size_t)NPAD * 4);
  // ebuf (NPAD x 8B = 9.6 MB) aliases Asrc+Adst (12.8 MB contiguous): CSR build
  // finishes (k_scatter2) before k_agg<0> writes Asrc/Adst. No overlap in stream order.
  uint2* ebuf = (uint2*)Asrc;

  hipMemsetAsync(bucket_cursor, 0, NBUCK * 4, stream);
  // bin (196) + proj w/ fused layer-0 msg (782) + te x4 + pack x5, co-scheduled
  kE<<<NBINBLK + NPROJ + 4 + 5, 256, 0, stream>>>(src, dst, etype, bucket_cursor, ebuf,
                                                  node_features, Wn, bn, ts, Wmp, bmp, attn_a,
                                                  msg0, pA, pdA,
                                                  edge_desc, query, Wq, bq, Ws_, bs,
                                                  Wns1, bns1, Wes1, bes1,
                                                  out_te, qb, ta3, Te2bf, WmpPk,
                                                  WnsPk, WesaPk, WesbPk);
  // order within bucket by node; emit rdeg + csr/csr_eid
  k_scatter2<<<NBUCK, 256, 0, stream>>>(bucket_cursor, ebuf, csr, csr_eid, rdeg);

  const int AGG_GRID = NN / 8;   // 6250 blocks, 8 nodes each
  // layer 0: gather msg0, emit msg1 = ht1 @ Wmp1 and p's for layer 1
  k_agg<1><<<AGG_GRID, 256, 0, stream>>>(rdeg, csr, pA, pdA, ta3 + 0 * NTT, msg0, s_buf,
                                         WmpPk + 1 * 4096, bmp + 1 * HD,
                                         attn_a + 1 * (2 * HD + TDD),
                                         msg1, pB, pdB,
                                         nullptr, nullptr, nullptr, nullptr, nullptr,
                                         nullptr, nullptr, nullptr, nullptr, nullptr);
  // layer 1: gather msg1, emit msg0 = ht2 @ Wmp2 and p's for layer 2
  k_agg<1><<<AGG_GRID, 256, 0, stream>>>(rdeg, csr, pB, pdB, ta3 + 1 * NTT, msg1, s_buf,
                                         WmpPk + 2 * 4096, bmp + 2 * HD,
                                         attn_a + 2 * (2 * HD + TDD),
                                         msg0, pA, pdA,
                                         nullptr, nullptr, nullptr, nullptr, nullptr,
                                         nullptr, nullptr, nullptr, nullptr, nullptr);
  // layer 2: gather msg0, fused heads (node_scores, h_out, Asrc, Adst)
  k_agg<0><<<AGG_GRID, 256, 0, stream>>>(rdeg, csr, pA, pdA, ta3 + 2 * NTT, msg0, s_buf,
                                         nullptr, nullptr, nullptr,
                                         nullptr, nullptr, nullptr,
                                         qb, Wns2, bns2, WnsPk, WesaPk, WesbPk,
                                         out_ns, out_h, Asrc, Adst);

  k_edge<<<(NN + 3) / 4, 256, 0, stream>>>(rdeg, csr, csr_eid, Asrc, Adst, Te2bf,
                                           Wes2, bes2, out_es);
}

// Round 7
// 281.877 us; speedup vs baseline: 1.4080x; 1.0116x over previous
//
#include <hip/hip_runtime.h>
#include <math.h>

#define NN 50000
#define NE 800000
#define NFD 256
#define HD 64
#define QDD 128
#define TDD 32
#define NTT 64
#define NLAY 3
#define LCLAMP 6.1030340f   // atanh(1 - 1e-5)
#define NBUCK 196           // ceil(50000/256) coarse buckets (dst >> 8)
#define SBUCK 6144          // padded slots per bucket (expected 4096, sigma ~64)
#define NPAD (NBUCK * SBUCK)
#define EPB 4096            // edges per bin block
#define NBINBLK 196         // ceil(800000/4096)
#define NPROJ 782           // ceil(50000/64)
#define PST 72              // proj LDS tile stride

typedef unsigned int uint;
typedef unsigned short ushort;
typedef __attribute__((ext_vector_type(8))) short bf16x8;
typedef __attribute__((ext_vector_type(4))) float f32x4;

__device__ __forceinline__ ushort f2bf(float f) {
  uint u = __float_as_uint(f);
  uint r = (u + 0x7FFFu + ((u >> 16) & 1u)) >> 16;
  return (ushort)r;
}
__device__ __forceinline__ short f2bfs(float f) { return (short)f2bf(f); }
__device__ __forceinline__ float bf2f(short s) { return __uint_as_float(((uint)(ushort)s) << 16); }
__device__ __forceinline__ float bflo(uint w) { return __uint_as_float(w << 16); }
__device__ __forceinline__ float bfhi(uint w) { return __uint_as_float(w & 0xFFFF0000u); }

// A-frag from 8 consecutive f32
__device__ __forceinline__ bf16x8 frag_f32(const float* p) {
  float4 a = *(const float4*)p;
  float4 b = *(const float4*)(p + 4);
  bf16x8 r;
  r[0] = f2bfs(a.x); r[1] = f2bfs(a.y); r[2] = f2bfs(a.z); r[3] = f2bfs(a.w);
  r[4] = f2bfs(b.x); r[5] = f2bfs(b.y); r[6] = f2bfs(b.z); r[7] = f2bfs(b.w);
  return r;
}
// B-frag from row-major W[K][64]: k=k0+quad*8+j, n=j0+lane15
__device__ __forceinline__ bf16x8 bfrag_w(const float* W, int k0, int j0, int lane15, int quad) {
  bf16x8 r;
#pragma unroll
  for (int j = 0; j < 8; ++j) r[j] = f2bfs(W[(k0 + quad * 8 + j) * HD + j0 + lane15]);
  return r;
}

// ---------------------------------------------------------------- te blocks (4): q/qe redundant, 16 types each
// block tb handles types [tb*16, tb*16+16); block 0 also emits qb.
__device__ void d_te(int tb,
                     const float* __restrict__ edge_desc, const float* __restrict__ query,
                     const float* __restrict__ Wq, const float* __restrict__ bq,
                     const float* __restrict__ Ws, const float* __restrict__ bs,
                     const float* __restrict__ attn_a,
                     const float* __restrict__ Wns1, const float* __restrict__ bns1,
                     const float* __restrict__ Wes1, const float* __restrict__ bes1,
                     float* __restrict__ out_type_emb,
                     float* __restrict__ qb, float* __restrict__ ta3,
                     ushort* __restrict__ Te2bf) {
  __shared__ float te_s[16 * TDD];   // this block's 16 rows
  __shared__ float q_s[HD];
  __shared__ float qe_s[HD];
  int t = threadIdx.x;
  if (t < HD) {
    float acc = bq[t];
    for (int k = 0; k < QDD; ++k) acc += query[k] * Wq[k * HD + t];
    q_s[t] = acc;
  }
  for (int idx = t; idx < 16 * TDD; idx += 256) {   // 2 iters
    int tyl = idx / TDD, d = idx % TDD;
    int ty = tb * 16 + tyl;
    float acc = bs[d];
    for (int k = 0; k < 64; ++k) acc += edge_desc[ty * 64 + k] * Ws[k * TDD + d];
    float v = tanhf(acc);
    te_s[idx] = v;
    out_type_emb[ty * TDD + d] = v;
  }
  __syncthreads();
  // qe (needs q_s); qb only on block 0
  if (t < HD) {
    float a2 = bes1[t];
    for (int k = 0; k < HD; ++k) a2 += q_s[k] * Wes1[(2 * HD + TDD + k) * HD + t];
    qe_s[t] = a2;
    if (tb == 0) {
      float a1 = bns1[t];
      for (int k = 0; k < HD; ++k) a1 += q_s[k] * Wns1[(HD + k) * HD + t];
      qb[t] = a1;
    }
  }
  // ta3 for this block's 16 types x 3 layers
  if (t < NLAY * 16) {
    int l = t >> 4, tyl = t & 15;
    float acc = 0.f;
    for (int d = 0; d < TDD; ++d) acc += te_s[tyl * TDD + d] * attn_a[l * (2 * HD + TDD) + 2 * HD + d];
    ta3[l * NTT + tb * 16 + tyl] = acc;
  }
  __syncthreads();
  // Te2bf rows
  for (int idx = t; idx < 16 * HD; idx += 256) {    // 4 iters
    int tyl = idx >> 6, j = idx & 63;
    float acc = qe_s[j];
#pragma unroll
    for (int d = 0; d < TDD; ++d) acc += te_s[tyl * TDD + d] * Wes1[(2 * HD + d) * HD + j];
    Te2bf[(tb * 16 + tyl) * HD + j] = f2bf(acc);
  }
}

// ---------------------------------------------------------------- pack blocks (5): one 4096-elem array each
__device__ void d_pack(int pid,
                       const float* __restrict__ Wmp, const float* __restrict__ Wns1,
                       const float* __restrict__ Wes1,
                       ushort* __restrict__ WmpPk, ushort* __restrict__ WnsPk,
                       ushort* __restrict__ WesaPk, ushort* __restrict__ WesbPk) {
  int t = threadIdx.x;
  for (int i = t; i < 4096; i += 256) {   // 16 iters
    int j = i & 7, lane = (i >> 3) & 63, f = (i >> 9) & 1, jt = (i >> 10) & 3;
    int q = lane >> 4, l15 = lane & 15;
    int row = f * 32 + q * 8 + j, col = jt * 16 + l15;
    if (pid < 2) {
      int l = pid + 1;   // layers 1,2 (layer 0 unused: proj loads Wmp0 direct)
      WmpPk[l * 4096 + i] = f2bf(Wmp[l * HD * HD + row * HD + col]);
    } else if (pid == 2) {
      WnsPk[i] = f2bf(Wns1[row * HD + col]);
    } else if (pid == 3) {
      WesaPk[i] = f2bf(Wes1[row * HD + col]);
    } else {
      WesbPk[i] = f2bf(Wes1[(64 + row) * HD + col]);
    }
  }
}

// ---------------------------------------------------------------- bin (device): append edges to padded bucket regions
// pk: src(16) | type(6)<<16 | (dst&255)<<22
__device__ void d_bin(int bbid,
                      const int* __restrict__ src,
                      const int* __restrict__ dst,
                      const int* __restrict__ etype,
                      int* __restrict__ bucket_cursor,
                      uint2* __restrict__ ebuf) {
  __shared__ int cntl[NBUCK];
  __shared__ int gbase[NBUCK];
  int t = threadIdx.x;
  for (int i = t; i < NBUCK; i += 256) cntl[i] = 0;
  __syncthreads();
  int e0 = bbid * EPB;
  int dd[16];
  uint pk[16];
  int rk[16];
#pragma unroll
  for (int c = 0; c < 4; ++c) {
    int eb = e0 + c * 1024 + t * 4;
    if (eb < NE) {   // NE%4==0 => eb<NE implies eb+3<NE
      int4 s4 = *(const int4*)&src[eb];
      int4 d4 = *(const int4*)&dst[eb];
      int4 y4 = *(const int4*)&etype[eb];
      int ds[4] = {d4.x, d4.y, d4.z, d4.w};
      int ss[4] = {s4.x, s4.y, s4.z, s4.w};
      int ys[4] = {y4.x, y4.y, y4.z, y4.w};
#pragma unroll
      for (int j = 0; j < 4; ++j) {
        int idx = c * 4 + j;
        int d = ds[j];
        dd[idx] = d;
        pk[idx] = (uint)ss[j] | ((uint)ys[j] << 16) | ((uint)(d & 255) << 22);
        rk[idx] = atomicAdd(&cntl[d >> 8], 1);
      }
    } else {
#pragma unroll
      for (int j = 0; j < 4; ++j) dd[c * 4 + j] = -1;
    }
  }
  __syncthreads();
  if (t < NBUCK && cntl[t] > 0)
    gbase[t] = t * SBUCK + atomicAdd(&bucket_cursor[t], cntl[t]);
  __syncthreads();
#pragma unroll
  for (int i = 0; i < 16; ++i) {
    if (dd[i] >= 0) {
      uint eid = (uint)(e0 + ((i >> 2) << 10) + t * 4 + (i & 3));
      ebuf[gbase[dd[i] >> 8] + rk[i]] = make_uint2(pk[i], eid);
    }
  }
}

// ---------------------------------------------------------------- proj (device) + fused layer-0 msg
// (Wmp0 B-frags loaded direct from f32 — no dependency on the setup blocks)
__device__ void d_proj(int pbid,
                       const float* __restrict__ X,
                       const float* __restrict__ Wn,
                       const float* __restrict__ bn,
                       const float* __restrict__ ts_p,
                       const float* __restrict__ Wmp0,
                       const float* __restrict__ bmp0,
                       const float* __restrict__ attn0,
                       ushort* __restrict__ msgbf,
                       float* __restrict__ p_src,
                       float* __restrict__ p_dst) {
  __shared__ ushort buf[2][64 * PST];            // 2 x 9216 B
  float* st = (float*)&buf[0][0];                // epilogue alias: 64 x 72 f32
  int t = threadIdx.x;
  int lane = t & 63, wv = t >> 6;
  int lane15 = lane & 15, quad = lane >> 4;
  int n0 = pbid * 64;
  int j0 = wv * 16;
  bf16x8 B[8];
#pragma unroll
  for (int fb = 0; fb < 8; ++fb) B[fb] = bfrag_w(Wn, fb * 32, j0, lane15, quad);

  int srow = t >> 2;
  int scg = (t & 3) * 16;
  int grow = n0 + srow; if (grow >= NN) grow = NN - 1;
  const float* xrow = X + (size_t)grow * NFD + scg;

  f32x4 acc[4];
#pragma unroll
  for (int mt = 0; mt < 4; ++mt) acc[mt] = (f32x4){0.f, 0.f, 0.f, 0.f};

  float4 r0 = *(const float4*)(xrow + 0);
  float4 r1 = *(const float4*)(xrow + 4);
  float4 r2 = *(const float4*)(xrow + 8);
  float4 r3 = *(const float4*)(xrow + 12);

  for (int c = 0; c < 4; ++c) {
    ushort* wp = &buf[c & 1][srow * PST + scg];
    uint4 o0, o1;
    o0.x = (uint)f2bf(r0.x) | ((uint)f2bf(r0.y) << 16);
    o0.y = (uint)f2bf(r0.z) | ((uint)f2bf(r0.w) << 16);
    o0.z = (uint)f2bf(r1.x) | ((uint)f2bf(r1.y) << 16);
    o0.w = (uint)f2bf(r1.z) | ((uint)f2bf(r1.w) << 16);
    o1.x = (uint)f2bf(r2.x) | ((uint)f2bf(r2.y) << 16);
    o1.y = (uint)f2bf(r2.z) | ((uint)f2bf(r2.w) << 16);
    o1.z = (uint)f2bf(r3.x) | ((uint)f2bf(r3.y) << 16);
    o1.w = (uint)f2bf(r3.z) | ((uint)f2bf(r3.w) << 16);
    *(uint4*)wp = o0;
    *(uint4*)(wp + 8) = o1;
    if (c < 3) {
      const float* nx = xrow + (c + 1) * 64;
      r0 = *(const float4*)(nx + 0);
      r1 = *(const float4*)(nx + 4);
      r2 = *(const float4*)(nx + 8);
      r3 = *(const float4*)(nx + 12);
    }
    __syncthreads();
    const ushort* bp = &buf[c & 1][0];
#pragma unroll
    for (int mt = 0; mt < 4; ++mt) {
#pragma unroll
      for (int ks = 0; ks < 2; ++ks) {
        bf16x8 A = *(const bf16x8*)&bp[(mt * 16 + lane15) * PST + ks * 32 + quad * 8];
        acc[mt] = __builtin_amdgcn_mfma_f32_16x16x32_bf16(A, B[c * 2 + ks], acc[mt], 0, 0, 0);
      }
    }
  }
  __syncthreads();
  float ts = ts_p[0];
  float vb = bn[j0 + lane15];
#pragma unroll
  for (int mt = 0; mt < 4; ++mt)
#pragma unroll
    for (int i = 0; i < 4; ++i)
      st[(mt * 16 + quad * 4 + i) * PST + j0 + lane15] = (acc[mt][i] + vb) * ts;
  __syncthreads();
  {
    int r = t >> 2, p = t & 3;
    float* rp = &st[r * PST + p * 16];
    float4 v0 = *(const float4*)(rp + 0);
    float4 v1 = *(const float4*)(rp + 4);
    float4 v2 = *(const float4*)(rp + 8);
    float4 v3 = *(const float4*)(rp + 12);
    float ssq = v0.x*v0.x + v0.y*v0.y + v0.z*v0.z + v0.w*v0.w
              + v1.x*v1.x + v1.y*v1.y + v1.z*v1.z + v1.w*v1.w
              + v2.x*v2.x + v2.y*v2.y + v2.z*v2.z + v2.w*v2.w
              + v3.x*v3.x + v3.y*v3.y + v3.z*v3.z + v3.w*v3.w;
    ssq += __shfl_xor(ssq, 1, 64);
    ssq += __shfl_xor(ssq, 2, 64);
    float nu = fmaxf(sqrtf(ssq), 1e-15f);
    float sc = fminf(nu, LCLAMP) / nu;
    *(float4*)(rp + 0) = make_float4(v0.x*sc, v0.y*sc, v0.z*sc, v0.w*sc);
    *(float4*)(rp + 4) = make_float4(v1.x*sc, v1.y*sc, v1.z*sc, v1.w*sc);
    *(float4*)(rp + 8) = make_float4(v2.x*sc, v2.y*sc, v2.z*sc, v2.w*sc);
    *(float4*)(rp + 12) = make_float4(v3.x*sc, v3.y*sc, v3.z*sc, v3.w*sc);
  }
  __syncthreads();
  // fused layer-0 msg
  {
    bf16x8 Bm0[4], Bm1[4];
    float vbm[4];
#pragma unroll
    for (int jt = 0; jt < 4; ++jt) {
      Bm0[jt] = bfrag_w(Wmp0, 0, jt * 16, lane15, quad);
      Bm1[jt] = bfrag_w(Wmp0, 32, jt * 16, lane15, quad);
      vbm[jt] = bmp0[jt * 16 + lane15];
    }
    int mrow = wv * 16 + lane15;
    bf16x8 A0 = frag_f32(&st[mrow * PST + quad * 8]);
    bf16x8 A1 = frag_f32(&st[mrow * PST + 32 + quad * 8]);
#pragma unroll
    for (int jt = 0; jt < 4; ++jt) {
      f32x4 z = {0.f, 0.f, 0.f, 0.f};
      z = __builtin_amdgcn_mfma_f32_16x16x32_bf16(A0, Bm0[jt], z, 0, 0, 0);
      z = __builtin_amdgcn_mfma_f32_16x16x32_bf16(A1, Bm1[jt], z, 0, 0, 0);
#pragma unroll
      for (int i = 0; i < 4; ++i) {
        int r = n0 + wv * 16 + quad * 4 + i;
        if (r < NN) msgbf[(size_t)r * HD + jt * 16 + lane15] = f2bf(z[i] + vbm[jt]);
      }
    }
    float4 a1l = *(const float4*)&attn0[quad * 8];
    float4 a1h = *(const float4*)&attn0[quad * 8 + 4];
    float4 a1l2 = *(const float4*)&attn0[32 + quad * 8];
    float4 a1h2 = *(const float4*)&attn0[32 + quad * 8 + 4];
    float4 a2l = *(const float4*)&attn0[64 + quad * 8];
    float4 a2h = *(const float4*)&attn0[64 + quad * 8 + 4];
    float4 a2l2 = *(const float4*)&attn0[96 + quad * 8];
    float4 a2h2 = *(const float4*)&attn0[96 + quad * 8 + 4];
    float p1 = bf2f(A0[0])*a1l.x + bf2f(A0[1])*a1l.y + bf2f(A0[2])*a1l.z + bf2f(A0[3])*a1l.w
             + bf2f(A0[4])*a1h.x + bf2f(A0[5])*a1h.y + bf2f(A0[6])*a1h.z + bf2f(A0[7])*a1h.w
             + bf2f(A1[0])*a1l2.x + bf2f(A1[1])*a1l2.y + bf2f(A1[2])*a1l2.z + bf2f(A1[3])*a1l2.w
             + bf2f(A1[4])*a1h2.x + bf2f(A1[5])*a1h2.y + bf2f(A1[6])*a1h2.z + bf2f(A1[7])*a1h2.w;
    float p2 = bf2f(A0[0])*a2l.x + bf2f(A0[1])*a2l.y + bf2f(A0[2])*a2l.z + bf2f(A0[3])*a2l.w
             + bf2f(A0[4])*a2h.x + bf2f(A0[5])*a2h.y + bf2f(A0[6])*a2h.z + bf2f(A0[7])*a2h.w
             + bf2f(A1[0])*a2l2.x + bf2f(A1[1])*a2l2.y + bf2f(A1[2])*a2l2.z + bf2f(A1[3])*a2l2.w
             + bf2f(A1[4])*a2h2.x + bf2f(A1[5])*a2h2.y + bf2f(A1[6])*a2h2.z + bf2f(A1[7])*a2h2.w;
    p1 += __shfl_xor(p1, 16, 64); p1 += __shfl_xor(p1, 32, 64);
    p2 += __shfl_xor(p2, 16, 64); p2 += __shfl_xor(p2, 32, 64);
    int prow = n0 + mrow;
    if (quad == 0 && prow < NN) { p_src[prow] = p1; p_dst[prow] = p2; }
  }
}

// kE: blocks [0,196)=bin, [196,978)=proj, [978,982)=te, [982,987)=pack — all independent
__global__ void __launch_bounds__(256) kE(const int* __restrict__ src, const int* __restrict__ dst,
                                          const int* __restrict__ etype, int* __restrict__ bucket_cursor,
                                          uint2* __restrict__ ebuf,
                                          const float* __restrict__ X, const float* __restrict__ Wn,
                                          const float* __restrict__ bn, const float* __restrict__ ts_p,
                                          const float* __restrict__ Wmp, const float* __restrict__ bmp,
                                          const float* __restrict__ attn_a,
                                          ushort* __restrict__ msgbf,
                                          float* __restrict__ p_src, float* __restrict__ p_dst,
                                          const float* __restrict__ edge_desc, const float* __restrict__ query,
                                          const float* __restrict__ Wq, const float* __restrict__ bq,
                                          const float* __restrict__ Ws, const float* __restrict__ bs,
                                          const float* __restrict__ Wns1, const float* __restrict__ bns1,
                                          const float* __restrict__ Wes1, const float* __restrict__ bes1,
                                          float* __restrict__ out_type_emb,
                                          float* __restrict__ qb, float* __restrict__ ta3,
                                          ushort* __restrict__ Te2bf, ushort* __restrict__ WmpPk,
                                          ushort* __restrict__ WnsPk, ushort* __restrict__ WesaPk,
                                          ushort* __restrict__ WesbPk) {
  if (blockIdx.x < NBINBLK)
    d_bin(blockIdx.x, src, dst, etype, bucket_cursor, ebuf);
  else if (blockIdx.x < NBINBLK + NPROJ)
    d_proj(blockIdx.x - NBINBLK, X, Wn, bn, ts_p, Wmp, bmp, attn_a, msgbf, p_src, p_dst);
  else if (blockIdx.x < NBINBLK + NPROJ + 4)
    d_te(blockIdx.x - (NBINBLK + NPROJ), edge_desc, query, Wq, bq, Ws, bs, attn_a,
         Wns1, bns1, Wes1, bes1, out_type_emb, qb, ta3, Te2bf);
  else
    d_pack(blockIdx.x - (NBINBLK + NPROJ + 4), Wmp, Wns1, Wes1, WmpPk, WnsPk, WesaPk, WesbPk);
}

// ---------------------------------------------------------------- scatter: order bucket by node, emit rdeg + csr
// 1024 threads/block: counting + scatter 4x parallel; 256-wide scan on waves 0-3.
__global__ void __launch_bounds__(1024) k_scatter2(const int* __restrict__ bucket_cursor,
                                                   const uint2* __restrict__ ebuf,
                                                   uint* __restrict__ csr,
                                                   uint* __restrict__ csr_eid,
                                                   uint2* __restrict__ rdeg) {
  __shared__ int cnt_l[256];
  __shared__ int curs[256];
  __shared__ int wsum[4], woff[4];
  int b = blockIdx.x;
  int t = threadIdx.x;
  int base = b * SBUCK;
  int cb = bucket_cursor[b];           // edges in this bucket
  if (t < 256) cnt_l[t] = 0;
  __syncthreads();
  for (int i = t; i < cb; i += 1024)
    atomicAdd(&cnt_l[(ebuf[base + i].x >> 22) & 255], 1);
  __syncthreads();
  int v = 0, x = 0;
  int lane = t & 63, wid = t >> 6;
  if (t < 256) {                       // waves 0-3 fully active: shfl is wave-uniform
    v = cnt_l[t];
    x = v;
#pragma unroll
    for (int off = 1; off < 64; off <<= 1) {
      int y = __shfl_up(x, off, 64);
      if (lane >= off) x += y;
    }
    if (lane == 63) wsum[wid] = x;
  }
  __syncthreads();
  if (t == 0) {
    int a = 0;
    for (int i = 0; i < 4; ++i) { woff[i] = a; a += wsum[i]; }
  }
  __syncthreads();
  if (t < 256) {
    int loff = woff[wid] + (x - v);    // exclusive prefix
    int n = (b << 8) + t;
    if (n < NN) rdeg[n] = make_uint2((uint)(base + loff), (uint)v);
    curs[t] = base + loff;
  }
  __syncthreads();
  for (int i = t; i < cb; i += 1024) {
    uint2 e = ebuf[base + i];
    int j = (e.x >> 22) & 255;
    int pos = atomicAdd(&curs[j], 1);
    csr[pos] = e.x & 0x3FFFFFu;
    csr_eid[pos] = e.y;
  }
}

// ---------------------------------------------------------------- softmax-aggregate (2 nodes/wave, 32 lanes each)
// FUSE=1: epilogue computes next-layer msg + p's.
// FUSE=0: final layer — epilogue fuses the former k_score (node head, Asrc/Adst, h_out).
template <int FUSE>
__global__ void __launch_bounds__(256) k_agg(const uint2* __restrict__ rdeg,
                                             const uint* __restrict__ csr,
                                             const float* __restrict__ p_src,
                                             const float* __restrict__ p_dst,
                                             const float* __restrict__ ta_l,
                                             const ushort* __restrict__ msgbf,
                                             float* __restrict__ s_buf,
                                             const ushort* __restrict__ WmpPk_next,
                                             const float* __restrict__ bmp_next,
                                             const float* __restrict__ attn_next,
                                             ushort* __restrict__ msg_out,
                                             float* __restrict__ p_src_out,
                                             float* __restrict__ p_dst_out,
                                             const float* __restrict__ qb,
                                             const float* __restrict__ Wns2,
                                             const float* __restrict__ bns2,
                                             const ushort* __restrict__ WnsPk,
                                             const ushort* __restrict__ WesaPk,
                                             const ushort* __restrict__ WesbPk,
                                             float* __restrict__ node_scores,
                                             float* __restrict__ h_out,
                                             ushort* __restrict__ Asrc,
                                             ushort* __restrict__ Adst) {
  __shared__ float v_lds[16][68];   // +4 pad: b128 reads 2-way max
  __shared__ float exs[4][64];      // per-wave staged exp(score)
  __shared__ uint  sis[4][64];      // per-wave staged src index
  __shared__ float sc_part[8][4];   // FUSE=0: node-head partials per wave
  int t = threadIdx.x;
  int lane = t & 63, wv = t >> 6;
  int nloc = t >> 5;                 // 0..7: node slot within block
  int half = (lane >> 5) & 1;        // which node within wave
  int l32 = lane & 31;               // lane within node's 32-group
  int lq = lane & 7;                 // dim group: owns dims lq*8..lq*8+7
  int lg32 = (lane >> 3) & 3;        // gather group within node (4 groups of 8)
  int n = blockIdx.x * 8 + nloc;     // grid exactly NN/8
  uint2 rd = rdeg[n];
  int start = (int)rd.x;
  int deg = (int)rd.y;
  int end = start + deg;
  float pd = p_dst[n];
  float acc[8];
#pragma unroll
  for (int u = 0; u < 8; ++u) acc[u] = 0.f;
  float exsum = 0.f;

  if (deg <= 32) {
    bool valid = l32 < deg;
    float s = -3.4e38f;
    int sidx = 0;
    if (valid) {
      uint pk = csr[start + l32];
      sidx = (int)(pk & 0xFFFFu);
      int ty = (int)(pk >> 16);
      float v = p_src[sidx] + pd + ta_l[ty];
      s = (v > 0.f) ? v : 0.2f * v;
    }
    float m = s;
#pragma unroll
    for (int off = 16; off >= 1; off >>= 1) m = fmaxf(m, __shfl_xor(m, off, 64));
    float ex = valid ? __expf(s - m) : 0.f;
    exsum = ex;
    if (valid) { exs[wv][lane] = ex; sis[wv][lane] = (uint)sidx; }
    for (int it = 0; it < deg; it += 4) {
      int el = it + lg32;
      if (el < deg) {
        float exk = exs[wv][half * 32 + el];       // 8 lanes same addr -> broadcast
        int sk = (int)sis[wv][half * 32 + el];
        uint4 mv = *(const uint4*)&msgbf[(size_t)sk * HD + lq * 8];
        acc[0] += exk * bflo(mv.x); acc[1] += exk * bfhi(mv.x);
        acc[2] += exk * bflo(mv.y); acc[3] += exk * bfhi(mv.y);
        acc[4] += exk * bflo(mv.z); acc[5] += exk * bfhi(mv.z);
        acc[6] += exk * bflo(mv.w); acc[7] += exk * bfhi(mv.w);
      }
    }
  } else {
    // rare path (deg>32): chunked at 32-lane width via s_buf
    float m = -3.4e38f;
    for (int base = start; base < end; base += 32) {
      int i = base + l32;
      float s = -3.4e38f;
      if (i < end) {
        uint pk = csr[i];
        int sidx = (int)(pk & 0xFFFFu);
        int ty = (int)(pk >> 16);
        float v = p_src[sidx] + pd + ta_l[ty];
        s = (v > 0.f) ? v : 0.2f * v;
        s_buf[i] = s;
      }
      m = fmaxf(m, s);
    }
#pragma unroll
    for (int off = 16; off >= 1; off >>= 1) m = fmaxf(m, __shfl_xor(m, off, 64));
    for (int base = start; base < end; base += 32) {
      int i = base + l32;
      if (i < end) {
        float ex = __expf(s_buf[i] - m);
        s_buf[i] = ex;
        exsum += ex;
      }
    }
    for (int it = start; it < end; it += 4) {
      int el = it + lg32;
      if (el < end) {
        float exk = s_buf[el];
        int sk = (int)(csr[el] & 0xFFFFu);
        uint4 mv = *(const uint4*)&msgbf[(size_t)sk * HD + lq * 8];
        acc[0] += exk * bflo(mv.x); acc[1] += exk * bfhi(mv.x);
        acc[2] += exk * bflo(mv.y); acc[3] += exk * bfhi(mv.y);
        acc[4] += exk * bflo(mv.z); acc[5] += exk * bfhi(mv.z);
        acc[6] += exk * bflo(mv.w); acc[7] += exk * bfhi(mv.w);
      }
    }
  }
  // reduce over the 4 gather groups (within each 32-half)
#pragma unroll
  for (int u = 0; u < 8; ++u) {
    acc[u] += __shfl_xor(acc[u], 8, 64);
    acc[u] += __shfl_xor(acc[u], 16, 64);
  }
#pragma unroll
  for (int off = 16; off >= 1; off >>= 1) exsum += __shfl_xor(exsum, off, 64);
  float inv = 1.f / (exsum + 1e-15f);
  float ss = 0.f;
#pragma unroll
  for (int u = 0; u < 8; ++u) {
    float v = fmaxf(acc[u] * inv, 0.f);
    acc[u] = v;
    ss += v * v;
  }
  ss += __shfl_xor(ss, 1, 64);
  ss += __shfl_xor(ss, 2, 64);
  ss += __shfl_xor(ss, 4, 64);
  float nu = fmaxf(sqrtf(ss), 1e-15f);
  float sc = fminf(nu, LCLAMP) / nu;

  if constexpr (FUSE == 0) {
    // ---- fused k_score: stage final ht rows, then heads + h_out from LDS ----
    if (l32 < 8) {
      *(float4*)&v_lds[nloc][l32 * 8] =
          make_float4(acc[0] * sc, acc[1] * sc, acc[2] * sc, acc[3] * sc);
      *(float4*)&v_lds[nloc][l32 * 8 + 4] =
          make_float4(acc[4] * sc, acc[5] * sc, acc[6] * sc, acc[7] * sc);
    }
    __syncthreads();
    int lane15 = lane & 15, quad = lane >> 4;
    int nb = blockIdx.x * 8;
    // h_out: exact f32 pass (replicates former k_score lane pattern bitwise)
    if (t < 32) {
      int r = t >> 2, p = t & 3;
      const float* rp = &v_lds[r][p * 16];
      float4 v0 = *(const float4*)(rp + 0);
      float4 v1 = *(const float4*)(rp + 4);
      float4 v2 = *(const float4*)(rp + 8);
      float4 v3 = *(const float4*)(rp + 12);
      float ssq = v0.x*v0.x + v0.y*v0.y + v0.z*v0.z + v0.w*v0.w
                + v1.x*v1.x + v1.y*v1.y + v1.z*v1.z + v1.w*v1.w
                + v2.x*v2.x + v2.y*v2.y + v2.z*v2.z + v2.w*v2.w
                + v3.x*v3.x + v3.y*v3.y + v3.z*v3.z + v3.w*v3.w;
      ssq += __shfl_xor(ssq, 1, 64);
      ssq += __shfl_xor(ssq, 2, 64);
      float nu2 = fmaxf(sqrtf(ssq), 1e-15f);
      float hs = tanhf(nu2) / nu2;
      float* op = h_out + (size_t)(nb + r) * HD + p * 16;
      *(float4*)(op + 0)  = make_float4(v0.x*hs, v0.y*hs, v0.z*hs, v0.w*hs);
      *(float4*)(op + 4)  = make_float4(v1.x*hs, v1.y*hs, v1.z*hs, v1.w*hs);
      *(float4*)(op + 8)  = make_float4(v2.x*hs, v2.y*hs, v2.z*hs, v2.w*hs);
      *(float4*)(op + 12) = make_float4(v3.x*hs, v3.y*hs, v3.z*hs, v3.w*hs);
    }
    // 3 GEMMs (node-head y, Asrc, Adst): wave wv computes cols wv*16..+15 for 8 nodes
    bf16x8 A0 = frag_f32(&v_lds[lane15][quad * 8]);      // rows 8..15 junk, outputs discarded
    bf16x8 A1 = frag_f32(&v_lds[lane15][32 + quad * 8]);
    // node head
    {
      bf16x8 B0 = *(const bf16x8*)&WnsPk[(wv * 2 + 0) * 512 + lane * 8];
      bf16x8 B1 = *(const bf16x8*)&WnsPk[(wv * 2 + 1) * 512 + lane * 8];
      f32x4 z = {0.f, 0.f, 0.f, 0.f};
      z = __builtin_amdgcn_mfma_f32_16x16x32_bf16(A0, B0, z, 0, 0, 0);
      z = __builtin_amdgcn_mfma_f32_16x16x32_bf16(A1, B1, z, 0, 0, 0);
      float vqb = qb[wv * 16 + lane15];
      float vw2 = Wns2[wv * 16 + lane15];
      if (quad < 2) {
#pragma unroll
        for (int i = 0; i < 4; ++i) {
          float part = fmaxf(z[i] + vqb, 0.f) * vw2;
          part += __shfl_xor(part, 1, 64);
          part += __shfl_xor(part, 2, 64);
          part += __shfl_xor(part, 4, 64);
          part += __shfl_xor(part, 8, 64);
          if (lane15 == 0) sc_part[quad * 4 + i][wv] = part;
        }
      }
    }
    // Asrc
    {
      bf16x8 B0 = *(const bf16x8*)&WesaPk[(wv * 2 + 0) * 512 + lane * 8];
      bf16x8 B1 = *(const bf16x8*)&WesaPk[(wv * 2 + 1) * 512 + lane * 8];
      f32x4 z = {0.f, 0.f, 0.f, 0.f};
      z = __builtin_amdgcn_mfma_f32_16x16x32_bf16(A0, B0, z, 0, 0, 0);
      z = __builtin_amdgcn_mfma_f32_16x16x32_bf16(A1, B1, z, 0, 0, 0);
      if (quad < 2) {
#pragma unroll
        for (int i = 0; i < 4; ++i)
          Asrc[(size_t)(nb + quad * 4 + i) * HD + wv * 16 + lane15] = f2bf(z[i]);
      }
    }
    // Adst
    {
      bf16x8 B0 = *(const bf16x8*)&WesbPk[(wv * 2 + 0) * 512 + lane * 8];
      bf16x8 B1 = *(const bf16x8*)&WesbPk[(wv * 2 + 1) * 512 + lane * 8];
      f32x4 z = {0.f, 0.f, 0.f, 0.f};
      z = __builtin_amdgcn_mfma_f32_16x16x32_bf16(A0, B0, z, 0, 0, 0);
      z = __builtin_amdgcn_mfma_f32_16x16x32_bf16(A1, B1, z, 0, 0, 0);
      if (quad < 2) {
#pragma unroll
        for (int i = 0; i < 4; ++i)
          Adst[(size_t)(nb + quad * 4 + i) * HD + wv * 16 + lane15] = f2bf(z[i]);
      }
    }
    __syncthreads();
    if (t < 8) {
      float si = sc_part[t][0] + sc_part[t][1] + sc_part[t][2] + sc_part[t][3];
      node_scores[nb + t] = 1.f / (1.f + __expf(-(si + bns2[0])));
    }
  } else {
    // next-layer p from bf16-rounded ht (element index = lq*8+u)
    float hb[8];
#pragma unroll
    for (int u = 0; u < 8; ++u) hb[u] = bf2f((short)f2bf(acc[u] * sc));
    float4 a1a = *(const float4*)&attn_next[lq * 8];
    float4 a1b = *(const float4*)&attn_next[lq * 8 + 4];
    float4 a2a = *(const float4*)&attn_next[64 + lq * 8];
    float4 a2b = *(const float4*)&attn_next[64 + lq * 8 + 4];
    float p1 = hb[0]*a1a.x + hb[1]*a1a.y + hb[2]*a1a.z + hb[3]*a1a.w
             + hb[4]*a1b.x + hb[5]*a1b.y + hb[6]*a1b.z + hb[7]*a1b.w;
    float p2 = hb[0]*a2a.x + hb[1]*a2a.y + hb[2]*a2a.z + hb[3]*a2a.w
             + hb[4]*a2b.x + hb[5]*a2b.y + hb[6]*a2b.z + hb[7]*a2b.w;
    p1 += __shfl_xor(p1, 1, 64); p1 += __shfl_xor(p1, 2, 64); p1 += __shfl_xor(p1, 4, 64);
    p2 += __shfl_xor(p2, 1, 64); p2 += __shfl_xor(p2, 2, 64); p2 += __shfl_xor(p2, 4, 64);
    if (l32 == 0) { p_src_out[n] = p1; p_dst_out[n] = p2; }
    if (l32 < 8) {
      *(float4*)&v_lds[nloc][l32 * 8] =
          make_float4(acc[0] * sc, acc[1] * sc, acc[2] * sc, acc[3] * sc);
      *(float4*)&v_lds[nloc][l32 * 8 + 4] =
          make_float4(acc[4] * sc, acc[5] * sc, acc[6] * sc, acc[7] * sc);
    }
    __syncthreads();
    // msg = ht @ Wmp_next + bmp_next for the block's 8 nodes; wave wv computes cols wv*16..+15
    int lane15 = lane & 15, quad = lane >> 4;
    bf16x8 A0 = frag_f32(&v_lds[lane15][quad * 8]);      // rows 8..15 junk, discarded
    bf16x8 A1 = frag_f32(&v_lds[lane15][32 + quad * 8]);
    bf16x8 B0 = *(const bf16x8*)&WmpPk_next[(wv * 2 + 0) * 512 + lane * 8];
    bf16x8 B1 = *(const bf16x8*)&WmpPk_next[(wv * 2 + 1) * 512 + lane * 8];
    f32x4 z = {0.f, 0.f, 0.f, 0.f};
    z = __builtin_amdgcn_mfma_f32_16x16x32_bf16(A0, B0, z, 0, 0, 0);
    z = __builtin_amdgcn_mfma_f32_16x16x32_bf16(A1, B1, z, 0, 0, 0);
    float vbm = bmp_next[wv * 16 + lane15];
    if (quad < 2) {
      int nb = blockIdx.x * 8;
#pragma unroll
      for (int i = 0; i < 4; ++i)
        msg_out[(size_t)(nb + quad * 4 + i) * HD + wv * 16 + lane15] = f2bf(z[i] + vbm);
    }
  }
}

// ---------------------------------------------------------------- edge scores (CSR order, 2 nodes/wave)
__global__ void __launch_bounds__(256) k_edge(const uint2* __restrict__ rdeg,
                                              const uint* __restrict__ csr,
                                              const uint* __restrict__ csr_eid,
                                              const ushort* __restrict__ Asrc,
                                              const ushort* __restrict__ Adst,
                                              const ushort* __restrict__ Te2bf,
                                              const float* __restrict__ Wes2,
                                              const float* __restrict__ bes2,
                                              float* __restrict__ edge_scores) {
  int t = threadIdx.x;
  int lane = t & 63;
  int n = blockIdx.x * 8 + (t >> 5);   // grid exactly NN/8
  int lq = lane & 7;                   // dim group
  int lg32 = (lane >> 3) & 3;          // edge slot within node (4 slots of 8 lanes)
  uint2 rd = rdeg[n];
  int start = (int)rd.x;
  int deg = (int)rd.y;
  int end = start + deg;
  uint4 bv = *(const uint4*)&Adst[(size_t)n * HD + lq * 8];
  const float* wp = &Wes2[lq * 8];
  float4 w0 = *(const float4*)wp;
  float4 w1 = *(const float4*)(wp + 4);
  float b2 = bes2[0];
  for (int it = start; it < end; it += 4) {
    int e = it + lg32;
    bool valid = e < end;
    float p = 0.f;
    if (valid) {
      uint pk = csr[e];
      int si = (int)(pk & 0xFFFFu);
      int ty = (int)((pk >> 16) & 0x3Fu);
      uint4 av = *(const uint4*)&Asrc[(size_t)si * HD + lq * 8];
      uint4 tv = *(const uint4*)&Te2bf[ty * HD + lq * 8];
      p += fmaxf(bflo(av.x) + bflo(bv.x) + bflo(tv.x), 0.f) * w0.x;
      p += fmaxf(bfhi(av.x) + bfhi(bv.x) + bfhi(tv.x), 0.f) * w0.y;
      p += fmaxf(bflo(av.y) + bflo(bv.y) + bflo(tv.y), 0.f) * w0.z;
      p += fmaxf(bfhi(av.y) + bfhi(bv.y) + bfhi(tv.y), 0.f) * w0.w;
      p += fmaxf(bflo(av.z) + bflo(bv.z) + bflo(tv.z), 0.f) * w1.x;
      p += fmaxf(bfhi(av.z) + bfhi(bv.z) + bfhi(tv.z), 0.f) * w1.y;
      p += fmaxf(bflo(av.w) + bflo(bv.w) + bflo(tv.w), 0.f) * w1.z;
      p += fmaxf(bfhi(av.w) + bfhi(bv.w) + bfhi(tv.w), 0.f) * w1.w;
    }
    p += __shfl_xor(p, 1, 64);
    p += __shfl_xor(p, 2, 64);
    p += __shfl_xor(p, 4, 64);
    if (valid && lq == 0) edge_scores[csr_eid[e]] = 1.f / (1.f + __expf(-(p + b2)));
  }
}

// ---------------------------------------------------------------- launch
extern "C" void kernel_launch(void* const* d_in, const int* in_sizes, int n_in,
                              void* d_out, int out_size, void* d_ws, size_t ws_size,
                              hipStream_t stream) {
  const float* node_features = (const float*)d_in[0];
  const float* edge_desc = (const float*)d_in[1];
  const float* query = (const float*)d_in[2];
  const float* Wn = (const float*)d_in[3];
  const float* bn = (const float*)d_in[4];
  const float* ts = (const float*)d_in[5];
  const float* Wq = (const float*)d_in[6];
  const float* bq = (const float*)d_in[7];
  const float* Ws_ = (const float*)d_in[8];
  const float* bs = (const float*)d_in[9];
  const float* attn_a = (const float*)d_in[10];
  const float* Wmp = (const float*)d_in[11];
  const float* bmp = (const float*)d_in[12];
  const float* Wns1 = (const float*)d_in[13];
  const float* bns1 = (const float*)d_in[14];
  const float* Wns2 = (const float*)d_in[15];
  const float* bns2 = (const float*)d_in[16];
  const float* Wes1 = (const float*)d_in[17];
  const float* bes1 = (const float*)d_in[18];
  const float* Wes2 = (const float*)d_in[19];
  const float* bes2 = (const float*)d_in[20];
  const int* edge_index = (const int*)d_in[21];
  const int* etype = (const int*)d_in[22];
  const int* src = edge_index;
  const int* dst = edge_index + NE;

  float* out_ns = (float*)d_out;
  float* out_es = out_ns + NN;
  float* out_h = out_es + NE;
  float* out_te = out_h + (size_t)NN * HD;

  char* w = (char*)d_ws;
  auto alloc = [&](size_t bytes) {
    char* p = w;
    w += (bytes + 1023) & ~(size_t)1023;
    return p;
  };
  ushort* msg0 = (ushort*)alloc((size_t)NN * HD * 2);      // msg ping
  ushort* msg1 = (ushort*)alloc((size_t)NN * HD * 2);      // msg pong
  ushort* Asrc = (ushort*)alloc((size_t)NN * HD * 2);      // } adjacent: ebuf alias spans both
  ushort* Adst = (ushort*)alloc((size_t)NN * HD * 2);      // }
  float* pA = (float*)alloc(NN * 4);
  float* pdA = (float*)alloc(NN * 4);
  float* pB = (float*)alloc(NN * 4);
  float* pdB = (float*)alloc(NN * 4);
  float* s_buf = (float*)alloc((size_t)NPAD * 4);
  float* qb = (float*)alloc(HD * 4);
  float* ta3 = (float*)alloc(NLAY * NTT * 4);
  ushort* Te2bf = (ushort*)alloc(NTT * HD * 2);
  ushort* WmpPk = (ushort*)alloc(NLAY * 4096 * 2);
  ushort* WnsPk = (ushort*)alloc(4096 * 2);
  ushort* WesaPk = (ushort*)alloc(4096 * 2);
  ushort* WesbPk = (ushort*)alloc(4096 * 2);
  int* bucket_cursor = (int*)alloc(NBUCK * 4);
  uint2* rdeg = (uint2*)alloc((size_t)NN * 8);
  uint* csr = (uint*)alloc((size_t)NPAD * 4);
  uint* csr_eid = (uint*)alloc((size_t)NPAD * 4);
  // ebuf (NPAD x 8B = 9.6 MB) aliases Asrc+Adst (12.8 MB contiguous): CSR build
  // finishes (k_scatter2) before k_agg<0> writes Asrc/Adst. No overlap in stream order.
  uint2* ebuf = (uint2*)Asrc;

  hipMemsetAsync(bucket_cursor, 0, NBUCK * 4, stream);
  // bin (196) + proj w/ fused layer-0 msg (782) + te x4 + pack x5, co-scheduled
  kE<<<NBINBLK + NPROJ + 4 + 5, 256, 0, stream>>>(src, dst, etype, bucket_cursor, ebuf,
                                                  node_features, Wn, bn, ts, Wmp, bmp, attn_a,
                                                  msg0, pA, pdA,
                                                  edge_desc, query, Wq, bq, Ws_, bs,
                                                  Wns1, bns1, Wes1, bes1,
                                                  out_te, qb, ta3, Te2bf, WmpPk,
                                                  WnsPk, WesaPk, WesbPk);
  // order within bucket by node; emit rdeg + csr/csr_eid
  k_scatter2<<<NBUCK, 1024, 0, stream>>>(bucket_cursor, ebuf, csr, csr_eid, rdeg);

  const int AGG_GRID = NN / 8;   // 6250 blocks, 8 nodes each
  // layer 0: gather msg0, emit msg1 = ht1 @ Wmp1 and p's for layer 1
  k_agg<1><<<AGG_GRID, 256, 0, stream>>>(rdeg, csr, pA, pdA, ta3 + 0 * NTT, msg0, s_buf,
                                         WmpPk + 1 * 4096, bmp + 1 * HD,
                                         attn_a + 1 * (2 * HD + TDD),
                                         msg1, pB, pdB,
                                         nullptr, nullptr, nullptr, nullptr, nullptr,
                                         nullptr, nullptr, nullptr, nullptr, nullptr);
  // layer 1: gather msg1, emit msg0 = ht2 @ Wmp2 and p's for layer 2
  k_agg<1><<<AGG_GRID, 256, 0, stream>>>(rdeg, csr, pB, pdB, ta3 + 1 * NTT, msg1, s_buf,
                                         WmpPk + 2 * 4096, bmp + 2 * HD,
                                         attn_a + 2 * (2 * HD + TDD),
                                         msg0, pA, pdA,
                                         nullptr, nullptr, nullptr, nullptr, nullptr,
                                         nullptr, nullptr, nullptr, nullptr, nullptr);
  // layer 2: gather msg0, fused heads (node_scores, h_out, Asrc, Adst)
  k_agg<0><<<AGG_GRID, 256, 0, stream>>>(rdeg, csr, pA, pdA, ta3 + 2 * NTT, msg0, s_buf,
                                         nullptr, nullptr, nullptr,
                                         nullptr, nullptr, nullptr,
                                         qb, Wns2, bns2, WnsPk, WesaPk, WesbPk,
                                         out_ns, out_h, Asrc, Adst);

  k_edge<<<NN / 8, 256, 0, stream>>>(rdeg, csr, csr_eid, Asrc, Adst, Te2bf,
                                     Wes2, bes2, out_es);
}

// Round 8
// 280.845 us; speedup vs baseline: 1.4132x; 1.0037x over previous
//
#include <hip/hip_runtime.h>
#include <math.h>

#define NN 50000
#define NE 800000
#define NFD 256
#define HD 64
#define QDD 128
#define TDD 32
#define NTT 64
#define NLAY 3
#define LCLAMP 6.1030340f   // atanh(1 - 1e-5)
#define NBUCK 196           // ceil(50000/256) coarse buckets (dst >> 8)
#define SBUCK 6144          // padded slots per bucket (expected 4096, sigma ~64)
#define NPAD (NBUCK * SBUCK)
#define EPB 4096            // edges per bin block
#define NBINBLK 196         // ceil(800000/4096)
#define NPROJ 782           // ceil(50000/64)
#define PST 72              // proj LDS tile stride

typedef unsigned int uint;
typedef unsigned short ushort;
typedef __attribute__((ext_vector_type(8))) short bf16x8;
typedef __attribute__((ext_vector_type(4))) float f32x4;

__device__ __forceinline__ ushort f2bf(float f) {
  uint u = __float_as_uint(f);
  uint r = (u + 0x7FFFu + ((u >> 16) & 1u)) >> 16;
  return (ushort)r;
}
__device__ __forceinline__ short f2bfs(float f) { return (short)f2bf(f); }
__device__ __forceinline__ float bf2f(short s) { return __uint_as_float(((uint)(ushort)s) << 16); }
__device__ __forceinline__ float bflo(uint w) { return __uint_as_float(w << 16); }
__device__ __forceinline__ float bfhi(uint w) { return __uint_as_float(w & 0xFFFF0000u); }

// A-frag from 8 consecutive f32
__device__ __forceinline__ bf16x8 frag_f32(const float* p) {
  float4 a = *(const float4*)p;
  float4 b = *(const float4*)(p + 4);
  bf16x8 r;
  r[0] = f2bfs(a.x); r[1] = f2bfs(a.y); r[2] = f2bfs(a.z); r[3] = f2bfs(a.w);
  r[4] = f2bfs(b.x); r[5] = f2bfs(b.y); r[6] = f2bfs(b.z); r[7] = f2bfs(b.w);
  return r;
}
// B-frag from row-major W[K][64]: k=k0+quad*8+j, n=j0+lane15
__device__ __forceinline__ bf16x8 bfrag_w(const float* W, int k0, int j0, int lane15, int quad) {
  bf16x8 r;
#pragma unroll
  for (int j = 0; j < 8; ++j) r[j] = f2bfs(W[(k0 + quad * 8 + j) * HD + j0 + lane15]);
  return r;
}

// ---------------------------------------------------------------- te blocks (4): q/qe redundant, 16 types each
// block tb handles types [tb*16, tb*16+16); block 0 also emits qb.
__device__ void d_te(int tb,
                     const float* __restrict__ edge_desc, const float* __restrict__ query,
                     const float* __restrict__ Wq, const float* __restrict__ bq,
                     const float* __restrict__ Ws, const float* __restrict__ bs,
                     const float* __restrict__ attn_a,
                     const float* __restrict__ Wns1, const float* __restrict__ bns1,
                     const float* __restrict__ Wes1, const float* __restrict__ bes1,
                     float* __restrict__ out_type_emb,
                     float* __restrict__ qb, float* __restrict__ ta3,
                     ushort* __restrict__ Te2bf) {
  __shared__ float te_s[16 * TDD];   // this block's 16 rows
  __shared__ float q_s[HD];
  __shared__ float qe_s[HD];
  int t = threadIdx.x;
  if (t < HD) {
    float acc = bq[t];
    for (int k = 0; k < QDD; ++k) acc += query[k] * Wq[k * HD + t];
    q_s[t] = acc;
  }
  for (int idx = t; idx < 16 * TDD; idx += 256) {   // 2 iters
    int tyl = idx / TDD, d = idx % TDD;
    int ty = tb * 16 + tyl;
    float acc = bs[d];
    for (int k = 0; k < 64; ++k) acc += edge_desc[ty * 64 + k] * Ws[k * TDD + d];
    float v = tanhf(acc);
    te_s[idx] = v;
    out_type_emb[ty * TDD + d] = v;
  }
  __syncthreads();
  // qe (needs q_s); qb only on block 0
  if (t < HD) {
    float a2 = bes1[t];
    for (int k = 0; k < HD; ++k) a2 += q_s[k] * Wes1[(2 * HD + TDD + k) * HD + t];
    qe_s[t] = a2;
    if (tb == 0) {
      float a1 = bns1[t];
      for (int k = 0; k < HD; ++k) a1 += q_s[k] * Wns1[(HD + k) * HD + t];
      qb[t] = a1;
    }
  }
  // ta3 for this block's 16 types x 3 layers
  if (t < NLAY * 16) {
    int l = t >> 4, tyl = t & 15;
    float acc = 0.f;
    for (int d = 0; d < TDD; ++d) acc += te_s[tyl * TDD + d] * attn_a[l * (2 * HD + TDD) + 2 * HD + d];
    ta3[l * NTT + tb * 16 + tyl] = acc;
  }
  __syncthreads();
  // Te2bf rows
  for (int idx = t; idx < 16 * HD; idx += 256) {    // 4 iters
    int tyl = idx >> 6, j = idx & 63;
    float acc = qe_s[j];
#pragma unroll
    for (int d = 0; d < TDD; ++d) acc += te_s[tyl * TDD + d] * Wes1[(2 * HD + d) * HD + j];
    Te2bf[(tb * 16 + tyl) * HD + j] = f2bf(acc);
  }
}

// ---------------------------------------------------------------- pack blocks (5): one 4096-elem array each
__device__ void d_pack(int pid,
                       const float* __restrict__ Wmp, const float* __restrict__ Wns1,
                       const float* __restrict__ Wes1,
                       ushort* __restrict__ WmpPk, ushort* __restrict__ WnsPk,
                       ushort* __restrict__ WesaPk, ushort* __restrict__ WesbPk) {
  int t = threadIdx.x;
  for (int i = t; i < 4096; i += 256) {   // 16 iters
    int j = i & 7, lane = (i >> 3) & 63, f = (i >> 9) & 1, jt = (i >> 10) & 3;
    int q = lane >> 4, l15 = lane & 15;
    int row = f * 32 + q * 8 + j, col = jt * 16 + l15;
    if (pid < 2) {
      int l = pid + 1;   // layers 1,2 (layer 0 unused: proj loads Wmp0 direct)
      WmpPk[l * 4096 + i] = f2bf(Wmp[l * HD * HD + row * HD + col]);
    } else if (pid == 2) {
      WnsPk[i] = f2bf(Wns1[row * HD + col]);
    } else if (pid == 3) {
      WesaPk[i] = f2bf(Wes1[row * HD + col]);
    } else {
      WesbPk[i] = f2bf(Wes1[(64 + row) * HD + col]);
    }
  }
}

// ---------------------------------------------------------------- bin (device): append edges to padded bucket regions
// pk: src(16) | type(6)<<16 | (dst&255)<<22
__device__ void d_bin(int bbid,
                      const int* __restrict__ src,
                      const int* __restrict__ dst,
                      const int* __restrict__ etype,
                      int* __restrict__ bucket_cursor,
                      uint2* __restrict__ ebuf) {
  __shared__ int cntl[NBUCK];
  __shared__ int gbase[NBUCK];
  int t = threadIdx.x;
  for (int i = t; i < NBUCK; i += 256) cntl[i] = 0;
  __syncthreads();
  int e0 = bbid * EPB;
  int dd[16];
  uint pk[16];
  int rk[16];
#pragma unroll
  for (int c = 0; c < 4; ++c) {
    int eb = e0 + c * 1024 + t * 4;
    if (eb < NE) {   // NE%4==0 => eb<NE implies eb+3<NE
      int4 s4 = *(const int4*)&src[eb];
      int4 d4 = *(const int4*)&dst[eb];
      int4 y4 = *(const int4*)&etype[eb];
      int ds[4] = {d4.x, d4.y, d4.z, d4.w};
      int ss[4] = {s4.x, s4.y, s4.z, s4.w};
      int ys[4] = {y4.x, y4.y, y4.z, y4.w};
#pragma unroll
      for (int j = 0; j < 4; ++j) {
        int idx = c * 4 + j;
        int d = ds[j];
        dd[idx] = d;
        pk[idx] = (uint)ss[j] | ((uint)ys[j] << 16) | ((uint)(d & 255) << 22);
        rk[idx] = atomicAdd(&cntl[d >> 8], 1);
      }
    } else {
#pragma unroll
      for (int j = 0; j < 4; ++j) dd[c * 4 + j] = -1;
    }
  }
  __syncthreads();
  if (t < NBUCK && cntl[t] > 0)
    gbase[t] = t * SBUCK + atomicAdd(&bucket_cursor[t], cntl[t]);
  __syncthreads();
#pragma unroll
  for (int i = 0; i < 16; ++i) {
    if (dd[i] >= 0) {
      uint eid = (uint)(e0 + ((i >> 2) << 10) + t * 4 + (i & 3));
      ebuf[gbase[dd[i] >> 8] + rk[i]] = make_uint2(pk[i], eid);
    }
  }
}

// ---------------------------------------------------------------- proj (device) + fused layer-0 msg
// (Wmp0 B-frags loaded direct from f32 — no dependency on the setup blocks)
__device__ void d_proj(int pbid,
                       const float* __restrict__ X,
                       const float* __restrict__ Wn,
                       const float* __restrict__ bn,
                       const float* __restrict__ ts_p,
                       const float* __restrict__ Wmp0,
                       const float* __restrict__ bmp0,
                       const float* __restrict__ attn0,
                       ushort* __restrict__ msgbf,
                       float* __restrict__ p_src,
                       float* __restrict__ p_dst) {
  __shared__ ushort buf[2][64 * PST];            // 2 x 9216 B
  float* st = (float*)&buf[0][0];                // epilogue alias: 64 x 72 f32
  int t = threadIdx.x;
  int lane = t & 63, wv = t >> 6;
  int lane15 = lane & 15, quad = lane >> 4;
  int n0 = pbid * 64;
  int j0 = wv * 16;
  bf16x8 B[8];
#pragma unroll
  for (int fb = 0; fb < 8; ++fb) B[fb] = bfrag_w(Wn, fb * 32, j0, lane15, quad);

  int srow = t >> 2;
  int scg = (t & 3) * 16;
  int grow = n0 + srow; if (grow >= NN) grow = NN - 1;
  const float* xrow = X + (size_t)grow * NFD + scg;

  f32x4 acc[4];
#pragma unroll
  for (int mt = 0; mt < 4; ++mt) acc[mt] = (f32x4){0.f, 0.f, 0.f, 0.f};

  float4 r0 = *(const float4*)(xrow + 0);
  float4 r1 = *(const float4*)(xrow + 4);
  float4 r2 = *(const float4*)(xrow + 8);
  float4 r3 = *(const float4*)(xrow + 12);

  for (int c = 0; c < 4; ++c) {
    ushort* wp = &buf[c & 1][srow * PST + scg];
    uint4 o0, o1;
    o0.x = (uint)f2bf(r0.x) | ((uint)f2bf(r0.y) << 16);
    o0.y = (uint)f2bf(r0.z) | ((uint)f2bf(r0.w) << 16);
    o0.z = (uint)f2bf(r1.x) | ((uint)f2bf(r1.y) << 16);
    o0.w = (uint)f2bf(r1.z) | ((uint)f2bf(r1.w) << 16);
    o1.x = (uint)f2bf(r2.x) | ((uint)f2bf(r2.y) << 16);
    o1.y = (uint)f2bf(r2.z) | ((uint)f2bf(r2.w) << 16);
    o1.z = (uint)f2bf(r3.x) | ((uint)f2bf(r3.y) << 16);
    o1.w = (uint)f2bf(r3.z) | ((uint)f2bf(r3.w) << 16);
    *(uint4*)wp = o0;
    *(uint4*)(wp + 8) = o1;
    if (c < 3) {
      const float* nx = xrow + (c + 1) * 64;
      r0 = *(const float4*)(nx + 0);
      r1 = *(const float4*)(nx + 4);
      r2 = *(const float4*)(nx + 8);
      r3 = *(const float4*)(nx + 12);
    }
    __syncthreads();
    const ushort* bp = &buf[c & 1][0];
#pragma unroll
    for (int mt = 0; mt < 4; ++mt) {
#pragma unroll
      for (int ks = 0; ks < 2; ++ks) {
        bf16x8 A = *(const bf16x8*)&bp[(mt * 16 + lane15) * PST + ks * 32 + quad * 8];
        acc[mt] = __builtin_amdgcn_mfma_f32_16x16x32_bf16(A, B[c * 2 + ks], acc[mt], 0, 0, 0);
      }
    }
  }
  __syncthreads();
  float ts = ts_p[0];
  float vb = bn[j0 + lane15];
#pragma unroll
  for (int mt = 0; mt < 4; ++mt)
#pragma unroll
    for (int i = 0; i < 4; ++i)
      st[(mt * 16 + quad * 4 + i) * PST + j0 + lane15] = (acc[mt][i] + vb) * ts;
  __syncthreads();
  {
    int r = t >> 2, p = t & 3;
    float* rp = &st[r * PST + p * 16];
    float4 v0 = *(const float4*)(rp + 0);
    float4 v1 = *(const float4*)(rp + 4);
    float4 v2 = *(const float4*)(rp + 8);
    float4 v3 = *(const float4*)(rp + 12);
    float ssq = v0.x*v0.x + v0.y*v0.y + v0.z*v0.z + v0.w*v0.w
              + v1.x*v1.x + v1.y*v1.y + v1.z*v1.z + v1.w*v1.w
              + v2.x*v2.x + v2.y*v2.y + v2.z*v2.z + v2.w*v2.w
              + v3.x*v3.x + v3.y*v3.y + v3.z*v3.z + v3.w*v3.w;
    ssq += __shfl_xor(ssq, 1, 64);
    ssq += __shfl_xor(ssq, 2, 64);
    float nu = fmaxf(sqrtf(ssq), 1e-15f);
    float sc = fminf(nu, LCLAMP) / nu;
    *(float4*)(rp + 0) = make_float4(v0.x*sc, v0.y*sc, v0.z*sc, v0.w*sc);
    *(float4*)(rp + 4) = make_float4(v1.x*sc, v1.y*sc, v1.z*sc, v1.w*sc);
    *(float4*)(rp + 8) = make_float4(v2.x*sc, v2.y*sc, v2.z*sc, v2.w*sc);
    *(float4*)(rp + 12) = make_float4(v3.x*sc, v3.y*sc, v3.z*sc, v3.w*sc);
  }
  __syncthreads();
  // fused layer-0 msg
  {
    bf16x8 Bm0[4], Bm1[4];
    float vbm[4];
#pragma unroll
    for (int jt = 0; jt < 4; ++jt) {
      Bm0[jt] = bfrag_w(Wmp0, 0, jt * 16, lane15, quad);
      Bm1[jt] = bfrag_w(Wmp0, 32, jt * 16, lane15, quad);
      vbm[jt] = bmp0[jt * 16 + lane15];
    }
    int mrow = wv * 16 + lane15;
    bf16x8 A0 = frag_f32(&st[mrow * PST + quad * 8]);
    bf16x8 A1 = frag_f32(&st[mrow * PST + 32 + quad * 8]);
#pragma unroll
    for (int jt = 0; jt < 4; ++jt) {
      f32x4 z = {0.f, 0.f, 0.f, 0.f};
      z = __builtin_amdgcn_mfma_f32_16x16x32_bf16(A0, Bm0[jt], z, 0, 0, 0);
      z = __builtin_amdgcn_mfma_f32_16x16x32_bf16(A1, Bm1[jt], z, 0, 0, 0);
#pragma unroll
      for (int i = 0; i < 4; ++i) {
        int r = n0 + wv * 16 + quad * 4 + i;
        if (r < NN) msgbf[(size_t)r * HD + jt * 16 + lane15] = f2bf(z[i] + vbm[jt]);
      }
    }
    float4 a1l = *(const float4*)&attn0[quad * 8];
    float4 a1h = *(const float4*)&attn0[quad * 8 + 4];
    float4 a1l2 = *(const float4*)&attn0[32 + quad * 8];
    float4 a1h2 = *(const float4*)&attn0[32 + quad * 8 + 4];
    float4 a2l = *(const float4*)&attn0[64 + quad * 8];
    float4 a2h = *(const float4*)&attn0[64 + quad * 8 + 4];
    float4 a2l2 = *(const float4*)&attn0[96 + quad * 8];
    float4 a2h2 = *(const float4*)&attn0[96 + quad * 8 + 4];
    float p1 = bf2f(A0[0])*a1l.x + bf2f(A0[1])*a1l.y + bf2f(A0[2])*a1l.z + bf2f(A0[3])*a1l.w
             + bf2f(A0[4])*a1h.x + bf2f(A0[5])*a1h.y + bf2f(A0[6])*a1h.z + bf2f(A0[7])*a1h.w
             + bf2f(A1[0])*a1l2.x + bf2f(A1[1])*a1l2.y + bf2f(A1[2])*a1l2.z + bf2f(A1[3])*a1l2.w
             + bf2f(A1[4])*a1h2.x + bf2f(A1[5])*a1h2.y + bf2f(A1[6])*a1h2.z + bf2f(A1[7])*a1h2.w;
    float p2 = bf2f(A0[0])*a2l.x + bf2f(A0[1])*a2l.y + bf2f(A0[2])*a2l.z + bf2f(A0[3])*a2l.w
             + bf2f(A0[4])*a2h.x + bf2f(A0[5])*a2h.y + bf2f(A0[6])*a2h.z + bf2f(A0[7])*a2h.w
             + bf2f(A1[0])*a2l2.x + bf2f(A1[1])*a2l2.y + bf2f(A1[2])*a2l2.z + bf2f(A1[3])*a2l2.w
             + bf2f(A1[4])*a2h2.x + bf2f(A1[5])*a2h2.y + bf2f(A1[6])*a2h2.z + bf2f(A1[7])*a2h2.w;
    p1 += __shfl_xor(p1, 16, 64); p1 += __shfl_xor(p1, 32, 64);
    p2 += __shfl_xor(p2, 16, 64); p2 += __shfl_xor(p2, 32, 64);
    int prow = n0 + mrow;
    if (quad == 0 && prow < NN) { p_src[prow] = p1; p_dst[prow] = p2; }
  }
}

// kE: blocks [0,196)=bin, [196,978)=proj, [978,982)=te, [982,987)=pack — all independent
__global__ void __launch_bounds__(256) kE(const int* __restrict__ src, const int* __restrict__ dst,
                                          const int* __restrict__ etype, int* __restrict__ bucket_cursor,
                                          uint2* __restrict__ ebuf,
                                          const float* __restrict__ X, const float* __restrict__ Wn,
                                          const float* __restrict__ bn, const float* __restrict__ ts_p,
                                          const float* __restrict__ Wmp, const float* __restrict__ bmp,
                                          const float* __restrict__ attn_a,
                                          ushort* __restrict__ msgbf,
                                          float* __restrict__ p_src, float* __restrict__ p_dst,
                                          const float* __restrict__ edge_desc, const float* __restrict__ query,
                                          const float* __restrict__ Wq, const float* __restrict__ bq,
                                          const float* __restrict__ Ws, const float* __restrict__ bs,
                                          const float* __restrict__ Wns1, const float* __restrict__ bns1,
                                          const float* __restrict__ Wes1, const float* __restrict__ bes1,
                                          float* __restrict__ out_type_emb,
                                          float* __restrict__ qb, float* __restrict__ ta3,
                                          ushort* __restrict__ Te2bf, ushort* __restrict__ WmpPk,
                                          ushort* __restrict__ WnsPk, ushort* __restrict__ WesaPk,
                                          ushort* __restrict__ WesbPk) {
  if (blockIdx.x < NBINBLK)
    d_bin(blockIdx.x, src, dst, etype, bucket_cursor, ebuf);
  else if (blockIdx.x < NBINBLK + NPROJ)
    d_proj(blockIdx.x - NBINBLK, X, Wn, bn, ts_p, Wmp, bmp, attn_a, msgbf, p_src, p_dst);
  else if (blockIdx.x < NBINBLK + NPROJ + 4)
    d_te(blockIdx.x - (NBINBLK + NPROJ), edge_desc, query, Wq, bq, Ws, bs, attn_a,
         Wns1, bns1, Wes1, bes1, out_type_emb, qb, ta3, Te2bf);
  else
    d_pack(blockIdx.x - (NBINBLK + NPROJ + 4), Wmp, Wns1, Wes1, WmpPk, WnsPk, WesaPk, WesbPk);
}

// ---------------------------------------------------------------- scatter: order bucket by node, emit rdeg + csr
// 1024 threads/block: counting + scatter 4x parallel; 256-wide scan on waves 0-3.
__global__ void __launch_bounds__(1024) k_scatter2(const int* __restrict__ bucket_cursor,
                                                   const uint2* __restrict__ ebuf,
                                                   uint* __restrict__ csr,
                                                   uint* __restrict__ csr_eid,
                                                   uint2* __restrict__ rdeg) {
  __shared__ int cnt_l[256];
  __shared__ int curs[256];
  __shared__ int wsum[4], woff[4];
  int b = blockIdx.x;
  int t = threadIdx.x;
  int base = b * SBUCK;
  int cb = bucket_cursor[b];           // edges in this bucket
  if (t < 256) cnt_l[t] = 0;
  __syncthreads();
  for (int i = t; i < cb; i += 1024)
    atomicAdd(&cnt_l[(ebuf[base + i].x >> 22) & 255], 1);
  __syncthreads();
  int v = 0, x = 0;
  int lane = t & 63, wid = t >> 6;
  if (t < 256) {                       // waves 0-3 fully active: shfl is wave-uniform
    v = cnt_l[t];
    x = v;
#pragma unroll
    for (int off = 1; off < 64; off <<= 1) {
      int y = __shfl_up(x, off, 64);
      if (lane >= off) x += y;
    }
    if (lane == 63) wsum[wid] = x;
  }
  __syncthreads();
  if (t == 0) {
    int a = 0;
    for (int i = 0; i < 4; ++i) { woff[i] = a; a += wsum[i]; }
  }
  __syncthreads();
  if (t < 256) {
    int loff = woff[wid] + (x - v);    // exclusive prefix
    int n = (b << 8) + t;
    if (n < NN) rdeg[n] = make_uint2((uint)(base + loff), (uint)v);
    curs[t] = base + loff;
  }
  __syncthreads();
  for (int i = t; i < cb; i += 1024) {
    uint2 e = ebuf[base + i];
    int j = (e.x >> 22) & 255;
    int pos = atomicAdd(&curs[j], 1);
    csr[pos] = e.x & 0x3FFFFFu;
    csr_eid[pos] = e.y;
  }
}

// ---------------------------------------------------------------- softmax-aggregate (2 nodes/wave, 32 lanes each)
// FUSE=1: epilogue computes next-layer msg + p's.
// FUSE=0: final layer — epilogue fuses the former k_score (node head, Asrc/Adst, h_out).
template <int FUSE>
__global__ void __launch_bounds__(256) k_agg(const uint2* __restrict__ rdeg,
                                             const uint* __restrict__ csr,
                                             const float* __restrict__ p_src,
                                             const float* __restrict__ p_dst,
                                             const float* __restrict__ ta_l,
                                             const ushort* __restrict__ msgbf,
                                             float* __restrict__ s_buf,
                                             const ushort* __restrict__ WmpPk_next,
                                             const float* __restrict__ bmp_next,
                                             const float* __restrict__ attn_next,
                                             ushort* __restrict__ msg_out,
                                             float* __restrict__ p_src_out,
                                             float* __restrict__ p_dst_out,
                                             const float* __restrict__ qb,
                                             const float* __restrict__ Wns2,
                                             const float* __restrict__ bns2,
                                             const ushort* __restrict__ WnsPk,
                                             const ushort* __restrict__ WesaPk,
                                             const ushort* __restrict__ WesbPk,
                                             float* __restrict__ node_scores,
                                             float* __restrict__ h_out,
                                             ushort* __restrict__ Asrc,
                                             ushort* __restrict__ Adst) {
  __shared__ float v_lds[16][68];   // +4 pad: b128 reads 2-way max
  __shared__ float exs[4][64];      // per-wave staged exp(score)
  __shared__ uint  sis[4][64];      // per-wave staged src index
  __shared__ float sc_part[8][4];   // FUSE=0: node-head partials per wave
  int t = threadIdx.x;
  int lane = t & 63, wv = t >> 6;
  int nloc = t >> 5;                 // 0..7: node slot within block
  int half = (lane >> 5) & 1;        // which node within wave
  int l32 = lane & 31;               // lane within node's 32-group
  int lq = lane & 7;                 // dim group: owns dims lq*8..lq*8+7
  int lg32 = (lane >> 3) & 3;        // gather group within node (4 groups of 8)
  int n = blockIdx.x * 8 + nloc;     // grid exactly NN/8
  uint2 rd = rdeg[n];
  int start = (int)rd.x;
  int deg = (int)rd.y;
  int end = start + deg;
  float pd = p_dst[n];
  float acc[8];
#pragma unroll
  for (int u = 0; u < 8; ++u) acc[u] = 0.f;
  float exsum = 0.f;

  if (deg <= 32) {
    bool valid = l32 < deg;
    float s = -3.4e38f;
    int sidx = 0;
    if (valid) {
      uint pk = csr[start + l32];
      sidx = (int)(pk & 0xFFFFu);
      int ty = (int)(pk >> 16);
      float v = p_src[sidx] + pd + ta_l[ty];
      s = (v > 0.f) ? v : 0.2f * v;
    }
    float m = s;
#pragma unroll
    for (int off = 16; off >= 1; off >>= 1) m = fmaxf(m, __shfl_xor(m, off, 64));
    float ex = valid ? __expf(s - m) : 0.f;
    exsum = ex;
    if (valid) { exs[wv][lane] = ex; sis[wv][lane] = (uint)sidx; }
    // fully-unrolled gather (compile-time trip count -> compiler batches loads, MLP >> 1)
#pragma unroll
    for (int u = 0; u < 8; ++u) {
      int el = u * 4 + lg32;
      if (el < deg) {
        float exk = exs[wv][half * 32 + el];       // 8 lanes same addr -> broadcast
        int sk = (int)sis[wv][half * 32 + el];
        uint4 mv = *(const uint4*)&msgbf[(size_t)sk * HD + lq * 8];
        acc[0] += exk * bflo(mv.x); acc[1] += exk * bfhi(mv.x);
        acc[2] += exk * bflo(mv.y); acc[3] += exk * bfhi(mv.y);
        acc[4] += exk * bflo(mv.z); acc[5] += exk * bfhi(mv.z);
        acc[6] += exk * bflo(mv.w); acc[7] += exk * bfhi(mv.w);
      }
    }
  } else {
    // rare path (deg>32): chunked at 32-lane width via s_buf
    float m = -3.4e38f;
    for (int base = start; base < end; base += 32) {
      int i = base + l32;
      float s = -3.4e38f;
      if (i < end) {
        uint pk = csr[i];
        int sidx = (int)(pk & 0xFFFFu);
        int ty = (int)(pk >> 16);
        float v = p_src[sidx] + pd + ta_l[ty];
        s = (v > 0.f) ? v : 0.2f * v;
        s_buf[i] = s;
      }
      m = fmaxf(m, s);
    }
#pragma unroll
    for (int off = 16; off >= 1; off >>= 1) m = fmaxf(m, __shfl_xor(m, off, 64));
    for (int base = start; base < end; base += 32) {
      int i = base + l32;
      if (i < end) {
        float ex = __expf(s_buf[i] - m);
        s_buf[i] = ex;
        exsum += ex;
      }
    }
    for (int it = start; it < end; it += 4) {
      int el = it + lg32;
      if (el < end) {
        float exk = s_buf[el];
        int sk = (int)(csr[el] & 0xFFFFu);
        uint4 mv = *(const uint4*)&msgbf[(size_t)sk * HD + lq * 8];
        acc[0] += exk * bflo(mv.x); acc[1] += exk * bfhi(mv.x);
        acc[2] += exk * bflo(mv.y); acc[3] += exk * bfhi(mv.y);
        acc[4] += exk * bflo(mv.z); acc[5] += exk * bfhi(mv.z);
        acc[6] += exk * bflo(mv.w); acc[7] += exk * bfhi(mv.w);
      }
    }
  }
  // reduce over the 4 gather groups (within each 32-half)
#pragma unroll
  for (int u = 0; u < 8; ++u) {
    acc[u] += __shfl_xor(acc[u], 8, 64);
    acc[u] += __shfl_xor(acc[u], 16, 64);
  }
#pragma unroll
  for (int off = 16; off >= 1; off >>= 1) exsum += __shfl_xor(exsum, off, 64);
  float inv = 1.f / (exsum + 1e-15f);
  float ss = 0.f;
#pragma unroll
  for (int u = 0; u < 8; ++u) {
    float v = fmaxf(acc[u] * inv, 0.f);
    acc[u] = v;
    ss += v * v;
  }
  ss += __shfl_xor(ss, 1, 64);
  ss += __shfl_xor(ss, 2, 64);
  ss += __shfl_xor(ss, 4, 64);
  float nu = fmaxf(sqrtf(ss), 1e-15f);
  float sc = fminf(nu, LCLAMP) / nu;

  if constexpr (FUSE == 0) {
    // ---- fused k_score: stage final ht rows, then heads + h_out from LDS ----
    if (l32 < 8) {
      *(float4*)&v_lds[nloc][l32 * 8] =
          make_float4(acc[0] * sc, acc[1] * sc, acc[2] * sc, acc[3] * sc);
      *(float4*)&v_lds[nloc][l32 * 8 + 4] =
          make_float4(acc[4] * sc, acc[5] * sc, acc[6] * sc, acc[7] * sc);
    }
    __syncthreads();
    int lane15 = lane & 15, quad = lane >> 4;
    int nb = blockIdx.x * 8;
    // h_out: exact f32 pass (replicates former k_score lane pattern bitwise)
    if (t < 32) {
      int r = t >> 2, p = t & 3;
      const float* rp = &v_lds[r][p * 16];
      float4 v0 = *(const float4*)(rp + 0);
      float4 v1 = *(const float4*)(rp + 4);
      float4 v2 = *(const float4*)(rp + 8);
      float4 v3 = *(const float4*)(rp + 12);
      float ssq = v0.x*v0.x + v0.y*v0.y + v0.z*v0.z + v0.w*v0.w
                + v1.x*v1.x + v1.y*v1.y + v1.z*v1.z + v1.w*v1.w
                + v2.x*v2.x + v2.y*v2.y + v2.z*v2.z + v2.w*v2.w
                + v3.x*v3.x + v3.y*v3.y + v3.z*v3.z + v3.w*v3.w;
      ssq += __shfl_xor(ssq, 1, 64);
      ssq += __shfl_xor(ssq, 2, 64);
      float nu2 = fmaxf(sqrtf(ssq), 1e-15f);
      float hs = tanhf(nu2) / nu2;
      float* op = h_out + (size_t)(nb + r) * HD + p * 16;
      *(float4*)(op + 0)  = make_float4(v0.x*hs, v0.y*hs, v0.z*hs, v0.w*hs);
      *(float4*)(op + 4)  = make_float4(v1.x*hs, v1.y*hs, v1.z*hs, v1.w*hs);
      *(float4*)(op + 8)  = make_float4(v2.x*hs, v2.y*hs, v2.z*hs, v2.w*hs);
      *(float4*)(op + 12) = make_float4(v3.x*hs, v3.y*hs, v3.z*hs, v3.w*hs);
    }
    // 3 GEMMs (node-head y, Asrc, Adst): wave wv computes cols wv*16..+15 for 8 nodes
    bf16x8 A0 = frag_f32(&v_lds[lane15][quad * 8]);      // rows 8..15 junk, outputs discarded
    bf16x8 A1 = frag_f32(&v_lds[lane15][32 + quad * 8]);
    // node head
    {
      bf16x8 B0 = *(const bf16x8*)&WnsPk[(wv * 2 + 0) * 512 + lane * 8];
      bf16x8 B1 = *(const bf16x8*)&WnsPk[(wv * 2 + 1) * 512 + lane * 8];
      f32x4 z = {0.f, 0.f, 0.f, 0.f};
      z = __builtin_amdgcn_mfma_f32_16x16x32_bf16(A0, B0, z, 0, 0, 0);
      z = __builtin_amdgcn_mfma_f32_16x16x32_bf16(A1, B1, z, 0, 0, 0);
      float vqb = qb[wv * 16 + lane15];
      float vw2 = Wns2[wv * 16 + lane15];
      if (quad < 2) {
#pragma unroll
        for (int i = 0; i < 4; ++i) {
          float part = fmaxf(z[i] + vqb, 0.f) * vw2;
          part += __shfl_xor(part, 1, 64);
          part += __shfl_xor(part, 2, 64);
          part += __shfl_xor(part, 4, 64);
          part += __shfl_xor(part, 8, 64);
          if (lane15 == 0) sc_part[quad * 4 + i][wv] = part;
        }
      }
    }
    // Asrc
    {
      bf16x8 B0 = *(const bf16x8*)&WesaPk[(wv * 2 + 0) * 512 + lane * 8];
      bf16x8 B1 = *(const bf16x8*)&WesaPk[(wv * 2 + 1) * 512 + lane * 8];
      f32x4 z = {0.f, 0.f, 0.f, 0.f};
      z = __builtin_amdgcn_mfma_f32_16x16x32_bf16(A0, B0, z, 0, 0, 0);
      z = __builtin_amdgcn_mfma_f32_16x16x32_bf16(A1, B1, z, 0, 0, 0);
      if (quad < 2) {
#pragma unroll
        for (int i = 0; i < 4; ++i)
          Asrc[(size_t)(nb + quad * 4 + i) * HD + wv * 16 + lane15] = f2bf(z[i]);
      }
    }
    // Adst
    {
      bf16x8 B0 = *(const bf16x8*)&WesbPk[(wv * 2 + 0) * 512 + lane * 8];
      bf16x8 B1 = *(const bf16x8*)&WesbPk[(wv * 2 + 1) * 512 + lane * 8];
      f32x4 z = {0.f, 0.f, 0.f, 0.f};
      z = __builtin_amdgcn_mfma_f32_16x16x32_bf16(A0, B0, z, 0, 0, 0);
      z = __builtin_amdgcn_mfma_f32_16x16x32_bf16(A1, B1, z, 0, 0, 0);
      if (quad < 2) {
#pragma unroll
        for (int i = 0; i < 4; ++i)
          Adst[(size_t)(nb + quad * 4 + i) * HD + wv * 16 + lane15] = f2bf(z[i]);
      }
    }
    __syncthreads();
    if (t < 8) {
      float si = sc_part[t][0] + sc_part[t][1] + sc_part[t][2] + sc_part[t][3];
      node_scores[nb + t] = 1.f / (1.f + __expf(-(si + bns2[0])));
    }
  } else {
    // next-layer p from bf16-rounded ht (element index = lq*8+u)
    float hb[8];
#pragma unroll
    for (int u = 0; u < 8; ++u) hb[u] = bf2f((short)f2bf(acc[u] * sc));
    float4 a1a = *(const float4*)&attn_next[lq * 8];
    float4 a1b = *(const float4*)&attn_next[lq * 8 + 4];
    float4 a2a = *(const float4*)&attn_next[64 + lq * 8];
    float4 a2b = *(const float4*)&attn_next[64 + lq * 8 + 4];
    float p1 = hb[0]*a1a.x + hb[1]*a1a.y + hb[2]*a1a.z + hb[3]*a1a.w
             + hb[4]*a1b.x + hb[5]*a1b.y + hb[6]*a1b.z + hb[7]*a1b.w;
    float p2 = hb[0]*a2a.x + hb[1]*a2a.y + hb[2]*a2a.z + hb[3]*a2a.w
             + hb[4]*a2b.x + hb[5]*a2b.y + hb[6]*a2b.z + hb[7]*a2b.w;
    p1 += __shfl_xor(p1, 1, 64); p1 += __shfl_xor(p1, 2, 64); p1 += __shfl_xor(p1, 4, 64);
    p2 += __shfl_xor(p2, 1, 64); p2 += __shfl_xor(p2, 2, 64); p2 += __shfl_xor(p2, 4, 64);
    if (l32 == 0) { p_src_out[n] = p1; p_dst_out[n] = p2; }
    if (l32 < 8) {
      *(float4*)&v_lds[nloc][l32 * 8] =
          make_float4(acc[0] * sc, acc[1] * sc, acc[2] * sc, acc[3] * sc);
      *(float4*)&v_lds[nloc][l32 * 8 + 4] =
          make_float4(acc[4] * sc, acc[5] * sc, acc[6] * sc, acc[7] * sc);
    }
    __syncthreads();
    // msg = ht @ Wmp_next + bmp_next for the block's 8 nodes; wave wv computes cols wv*16..+15
    int lane15 = lane & 15, quad = lane >> 4;
    bf16x8 A0 = frag_f32(&v_lds[lane15][quad * 8]);      // rows 8..15 junk, discarded
    bf16x8 A1 = frag_f32(&v_lds[lane15][32 + quad * 8]);
    bf16x8 B0 = *(const bf16x8*)&WmpPk_next[(wv * 2 + 0) * 512 + lane * 8];
    bf16x8 B1 = *(const bf16x8*)&WmpPk_next[(wv * 2 + 1) * 512 + lane * 8];
    f32x4 z = {0.f, 0.f, 0.f, 0.f};
    z = __builtin_amdgcn_mfma_f32_16x16x32_bf16(A0, B0, z, 0, 0, 0);
    z = __builtin_amdgcn_mfma_f32_16x16x32_bf16(A1, B1, z, 0, 0, 0);
    float vbm = bmp_next[wv * 16 + lane15];
    if (quad < 2) {
      int nb = blockIdx.x * 8;
#pragma unroll
      for (int i = 0; i < 4; ++i)
        msg_out[(size_t)(nb + quad * 4 + i) * HD + wv * 16 + lane15] = f2bf(z[i] + vbm);
    }
  }
}

// ---------------------------------------------------------------- edge scores (CSR order, 2 nodes/wave)
__global__ void __launch_bounds__(256) k_edge(const uint2* __restrict__ rdeg,
                                              const uint* __restrict__ csr,
                                              const uint* __restrict__ csr_eid,
                                              const ushort* __restrict__ Asrc,
                                              const ushort* __restrict__ Adst,
                                              const ushort* __restrict__ Te2bf,
                                              const float* __restrict__ Wes2,
                                              const float* __restrict__ bes2,
                                              float* __restrict__ edge_scores) {
  int t = threadIdx.x;
  int lane = t & 63;
  int n = blockIdx.x * 8 + (t >> 5);   // grid exactly NN/8
  int lq = lane & 7;                   // dim group
  int lg32 = (lane >> 3) & 3;          // edge slot within node (4 slots of 8 lanes)
  uint2 rd = rdeg[n];
  int start = (int)rd.x;
  int deg = (int)rd.y;
  int end = start + deg;
  uint4 bv = *(const uint4*)&Adst[(size_t)n * HD + lq * 8];
  const float* wp = &Wes2[lq * 8];
  float4 w0 = *(const float4*)wp;
  float4 w1 = *(const float4*)(wp + 4);
  float b2 = bes2[0];
  if (deg <= 32) {
    // fully-unrolled fast path (compile-time trip count -> batched loads)
#pragma unroll
    for (int u = 0; u < 8; ++u) {
      int el = u * 4 + lg32;
      bool valid = el < deg;
      int e = start + el;
      float p = 0.f;
      if (valid) {
        uint pk = csr[e];
        int si = (int)(pk & 0xFFFFu);
        int ty = (int)((pk >> 16) & 0x3Fu);
        uint4 av = *(const uint4*)&Asrc[(size_t)si * HD + lq * 8];
        uint4 tv = *(const uint4*)&Te2bf[ty * HD + lq * 8];
        p += fmaxf(bflo(av.x) + bflo(bv.x) + bflo(tv.x), 0.f) * w0.x;
        p += fmaxf(bfhi(av.x) + bfhi(bv.x) + bfhi(tv.x), 0.f) * w0.y;
        p += fmaxf(bflo(av.y) + bflo(bv.y) + bflo(tv.y), 0.f) * w0.z;
        p += fmaxf(bfhi(av.y) + bfhi(bv.y) + bfhi(tv.y), 0.f) * w0.w;
        p += fmaxf(bflo(av.z) + bflo(bv.z) + bflo(tv.z), 0.f) * w1.x;
        p += fmaxf(bfhi(av.z) + bfhi(bv.z) + bfhi(tv.z), 0.f) * w1.y;
        p += fmaxf(bflo(av.w) + bflo(bv.w) + bflo(tv.w), 0.f) * w1.z;
        p += fmaxf(bfhi(av.w) + bfhi(bv.w) + bfhi(tv.w), 0.f) * w1.w;
      }
      p += __shfl_xor(p, 1, 64);
      p += __shfl_xor(p, 2, 64);
      p += __shfl_xor(p, 4, 64);
      if (valid && lq == 0) edge_scores[csr_eid[e]] = 1.f / (1.f + __expf(-(p + b2)));
    }
  } else {
    for (int it = start; it < end; it += 4) {
      int e = it + lg32;
      bool valid = e < end;
      float p = 0.f;
      if (valid) {
        uint pk = csr[e];
        int si = (int)(pk & 0xFFFFu);
        int ty = (int)((pk >> 16) & 0x3Fu);
        uint4 av = *(const uint4*)&Asrc[(size_t)si * HD + lq * 8];
        uint4 tv = *(const uint4*)&Te2bf[ty * HD + lq * 8];
        p += fmaxf(bflo(av.x) + bflo(bv.x) + bflo(tv.x), 0.f) * w0.x;
        p += fmaxf(bfhi(av.x) + bfhi(bv.x) + bfhi(tv.x), 0.f) * w0.y;
        p += fmaxf(bflo(av.y) + bflo(bv.y) + bflo(tv.y), 0.f) * w0.z;
        p += fmaxf(bfhi(av.y) + bfhi(bv.y) + bfhi(tv.y), 0.f) * w0.w;
        p += fmaxf(bflo(av.z) + bflo(bv.z) + bflo(tv.z), 0.f) * w1.x;
        p += fmaxf(bfhi(av.z) + bfhi(bv.z) + bfhi(tv.z), 0.f) * w1.y;
        p += fmaxf(bflo(av.w) + bflo(bv.w) + bflo(tv.w), 0.f) * w1.z;
        p += fmaxf(bfhi(av.w) + bfhi(bv.w) + bfhi(tv.w), 0.f) * w1.w;
      }
      p += __shfl_xor(p, 1, 64);
      p += __shfl_xor(p, 2, 64);
      p += __shfl_xor(p, 4, 64);
      if (valid && lq == 0) edge_scores[csr_eid[e]] = 1.f / (1.f + __expf(-(p + b2)));
    }
  }
}

// ---------------------------------------------------------------- launch
extern "C" void kernel_launch(void* const* d_in, const int* in_sizes, int n_in,
                              void* d_out, int out_size, void* d_ws, size_t ws_size,
                              hipStream_t stream) {
  const float* node_features = (const float*)d_in[0];
  const float* edge_desc = (const float*)d_in[1];
  const float* query = (const float*)d_in[2];
  const float* Wn = (const float*)d_in[3];
  const float* bn = (const float*)d_in[4];
  const float* ts = (const float*)d_in[5];
  const float* Wq = (const float*)d_in[6];
  const float* bq = (const float*)d_in[7];
  const float* Ws_ = (const float*)d_in[8];
  const float* bs = (const float*)d_in[9];
  const float* attn_a = (const float*)d_in[10];
  const float* Wmp = (const float*)d_in[11];
  const float* bmp = (const float*)d_in[12];
  const float* Wns1 = (const float*)d_in[13];
  const float* bns1 = (const float*)d_in[14];
  const float* Wns2 = (const float*)d_in[15];
  const float* bns2 = (const float*)d_in[16];
  const float* Wes1 = (const float*)d_in[17];
  const float* bes1 = (const float*)d_in[18];
  const float* Wes2 = (const float*)d_in[19];
  const float* bes2 = (const float*)d_in[20];
  const int* edge_index = (const int*)d_in[21];
  const int* etype = (const int*)d_in[22];
  const int* src = edge_index;
  const int* dst = edge_index + NE;

  float* out_ns = (float*)d_out;
  float* out_es = out_ns + NN;
  float* out_h = out_es + NE;
  float* out_te = out_h + (size_t)NN * HD;

  char* w = (char*)d_ws;
  auto alloc = [&](size_t bytes) {
    char* p = w;
    w += (bytes + 1023) & ~(size_t)1023;
    return p;
  };
  ushort* msg0 = (ushort*)alloc((size_t)NN * HD * 2);      // msg ping
  ushort* msg1 = (ushort*)alloc((size_t)NN * HD * 2);      // msg pong
  ushort* Asrc = (ushort*)alloc((size_t)NN * HD * 2);      // } adjacent: ebuf alias spans both
  ushort* Adst = (ushort*)alloc((size_t)NN * HD * 2);      // }
  float* pA = (float*)alloc(NN * 4);
  float* pdA = (float*)alloc(NN * 4);
  float* pB = (float*)alloc(NN * 4);
  float* pdB = (float*)alloc(NN * 4);
  float* s_buf = (float*)alloc((size_t)NPAD * 4);
  float* qb = (float*)alloc(HD * 4);
  float* ta3 = (float*)alloc(NLAY * NTT * 4);
  ushort* Te2bf = (ushort*)alloc(NTT * HD * 2);
  ushort* WmpPk = (ushort*)alloc(NLAY * 4096 * 2);
  ushort* WnsPk = (ushort*)alloc(4096 * 2);
  ushort* WesaPk = (ushort*)alloc(4096 * 2);
  ushort* WesbPk = (ushort*)alloc(4096 * 2);
  int* bucket_cursor = (int*)alloc(NBUCK * 4);
  uint2* rdeg = (uint2*)alloc((size_t)NN * 8);
  uint* csr = (uint*)alloc((size_t)NPAD * 4);
  uint* csr_eid = (uint*)alloc((size_t)NPAD * 4);
  // ebuf (NPAD x 8B = 9.6 MB) aliases Asrc+Adst (12.8 MB contiguous): CSR build
  // finishes (k_scatter2) before k_agg<0> writes Asrc/Adst. No overlap in stream order.
  uint2* ebuf = (uint2*)Asrc;

  hipMemsetAsync(bucket_cursor, 0, NBUCK * 4, stream);
  // bin (196) + proj w/ fused layer-0 msg (782) + te x4 + pack x5, co-scheduled
  kE<<<NBINBLK + NPROJ + 4 + 5, 256, 0, stream>>>(src, dst, etype, bucket_cursor, ebuf,
                                                  node_features, Wn, bn, ts, Wmp, bmp, attn_a,
                                                  msg0, pA, pdA,
                                                  edge_desc, query, Wq, bq, Ws_, bs,
                                                  Wns1, bns1, Wes1, bes1,
                                                  out_te, qb, ta3, Te2bf, WmpPk,
                                                  WnsPk, WesaPk, WesbPk);
  // order within bucket by node; emit rdeg + csr/csr_eid
  k_scatter2<<<NBUCK, 1024, 0, stream>>>(bucket_cursor, ebuf, csr, csr_eid, rdeg);

  const int AGG_GRID = NN / 8;   // 6250 blocks, 8 nodes each
  // layer 0: gather msg0, emit msg1 = ht1 @ Wmp1 and p's for layer 1
  k_agg<1><<<AGG_GRID, 256, 0, stream>>>(rdeg, csr, pA, pdA, ta3 + 0 * NTT, msg0, s_buf,
                                         WmpPk + 1 * 4096, bmp + 1 * HD,
                                         attn_a + 1 * (2 * HD + TDD),
                                         msg1, pB, pdB,
                                         nullptr, nullptr, nullptr, nullptr, nullptr,
                                         nullptr, nullptr, nullptr, nullptr, nullptr);
  // layer 1: gather msg1, emit msg0 = ht2 @ Wmp2 and p's for layer 2
  k_agg<1><<<AGG_GRID, 256, 0, stream>>>(rdeg, csr, pB, pdB, ta3 + 1 * NTT, msg1, s_buf,
                                         WmpPk + 2 * 4096, bmp + 2 * HD,
                                         attn_a + 2 * (2 * HD + TDD),
                                         msg0, pA, pdA,
                                         nullptr, nullptr, nullptr, nullptr, nullptr,
                                         nullptr, nullptr, nullptr, nullptr, nullptr);
  // layer 2: gather msg0, fused heads (node_scores, h_out, Asrc, Adst)
  k_agg<0><<<AGG_GRID, 256, 0, stream>>>(rdeg, csr, pA, pdA, ta3 + 2 * NTT, msg0, s_buf,
                                         nullptr, nullptr, nullptr,
                                         nullptr, nullptr, nullptr,
                                         qb, Wns2, bns2, WnsPk, WesaPk, WesbPk,
                                         out_ns, out_h, Asrc, Adst);

  k_edge<<<NN / 8, 256, 0, stream>>>(rdeg, csr, csr_eid, Asrc, Adst, Te2bf,
                                     Wes2, bes2, out_es);
}

// Round 9
// 278.541 us; speedup vs baseline: 1.4249x; 1.0083x over previous
//
#include <hip/hip_runtime.h>
#include <math.h>

#define NN 50000
#define NE 800000
#define NFD 256
#define HD 64
#define QDD 128
#define TDD 32
#define NTT 64
#define NLAY 3
#define LCLAMP 6.1030340f   // atanh(1 - 1e-5)
#define NBUCK 196           // ceil(50000/256) coarse buckets (dst >> 8)
#define SBUCK 6144          // padded slots per bucket (expected 4096, sigma ~64)
#define NPAD (NBUCK * SBUCK)
#define EPB 4096            // edges per bin block
#define NBINBLK 196         // ceil(800000/4096)
#define NPROJ 782           // ceil(50000/64)
#define PST 72              // proj LDS tile stride

typedef unsigned int uint;
typedef unsigned short ushort;
typedef __attribute__((ext_vector_type(8))) short bf16x8;
typedef __attribute__((ext_vector_type(4))) float f32x4;

__device__ __forceinline__ ushort f2bf(float f) {
  uint u = __float_as_uint(f);
  uint r = (u + 0x7FFFu + ((u >> 16) & 1u)) >> 16;
  return (ushort)r;
}
__device__ __forceinline__ short f2bfs(float f) { return (short)f2bf(f); }
__device__ __forceinline__ float bf2f(short s) { return __uint_as_float(((uint)(ushort)s) << 16); }
__device__ __forceinline__ float bflo(uint w) { return __uint_as_float(w << 16); }
__device__ __forceinline__ float bfhi(uint w) { return __uint_as_float(w & 0xFFFF0000u); }

// A-frag from 8 consecutive f32
__device__ __forceinline__ bf16x8 frag_f32(const float* p) {
  float4 a = *(const float4*)p;
  float4 b = *(const float4*)(p + 4);
  bf16x8 r;
  r[0] = f2bfs(a.x); r[1] = f2bfs(a.y); r[2] = f2bfs(a.z); r[3] = f2bfs(a.w);
  r[4] = f2bfs(b.x); r[5] = f2bfs(b.y); r[6] = f2bfs(b.z); r[7] = f2bfs(b.w);
  return r;
}
// B-frag from row-major W[K][64]: k=k0+quad*8+j, n=j0+lane15
__device__ __forceinline__ bf16x8 bfrag_w(const float* W, int k0, int j0, int lane15, int quad) {
  bf16x8 r;
#pragma unroll
  for (int j = 0; j < 8; ++j) r[j] = f2bfs(W[(k0 + quad * 8 + j) * HD + j0 + lane15]);
  return r;
}

// ---------------------------------------------------------------- k0: pre-pack Wn + Wmp0 B-frags; zero cursors
// Replaces the hipMemsetAsync dispatch. 20 blocks x 256.
__global__ void __launch_bounds__(256) k0(const float* __restrict__ Wn,
                                          const float* __restrict__ Wmp,
                                          ushort* __restrict__ WnPk,
                                          ushort* __restrict__ WmpPk,
                                          int* __restrict__ bucket_cursor) {
  int i0 = blockIdx.x * 256 + threadIdx.x;
  const int NWN = 4 * 8 * 64 * 8;   // 16384: [wv][fb][lane][j]
  for (int i = i0; i < NWN; i += 20 * 256) {
    int j = i & 7, lane = (i >> 3) & 63, fb = (i >> 9) & 7, wv = i >> 12;
    int q = lane >> 4, l15 = lane & 15;
    WnPk[i] = f2bf(Wn[(fb * 32 + q * 8 + j) * HD + wv * 16 + l15]);
  }
  // layer-0 WmpPk slot (layers 1,2 packed by d_pack inside kE)
  for (int i = i0; i < 4096; i += 20 * 256) {
    int j = i & 7, lane = (i >> 3) & 63, f = (i >> 9) & 1, jt = (i >> 10) & 3;
    int q = lane >> 4, l15 = lane & 15;
    WmpPk[i] = f2bf(Wmp[(f * 32 + q * 8 + j) * HD + jt * 16 + l15]);
  }
  if (i0 < NBUCK) bucket_cursor[i0] = 0;
}

// ---------------------------------------------------------------- te blocks (4): q/qe redundant, 16 types each
__device__ void d_te(int tb,
                     const float* __restrict__ edge_desc, const float* __restrict__ query,
                     const float* __restrict__ Wq, const float* __restrict__ bq,
                     const float* __restrict__ Ws, const float* __restrict__ bs,
                     const float* __restrict__ attn_a,
                     const float* __restrict__ Wns1, const float* __restrict__ bns1,
                     const float* __restrict__ Wes1, const float* __restrict__ bes1,
                     float* __restrict__ out_type_emb,
                     float* __restrict__ qb, float* __restrict__ ta3,
                     ushort* __restrict__ Te2bf) {
  __shared__ float te_s[16 * TDD];
  __shared__ float q_s[HD];
  __shared__ float qe_s[HD];
  int t = threadIdx.x;
  if (t < HD) {
    float acc = bq[t];
    for (int k = 0; k < QDD; ++k) acc += query[k] * Wq[k * HD + t];
    q_s[t] = acc;
  }
  for (int idx = t; idx < 16 * TDD; idx += 256) {
    int tyl = idx / TDD, d = idx % TDD;
    int ty = tb * 16 + tyl;
    float acc = bs[d];
    for (int k = 0; k < 64; ++k) acc += edge_desc[ty * 64 + k] * Ws[k * TDD + d];
    float v = tanhf(acc);
    te_s[idx] = v;
    out_type_emb[ty * TDD + d] = v;
  }
  __syncthreads();
  if (t < HD) {
    float a2 = bes1[t];
    for (int k = 0; k < HD; ++k) a2 += q_s[k] * Wes1[(2 * HD + TDD + k) * HD + t];
    qe_s[t] = a2;
    if (tb == 0) {
      float a1 = bns1[t];
      for (int k = 0; k < HD; ++k) a1 += q_s[k] * Wns1[(HD + k) * HD + t];
      qb[t] = a1;
    }
  }
  if (t < NLAY * 16) {
    int l = t >> 4, tyl = t & 15;
    float acc = 0.f;
    for (int d = 0; d < TDD; ++d) acc += te_s[tyl * TDD + d] * attn_a[l * (2 * HD + TDD) + 2 * HD + d];
    ta3[l * NTT + tb * 16 + tyl] = acc;
  }
  __syncthreads();
  for (int idx = t; idx < 16 * HD; idx += 256) {
    int tyl = idx >> 6, j = idx & 63;
    float acc = qe_s[j];
#pragma unroll
    for (int d = 0; d < TDD; ++d) acc += te_s[tyl * TDD + d] * Wes1[(2 * HD + d) * HD + j];
    Te2bf[(tb * 16 + tyl) * HD + j] = f2bf(acc);
  }
}

// ---------------------------------------------------------------- pack blocks (5): one 4096-elem array each
__device__ void d_pack(int pid,
                       const float* __restrict__ Wmp, const float* __restrict__ Wns1,
                       const float* __restrict__ Wes1,
                       ushort* __restrict__ WmpPk, ushort* __restrict__ WnsPk,
                       ushort* __restrict__ WesaPk, ushort* __restrict__ WesbPk) {
  int t = threadIdx.x;
  for (int i = t; i < 4096; i += 256) {
    int j = i & 7, lane = (i >> 3) & 63, f = (i >> 9) & 1, jt = (i >> 10) & 3;
    int q = lane >> 4, l15 = lane & 15;
    int row = f * 32 + q * 8 + j, col = jt * 16 + l15;
    if (pid < 2) {
      int l = pid + 1;   // layers 1,2 (layer 0 packed by k0)
      WmpPk[l * 4096 + i] = f2bf(Wmp[l * HD * HD + row * HD + col]);
    } else if (pid == 2) {
      WnsPk[i] = f2bf(Wns1[row * HD + col]);
    } else if (pid == 3) {
      WesaPk[i] = f2bf(Wes1[row * HD + col]);
    } else {
      WesbPk[i] = f2bf(Wes1[(64 + row) * HD + col]);
    }
  }
}

// ---------------------------------------------------------------- bin (device)
// pk: src(16) | type(6)<<16 | (dst&255)<<22
__device__ void d_bin(int bbid,
                      const int* __restrict__ src,
                      const int* __restrict__ dst,
                      const int* __restrict__ etype,
                      int* __restrict__ bucket_cursor,
                      uint2* __restrict__ ebuf) {
  __shared__ int cntl[NBUCK];
  __shared__ int gbase[NBUCK];
  int t = threadIdx.x;
  for (int i = t; i < NBUCK; i += 256) cntl[i] = 0;
  __syncthreads();
  int e0 = bbid * EPB;
  int dd[16];
  uint pk[16];
  int rk[16];
#pragma unroll
  for (int c = 0; c < 4; ++c) {
    int eb = e0 + c * 1024 + t * 4;
    if (eb < NE) {
      int4 s4 = *(const int4*)&src[eb];
      int4 d4 = *(const int4*)&dst[eb];
      int4 y4 = *(const int4*)&etype[eb];
      int ds[4] = {d4.x, d4.y, d4.z, d4.w};
      int ss[4] = {s4.x, s4.y, s4.z, s4.w};
      int ys[4] = {y4.x, y4.y, y4.z, y4.w};
#pragma unroll
      for (int j = 0; j < 4; ++j) {
        int idx = c * 4 + j;
        int d = ds[j];
        dd[idx] = d;
        pk[idx] = (uint)ss[j] | ((uint)ys[j] << 16) | ((uint)(d & 255) << 22);
        rk[idx] = atomicAdd(&cntl[d >> 8], 1);
      }
    } else {
#pragma unroll
      for (int j = 0; j < 4; ++j) dd[c * 4 + j] = -1;
    }
  }
  __syncthreads();
  if (t < NBUCK && cntl[t] > 0)
    gbase[t] = t * SBUCK + atomicAdd(&bucket_cursor[t], cntl[t]);
  __syncthreads();
#pragma unroll
  for (int i = 0; i < 16; ++i) {
    if (dd[i] >= 0) {
      uint eid = (uint)(e0 + ((i >> 2) << 10) + t * 4 + (i & 3));
      ebuf[gbase[dd[i] >> 8] + rk[i]] = make_uint2(pk[i], eid);
    }
  }
}

// ---------------------------------------------------------------- proj (device) + fused layer-0 msg
// B-frags now vector-loaded from WnPk / WmpPk[0] (packed by k0) — no per-wave f32->bf16 prep.
__device__ void d_proj(int pbid,
                       const float* __restrict__ X,
                       const ushort* __restrict__ WnPk,
                       const float* __restrict__ bn,
                       const float* __restrict__ ts_p,
                       const ushort* __restrict__ WmpPk0,
                       const float* __restrict__ bmp0,
                       const float* __restrict__ attn0,
                       ushort* __restrict__ msgbf,
                       float* __restrict__ p_src,
                       float* __restrict__ p_dst) {
  __shared__ ushort buf[2][64 * PST];            // 2 x 9216 B
  float* st = (float*)&buf[0][0];                // epilogue alias: 64 x 72 f32
  int t = threadIdx.x;
  int lane = t & 63, wv = t >> 6;
  int lane15 = lane & 15, quad = lane >> 4;
  int n0 = pbid * 64;
  int j0 = wv * 16;
  bf16x8 B[8];
#pragma unroll
  for (int fb = 0; fb < 8; ++fb)
    B[fb] = *(const bf16x8*)&WnPk[((wv * 8 + fb) * 64 + lane) * 8];

  int srow = t >> 2;
  int scg = (t & 3) * 16;
  int grow = n0 + srow; if (grow >= NN) grow = NN - 1;
  const float* xrow = X + (size_t)grow * NFD + scg;

  f32x4 acc[4];
#pragma unroll
  for (int mt = 0; mt < 4; ++mt) acc[mt] = (f32x4){0.f, 0.f, 0.f, 0.f};

  float4 r0 = *(const float4*)(xrow + 0);
  float4 r1 = *(const float4*)(xrow + 4);
  float4 r2 = *(const float4*)(xrow + 8);
  float4 r3 = *(const float4*)(xrow + 12);

  for (int c = 0; c < 4; ++c) {
    ushort* wp = &buf[c & 1][srow * PST + scg];
    uint4 o0, o1;
    o0.x = (uint)f2bf(r0.x) | ((uint)f2bf(r0.y) << 16);
    o0.y = (uint)f2bf(r0.z) | ((uint)f2bf(r0.w) << 16);
    o0.z = (uint)f2bf(r1.x) | ((uint)f2bf(r1.y) << 16);
    o0.w = (uint)f2bf(r1.z) | ((uint)f2bf(r1.w) << 16);
    o1.x = (uint)f2bf(r2.x) | ((uint)f2bf(r2.y) << 16);
    o1.y = (uint)f2bf(r2.z) | ((uint)f2bf(r2.w) << 16);
    o1.z = (uint)f2bf(r3.x) | ((uint)f2bf(r3.y) << 16);
    o1.w = (uint)f2bf(r3.z) | ((uint)f2bf(r3.w) << 16);
    *(uint4*)wp = o0;
    *(uint4*)(wp + 8) = o1;
    if (c < 3) {
      const float* nx = xrow + (c + 1) * 64;
      r0 = *(const float4*)(nx + 0);
      r1 = *(const float4*)(nx + 4);
      r2 = *(const float4*)(nx + 8);
      r3 = *(const float4*)(nx + 12);
    }
    __syncthreads();
    const ushort* bp = &buf[c & 1][0];
#pragma unroll
    for (int mt = 0; mt < 4; ++mt) {
#pragma unroll
      for (int ks = 0; ks < 2; ++ks) {
        bf16x8 A = *(const bf16x8*)&bp[(mt * 16 + lane15) * PST + ks * 32 + quad * 8];
        acc[mt] = __builtin_amdgcn_mfma_f32_16x16x32_bf16(A, B[c * 2 + ks], acc[mt], 0, 0, 0);
      }
    }
  }
  __syncthreads();
  float ts = ts_p[0];
  float vb = bn[j0 + lane15];
#pragma unroll
  for (int mt = 0; mt < 4; ++mt)
#pragma unroll
    for (int i = 0; i < 4; ++i)
      st[(mt * 16 + quad * 4 + i) * PST + j0 + lane15] = (acc[mt][i] + vb) * ts;
  __syncthreads();
  {
    int r = t >> 2, p = t & 3;
    float* rp = &st[r * PST + p * 16];
    float4 v0 = *(const float4*)(rp + 0);
    float4 v1 = *(const float4*)(rp + 4);
    float4 v2 = *(const float4*)(rp + 8);
    float4 v3 = *(const float4*)(rp + 12);
    float ssq = v0.x*v0.x + v0.y*v0.y + v0.z*v0.z + v0.w*v0.w
              + v1.x*v1.x + v1.y*v1.y + v1.z*v1.z + v1.w*v1.w
              + v2.x*v2.x + v2.y*v2.y + v2.z*v2.z + v2.w*v2.w
              + v3.x*v3.x + v3.y*v3.y + v3.z*v3.z + v3.w*v3.w;
    ssq += __shfl_xor(ssq, 1, 64);
    ssq += __shfl_xor(ssq, 2, 64);
    float nu = fmaxf(sqrtf(ssq), 1e-15f);
    float sc = fminf(nu, LCLAMP) / nu;
    *(float4*)(rp + 0) = make_float4(v0.x*sc, v0.y*sc, v0.z*sc, v0.w*sc);
    *(float4*)(rp + 4) = make_float4(v1.x*sc, v1.y*sc, v1.z*sc, v1.w*sc);
    *(float4*)(rp + 8) = make_float4(v2.x*sc, v2.y*sc, v2.z*sc, v2.w*sc);
    *(float4*)(rp + 12) = make_float4(v3.x*sc, v3.y*sc, v3.z*sc, v3.w*sc);
  }
  __syncthreads();
  // fused layer-0 msg
  {
    bf16x8 Bm0[4], Bm1[4];
    float vbm[4];
#pragma unroll
    for (int jt = 0; jt < 4; ++jt) {
      Bm0[jt] = *(const bf16x8*)&WmpPk0[((jt * 2 + 0) * 64 + lane) * 8];
      Bm1[jt] = *(const bf16x8*)&WmpPk0[((jt * 2 + 1) * 64 + lane) * 8];
      vbm[jt] = bmp0[jt * 16 + lane15];
    }
    int mrow = wv * 16 + lane15;
    bf16x8 A0 = frag_f32(&st[mrow * PST + quad * 8]);
    bf16x8 A1 = frag_f32(&st[mrow * PST + 32 + quad * 8]);
#pragma unroll
    for (int jt = 0; jt < 4; ++jt) {
      f32x4 z = {0.f, 0.f, 0.f, 0.f};
      z = __builtin_amdgcn_mfma_f32_16x16x32_bf16(A0, Bm0[jt], z, 0, 0, 0);
      z = __builtin_amdgcn_mfma_f32_16x16x32_bf16(A1, Bm1[jt], z, 0, 0, 0);
#pragma unroll
      for (int i = 0; i < 4; ++i) {
        int r = n0 + wv * 16 + quad * 4 + i;
        if (r < NN) msgbf[(size_t)r * HD + jt * 16 + lane15] = f2bf(z[i] + vbm[jt]);
      }
    }
    float4 a1l = *(const float4*)&attn0[quad * 8];
    float4 a1h = *(const float4*)&attn0[quad * 8 + 4];
    float4 a1l2 = *(const float4*)&attn0[32 + quad * 8];
    float4 a1h2 = *(const float4*)&attn0[32 + quad * 8 + 4];
    float4 a2l = *(const float4*)&attn0[64 + quad * 8];
    float4 a2h = *(const float4*)&attn0[64 + quad * 8 + 4];
    float4 a2l2 = *(const float4*)&attn0[96 + quad * 8];
    float4 a2h2 = *(const float4*)&attn0[96 + quad * 8 + 4];
    float p1 = bf2f(A0[0])*a1l.x + bf2f(A0[1])*a1l.y + bf2f(A0[2])*a1l.z + bf2f(A0[3])*a1l.w
             + bf2f(A0[4])*a1h.x + bf2f(A0[5])*a1h.y + bf2f(A0[6])*a1h.z + bf2f(A0[7])*a1h.w
             + bf2f(A1[0])*a1l2.x + bf2f(A1[1])*a1l2.y + bf2f(A1[2])*a1l2.z + bf2f(A1[3])*a1l2.w
             + bf2f(A1[4])*a1h2.x + bf2f(A1[5])*a1h2.y + bf2f(A1[6])*a1h2.z + bf2f(A1[7])*a1h2.w;
    float p2 = bf2f(A0[0])*a2l.x + bf2f(A0[1])*a2l.y + bf2f(A0[2])*a2l.z + bf2f(A0[3])*a2l.w
             + bf2f(A0[4])*a2h.x + bf2f(A0[5])*a2h.y + bf2f(A0[6])*a2h.z + bf2f(A0[7])*a2h.w
             + bf2f(A1[0])*a2l2.x + bf2f(A1[1])*a2l2.y + bf2f(A1[2])*a2l2.z + bf2f(A1[3])*a2l2.w
             + bf2f(A1[4])*a2h2.x + bf2f(A1[5])*a2h2.y + bf2f(A1[6])*a2h2.z + bf2f(A1[7])*a2h2.w;
    p1 += __shfl_xor(p1, 16, 64); p1 += __shfl_xor(p1, 32, 64);
    p2 += __shfl_xor(p2, 16, 64); p2 += __shfl_xor(p2, 32, 64);
    int prow = n0 + mrow;
    if (quad == 0 && prow < NN) { p_src[prow] = p1; p_dst[prow] = p2; }
  }
}

// kE: blocks [0,196)=bin, [196,978)=proj, [978,982)=te, [982,987)=pack — all independent
__global__ void __launch_bounds__(256) kE(const int* __restrict__ src, const int* __restrict__ dst,
                                          const int* __restrict__ etype, int* __restrict__ bucket_cursor,
                                          uint2* __restrict__ ebuf,
                                          const float* __restrict__ X, const ushort* __restrict__ WnPk,
                                          const float* __restrict__ bn, const float* __restrict__ ts_p,
                                          const float* __restrict__ Wmp, const float* __restrict__ bmp,
                                          const float* __restrict__ attn_a,
                                          ushort* __restrict__ msgbf,
                                          float* __restrict__ p_src, float* __restrict__ p_dst,
                                          const float* __restrict__ edge_desc, const float* __restrict__ query,
                                          const float* __restrict__ Wq, const float* __restrict__ bq,
                                          const float* __restrict__ Ws, const float* __restrict__ bs,
                                          const float* __restrict__ Wns1, const float* __restrict__ bns1,
                                          const float* __restrict__ Wes1, const float* __restrict__ bes1,
                                          float* __restrict__ out_type_emb,
                                          float* __restrict__ qb, float* __restrict__ ta3,
                                          ushort* __restrict__ Te2bf, ushort* __restrict__ WmpPk,
                                          ushort* __restrict__ WnsPk, ushort* __restrict__ WesaPk,
                                          ushort* __restrict__ WesbPk) {
  if (blockIdx.x < NBINBLK)
    d_bin(blockIdx.x, src, dst, etype, bucket_cursor, ebuf);
  else if (blockIdx.x < NBINBLK + NPROJ)
    d_proj(blockIdx.x - NBINBLK, X, WnPk, bn, ts_p, WmpPk, bmp, attn_a, msgbf, p_src, p_dst);
  else if (blockIdx.x < NBINBLK + NPROJ + 4)
    d_te(blockIdx.x - (NBINBLK + NPROJ), edge_desc, query, Wq, bq, Ws, bs, attn_a,
         Wns1, bns1, Wes1, bes1, out_type_emb, qb, ta3, Te2bf);
  else
    d_pack(blockIdx.x - (NBINBLK + NPROJ + 4), Wmp, Wns1, Wes1, WmpPk, WnsPk, WesaPk, WesbPk);
}

// ---------------------------------------------------------------- scatter: order bucket by node, emit rdeg + csr
__global__ void __launch_bounds__(1024) k_scatter2(const int* __restrict__ bucket_cursor,
                                                   const uint2* __restrict__ ebuf,
                                                   uint* __restrict__ csr,
                                                   uint* __restrict__ csr_eid,
                                                   uint2* __restrict__ rdeg) {
  __shared__ int cnt_l[256];
  __shared__ int curs[256];
  __shared__ int wsum[4], woff[4];
  int b = blockIdx.x;
  int t = threadIdx.x;
  int base = b * SBUCK;
  int cb = bucket_cursor[b];
  if (t < 256) cnt_l[t] = 0;
  __syncthreads();
  for (int i = t; i < cb; i += 1024)
    atomicAdd(&cnt_l[(ebuf[base + i].x >> 22) & 255], 1);
  __syncthreads();
  int v = 0, x = 0;
  int lane = t & 63, wid = t >> 6;
  if (t < 256) {
    v = cnt_l[t];
    x = v;
#pragma unroll
    for (int off = 1; off < 64; off <<= 1) {
      int y = __shfl_up(x, off, 64);
      if (lane >= off) x += y;
    }
    if (lane == 63) wsum[wid] = x;
  }
  __syncthreads();
  if (t == 0) {
    int a = 0;
    for (int i = 0; i < 4; ++i) { woff[i] = a; a += wsum[i]; }
  }
  __syncthreads();
  if (t < 256) {
    int loff = woff[wid] + (x - v);
    int n = (b << 8) + t;
    if (n < NN) rdeg[n] = make_uint2((uint)(base + loff), (uint)v);
    curs[t] = base + loff;
  }
  __syncthreads();
  for (int i = t; i < cb; i += 1024) {
    uint2 e = ebuf[base + i];
    int j = (e.x >> 22) & 255;
    int pos = atomicAdd(&curs[j], 1);
    csr[pos] = e.x & 0x3FFFFFu;
    csr_eid[pos] = e.y;
  }
}

// ---------------------------------------------------------------- softmax-aggregate (2 nodes/wave, 32 lanes each)
template <int FUSE>
__global__ void __launch_bounds__(256) k_agg(const uint2* __restrict__ rdeg,
                                             const uint* __restrict__ csr,
                                             const float* __restrict__ p_src,
                                             const float* __restrict__ p_dst,
                                             const float* __restrict__ ta_l,
                                             const ushort* __restrict__ msgbf,
                                             float* __restrict__ s_buf,
                                             const ushort* __restrict__ WmpPk_next,
                                             const float* __restrict__ bmp_next,
                                             const float* __restrict__ attn_next,
                                             ushort* __restrict__ msg_out,
                                             float* __restrict__ p_src_out,
                                             float* __restrict__ p_dst_out,
                                             const float* __restrict__ qb,
                                             const float* __restrict__ Wns2,
                                             const float* __restrict__ bns2,
                                             const ushort* __restrict__ WnsPk,
                                             const ushort* __restrict__ WesaPk,
                                             const ushort* __restrict__ WesbPk,
                                             float* __restrict__ node_scores,
                                             float* __restrict__ h_out,
                                             ushort* __restrict__ Asrc,
                                             ushort* __restrict__ Adst) {
  __shared__ float v_lds[16][68];   // +4 pad: b128 reads 2-way max
  __shared__ uint2 exsi[4][64];     // packed (exp(score), src idx): single ds_read_b64 per gather iter
  __shared__ float sc_part[8][4];   // FUSE=0: node-head partials per wave
  int t = threadIdx.x;
  int lane = t & 63, wv = t >> 6;
  int nloc = t >> 5;                 // 0..7: node slot within block
  int half = (lane >> 5) & 1;        // which node within wave
  int l32 = lane & 31;               // lane within node's 32-group
  int lq = lane & 7;                 // dim group: owns dims lq*8..lq*8+7
  int lg32 = (lane >> 3) & 3;        // gather group within node (4 groups of 8)
  int n = blockIdx.x * 8 + nloc;     // grid exactly NN/8
  uint2 rd = rdeg[n];
  int start = (int)rd.x;
  int deg = (int)rd.y;
  int end = start + deg;
  float pd = p_dst[n];
  float acc[8];
#pragma unroll
  for (int u = 0; u < 8; ++u) acc[u] = 0.f;
  float exsum = 0.f;

  if (deg <= 32) {
    bool valid = l32 < deg;
    float s = -3.4e38f;
    int sidx = 0;
    if (valid) {
      uint pk = csr[start + l32];
      sidx = (int)(pk & 0xFFFFu);
      int ty = (int)(pk >> 16);
      float v = p_src[sidx] + pd + ta_l[ty];
      s = (v > 0.f) ? v : 0.2f * v;
    }
    float m = s;
#pragma unroll
    for (int off = 16; off >= 1; off >>= 1) m = fmaxf(m, __shfl_xor(m, off, 64));
    float ex = valid ? __expf(s - m) : 0.f;
    exsum = ex;
    if (valid) exsi[wv][lane] = make_uint2(__float_as_uint(ex), (uint)sidx);
#pragma unroll
    for (int u = 0; u < 8; ++u) {
      int el = u * 4 + lg32;
      if (el < deg) {
        uint2 es = exsi[wv][half * 32 + el];       // 8 lanes same addr -> broadcast
        float exk = __uint_as_float(es.x);
        int sk = (int)es.y;
        uint4 mv = *(const uint4*)&msgbf[(size_t)sk * HD + lq * 8];
        acc[0] += exk * bflo(mv.x); acc[1] += exk * bfhi(mv.x);
        acc[2] += exk * bflo(mv.y); acc[3] += exk * bfhi(mv.y);
        acc[4] += exk * bflo(mv.z); acc[5] += exk * bfhi(mv.z);
        acc[6] += exk * bflo(mv.w); acc[7] += exk * bfhi(mv.w);
      }
    }
  } else {
    // rare path (deg>32): chunked at 32-lane width via s_buf
    float m = -3.4e38f;
    for (int base = start; base < end; base += 32) {
      int i = base + l32;
      float s = -3.4e38f;
      if (i < end) {
        uint pk = csr[i];
        int sidx = (int)(pk & 0xFFFFu);
        int ty = (int)(pk >> 16);
        float v = p_src[sidx] + pd + ta_l[ty];
        s = (v > 0.f) ? v : 0.2f * v;
        s_buf[i] = s;
      }
      m = fmaxf(m, s);
    }
#pragma unroll
    for (int off = 16; off >= 1; off >>= 1) m = fmaxf(m, __shfl_xor(m, off, 64));
    for (int base = start; base < end; base += 32) {
      int i = base + l32;
      if (i < end) {
        float ex = __expf(s_buf[i] - m);
        s_buf[i] = ex;
        exsum += ex;
      }
    }
    for (int it = start; it < end; it += 4) {
      int el = it + lg32;
      if (el < end) {
        float exk = s_buf[el];
        int sk = (int)(csr[el] & 0xFFFFu);
        uint4 mv = *(const uint4*)&msgbf[(size_t)sk * HD + lq * 8];
        acc[0] += exk * bflo(mv.x); acc[1] += exk * bfhi(mv.x);
        acc[2] += exk * bflo(mv.y); acc[3] += exk * bfhi(mv.y);
        acc[4] += exk * bflo(mv.z); acc[5] += exk * bfhi(mv.z);
        acc[6] += exk * bflo(mv.w); acc[7] += exk * bfhi(mv.w);
      }
    }
  }
  // reduce over the 4 gather groups (within each 32-half)
#pragma unroll
  for (int u = 0; u < 8; ++u) {
    acc[u] += __shfl_xor(acc[u], 8, 64);
    acc[u] += __shfl_xor(acc[u], 16, 64);
  }
#pragma unroll
  for (int off = 16; off >= 1; off >>= 1) exsum += __shfl_xor(exsum, off, 64);
  float inv = 1.f / (exsum + 1e-15f);
  float ss = 0.f;
#pragma unroll
  for (int u = 0; u < 8; ++u) {
    float v = fmaxf(acc[u] * inv, 0.f);
    acc[u] = v;
    ss += v * v;
  }
  ss += __shfl_xor(ss, 1, 64);
  ss += __shfl_xor(ss, 2, 64);
  ss += __shfl_xor(ss, 4, 64);
  float nu = fmaxf(sqrtf(ss), 1e-15f);
  float sc = fminf(nu, LCLAMP) / nu;

  if constexpr (FUSE == 0) {
    // ---- fused k_score: stage final ht rows, then heads + h_out from LDS ----
    if (l32 < 8) {
      *(float4*)&v_lds[nloc][l32 * 8] =
          make_float4(acc[0] * sc, acc[1] * sc, acc[2] * sc, acc[3] * sc);
      *(float4*)&v_lds[nloc][l32 * 8 + 4] =
          make_float4(acc[4] * sc, acc[5] * sc, acc[6] * sc, acc[7] * sc);
    }
    __syncthreads();
    int lane15 = lane & 15, quad = lane >> 4;
    int nb = blockIdx.x * 8;
    // h_out: exact f32 pass (replicates former k_score lane pattern bitwise)
    if (t < 32) {
      int r = t >> 2, p = t & 3;
      const float* rp = &v_lds[r][p * 16];
      float4 v0 = *(const float4*)(rp + 0);
      float4 v1 = *(const float4*)(rp + 4);
      float4 v2 = *(const float4*)(rp + 8);
      float4 v3 = *(const float4*)(rp + 12);
      float ssq = v0.x*v0.x + v0.y*v0.y + v0.z*v0.z + v0.w*v0.w
                + v1.x*v1.x + v1.y*v1.y + v1.z*v1.z + v1.w*v1.w
                + v2.x*v2.x + v2.y*v2.y + v2.z*v2.z + v2.w*v2.w
                + v3.x*v3.x + v3.y*v3.y + v3.z*v3.z + v3.w*v3.w;
      ssq += __shfl_xor(ssq, 1, 64);
      ssq += __shfl_xor(ssq, 2, 64);
      float nu2 = fmaxf(sqrtf(ssq), 1e-15f);
      float hs = tanhf(nu2) / nu2;
      float* op = h_out + (size_t)(nb + r) * HD + p * 16;
      *(float4*)(op + 0)  = make_float4(v0.x*hs, v0.y*hs, v0.z*hs, v0.w*hs);
      *(float4*)(op + 4)  = make_float4(v1.x*hs, v1.y*hs, v1.z*hs, v1.w*hs);
      *(float4*)(op + 8)  = make_float4(v2.x*hs, v2.y*hs, v2.z*hs, v2.w*hs);
      *(float4*)(op + 12) = make_float4(v3.x*hs, v3.y*hs, v3.z*hs, v3.w*hs);
    }
    // 3 GEMMs (node-head y, Asrc, Adst): wave wv computes cols wv*16..+15 for 8 nodes
    bf16x8 A0 = frag_f32(&v_lds[lane15][quad * 8]);      // rows 8..15 junk, outputs discarded
    bf16x8 A1 = frag_f32(&v_lds[lane15][32 + quad * 8]);
    // node head
    {
      bf16x8 B0 = *(const bf16x8*)&WnsPk[(wv * 2 + 0) * 512 + lane * 8];
      bf16x8 B1 = *(const bf16x8*)&WnsPk[(wv * 2 + 1) * 512 + lane * 8];
      f32x4 z = {0.f, 0.f, 0.f, 0.f};
      z = __builtin_amdgcn_mfma_f32_16x16x32_bf16(A0, B0, z, 0, 0, 0);
      z = __builtin_amdgcn_mfma_f32_16x16x32_bf16(A1, B1, z, 0, 0, 0);
      float vqb = qb[wv * 16 + lane15];
      float vw2 = Wns2[wv * 16 + lane15];
      if (quad < 2) {
#pragma unroll
        for (int i = 0; i < 4; ++i) {
          float part = fmaxf(z[i] + vqb, 0.f) * vw2;
          part += __shfl_xor(part, 1, 64);
          part += __shfl_xor(part, 2, 64);
          part += __shfl_xor(part, 4, 64);
          part += __shfl_xor(part, 8, 64);
          if (lane15 == 0) sc_part[quad * 4 + i][wv] = part;
        }
      }
    }
    // Asrc
    {
      bf16x8 B0 = *(const bf16x8*)&WesaPk[(wv * 2 + 0) * 512 + lane * 8];
      bf16x8 B1 = *(const bf16x8*)&WesaPk[(wv * 2 + 1) * 512 + lane * 8];
      f32x4 z = {0.f, 0.f, 0.f, 0.f};
      z = __builtin_amdgcn_mfma_f32_16x16x32_bf16(A0, B0, z, 0, 0, 0);
      z = __builtin_amdgcn_mfma_f32_16x16x32_bf16(A1, B1, z, 0, 0, 0);
      if (quad < 2) {
#pragma unroll
        for (int i = 0; i < 4; ++i)
          Asrc[(size_t)(nb + quad * 4 + i) * HD + wv * 16 + lane15] = f2bf(z[i]);
      }
    }
    // Adst
    {
      bf16x8 B0 = *(const bf16x8*)&WesbPk[(wv * 2 + 0) * 512 + lane * 8];
      bf16x8 B1 = *(const bf16x8*)&WesbPk[(wv * 2 + 1) * 512 + lane * 8];
      f32x4 z = {0.f, 0.f, 0.f, 0.f};
      z = __builtin_amdgcn_mfma_f32_16x16x32_bf16(A0, B0, z, 0, 0, 0);
      z = __builtin_amdgcn_mfma_f32_16x16x32_bf16(A1, B1, z, 0, 0, 0);
      if (quad < 2) {
#pragma unroll
        for (int i = 0; i < 4; ++i)
          Adst[(size_t)(nb + quad * 4 + i) * HD + wv * 16 + lane15] = f2bf(z[i]);
      }
    }
    __syncthreads();
    if (t < 8) {
      float si = sc_part[t][0] + sc_part[t][1] + sc_part[t][2] + sc_part[t][3];
      node_scores[nb + t] = 1.f / (1.f + __expf(-(si + bns2[0])));
    }
  } else {
    // next-layer p from bf16-rounded ht (element index = lq*8+u)
    float hb[8];
#pragma unroll
    for (int u = 0; u < 8; ++u) hb[u] = bf2f((short)f2bf(acc[u] * sc));
    float4 a1a = *(const float4*)&attn_next[lq * 8];
    float4 a1b = *(const float4*)&attn_next[lq * 8 + 4];
    float4 a2a = *(const float4*)&attn_next[64 + lq * 8];
    float4 a2b = *(const float4*)&attn_next[64 + lq * 8 + 4];
    float p1 = hb[0]*a1a.x + hb[1]*a1a.y + hb[2]*a1a.z + hb[3]*a1a.w
             + hb[4]*a1b.x + hb[5]*a1b.y + hb[6]*a1b.z + hb[7]*a1b.w;
    float p2 = hb[0]*a2a.x + hb[1]*a2a.y + hb[2]*a2a.z + hb[3]*a2a.w
             + hb[4]*a2b.x + hb[5]*a2b.y + hb[6]*a2b.z + hb[7]*a2b.w;
    p1 += __shfl_xor(p1, 1, 64); p1 += __shfl_xor(p1, 2, 64); p1 += __shfl_xor(p1, 4, 64);
    p2 += __shfl_xor(p2, 1, 64); p2 += __shfl_xor(p2, 2, 64); p2 += __shfl_xor(p2, 4, 64);
    if (l32 == 0) { p_src_out[n] = p1; p_dst_out[n] = p2; }
    if (l32 < 8) {
      *(float4*)&v_lds[nloc][l32 * 8] =
          make_float4(acc[0] * sc, acc[1] * sc, acc[2] * sc, acc[3] * sc);
      *(float4*)&v_lds[nloc][l32 * 8 + 4] =
          make_float4(acc[4] * sc, acc[5] * sc, acc[6] * sc, acc[7] * sc);
    }
    __syncthreads();
    // msg = ht @ Wmp_next + bmp_next for the block's 8 nodes; wave wv computes cols wv*16..+15
    int lane15 = lane & 15, quad = lane >> 4;
    bf16x8 A0 = frag_f32(&v_lds[lane15][quad * 8]);      // rows 8..15 junk, discarded
    bf16x8 A1 = frag_f32(&v_lds[lane15][32 + quad * 8]);
    bf16x8 B0 = *(const bf16x8*)&WmpPk_next[(wv * 2 + 0) * 512 + lane * 8];
    bf16x8 B1 = *(const bf16x8*)&WmpPk_next[(wv * 2 + 1) * 512 + lane * 8];
    f32x4 z = {0.f, 0.f, 0.f, 0.f};
    z = __builtin_amdgcn_mfma_f32_16x16x32_bf16(A0, B0, z, 0, 0, 0);
    z = __builtin_amdgcn_mfma_f32_16x16x32_bf16(A1, B1, z, 0, 0, 0);
    float vbm = bmp_next[wv * 16 + lane15];
    if (quad < 2) {
      int nb = blockIdx.x * 8;
#pragma unroll
      for (int i = 0; i < 4; ++i)
        msg_out[(size_t)(nb + quad * 4 + i) * HD + wv * 16 + lane15] = f2bf(z[i] + vbm);
    }
  }
}

// ---------------------------------------------------------------- edge scores (CSR order, 2 nodes/wave)
__global__ void __launch_bounds__(256) k_edge(const uint2* __restrict__ rdeg,
                                              const uint* __restrict__ csr,
                                              const uint* __restrict__ csr_eid,
                                              const ushort* __restrict__ Asrc,
                                              const ushort* __restrict__ Adst,
                                              const ushort* __restrict__ Te2bf,
                                              const float* __restrict__ Wes2,
                                              const float* __restrict__ bes2,
                                              float* __restrict__ edge_scores) {
  int t = threadIdx.x;
  int lane = t & 63;
  int n = blockIdx.x * 8 + (t >> 5);   // grid exactly NN/8
  int lq = lane & 7;                   // dim group
  int lg32 = (lane >> 3) & 3;          // edge slot within node (4 slots of 8 lanes)
  uint2 rd = rdeg[n];
  int start = (int)rd.x;
  int deg = (int)rd.y;
  int end = start + deg;
  uint4 bv = *(const uint4*)&Adst[(size_t)n * HD + lq * 8];
  const float* wp = &Wes2[lq * 8];
  float4 w0 = *(const float4*)wp;
  float4 w1 = *(const float4*)(wp + 4);
  float b2 = bes2[0];
  if (deg <= 32) {
#pragma unroll
    for (int u = 0; u < 8; ++u) {
      int el = u * 4 + lg32;
      bool valid = el < deg;
      int e = start + el;
      float p = 0.f;
      if (valid) {
        uint pk = csr[e];
        int si = (int)(pk & 0xFFFFu);
        int ty = (int)((pk >> 16) & 0x3Fu);
        uint4 av = *(const uint4*)&Asrc[(size_t)si * HD + lq * 8];
        uint4 tv = *(const uint4*)&Te2bf[ty * HD + lq * 8];
        p += fmaxf(bflo(av.x) + bflo(bv.x) + bflo(tv.x), 0.f) * w0.x;
        p += fmaxf(bfhi(av.x) + bfhi(bv.x) + bfhi(tv.x), 0.f) * w0.y;
        p += fmaxf(bflo(av.y) + bflo(bv.y) + bflo(tv.y), 0.f) * w0.z;
        p += fmaxf(bfhi(av.y) + bfhi(bv.y) + bfhi(tv.y), 0.f) * w0.w;
        p += fmaxf(bflo(av.z) + bflo(bv.z) + bflo(tv.z), 0.f) * w1.x;
        p += fmaxf(bfhi(av.z) + bfhi(bv.z) + bfhi(tv.z), 0.f) * w1.y;
        p += fmaxf(bflo(av.w) + bflo(bv.w) + bflo(tv.w), 0.f) * w1.z;
        p += fmaxf(bfhi(av.w) + bfhi(bv.w) + bfhi(tv.w), 0.f) * w1.w;
      }
      p += __shfl_xor(p, 1, 64);
      p += __shfl_xor(p, 2, 64);
      p += __shfl_xor(p, 4, 64);
      if (valid && lq == 0) edge_scores[csr_eid[e]] = 1.f / (1.f + __expf(-(p + b2)));
    }
  } else {
    for (int it = start; it < end; it += 4) {
      int e = it + lg32;
      bool valid = e < end;
      float p = 0.f;
      if (valid) {
        uint pk = csr[e];
        int si = (int)(pk & 0xFFFFu);
        int ty = (int)((pk >> 16) & 0x3Fu);
        uint4 av = *(const uint4*)&Asrc[(size_t)si * HD + lq * 8];
        uint4 tv = *(const uint4*)&Te2bf[ty * HD + lq * 8];
        p += fmaxf(bflo(av.x) + bflo(bv.x) + bflo(tv.x), 0.f) * w0.x;
        p += fmaxf(bfhi(av.x) + bfhi(bv.x) + bfhi(tv.x), 0.f) * w0.y;
        p += fmaxf(bflo(av.y) + bflo(bv.y) + bflo(tv.y), 0.f) * w0.z;
        p += fmaxf(bfhi(av.y) + bfhi(bv.y) + bfhi(tv.y), 0.f) * w0.w;
        p += fmaxf(bflo(av.z) + bflo(bv.z) + bflo(tv.z), 0.f) * w1.x;
        p += fmaxf(bfhi(av.z) + bfhi(bv.z) + bfhi(tv.z), 0.f) * w1.y;
        p += fmaxf(bflo(av.w) + bflo(bv.w) + bflo(tv.w), 0.f) * w1.z;
        p += fmaxf(bfhi(av.w) + bfhi(bv.w) + bfhi(tv.w), 0.f) * w1.w;
      }
      p += __shfl_xor(p, 1, 64);
      p += __shfl_xor(p, 2, 64);
      p += __shfl_xor(p, 4, 64);
      if (valid && lq == 0) edge_scores[csr_eid[e]] = 1.f / (1.f + __expf(-(p + b2)));
    }
  }
}

// ---------------------------------------------------------------- launch
extern "C" void kernel_launch(void* const* d_in, const int* in_sizes, int n_in,
                              void* d_out, int out_size, void* d_ws, size_t ws_size,
                              hipStream_t stream) {
  const float* node_features = (const float*)d_in[0];
  const float* edge_desc = (const float*)d_in[1];
  const float* query = (const float*)d_in[2];
  const float* Wn = (const float*)d_in[3];
  const float* bn = (const float*)d_in[4];
  const float* ts = (const float*)d_in[5];
  const float* Wq = (const float*)d_in[6];
  const float* bq = (const float*)d_in[7];
  const float* Ws_ = (const float*)d_in[8];
  const float* bs = (const float*)d_in[9];
  const float* attn_a = (const float*)d_in[10];
  const float* Wmp = (const float*)d_in[11];
  const float* bmp = (const float*)d_in[12];
  const float* Wns1 = (const float*)d_in[13];
  const float* bns1 = (const float*)d_in[14];
  const float* Wns2 = (const float*)d_in[15];
  const float* bns2 = (const float*)d_in[16];
  const float* Wes1 = (const float*)d_in[17];
  const float* bes1 = (const float*)d_in[18];
  const float* Wes2 = (const float*)d_in[19];
  const float* bes2 = (const float*)d_in[20];
  const int* edge_index = (const int*)d_in[21];
  const int* etype = (const int*)d_in[22];
  const int* src = edge_index;
  const int* dst = edge_index + NE;

  float* out_ns = (float*)d_out;
  float* out_es = out_ns + NN;
  float* out_h = out_es + NE;
  float* out_te = out_h + (size_t)NN * HD;

  char* w = (char*)d_ws;
  auto alloc = [&](size_t bytes) {
    char* p = w;
    w += (bytes + 1023) & ~(size_t)1023;
    return p;
  };
  ushort* msg0 = (ushort*)alloc((size_t)NN * HD * 2);      // msg ping
  ushort* msg1 = (ushort*)alloc((size_t)NN * HD * 2);      // msg pong
  ushort* Asrc = (ushort*)alloc((size_t)NN * HD * 2);      // } adjacent: ebuf alias spans both
  ushort* Adst = (ushort*)alloc((size_t)NN * HD * 2);      // }
  float* pA = (float*)alloc(NN * 4);
  float* pdA = (float*)alloc(NN * 4);
  float* pB = (float*)alloc(NN * 4);
  float* pdB = (float*)alloc(NN * 4);
  float* s_buf = (float*)alloc((size_t)NPAD * 4);
  float* qb = (float*)alloc(HD * 4);
  float* ta3 = (float*)alloc(NLAY * NTT * 4);
  ushort* Te2bf = (ushort*)alloc(NTT * HD * 2);
  ushort* WmpPk = (ushort*)alloc(NLAY * 4096 * 2);
  ushort* WnsPk = (ushort*)alloc(4096 * 2);
  ushort* WesaPk = (ushort*)alloc(4096 * 2);
  ushort* WesbPk = (ushort*)alloc(4096 * 2);
  ushort* WnPk = (ushort*)alloc(16384 * 2);
  int* bucket_cursor = (int*)alloc(NBUCK * 4);
  uint2* rdeg = (uint2*)alloc((size_t)NN * 8);
  uint* csr = (uint*)alloc((size_t)NPAD * 4);
  uint* csr_eid = (uint*)alloc((size_t)NPAD * 4);
  // ebuf (NPAD x 8B = 9.6 MB) aliases Asrc+Adst (12.8 MB contiguous): CSR build
  // finishes (k_scatter2) before k_agg<0> writes Asrc/Adst. No overlap in stream order.
  uint2* ebuf = (uint2*)Asrc;

  // k0: zero cursors + pre-pack Wn/Wmp0 B-frags (replaces hipMemsetAsync dispatch)
  k0<<<20, 256, 0, stream>>>(Wn, Wmp, WnPk, WmpPk, bucket_cursor);
  // bin (196) + proj w/ fused layer-0 msg (782) + te x4 + pack x5, co-scheduled
  kE<<<NBINBLK + NPROJ + 4 + 5, 256, 0, stream>>>(src, dst, etype, bucket_cursor, ebuf,
                                                  node_features, WnPk, bn, ts, Wmp, bmp, attn_a,
                                                  msg0, pA, pdA,
                                                  edge_desc, query, Wq, bq, Ws_, bs,
                                                  Wns1, bns1, Wes1, bes1,
                                                  out_te, qb, ta3, Te2bf, WmpPk,
                                                  WnsPk, WesaPk, WesbPk);
  // order within bucket by node; emit rdeg + csr/csr_eid
  k_scatter2<<<NBUCK, 1024, 0, stream>>>(bucket_cursor, ebuf, csr, csr_eid, rdeg);

  const int AGG_GRID = NN / 8;   // 6250 blocks, 8 nodes each
  // layer 0: gather msg0, emit msg1 = ht1 @ Wmp1 and p's for layer 1
  k_agg<1><<<AGG_GRID, 256, 0, stream>>>(rdeg, csr, pA, pdA, ta3 + 0 * NTT, msg0, s_buf,
                                         WmpPk + 1 * 4096, bmp + 1 * HD,
                                         attn_a + 1 * (2 * HD + TDD),
                                         msg1, pB, pdB,
                                         nullptr, nullptr, nullptr, nullptr, nullptr,
                                         nullptr, nullptr, nullptr, nullptr, nullptr);
  // layer 1: gather msg1, emit msg0 = ht2 @ Wmp2 and p's for layer 2
  k_agg<1><<<AGG_GRID, 256, 0, stream>>>(rdeg, csr, pB, pdB, ta3 + 1 * NTT, msg1, s_buf,
                                         WmpPk + 2 * 4096, bmp + 2 * HD,
                                         attn_a + 2 * (2 * HD + TDD),
                                         msg0, pA, pdA,
                                         nullptr, nullptr, nullptr, nullptr, nullptr,
                                         nullptr, nullptr, nullptr, nullptr, nullptr);
  // layer 2: gather msg0, fused heads (node_scores, h_out, Asrc, Adst)
  k_agg<0><<<AGG_GRID, 256, 0, stream>>>(rdeg, csr, pA, pdA, ta3 + 2 * NTT, msg0, s_buf,
                                         nullptr, nullptr, nullptr,
                                         nullptr, nullptr, nullptr,
                                         qb, Wns2, bns2, WnsPk, WesaPk, WesbPk,
                                         out_ns, out_h, Asrc, Adst);

  k_edge<<<NN / 8, 256, 0, stream>>>(rdeg, csr, csr_eid, Asrc, Adst, Te2bf,
                                     Wes2, bes2, out_es);
}